// Round 3
// baseline (455.696 us; speedup 1.0000x reference)
//
#include <hip/hip_runtime.h>
#include <hip/hip_bf16.h>

typedef __hip_bfloat16 bf16;
typedef unsigned short ushort_t;
typedef __attribute__((ext_vector_type(8))) __bf16 bfv8;
typedef __attribute__((ext_vector_type(16))) float f32x16;

#define B_   4
#define CIN  64
#define CI   16
#define H_   127
#define W_   127
#define HW   (H_*W_)
#define KS   7
#define ST   4
#define OH_  31
#define L_   961
#define D_   784
#define TOPM 100

// ---- workspace layout (float offsets) ----
#define N1   1032256          // B*HW*CI elements (one conv-out array)
#define WG_O 4
#define WT_O (WG_O + 9216)
#define WP_O (WT_O + 1024)
#define BG_O (WP_O + 1024)
#define BT_O (BG_O + 16)
#define BP_O (BT_O + 16)
#define SM_O (BP_O + 16)
#define SB_O (SM_O + 16)
#define RW_O (SB_O + 16)
#define RB_O (RW_O + 1024)
#define B1_O 12448
// planes at B1_O: b1h,b1l,b2h,b2l each N1 ushorts (2*N1 floats); b3 bf16 N1 ushorts
#define S3_O (B1_O + 3*N1)
#define WB_O (S3_O + B_*D_)   // conv MFMA B: wBh + wBl = 36864 floats
#define REG_O (WB_O + 36864)
#define XHSZ 4129024          // B*HW*64 ushorts per x plane (2 planes = XHSZ floats)
#define SROW 964              // padded Sc row stride
#define SCSLOT 926464
#define AGSZ 753424
#define TKROW 112
#define SLST 72               // LDS row stride in ushorts (conflict-free, measured r8)

#define FULL_BYTES ((size_t)(REG_O + XHSZ + 4*AGSZ) * 4)   // ~41.1 MB
#define MID_BYTES  ((size_t)(REG_O + XHSZ) * 4)            // ~29.1 MB

__device__ __forceinline__ float bf2f(bf16 v) { return __bfloat162float(v); }
__device__ __forceinline__ float bflo(unsigned u) { return __uint_as_float(u << 16); }
__device__ __forceinline__ float bfhi(unsigned u) { return __uint_as_float(u & 0xFFFF0000u); }

template <typename T> struct Ld;
template <> struct Ld<float> {
  static __device__ __forceinline__ float f(const void* p, int i) { return ((const float*)p)[i]; }
};
template <> struct Ld<bf16> {
  static __device__ __forceinline__ float f(const void* p, int i) { return bf2f(((const bf16*)p)[i]); }
};

__device__ __forceinline__ unsigned fmap(float f) {
  unsigned u = __float_as_uint(f);
  return (u & 0x80000000u) ? ~u : (u | 0x80000000u);
}
__device__ __forceinline__ float unfmap(unsigned kk) {
  unsigned u = (kk & 0x80000000u) ? (kk & 0x7fffffffu) : ~kk;
  return __uint_as_float(u);
}

// RNE fp32 -> bf16 bits, and hi/lo split
__device__ __forceinline__ ushort_t f2bf(float x) {
  unsigned u = __float_as_uint(x);
  return (ushort_t)((u + 0x7FFFu + ((u >> 16) & 1u)) >> 16);
}
__device__ __forceinline__ void splitbf(float x, ushort_t& h, ushort_t& l) {
  h = f2bf(x);
  float hf = __uint_as_float(((unsigned)h) << 16);
  l = f2bf(x - hf);
}

// -------- dtype detector: flag=1 -> fp32 buffers, flag=0 -> bf16 -----------------
__global__ void k_detect(const unsigned short* __restrict__ xh, int* __restrict__ flag) {
  int tid = threadIdx.x;  // 64
  int c = 0;
#pragma unroll
  for (int j = 0; j < 2; ++j) {
    unsigned u = xh[tid * 2 + j];
    unsigned e = (u >> 7) & 0xFF;
    if (e >= 134) c++;
  }
#pragma unroll
  for (int o = 32; o; o >>= 1) c += __shfl_down(c, o);
  if (tid == 0) *flag = (c >= 8) ? 1 : 0;
}

// -------- weight prep ------------------------------------------------------------
#define LDW(ptr, i) (f ? ((const float*)(ptr))[i] : bf2f(((const bf16*)(ptr))[i]))
__global__ __launch_bounds__(256) void k_prep(
    const int* __restrict__ flag,
    const void* g_w, const void* t_w, const void* p_w,
    const void* g_b, const void* t_b, const void* p_b,
    const void* m_w, const void* m_b, const void* r_w, const void* r_b,
    float* __restrict__ ws)
{
  int tid = threadIdx.x;
  int f = *flag;
  for (int i = tid; i < 9216; i += 256) {
    int o = i & 15, t = i >> 4, c = t & 63, tap = t >> 6;
    ws[WG_O + i] = LDW(g_w, (o * 64 + c) * 9 + tap);
  }
  for (int i = tid; i < 1024; i += 256) {
    int o = i & 15, c = i >> 4;
    ws[WT_O + i] = LDW(t_w, o * 64 + c);
    ws[WP_O + i] = LDW(p_w, o * 64 + c);
  }
  if (tid < 16) {
    ws[BG_O + tid] = LDW(g_b, tid);
    ws[BT_O + tid] = LDW(t_b, tid);
    ws[BP_O + tid] = LDW(p_b, tid);
    float s = 0.f;
    for (int c = 0; c < 64; ++c) s += LDW(m_w, tid * 64 + c);
    ws[SM_O + tid] = s;
    ws[SB_O + tid] = LDW(m_b, tid);
  }
  for (int i = tid; i < 1024; i += 256) ws[RW_O + i] = LDW(r_w, i);
  if (tid < 64) ws[RB_O + tid] = LDW(r_b, tid);
  // conv MFMA B, split hi/lo: wB[tap][col64][c64]
  ushort_t* wBh = (ushort_t*)(ws + WB_O);
  ushort_t* wBl = wBh + 9 * 64 * 64;
  for (int i = tid; i < 9 * 64 * 64; i += 256) {
    int c = i & 63, t = i >> 6, col = t & 63, tap = t >> 6;
    float v = 0.f;
    if (col < 16) v = LDW(g_w, (col * 64 + c) * 9 + tap);
    else if (col < 32) { if (tap == 4) v = LDW(t_w, (col - 16) * 64 + c); }
    else if (col < 48) { if (tap == 4) v = LDW(p_w, (col - 32) * 64 + c); }
    ushort_t h, l; splitbf(v, h, l);
    wBh[i] = h; wBl[i] = l;
  }
}

// -------- x [B,64,H,W] -> HWC bf16 hi/lo planes ----------------------------------
__global__ __launch_bounds__(256) void k_hwc(
    const int* __restrict__ flag, const void* __restrict__ x,
    ushort_t* __restrict__ xhh, ushort_t* __restrict__ xhl)
{
  __shared__ float tile[64][65];
  int pix0 = blockIdx.x * 64;
  int tid = threadIdx.x;
  int g = tid >> 6, p = tid & 63;
  int pix = pix0 + p;
  bool ok = pix < B_ * HW;
  int bb = ok ? pix / HW : 0;
  int r  = ok ? pix - bb * HW : 0;
  if (*flag) {
    const float* xf = (const float*)x;
    for (int c = g * 16; c < g * 16 + 16; ++c)
      tile[p][c] = ok ? xf[((size_t)bb * CIN + c) * HW + r] : 0.f;
  } else {
    const bf16* xb = (const bf16*)x;
    for (int c = g * 16; c < g * 16 + 16; ++c)
      tile[p][c] = ok ? bf2f(xb[((size_t)bb * CIN + c) * HW + r]) : 0.f;
  }
  __syncthreads();
  int c2 = tid & 63, pg = tid >> 6;
  for (int k = 0; k < 16; ++k) {
    int p2 = pg * 16 + k;
    int pix2 = pix0 + p2;
    if (pix2 < B_ * HW) {
      ushort_t h, l; splitbf(tile[p2][c2], h, l);
      xhh[(size_t)pix2 * 64 + c2] = h;
      xhl[(size_t)pix2 * 64 + c2] = l;
    }
  }
}

// -------- unified split-bf16 MFMA conv, 128-pixel tile, cooperative staging ------
// TA fix: lane (grp=l>>3, ch=l&7); instr j loads 8 consecutive rows x 8 chunks
// = ~1KB contiguous (16-18 cache lines vs 64 with per-lane-row loads).
__global__ __launch_bounds__(256) void k_conv3(
    const float* __restrict__ ws,
    const ushort_t* __restrict__ xhh, const ushort_t* __restrict__ xhl,
    ushort_t* __restrict__ b1h, ushort_t* __restrict__ b1l,
    ushort_t* __restrict__ b2h, ushort_t* __restrict__ b2l,
    ushort_t* __restrict__ b3)
{
  __shared__ ushort_t sAh[128 * SLST], sAl[128 * SLST];
  __shared__ ushort_t sBh[64 * SLST],  sBl[64 * SLST];
  int bz = blockIdx.z;
  int px0 = blockIdx.x * 128;
  int tid = threadIdx.x, lane = tid & 63, wv = tid >> 6;
  int grp = lane >> 3, ch = lane & 7;

  const ushort_t* xplane = ((wv == 0) ? xhh : xhl) + (size_t)bz * HW * 64;
  const ushort_t* wBh_ = (const ushort_t*)(ws + WB_O);
  const ushort_t* bsrc = (wv == 2) ? wBh_ : (wBh_ + 9 * 64 * 64);
  ushort_t* dplane = (wv == 0) ? sAh : (wv == 1) ? sAl : (wv == 2) ? sBh : sBl;

  // per-lane row coordinates for cooperative staging (A-waves: 16 rows each lane
  // participates in; B-waves: 8). phh=-1000 marks out-of-tile rows.
  int phh[16], pww[16];
  if (wv < 2) {
#pragma unroll
    for (int j = 0; j < 16; ++j) {
      int p = px0 + 8 * j + grp;
      if (p < HW) { phh[j] = p / W_; pww[j] = p - phh[j] * W_; }
      else        { phh[j] = -1000;  pww[j] = 0; }
    }
  }

  int fr = lane & 31, kh = (lane >> 5) << 3;
  int mt = (wv >> 1) << 1;
  int aoff0 = (mt * 32 + fr) * SLST + kh;
  int aoff1 = ((mt + 1) * 32 + fr) * SLST + kh;
  int boff  = (((wv & 1) << 5) + fr) * SLST + kh;

  f32x16 acc0 = {0.f,0.f,0.f,0.f,0.f,0.f,0.f,0.f,0.f,0.f,0.f,0.f,0.f,0.f,0.f,0.f};
  f32x16 acc1 = {0.f,0.f,0.f,0.f,0.f,0.f,0.f,0.f,0.f,0.f,0.f,0.f,0.f,0.f,0.f,0.f};
  const int4 z4 = make_int4(0, 0, 0, 0);
  int4 pv[16];
#pragma unroll
  for (int j = 0; j < 16; ++j) pv[j] = z4;

  // prefetch tap 0 (dh=-1, dw=-1)
  {
    if (wv < 2) {
#pragma unroll
      for (int j = 0; j < 16; ++j) {
        int hh = phh[j] - 1, ww = pww[j] - 1;
        bool ok = ((unsigned)hh < (unsigned)H_) && ((unsigned)ww < (unsigned)W_);
        int off = ok ? (hh * W_ + ww) : 0;
        int4 t = *(const int4*)(xplane + (size_t)off * 64 + ch * 8);
        pv[j] = ok ? t : z4;
      }
    } else {
#pragma unroll
      for (int j = 0; j < 8; ++j)
        pv[j] = *(const int4*)(bsrc + (size_t)(8 * j + grp) * 64 + ch * 8);
    }
  }

  for (int r = 0; r < 9; ++r) {
    __syncthreads();
    {
      ushort_t* d0 = dplane + grp * SLST + ch * 8;
      if (wv < 2) {
#pragma unroll
        for (int j = 0; j < 16; ++j) *(int4*)(d0 + j * 8 * SLST) = pv[j];
      } else {
#pragma unroll
        for (int j = 0; j < 8; ++j) *(int4*)(d0 + j * 8 * SLST) = pv[j];
      }
    }
    __syncthreads();
    if (r < 8) {
      int rn = r + 1;
      int dh = rn / 3 - 1, dw = rn % 3 - 1;
      if (wv < 2) {
#pragma unroll
        for (int j = 0; j < 16; ++j) {
          int hh = phh[j] + dh, ww = pww[j] + dw;
          bool ok = ((unsigned)hh < (unsigned)H_) && ((unsigned)ww < (unsigned)W_);
          int off = ok ? (hh * W_ + ww) : 0;
          int4 t = *(const int4*)(xplane + (size_t)off * 64 + ch * 8);
          pv[j] = ok ? t : z4;
        }
      } else {
#pragma unroll
        for (int j = 0; j < 8; ++j)
          pv[j] = *(const int4*)(bsrc + ((size_t)rn * 64 + 8 * j + grp) * 64 + ch * 8);
      }
    }
#pragma unroll
    for (int t = 0; t < 4; ++t) {
      bfv8 ah0 = *(const bfv8*)(sAh + aoff0 + t * 16);
      bfv8 al0 = *(const bfv8*)(sAl + aoff0 + t * 16);
      bfv8 ah1 = *(const bfv8*)(sAh + aoff1 + t * 16);
      bfv8 al1 = *(const bfv8*)(sAl + aoff1 + t * 16);
      bfv8 bh  = *(const bfv8*)(sBh + boff + t * 16);
      bfv8 bl  = *(const bfv8*)(sBl + boff + t * 16);
      acc0 = __builtin_amdgcn_mfma_f32_32x32x16_bf16(al0, bh, acc0, 0, 0, 0);
      acc0 = __builtin_amdgcn_mfma_f32_32x32x16_bf16(ah0, bl, acc0, 0, 0, 0);
      acc0 = __builtin_amdgcn_mfma_f32_32x32x16_bf16(ah0, bh, acc0, 0, 0, 0);
      acc1 = __builtin_amdgcn_mfma_f32_32x32x16_bf16(al1, bh, acc1, 0, 0, 0);
      acc1 = __builtin_amdgcn_mfma_f32_32x32x16_bf16(ah1, bl, acc1, 0, 0, 0);
      acc1 = __builtin_amdgcn_mfma_f32_32x32x16_bf16(ah1, bh, acc1, 0, 0, 0);
    }
  }

  int nw = ((wv & 1) << 5) + fr;
#pragma unroll
  for (int s = 0; s < 2; ++s) {
    int mbase = (mt + s) * 32;
#pragma unroll
    for (int r = 0; r < 16; ++r) {
      int m = mbase + (r & 3) + ((r >> 2) << 3) + ((lane >> 5) << 2);
      int p2 = px0 + m;
      if (p2 >= HW) continue;
      size_t ob = ((size_t)bz * HW + p2) * 16;
      float val = s ? acc1[r] : acc0[r];
      if (nw < 16) {
        ushort_t h2, l2; splitbf(val + ws[BG_O + nw], h2, l2);
        b1h[ob + nw] = h2; b1l[ob + nw] = l2;
      } else if (nw < 32) {
        int o = nw - 16; ushort_t h2, l2; splitbf(val + ws[BT_O + o], h2, l2);
        b2h[ob + o] = h2; b2l[ob + o] = l2;
      } else if (nw < 48) {
        int o = nw - 32; b3[ob + o] = f2bf(val + ws[BP_O + o]);
      }
    }
  }
}

// -------- fallback conv (LOW tier), dtype-templated VALU -------------------------
template <typename T>
__device__ __forceinline__ void convF_body(
    const void* x, const void* g_w, const void* g_b,
    const void* t_w, const void* t_b, const void* p_w, const void* p_b,
    ushort_t* b1h, ushort_t* b1l, ushort_t* b2h, ushort_t* b2l, ushort_t* b3,
    float* sgw, float* stw, float* spw)
{
  int tid = threadIdx.y * 32 + threadIdx.x;
  for (int i = tid; i < CI * CIN * 9; i += 256) sgw[i] = Ld<T>::f(g_w, i);
  for (int i = tid; i < CI * CIN; i += 256) { stw[i] = Ld<T>::f(t_w, i); spw[i] = Ld<T>::f(p_w, i); }
  __syncthreads();

  int w = blockIdx.x * 32 + threadIdx.x;
  int h = blockIdx.y * 8 + threadIdx.y;
  int b = blockIdx.z;
  if (w >= W_ || h >= H_) return;

  float a1[CI], a2[CI], a3[CI];
#pragma unroll
  for (int o = 0; o < CI; ++o) { a1[o] = 0.f; a2[o] = 0.f; a3[o] = 0.f; }

  const size_t xb = (size_t)b * CIN * HW;
  for (int c = 0; c < CIN; ++c) {
    float xv[9];
#pragma unroll
    for (int dh = 0; dh < 3; ++dh) {
      int hh = h + dh - 1;
      bool rok = ((unsigned)hh < (unsigned)H_);
#pragma unroll
      for (int dw = 0; dw < 3; ++dw) {
        int ww = w + dw - 1;
        bool ok = rok && ((unsigned)ww < (unsigned)W_);
        xv[dh * 3 + dw] = ok ? Ld<T>::f(x, (int)(xb + (size_t)c * HW + hh * W_ + ww)) : 0.f;
      }
    }
    float xc = xv[4];
#pragma unroll
    for (int o = 0; o < CI; ++o) {
      const float* gg = &sgw[(o * CIN + c) * 9];
      float s = gg[0]*xv[0] + gg[1]*xv[1] + gg[2]*xv[2]
              + gg[3]*xv[3] + gg[4]*xv[4] + gg[5]*xv[5]
              + gg[6]*xv[6] + gg[7]*xv[7] + gg[8]*xv[8];
      a1[o] += s;
      a2[o] += stw[o * CIN + c] * xc;
      a3[o] += spw[o * CIN + c] * xc;
    }
  }
  size_t base = ((size_t)b * HW + h * W_ + w) * CI;
#pragma unroll
  for (int o = 0; o < CI; ++o) {
    float v1 = a1[o] + Ld<T>::f(g_b, o);
    float v2 = a2[o] + Ld<T>::f(t_b, o);
    ushort_t hh2, ll2;
    splitbf(v1, hh2, ll2); b1h[base + o] = hh2; b1l[base + o] = ll2;
    splitbf(v2, hh2, ll2); b2h[base + o] = hh2; b2l[base + o] = ll2;
    b3[base + o] = f2bf(a3[o] + Ld<T>::f(p_b, o));
  }
}

__global__ __launch_bounds__(256) void k_convF(
    const int* __restrict__ flag, const void* x,
    const void* g_w, const void* g_b, const void* t_w, const void* t_b,
    const void* p_w, const void* p_b,
    ushort_t* __restrict__ b1h, ushort_t* __restrict__ b1l,
    ushort_t* __restrict__ b2h, ushort_t* __restrict__ b2l,
    ushort_t* __restrict__ b3)
{
  __shared__ float sgw[CI * CIN * 9];
  __shared__ float stw[CI * CIN];
  __shared__ float spw[CI * CIN];
  if (*flag) convF_body<float>(x, g_w, g_b, t_w, t_b, p_w, p_b, b1h, b1l, b2h, b2l, b3, sgw, stw, spw);
  else       convF_body<bf16 >(x, g_w, g_b, t_w, t_b, p_w, p_b, b1h, b1l, b2h, b2l, b3, sgw, stw, spw);
}

// -------- S3[b, pos*16+c] = sum over patches of b3 (bf16 src, fp32 acc) ----------
__global__ __launch_bounds__(256) void k_colsum(const ushort_t* __restrict__ b3, float* __restrict__ S3)
{
  __shared__ float red[16][17];
  int b = blockIdx.x, pos = blockIdx.y;
  int ki = pos / 7, kj = pos % 7;
  int c = threadIdx.x & 15, chunk = threadIdx.x >> 4;
  const ushort_t* B3 = b3 + (size_t)b * HW * CI;
  float s = 0.f;
  for (int l = chunk; l < L_; l += 16) {
    int lh = l / OH_, lw = l % OH_;
    s += bflo((unsigned)B3[((lh * ST + ki) * W_ + lw * ST + kj) * CI + c]);
  }
  red[chunk][c] = s;
  __syncthreads();
  if (threadIdx.x < 16) {
    float t = 0.f;
#pragma unroll
    for (int k = 0; k < 16; ++k) t += red[k][threadIdx.x];
    S3[(b * 49 + pos) * 16 + threadIdx.x] = t;
  }
}

// -------- score GEMM via split-bf16 MFMA, 128x64 tile, cooperative staging -------
// Same MFMA/epilogue as the 322-us baseline; staging transposed so each load
// instruction covers 8 consecutive patch rows x 8 chunks (~1KB contiguous).
__global__ __launch_bounds__(256) void k_score(
    const ushort_t* __restrict__ b1h, const ushort_t* __restrict__ b1l,
    const ushort_t* __restrict__ b2h, const ushort_t* __restrict__ b2l,
    float* __restrict__ scb, int b0, unsigned scstride_z)
{
  __shared__ ushort_t sAh[128 * SLST], sAl[128 * SLST];
  __shared__ ushort_t sBh[64 * SLST],  sBl[64 * SLST];
  int batch = b0 + blockIdx.z;
  size_t poff_g = (size_t)batch * HW * CI;
  float* Sc = scb + (size_t)blockIdx.z * scstride_z;

  int tid = threadIdx.x;
  int m0 = blockIdx.y * 128, n0 = blockIdx.x * 64;
  int lane = tid & 63;
  int wv = tid >> 6;
  int grp = lane >> 3, ch = lane & 7;

  const ushort_t* splane = (wv == 0) ? (b1h + poff_g) : (wv == 1) ? (b1l + poff_g)
                          : (wv == 2) ? (b2h + poff_g) : (b2l + poff_g);
  ushort_t* dplane = (wv == 0) ? sAh : (wv == 1) ? sAl : (wv == 2) ? sBh : sBl;

  // per-lane patch-row base (pixels) for each cooperative instruction
  int base_mn = (wv < 2) ? m0 : n0;
  int sb[16];
#pragma unroll
  for (int j = 0; j < 8; ++j) {
    int srow = base_mn + 8 * j + grp;
    if (srow > L_ - 1) srow = L_ - 1;
    int slh = srow / OH_, slw = srow - slh * OH_;
    sb[j] = (slh * ST) * W_ + slw * ST;
  }
  if (wv < 2) {
#pragma unroll
    for (int j = 8; j < 16; ++j) {
      int srow = base_mn + 8 * j + grp;
      if (srow > L_ - 1) srow = L_ - 1;
      int slh = srow / OH_, slw = srow - slh * OH_;
      sb[j] = (slh * ST) * W_ + slw * ST;
    }
  }

  int fr = lane & 31;
  int kh = (lane >> 5) << 3;
  int mt = (wv >> 1) << 1;                         // first m-subtile: 0 or 2
  int aoff0 = (mt * 32 + fr) * SLST + kh;
  int aoff1 = ((mt + 1) * 32 + fr) * SLST + kh;
  int boff  = (((wv & 1) << 5) + fr) * SLST + kh;

  f32x16 acc0 = {0.f,0.f,0.f,0.f,0.f,0.f,0.f,0.f,0.f,0.f,0.f,0.f,0.f,0.f,0.f,0.f};
  f32x16 acc1 = {0.f,0.f,0.f,0.f,0.f,0.f,0.f,0.f,0.f,0.f,0.f,0.f,0.f,0.f,0.f,0.f};

  int4 pv[16];
  // prefetch iter 0: nki=0, nkj0=0
  {
    int ko = ch * 8;
    if (wv < 2) {
#pragma unroll
      for (int j = 0; j < 16; ++j)
        pv[j] = *(const int4*)(splane + (size_t)sb[j] * 16 + ko);
    } else {
#pragma unroll
      for (int j = 0; j < 8; ++j)
        pv[j] = *(const int4*)(splane + (size_t)sb[j] * 16 + ko);
    }
  }

  for (int r = 0; r < 14; ++r) {
    int half = r & 1;
    __syncthreads();
    {
      ushort_t* d0 = dplane + grp * SLST + ch * 8;
      if (wv < 2) {
#pragma unroll
        for (int j = 0; j < 16; ++j) *(int4*)(d0 + j * 8 * SLST) = pv[j];
      } else {
#pragma unroll
        for (int j = 0; j < 8; ++j) *(int4*)(d0 + j * 8 * SLST) = pv[j];
      }
    }
    __syncthreads();
    if (r < 13) {
      int rn = r + 1;
      int nki = rn >> 1, nkj0 = (rn & 1) * 4;
      int ko = (nki * W_ + nkj0) * 16 + ch * 8;
      if (wv < 2) {
#pragma unroll
        for (int j = 0; j < 16; ++j)
          pv[j] = *(const int4*)(splane + (size_t)sb[j] * 16 + ko);
      } else {
#pragma unroll
        for (int j = 0; j < 8; ++j)
          pv[j] = *(const int4*)(splane + (size_t)sb[j] * 16 + ko);
      }
    }
    if (!half) {
#pragma unroll
      for (int t = 0; t < 4; ++t) {
        bfv8 ah0 = *(const bfv8*)(sAh + aoff0 + t * 16);
        bfv8 al0 = *(const bfv8*)(sAl + aoff0 + t * 16);
        bfv8 ah1 = *(const bfv8*)(sAh + aoff1 + t * 16);
        bfv8 al1 = *(const bfv8*)(sAl + aoff1 + t * 16);
        bfv8 bh  = *(const bfv8*)(sBh + boff + t * 16);
        bfv8 bl  = *(const bfv8*)(sBl + boff + t * 16);
        acc0 = __builtin_amdgcn_mfma_f32_32x32x16_bf16(al0, bh, acc0, 0, 0, 0);
        acc0 = __builtin_amdgcn_mfma_f32_32x32x16_bf16(ah0, bl, acc0, 0, 0, 0);
        acc0 = __builtin_amdgcn_mfma_f32_32x32x16_bf16(ah0, bh, acc0, 0, 0, 0);
        acc1 = __builtin_amdgcn_mfma_f32_32x32x16_bf16(al1, bh, acc1, 0, 0, 0);
        acc1 = __builtin_amdgcn_mfma_f32_32x32x16_bf16(ah1, bl, acc1, 0, 0, 0);
        acc1 = __builtin_amdgcn_mfma_f32_32x32x16_bf16(ah1, bh, acc1, 0, 0, 0);
      }
    } else {
#pragma unroll
      for (int t = 0; t < 3; ++t) {
        bfv8 ah0 = *(const bfv8*)(sAh + aoff0 + t * 16);
        bfv8 al0 = *(const bfv8*)(sAl + aoff0 + t * 16);
        bfv8 ah1 = *(const bfv8*)(sAh + aoff1 + t * 16);
        bfv8 al1 = *(const bfv8*)(sAl + aoff1 + t * 16);
        bfv8 bh  = *(const bfv8*)(sBh + boff + t * 16);
        bfv8 bl  = *(const bfv8*)(sBl + boff + t * 16);
        acc0 = __builtin_amdgcn_mfma_f32_32x32x16_bf16(al0, bh, acc0, 0, 0, 0);
        acc0 = __builtin_amdgcn_mfma_f32_32x32x16_bf16(ah0, bl, acc0, 0, 0, 0);
        acc0 = __builtin_amdgcn_mfma_f32_32x32x16_bf16(ah0, bh, acc0, 0, 0, 0);
        acc1 = __builtin_amdgcn_mfma_f32_32x32x16_bf16(al1, bh, acc1, 0, 0, 0);
        acc1 = __builtin_amdgcn_mfma_f32_32x32x16_bf16(ah1, bl, acc1, 0, 0, 0);
        acc1 = __builtin_amdgcn_mfma_f32_32x32x16_bf16(ah1, bh, acc1, 0, 0, 0);
      }
    }
  }

  int nw = n0 + ((wv & 1) << 5) + fr;
  if (nw < L_) {
    int mw0 = m0 + mt * 32;
#pragma unroll
    for (int r = 0; r < 16; ++r) {
      int m = mw0 + (r & 3) + ((r >> 2) << 3) + ((lane >> 5) << 2);
      if (m < L_) Sc[(size_t)m * SROW + nw] = acc0[r];
    }
    int mw1 = m0 + (mt + 1) * 32;
#pragma unroll
    for (int r = 0; r < 16; ++r) {
      int m = mw1 + (r & 3) + ((r >> 2) << 3) + ((lane >> 5) << 2);
      if (m < L_) Sc[(size_t)m * SROW + nw] = acc1[r];
    }
  }
}

// -------- top-100 + softmax weights: 4 rows per block (1 wave each) --------------
__global__ __launch_bounds__(256) void k_topk(
    const float* __restrict__ scb, float* __restrict__ tkw, int* __restrict__ tkp,
    unsigned scstride_z)
{
  __shared__ float swv[4][TOPM];
  __shared__ int spx[4][TOPM];
  int tid = threadIdx.x;
  int wvi = tid >> 6, lane = tid & 63;
  int l = blockIdx.x * 4 + wvi;
  if (l > L_ - 1) l = L_ - 1;        // clamp: duplicate rows write identical data
  int bz = blockIdx.y;
  const float4* row4 = (const float4*)(scb + (size_t)bz * scstride_z + (size_t)l * SROW);
  int trow = (bz * L_ + l) * TKROW;

  unsigned k[16];
#pragma unroll
  for (int q = 0; q < 4; ++q) {
    float4 v = row4[q * 64 + lane];
    int ib = (q * 64 + lane) * 4;
    k[q * 4 + 0] = (ib + 0 < L_) ? fmap(v.x) : 0u;
    k[q * 4 + 1] = (ib + 1 < L_) ? fmap(v.y) : 0u;
    k[q * 4 + 2] = (ib + 2 < L_) ? fmap(v.z) : 0u;
    k[q * 4 + 3] = (ib + 3 < L_) ? fmap(v.w) : 0u;
  }

  unsigned mk = 0;
#pragma unroll
  for (int r = 0; r < 16; ++r) mk = max(mk, k[r]);
#pragma unroll
  for (int o = 32; o; o >>= 1) mk = max(mk, (unsigned)__shfl_down((int)mk, o));
  mk = (unsigned)__shfl((int)mk, 0);
  float vmax = unfmap(mk);

  unsigned alive = 0xFFFFu;
  unsigned prefix = 0; int base = 0;
  for (int bit = 30; bit >= 0; bit -= 2) {
    int c1 = 0, c2 = 0, c3 = 0;
#pragma unroll
    for (int r = 0; r < 16; ++r) {
      if ((alive >> r) & 1) {
        unsigned f = (k[r] >> bit) & 3u;
        c3 += (f == 3); c2 += (f >= 2); c1 += (f >= 1);
      }
    }
    int p = c3 | (c2 << 10) | (c1 << 20);
#pragma unroll
    for (int o = 32; o; o >>= 1) p += __shfl_down(p, o);
    p = __shfl(p, 0);
    int n3 = p & 1023, n2 = (p >> 10) & 1023, n1 = (p >> 20) & 1023;
    unsigned ch;
    if (base + n3 >= TOPM) ch = 3;
    else if (base + n2 >= TOPM) { ch = 2; base += n3; }
    else if (base + n1 >= TOPM) { ch = 1; base += n2; }
    else { ch = 0; base += n1; }
    prefix |= ch << bit;
#pragma unroll
    for (int r = 0; r < 16; ++r) {
      if ((alive >> r) & 1) {
        unsigned f = (k[r] >> bit) & 3u;
        if (f != ch) alive &= ~(1u << r);
      }
    }
  }
  int nA = base;
  int needT = TOPM - nA;

  int cA = 0, cT = 0;
#pragma unroll
  for (int r = 0; r < 16; ++r) { cA += (k[r] > prefix); cT += (k[r] == prefix); }
  int pk = cA | (cT << 16);
  int incl = pk;
#pragma unroll
  for (int o = 1; o < 64; o <<= 1) { int t = __shfl_up(incl, o); if (lane >= o) incl += t; }
  int excl = incl - pk;
  int tA = excl & 0xFFFF, tT = excl >> 16;

  float M = fmaxf(10.f * vmax, 0.f);
  float e0 = expf(-M);
  float z = 0.f;
#pragma unroll
  for (int r = 0; r < 16; ++r) {
    unsigned kk = k[r];
    int slot = -1;
    if (kk > prefix) slot = tA++;
    else if (kk == prefix) { if (tT < needT) slot = nA + tT; tT++; }
    if (slot >= 0) {
      float v = unfmap(kk);
      float wv = expf(10.f * v - M);
      swv[wvi][slot] = wv; z += wv;
      int gi = 256 * (r >> 2) + 4 * lane + (r & 3);
      int lh = gi / OH_, lw = gi - lh * OH_;
      spx[wvi][slot] = ((lh * ST) * W_ + lw * ST) * CI;
    }
  }
#pragma unroll
  for (int o = 32; o; o >>= 1) z += __shfl_down(z, o);
  z = __shfl(z, 0);
  float Z = z + (float)(L_ - TOPM) * e0;
  float invZ = 1.f / Z;
  float w0 = e0 / Z;
  __syncthreads();
#pragma unroll
  for (int s0 = 0; s0 < 2; ++s0) {
    int s = lane + 64 * s0;
    if (s < TOPM) {
      tkw[trow + s] = swv[wvi][s] * invZ - w0;
      tkp[trow + s] = spx[wvi][s];
    }
  }
  if (lane == 0) tkw[trow + TOPM] = w0;
}

// -------- PV gather (bf16 b3, uint4 full-line): 98 lanes x 8 channels ------------
__global__ __launch_bounds__(128) void k_pv(
    const float* __restrict__ tkw, const int* __restrict__ tkp,
    const ushort_t* __restrict__ b3, const float* __restrict__ s3,
    float* __restrict__ agb, int b0, unsigned agstride_z)
{
  int l = blockIdx.x, bz = blockIdx.y;
  int batch = b0 + bz;
  int trow = (bz * L_ + l) * TKROW;
  const ushort_t* B3 = b3 + (size_t)batch * HW * CI;
  const float* S3 = s3 + (size_t)batch * D_;
  float* agg = agb + (size_t)bz * agstride_z;
  int tid = threadIdx.x;
  if (tid >= 98) return;

  float w0 = tkw[trow + TOPM];
  int pos = tid >> 1;
  int c0 = (tid & 1) << 3;                 // 0 or 8
  int ki = pos / 7, kj = pos - (pos / 7) * 7;
  int poff = (ki * W_ + kj) * CI + c0;

  float a0 = 0.f, a1 = 0.f, a2 = 0.f, a3 = 0.f;
  float a4 = 0.f, a5 = 0.f, a6 = 0.f, a7 = 0.f;
  for (int j0 = 0; j0 < TOPM; j0 += 4) {
    float w_0 = tkw[trow + j0 + 0];
    float w_1 = tkw[trow + j0 + 1];
    float w_2 = tkw[trow + j0 + 2];
    float w_3 = tkw[trow + j0 + 3];
    int p_0 = tkp[trow + j0 + 0];
    int p_1 = tkp[trow + j0 + 1];
    int p_2 = tkp[trow + j0 + 2];
    int p_3 = tkp[trow + j0 + 3];
    const uint4 q0 = *(const uint4*)(B3 + p_0 + poff);
    const uint4 q1 = *(const uint4*)(B3 + p_1 + poff);
    const uint4 q2 = *(const uint4*)(B3 + p_2 + poff);
    const uint4 q3 = *(const uint4*)(B3 + p_3 + poff);
    a0 += w_0 * bflo(q0.x); a1 += w_0 * bfhi(q0.x); a2 += w_0 * bflo(q0.y); a3 += w_0 * bfhi(q0.y);
    a4 += w_0 * bflo(q0.z); a5 += w_0 * bfhi(q0.z); a6 += w_0 * bflo(q0.w); a7 += w_0 * bfhi(q0.w);
    a0 += w_1 * bflo(q1.x); a1 += w_1 * bfhi(q1.x); a2 += w_1 * bflo(q1.y); a3 += w_1 * bfhi(q1.y);
    a4 += w_1 * bflo(q1.z); a5 += w_1 * bfhi(q1.z); a6 += w_1 * bflo(q1.w); a7 += w_1 * bfhi(q1.w);
    a0 += w_2 * bflo(q2.x); a1 += w_2 * bfhi(q2.x); a2 += w_2 * bflo(q2.y); a3 += w_2 * bfhi(q2.y);
    a4 += w_2 * bflo(q2.z); a5 += w_2 * bfhi(q2.z); a6 += w_2 * bflo(q2.w); a7 += w_2 * bfhi(q2.w);
    a0 += w_3 * bflo(q3.x); a1 += w_3 * bfhi(q3.x); a2 += w_3 * bflo(q3.y); a3 += w_3 * bfhi(q3.y);
    a4 += w_3 * bflo(q3.z); a5 += w_3 * bfhi(q3.z); a6 += w_3 * bflo(q3.w); a7 += w_3 * bfhi(q3.w);
  }
  const float4 s40 = *(const float4*)(S3 + tid * 8);
  const float4 s41 = *(const float4*)(S3 + tid * 8 + 4);
  a0 += w0 * s40.x; a1 += w0 * s40.y; a2 += w0 * s40.z; a3 += w0 * s40.w;
  a4 += w0 * s41.x; a5 += w0 * s41.y; a6 += w0 * s41.z; a7 += w0 * s41.w;
  float* dst = agg + (size_t)l * D_ + tid * 8;
  *(float4*)(dst)     = make_float4(a0, a1, a2, a3);
  *(float4*)(dst + 4) = make_float4(a4, a5, a6, a7);
}

// -------- fold + mask divide + restore (16->64), batched -------------------------
__global__ __launch_bounds__(256) void k_fold(
    const int* __restrict__ flag, const float* __restrict__ ws,
    const float* __restrict__ agb, void* __restrict__ out,
    int b0, unsigned agstride_z)
{
  __shared__ float srw[CIN * CI];
  int tid = threadIdx.x;
  for (int i = tid; i < CIN * CI; i += 256) srw[i] = ws[RW_O + i];
  __syncthreads();

  int bz = blockIdx.y;
  int batch = b0 + bz;
  const float* agg = agb + (size_t)bz * agstride_z;

  int gid = blockIdx.x * 256 + tid;
  if (gid >= HW) return;
  int h = gid / W_;
  int w = gid % W_;

  int lh0 = (h >= KS - 1) ? ((h - (KS - 1) + (ST - 1)) >> 2) : 0;
  int lh1 = min(OH_ - 1, h >> 2);
  int lw0 = (w >= KS - 1) ? ((w - (KS - 1) + (ST - 1)) >> 2) : 0;
  int lw1 = min(OH_ - 1, w >> 2);

  float t[CI];
#pragma unroll
  for (int c = 0; c < CI; ++c) t[c] = 0.f;
  for (int lh = lh0; lh <= lh1; ++lh) {
    int ki = h - ST * lh;
    for (int lw = lw0; lw <= lw1; ++lw) {
      int kj = w - ST * lw;
      const float* pb = agg + (size_t)(lh * OH_ + lw) * D_ + (ki * KS + kj) * CI;
      float4 q0 = *(const float4*)(pb);
      float4 q1 = *(const float4*)(pb + 4);
      float4 q2 = *(const float4*)(pb + 8);
      float4 q3 = *(const float4*)(pb + 12);
      t[0] += q0.x; t[1] += q0.y; t[2] += q0.z; t[3] += q0.w;
      t[4] += q1.x; t[5] += q1.y; t[6] += q1.z; t[7] += q1.w;
      t[8] += q2.x; t[9] += q2.y; t[10] += q2.z; t[11] += q2.w;
      t[12] += q3.x; t[13] += q3.y; t[14] += q3.z; t[15] += q3.w;
    }
  }
  float cnt = (float)((lh1 - lh0 + 1) * (lw1 - lw0 + 1));
  float r[CI];
#pragma unroll
  for (int c = 0; c < CI; ++c) r[c] = t[c] / (cnt * ws[SM_O + c] + ws[SB_O + c] + 1e-8f);

  size_t ob = (size_t)batch * CIN * HW + (size_t)h * W_ + w;
  if (*flag) {
    float* of = (float*)out;
#pragma unroll
    for (int o = 0; o < CIN; ++o) {
      float s = ws[RB_O + o];
#pragma unroll
      for (int c = 0; c < CI; ++c) s += srw[o * CI + c] * r[c];
      of[ob + (size_t)o * HW] = s;
    }
  } else {
    bf16* of = (bf16*)out;
#pragma unroll
    for (int o = 0; o < CIN; ++o) {
      float s = ws[RB_O + o];
#pragma unroll
      for (int c = 0; c < CI; ++c) s += srw[o * CI + c] * r[c];
      of[ob + (size_t)o * HW] = __float2bfloat16(s);
    }
  }
}

extern "C" void kernel_launch(void* const* d_in, const int* in_sizes, int n_in,
                              void* d_out, int out_size, void* d_ws, size_t ws_size,
                              hipStream_t stream)
{
  const void* x    = d_in[0];
  const void* g_w  = d_in[1];
  const void* g_b  = d_in[2];
  const void* th_w = d_in[3];
  const void* th_b = d_in[4];
  const void* ph_w = d_in[5];
  const void* ph_b = d_in[6];
  const void* m_w  = d_in[7];
  const void* m_b  = d_in[8];
  const void* r_w  = d_in[9];
  const void* r_b  = d_in[10];

  float* W = (float*)d_ws;
  int* flag = (int*)d_ws;
  ushort_t* planes = (ushort_t*)(W + B1_O);
  ushort_t* b1h = planes;
  ushort_t* b1l = planes + (size_t)N1;
  ushort_t* b2h = planes + (size_t)2 * N1;
  ushort_t* b2l = planes + (size_t)3 * N1;
  ushort_t* b3  = planes + (size_t)4 * N1;   // bf16 plane, N1 ushorts
  float* s3 = W + S3_O;

  k_detect<<<1, 64, 0, stream>>>((const unsigned short*)x, flag);
  k_prep<<<1, 256, 0, stream>>>(flag, g_w, th_w, ph_w, g_b, th_b, ph_b,
                                m_w, m_b, r_w, r_b, W);

  if (ws_size >= FULL_BYTES) {
    ushort_t* xhh = (ushort_t*)(W + REG_O);    // bf16 hi/lo x planes, dead after conv
    ushort_t* xhl = xhh + (size_t)XHSZ;
    float* sc = W + REG_O;                     // 4 x SCSLOT, aliases x planes
    float* ag = W + REG_O + XHSZ;              // 4 x AGSZ
    float* tkw = W + B1_O + N1;                // b2h region (dead after k_score)
    int*   tkp = (int*)(W + B1_O + N1 + N1 / 2);
    k_hwc<<<dim3((B_ * HW + 63) / 64), 256, 0, stream>>>(flag, x, xhh, xhl);
    k_conv3<<<dim3((HW + 127) / 128, 1, B_), 256, 0, stream>>>(
        W, xhh, xhl, b1h, b1l, b2h, b2l, b3);
    k_colsum<<<dim3(B_, 49), 256, 0, stream>>>(b3, s3);
    k_score<<<dim3(16, 8, B_), 256, 0, stream>>>(b1h, b1l, b2h, b2l, sc, 0, SCSLOT);
    k_topk<<<dim3((L_ + 3) / 4, B_), 256, 0, stream>>>(sc, tkw, tkp, SCSLOT);
    k_pv<<<dim3(L_, B_), 128, 0, stream>>>(tkw, tkp, b3, s3, ag, 0, AGSZ);
    k_fold<<<dim3(64, B_), 256, 0, stream>>>(flag, W, ag, d_out, 0, AGSZ);
  } else if (ws_size >= MID_BYTES) {
    ushort_t* xhh = (ushort_t*)(W + REG_O);
    ushort_t* xhl = xhh + (size_t)XHSZ;
    float* sc = W + REG_O;
    float* ag = W + REG_O + SCSLOT;
    k_hwc<<<dim3((B_ * HW + 63) / 64), 256, 0, stream>>>(flag, x, xhh, xhl);
    k_conv3<<<dim3((HW + 127) / 128, 1, B_), 256, 0, stream>>>(
        W, xhh, xhl, b1h, b1l, b2h, b2l, b3);
    k_colsum<<<dim3(B_, 49), 256, 0, stream>>>(b3, s3);
    for (int b = 0; b < B_; ++b) {
      float* tkw = W + B1_O + N1 + (size_t)b * (HW * CI / 2);
      int*   tkp = (int*)(W + B1_O + N1 + N1 / 2 + (size_t)b * (HW * CI / 2));
      k_score<<<dim3(16, 8, 1), 256, 0, stream>>>(b1h, b1l, b2h, b2l, sc, b, 0);
      k_topk<<<dim3((L_ + 3) / 4, 1), 256, 0, stream>>>(sc, tkw, tkp, 0);
      k_pv<<<dim3(L_, 1), 128, 0, stream>>>(tkw, tkp, b3, s3, ag, b, 0);
      k_fold<<<dim3(64, 1), 256, 0, stream>>>(flag, W, ag, d_out, b, 0);
    }
  } else {
    float* sc = W + REG_O;
    float* ag = W + REG_O + SCSLOT;
    k_convF<<<dim3(4, 16, B_), dim3(32, 8, 1), 0, stream>>>(
        flag, x, g_w, g_b, th_w, th_b, ph_w, ph_b, b1h, b1l, b2h, b2l, b3);
    k_colsum<<<dim3(B_, 49), 256, 0, stream>>>(b3, s3);
    for (int b = 0; b < B_; ++b) {
      float* tkw = W + B1_O + N1 + (size_t)b * (HW * CI / 2);
      int*   tkp = (int*)(W + B1_O + N1 + N1 / 2 + (size_t)b * (HW * CI / 2));
      k_score<<<dim3(16, 8, 1), 256, 0, stream>>>(b1h, b1l, b2h, b2l, sc, b, 0);
      k_topk<<<dim3((L_ + 3) / 4, 1), 256, 0, stream>>>(sc, tkw, tkp, 0);
      k_pv<<<dim3(L_, 1), 128, 0, stream>>>(tkw, tkp, b3, s3, ag, b, 0);
      k_fold<<<dim3(64, 1), 256, 0, stream>>>(flag, W, ag, d_out, b, 0);
    }
  }
}

// Round 4
// 320.121 us; speedup vs baseline: 1.4235x; 1.4235x over previous
//
#include <hip/hip_runtime.h>
#include <hip/hip_bf16.h>

typedef __hip_bfloat16 bf16;
typedef unsigned short ushort_t;
typedef __attribute__((ext_vector_type(8))) __bf16 bfv8;
typedef __attribute__((ext_vector_type(16))) float f32x16;

#define B_   4
#define CIN  64
#define CI   16
#define H_   127
#define W_   127
#define HW   (H_*W_)
#define KS   7
#define ST   4
#define OH_  31
#define L_   961
#define D_   784
#define TOPM 100

// ---- workspace layout (float offsets) ----
#define N1   1032256          // B*HW*CI elements (one conv-out array)
#define WG_O 4
#define WT_O (WG_O + 9216)
#define WP_O (WT_O + 1024)
#define BG_O (WP_O + 1024)
#define BT_O (BG_O + 16)
#define BP_O (BT_O + 16)
#define SM_O (BP_O + 16)
#define SB_O (SM_O + 16)
#define RW_O (SB_O + 16)
#define RB_O (RW_O + 1024)
#define B1_O 12448
// planes at B1_O: b1h,b1l,b2h,b2l each N1 ushorts (2*N1 floats); b3 bf16 N1 ushorts
#define S3_O (B1_O + 3*N1)
#define WB_O (S3_O + B_*D_)   // conv MFMA B: wBh + wBl = 36864 floats
#define REG_O (WB_O + 36864)
#define XHSZ 4129024          // B*HW*64 ushorts per x plane (2 planes = XHSZ floats)
#define SROW 964              // padded Sc row stride
#define SCSLOT 926464
#define AGSZ 753424
#define TKROW 112
#define SLST 72               // LDS row stride in ushorts (conflict-free, measured r8)
// PK: unfold-packed A operand. Per plane: 7 nki x 961 rows x 112 ushorts = 753424.
// Per batch (h+l): 1506848 ushorts = 753424 floats = exactly one AGSZ slot.
#define PKPLANE 753424
#define PKSTR   1506848

#define FULL_BYTES ((size_t)(REG_O + XHSZ + 4*AGSZ) * 4)   // ~41.1 MB
#define MID_BYTES  ((size_t)(REG_O + XHSZ) * 4)            // ~29.1 MB

__device__ __forceinline__ float bf2f(bf16 v) { return __bfloat162float(v); }
__device__ __forceinline__ float bflo(unsigned u) { return __uint_as_float(u << 16); }
__device__ __forceinline__ float bfhi(unsigned u) { return __uint_as_float(u & 0xFFFF0000u); }

template <typename T> struct Ld;
template <> struct Ld<float> {
  static __device__ __forceinline__ float f(const void* p, int i) { return ((const float*)p)[i]; }
};
template <> struct Ld<bf16> {
  static __device__ __forceinline__ float f(const void* p, int i) { return bf2f(((const bf16*)p)[i]); }
};

__device__ __forceinline__ unsigned fmap(float f) {
  unsigned u = __float_as_uint(f);
  return (u & 0x80000000u) ? ~u : (u | 0x80000000u);
}
__device__ __forceinline__ float unfmap(unsigned kk) {
  unsigned u = (kk & 0x80000000u) ? (kk & 0x7fffffffu) : ~kk;
  return __uint_as_float(u);
}

// RNE fp32 -> bf16 bits, and hi/lo split
__device__ __forceinline__ ushort_t f2bf(float x) {
  unsigned u = __float_as_uint(x);
  return (ushort_t)((u + 0x7FFFu + ((u >> 16) & 1u)) >> 16);
}
__device__ __forceinline__ void splitbf(float x, ushort_t& h, ushort_t& l) {
  h = f2bf(x);
  float hf = __uint_as_float(((unsigned)h) << 16);
  l = f2bf(x - hf);
}

// -------- dtype detector: flag=1 -> fp32 buffers, flag=0 -> bf16 -----------------
__global__ void k_detect(const unsigned short* __restrict__ xh, int* __restrict__ flag) {
  int tid = threadIdx.x;  // 64
  int c = 0;
#pragma unroll
  for (int j = 0; j < 2; ++j) {
    unsigned u = xh[tid * 2 + j];
    unsigned e = (u >> 7) & 0xFF;
    if (e >= 134) c++;
  }
#pragma unroll
  for (int o = 32; o; o >>= 1) c += __shfl_down(c, o);
  if (tid == 0) *flag = (c >= 8) ? 1 : 0;
}

// -------- weight prep ------------------------------------------------------------
#define LDW(ptr, i) (f ? ((const float*)(ptr))[i] : bf2f(((const bf16*)(ptr))[i]))
__global__ __launch_bounds__(256) void k_prep(
    const int* __restrict__ flag,
    const void* g_w, const void* t_w, const void* p_w,
    const void* g_b, const void* t_b, const void* p_b,
    const void* m_w, const void* m_b, const void* r_w, const void* r_b,
    float* __restrict__ ws)
{
  int tid = threadIdx.x;
  int f = *flag;
  for (int i = tid; i < 9216; i += 256) {
    int o = i & 15, t = i >> 4, c = t & 63, tap = t >> 6;
    ws[WG_O + i] = LDW(g_w, (o * 64 + c) * 9 + tap);
  }
  for (int i = tid; i < 1024; i += 256) {
    int o = i & 15, c = i >> 4;
    ws[WT_O + i] = LDW(t_w, o * 64 + c);
    ws[WP_O + i] = LDW(p_w, o * 64 + c);
  }
  if (tid < 16) {
    ws[BG_O + tid] = LDW(g_b, tid);
    ws[BT_O + tid] = LDW(t_b, tid);
    ws[BP_O + tid] = LDW(p_b, tid);
    float s = 0.f;
    for (int c = 0; c < 64; ++c) s += LDW(m_w, tid * 64 + c);
    ws[SM_O + tid] = s;
    ws[SB_O + tid] = LDW(m_b, tid);
  }
  for (int i = tid; i < 1024; i += 256) ws[RW_O + i] = LDW(r_w, i);
  if (tid < 64) ws[RB_O + tid] = LDW(r_b, tid);
  // conv MFMA B, split hi/lo: wB[tap][col64][c64]
  ushort_t* wBh = (ushort_t*)(ws + WB_O);
  ushort_t* wBl = wBh + 9 * 64 * 64;
  for (int i = tid; i < 9 * 64 * 64; i += 256) {
    int c = i & 63, t = i >> 6, col = t & 63, tap = t >> 6;
    float v = 0.f;
    if (col < 16) v = LDW(g_w, (col * 64 + c) * 9 + tap);
    else if (col < 32) { if (tap == 4) v = LDW(t_w, (col - 16) * 64 + c); }
    else if (col < 48) { if (tap == 4) v = LDW(p_w, (col - 32) * 64 + c); }
    ushort_t h, l; splitbf(v, h, l);
    wBh[i] = h; wBl[i] = l;
  }
}

// -------- x [B,64,H,W] -> HWC bf16 hi/lo planes ----------------------------------
__global__ __launch_bounds__(256) void k_hwc(
    const int* __restrict__ flag, const void* __restrict__ x,
    ushort_t* __restrict__ xhh, ushort_t* __restrict__ xhl)
{
  __shared__ float tile[64][65];
  int pix0 = blockIdx.x * 64;
  int tid = threadIdx.x;
  int g = tid >> 6, p = tid & 63;
  int pix = pix0 + p;
  bool ok = pix < B_ * HW;
  int bb = ok ? pix / HW : 0;
  int r  = ok ? pix - bb * HW : 0;
  if (*flag) {
    const float* xf = (const float*)x;
    for (int c = g * 16; c < g * 16 + 16; ++c)
      tile[p][c] = ok ? xf[((size_t)bb * CIN + c) * HW + r] : 0.f;
  } else {
    const bf16* xb = (const bf16*)x;
    for (int c = g * 16; c < g * 16 + 16; ++c)
      tile[p][c] = ok ? bf2f(xb[((size_t)bb * CIN + c) * HW + r]) : 0.f;
  }
  __syncthreads();
  int c2 = tid & 63, pg = tid >> 6;
  for (int k = 0; k < 16; ++k) {
    int p2 = pg * 16 + k;
    int pix2 = pix0 + p2;
    if (pix2 < B_ * HW) {
      ushort_t h, l; splitbf(tile[p2][c2], h, l);
      xhh[(size_t)pix2 * 64 + c2] = h;
      xhl[(size_t)pix2 * 64 + c2] = l;
    }
  }
}

// -------- unified split-bf16 MFMA conv, 128-pixel tile (round-0 verbatim) --------
__global__ __launch_bounds__(256) void k_conv3(
    const float* __restrict__ ws,
    const ushort_t* __restrict__ xhh, const ushort_t* __restrict__ xhl,
    ushort_t* __restrict__ b1h, ushort_t* __restrict__ b1l,
    ushort_t* __restrict__ b2h, ushort_t* __restrict__ b2l,
    ushort_t* __restrict__ b3)
{
  __shared__ ushort_t sAh[128 * SLST], sAl[128 * SLST];
  __shared__ ushort_t sBh[64 * SLST],  sBl[64 * SLST];
  int bz = blockIdx.z;
  int px0 = blockIdx.x * 128;
  int tid = threadIdx.x, lane = tid & 63, wv = tid >> 6;

  int pix0 = px0 + lane, pix1 = px0 + lane + 64;
  bool pok0 = pix0 < HW, pok1 = pix1 < HW;
  int ph0 = pok0 ? pix0 / W_ : 0, pw0 = pok0 ? pix0 - ph0 * W_ : 0;
  int ph1 = pok1 ? pix1 / W_ : 0, pw1 = pok1 ? pix1 - ph1 * W_ : 0;
  const ushort_t* xplane = ((wv == 0) ? xhh : xhl) + (size_t)bz * HW * 64;
  const ushort_t* wBh_ = (const ushort_t*)(ws + WB_O);
  const ushort_t* bsrc = (wv == 2) ? wBh_ : (wBh_ + 9 * 64 * 64);
  ushort_t* dplane = (wv == 0) ? sAh : (wv == 1) ? sAl : (wv == 2) ? sBh : sBl;
  ushort_t* drow0 = dplane + lane * SLST;
  ushort_t* drow1 = dplane + (lane + 64) * SLST;   // wv<2 only

  int fr = lane & 31, kh = (lane >> 5) << 3;
  int mt = (wv >> 1) << 1;
  int aoff0 = (mt * 32 + fr) * SLST + kh;
  int aoff1 = ((mt + 1) * 32 + fr) * SLST + kh;
  int boff  = (((wv & 1) << 5) + fr) * SLST + kh;

  f32x16 acc0 = {0.f,0.f,0.f,0.f,0.f,0.f,0.f,0.f,0.f,0.f,0.f,0.f,0.f,0.f,0.f,0.f};
  f32x16 acc1 = {0.f,0.f,0.f,0.f,0.f,0.f,0.f,0.f,0.f,0.f,0.f,0.f,0.f,0.f,0.f,0.f};
  const int4 z4 = make_int4(0, 0, 0, 0);
  int4 v0 = z4, v1 = z4, v2 = z4, v3 = z4, v4 = z4, v5 = z4, v6 = z4, v7 = z4;
  int4 u0 = z4, u1 = z4, u2 = z4, u3 = z4, u4 = z4, u5 = z4, u6 = z4, u7 = z4;

  // prefetch tap 0 (dh=-1, dw=-1)
  if (wv < 2) {
    int hh = ph0 - 1, ww = pw0 - 1;
    if (pok0 && hh >= 0 && ww >= 0) {
      const int4* s = (const int4*)(xplane + (size_t)(hh * W_ + ww) * 64);
      v0 = s[0]; v1 = s[1]; v2 = s[2]; v3 = s[3]; v4 = s[4]; v5 = s[5]; v6 = s[6]; v7 = s[7];
    }
    int hh1 = ph1 - 1, ww1 = pw1 - 1;
    if (pok1 && hh1 >= 0 && ww1 >= 0) {
      const int4* s = (const int4*)(xplane + (size_t)(hh1 * W_ + ww1) * 64);
      u0 = s[0]; u1 = s[1]; u2 = s[2]; u3 = s[3]; u4 = s[4]; u5 = s[5]; u6 = s[6]; u7 = s[7];
    }
  } else {
    const int4* s = (const int4*)(bsrc + (size_t)lane * 64);
    v0 = s[0]; v1 = s[1]; v2 = s[2]; v3 = s[3]; v4 = s[4]; v5 = s[5]; v6 = s[6]; v7 = s[7];
  }

  for (int r = 0; r < 9; ++r) {
    __syncthreads();
    *(int4*)(drow0 + 0)  = v0;  *(int4*)(drow0 + 8)  = v1;
    *(int4*)(drow0 + 16) = v2;  *(int4*)(drow0 + 24) = v3;
    *(int4*)(drow0 + 32) = v4;  *(int4*)(drow0 + 40) = v5;
    *(int4*)(drow0 + 48) = v6;  *(int4*)(drow0 + 56) = v7;
    if (wv < 2) {
      *(int4*)(drow1 + 0)  = u0;  *(int4*)(drow1 + 8)  = u1;
      *(int4*)(drow1 + 16) = u2;  *(int4*)(drow1 + 24) = u3;
      *(int4*)(drow1 + 32) = u4;  *(int4*)(drow1 + 40) = u5;
      *(int4*)(drow1 + 48) = u6;  *(int4*)(drow1 + 56) = u7;
    }
    __syncthreads();
    if (r < 8) {
      int rn = r + 1;
      int dh = rn / 3 - 1, dw = rn % 3 - 1;
      if (wv < 2) {
        int hh = ph0 + dh, ww = pw0 + dw;
        if (pok0 && (unsigned)hh < (unsigned)H_ && (unsigned)ww < (unsigned)W_) {
          const int4* s = (const int4*)(xplane + (size_t)(hh * W_ + ww) * 64);
          v0 = s[0]; v1 = s[1]; v2 = s[2]; v3 = s[3]; v4 = s[4]; v5 = s[5]; v6 = s[6]; v7 = s[7];
        } else {
          v0 = z4; v1 = z4; v2 = z4; v3 = z4; v4 = z4; v5 = z4; v6 = z4; v7 = z4;
        }
        int hh1 = ph1 + dh, ww1 = pw1 + dw;
        if (pok1 && (unsigned)hh1 < (unsigned)H_ && (unsigned)ww1 < (unsigned)W_) {
          const int4* s = (const int4*)(xplane + (size_t)(hh1 * W_ + ww1) * 64);
          u0 = s[0]; u1 = s[1]; u2 = s[2]; u3 = s[3]; u4 = s[4]; u5 = s[5]; u6 = s[6]; u7 = s[7];
        } else {
          u0 = z4; u1 = z4; u2 = z4; u3 = z4; u4 = z4; u5 = z4; u6 = z4; u7 = z4;
        }
      } else {
        const int4* s = (const int4*)(bsrc + ((size_t)rn * 64 + lane) * 64);
        v0 = s[0]; v1 = s[1]; v2 = s[2]; v3 = s[3]; v4 = s[4]; v5 = s[5]; v6 = s[6]; v7 = s[7];
      }
    }
#pragma unroll
    for (int t = 0; t < 4; ++t) {
      bfv8 ah0 = *(const bfv8*)(sAh + aoff0 + t * 16);
      bfv8 al0 = *(const bfv8*)(sAl + aoff0 + t * 16);
      bfv8 ah1 = *(const bfv8*)(sAh + aoff1 + t * 16);
      bfv8 al1 = *(const bfv8*)(sAl + aoff1 + t * 16);
      bfv8 bh  = *(const bfv8*)(sBh + boff + t * 16);
      bfv8 bl  = *(const bfv8*)(sBl + boff + t * 16);
      acc0 = __builtin_amdgcn_mfma_f32_32x32x16_bf16(al0, bh, acc0, 0, 0, 0);
      acc0 = __builtin_amdgcn_mfma_f32_32x32x16_bf16(ah0, bl, acc0, 0, 0, 0);
      acc0 = __builtin_amdgcn_mfma_f32_32x32x16_bf16(ah0, bh, acc0, 0, 0, 0);
      acc1 = __builtin_amdgcn_mfma_f32_32x32x16_bf16(al1, bh, acc1, 0, 0, 0);
      acc1 = __builtin_amdgcn_mfma_f32_32x32x16_bf16(ah1, bl, acc1, 0, 0, 0);
      acc1 = __builtin_amdgcn_mfma_f32_32x32x16_bf16(ah1, bh, acc1, 0, 0, 0);
    }
  }

  int nw = ((wv & 1) << 5) + fr;
#pragma unroll
  for (int s = 0; s < 2; ++s) {
    int mbase = (mt + s) * 32;
#pragma unroll
    for (int r = 0; r < 16; ++r) {
      int m = mbase + (r & 3) + ((r >> 2) << 3) + ((lane >> 5) << 2);
      int p2 = px0 + m;
      if (p2 >= HW) continue;
      size_t ob = ((size_t)bz * HW + p2) * 16;
      float val = s ? acc1[r] : acc0[r];
      if (nw < 16) {
        ushort_t h2, l2; splitbf(val + ws[BG_O + nw], h2, l2);
        b1h[ob + nw] = h2; b1l[ob + nw] = l2;
      } else if (nw < 32) {
        int o = nw - 16; ushort_t h2, l2; splitbf(val + ws[BT_O + o], h2, l2);
        b2h[ob + o] = h2; b2l[ob + o] = l2;
      } else if (nw < 48) {
        int o = nw - 32; b3[ob + o] = f2bf(val + ws[BP_O + o]);
      }
    }
  }
}

// -------- fallback conv (LOW tier), dtype-templated VALU -------------------------
template <typename T>
__device__ __forceinline__ void convF_body(
    const void* x, const void* g_w, const void* g_b,
    const void* t_w, const void* t_b, const void* p_w, const void* p_b,
    ushort_t* b1h, ushort_t* b1l, ushort_t* b2h, ushort_t* b2l, ushort_t* b3,
    float* sgw, float* stw, float* spw)
{
  int tid = threadIdx.y * 32 + threadIdx.x;
  for (int i = tid; i < CI * CIN * 9; i += 256) sgw[i] = Ld<T>::f(g_w, i);
  for (int i = tid; i < CI * CIN; i += 256) { stw[i] = Ld<T>::f(t_w, i); spw[i] = Ld<T>::f(p_w, i); }
  __syncthreads();

  int w = blockIdx.x * 32 + threadIdx.x;
  int h = blockIdx.y * 8 + threadIdx.y;
  int b = blockIdx.z;
  if (w >= W_ || h >= H_) return;

  float a1[CI], a2[CI], a3[CI];
#pragma unroll
  for (int o = 0; o < CI; ++o) { a1[o] = 0.f; a2[o] = 0.f; a3[o] = 0.f; }

  const size_t xb = (size_t)b * CIN * HW;
  for (int c = 0; c < CIN; ++c) {
    float xv[9];
#pragma unroll
    for (int dh = 0; dh < 3; ++dh) {
      int hh = h + dh - 1;
      bool rok = ((unsigned)hh < (unsigned)H_);
#pragma unroll
      for (int dw = 0; dw < 3; ++dw) {
        int ww = w + dw - 1;
        bool ok = rok && ((unsigned)ww < (unsigned)W_);
        xv[dh * 3 + dw] = ok ? Ld<T>::f(x, (int)(xb + (size_t)c * HW + hh * W_ + ww)) : 0.f;
      }
    }
    float xc = xv[4];
#pragma unroll
    for (int o = 0; o < CI; ++o) {
      const float* gg = &sgw[(o * CIN + c) * 9];
      float s = gg[0]*xv[0] + gg[1]*xv[1] + gg[2]*xv[2]
              + gg[3]*xv[3] + gg[4]*xv[4] + gg[5]*xv[5]
              + gg[6]*xv[6] + gg[7]*xv[7] + gg[8]*xv[8];
      a1[o] += s;
      a2[o] += stw[o * CIN + c] * xc;
      a3[o] += spw[o * CIN + c] * xc;
    }
  }
  size_t base = ((size_t)b * HW + h * W_ + w) * CI;
#pragma unroll
  for (int o = 0; o < CI; ++o) {
    float v1 = a1[o] + Ld<T>::f(g_b, o);
    float v2 = a2[o] + Ld<T>::f(t_b, o);
    ushort_t hh2, ll2;
    splitbf(v1, hh2, ll2); b1h[base + o] = hh2; b1l[base + o] = ll2;
    splitbf(v2, hh2, ll2); b2h[base + o] = hh2; b2l[base + o] = ll2;
    b3[base + o] = f2bf(a3[o] + Ld<T>::f(p_b, o));
  }
}

__global__ __launch_bounds__(256) void k_convF(
    const int* __restrict__ flag, const void* x,
    const void* g_w, const void* g_b, const void* t_w, const void* t_b,
    const void* p_w, const void* p_b,
    ushort_t* __restrict__ b1h, ushort_t* __restrict__ b1l,
    ushort_t* __restrict__ b2h, ushort_t* __restrict__ b2l,
    ushort_t* __restrict__ b3)
{
  __shared__ float sgw[CI * CIN * 9];
  __shared__ float stw[CI * CIN];
  __shared__ float spw[CI * CIN];
  if (*flag) convF_body<float>(x, g_w, g_b, t_w, t_b, p_w, p_b, b1h, b1l, b2h, b2l, b3, sgw, stw, spw);
  else       convF_body<bf16 >(x, g_w, g_b, t_w, t_b, p_w, p_b, b1h, b1l, b2h, b2l, b3, sgw, stw, spw);
}

// -------- S3[b, pos*16+c] = sum over patches of b3 (bf16 src, fp32 acc) ----------
__global__ __launch_bounds__(256) void k_colsum(const ushort_t* __restrict__ b3, float* __restrict__ S3)
{
  __shared__ float red[16][17];
  int b = blockIdx.x, pos = blockIdx.y;
  int ki = pos / 7, kj = pos % 7;
  int c = threadIdx.x & 15, chunk = threadIdx.x >> 4;
  const ushort_t* B3 = b3 + (size_t)b * HW * CI;
  float s = 0.f;
  for (int l = chunk; l < L_; l += 16) {
    int lh = l / OH_, lw = l % OH_;
    s += bflo((unsigned)B3[((lh * ST + ki) * W_ + lw * ST + kj) * CI + c]);
  }
  red[chunk][c] = s;
  __syncthreads();
  if (threadIdx.x < 16) {
    float t = 0.f;
#pragma unroll
    for (int k = 0; k < 16; ++k) t += red[k][threadIdx.x];
    S3[(b * 49 + pos) * 16 + threadIdx.x] = t;
  }
}

// -------- pack A operand: PK[plane][nki][row][112] = b1 patch-row segments -------
// Pure contiguous copy: 14 int4 per (row,nki) read, coalesced write. Exact bits.
__global__ __launch_bounds__(256) void k_pack(
    const ushort_t* __restrict__ b1h, const ushort_t* __restrict__ b1l,
    ushort_t* __restrict__ pk, int b0, unsigned pkstride_z)
{
  int idx = blockIdx.x * 256 + threadIdx.x;
  if (idx >= 961 * 98) return;
  int row = idx / 98, rem = idx - row * 98;
  int nki = rem / 14, q = rem - nki * 14;
  int slh = row / OH_, slw = row - slh * OH_;
  int src = ((slh * ST) * W_ + slw * ST + nki * W_) * 16 + q * 8;
  int dst = (nki * 961 + row) * 112 + q * 8;
  int batch = b0 + blockIdx.y;
  size_t poff = (size_t)batch * HW * CI;
  ushort_t* pkb = pk + (size_t)blockIdx.y * pkstride_z;
  *(int4*)(pkb + dst)           = *(const int4*)(b1h + poff + src);
  *(int4*)(pkb + PKPLANE + dst) = *(const int4*)(b1l + poff + src);
}

// -------- score GEMM via split-bf16 MFMA, 128x64 tile ----------------------------
// A staged cooperatively from PK (one base + imm offsets, named regs -> no spill,
// consecutive lanes contiguous -> ~3x fewer cache-line requests). B per-lane-row,
// LDS layout/MFMA/epilogue byte-identical to the 322us round-0 kernel.
__global__ __launch_bounds__(256) void k_score(
    const ushort_t* __restrict__ b2h, const ushort_t* __restrict__ b2l,
    const ushort_t* __restrict__ pk,
    float* __restrict__ scb, int b0, unsigned scstride_z, unsigned pkstride_z)
{
  __shared__ ushort_t sAh[128 * SLST], sAl[128 * SLST];
  __shared__ ushort_t sBh[64 * SLST],  sBl[64 * SLST];
  int batch = b0 + blockIdx.z;
  size_t poff_g = (size_t)batch * HW * CI;
  float* Sc = scb + (size_t)blockIdx.z * scstride_z;

  int tid = threadIdx.x;
  int m0 = blockIdx.y * 128, n0 = blockIdx.x * 64;
  int lane = tid & 63;
  int wv = tid >> 6;
  int grp = lane >> 3, ch = lane & 7;

  const ushort_t* pkb = pk + (size_t)blockIdx.z * pkstride_z + (size_t)(wv & 1) * PKPLANE;

  // B-side per-lane-row base (wv>=2)
  int srow = n0 + lane;  if (srow > L_ - 1) srow = L_ - 1;
  int slh = srow / OH_, slw = srow - slh * OH_;
  int sbase = (slh * ST) * W_ + slw * ST;
  const ushort_t* splane = (wv == 2) ? (b2h + poff_g) : (b2l + poff_g);
  ushort_t* dplane = (wv == 0) ? sAh : (wv == 1) ? sAl : (wv == 2) ? sBh : sBl;
  ushort_t* drowB = dplane + lane * SLST;

  int fr = lane & 31;
  int kh = (lane >> 5) << 3;
  int mt = (wv >> 1) << 1;                         // first m-subtile: 0 or 2
  int aoff0 = (mt * 32 + fr) * SLST + kh;
  int aoff1 = ((mt + 1) * 32 + fr) * SLST + kh;
  int boff  = (((wv & 1) << 5) + fr) * SLST + kh;

  f32x16 acc0 = {0.f,0.f,0.f,0.f,0.f,0.f,0.f,0.f,0.f,0.f,0.f,0.f,0.f,0.f,0.f,0.f};
  f32x16 acc1 = {0.f,0.f,0.f,0.f,0.f,0.f,0.f,0.f,0.f,0.f,0.f,0.f,0.f,0.f,0.f,0.f};

  int4 pv0, pv1, pv2, pv3, pv4, pv5, pv6, pv7;
  int4 pv8, pv9, pv10, pv11, pv12, pv13, pv14, pv15;

#define LA(j) pv##j = *(const int4*)(pks + (size_t)min(m0 + 8*j + grp, 960) * 112)
#define LA_ALL LA(0); LA(1); LA(2); LA(3); LA(4); LA(5); LA(6); LA(7); \
               LA(8); LA(9); LA(10); LA(11); LA(12); LA(13); LA(14); LA(15)
#define WA(j) *(int4*)(d0 + (j) * 8 * SLST) = pv##j
#define WA_ALL WA(0); WA(1); WA(2); WA(3); WA(4); WA(5); WA(6); WA(7); \
               WA(8); WA(9); WA(10); WA(11); WA(12); WA(13); WA(14); WA(15)

  // initial prefetch: rn=0 (nki=0, even)
  if (wv < 2) {
    const ushort_t* pks = pkb + ch * 8;
    LA_ALL;
  } else {
    const int4* s0 = (const int4*)(splane + (size_t)sbase * 16);
    pv0 = s0[0]; pv1 = s0[1]; pv2 = s0[2]; pv3 = s0[3];
    pv4 = s0[4]; pv5 = s0[5]; pv6 = s0[6]; pv7 = s0[7];
  }

  for (int r = 0; r < 14; ++r) {
    int half = r & 1;
    __syncthreads();
    if (wv < 2) {
      ushort_t* d0 = dplane + grp * SLST + ch * 8;
      if (!half) { WA_ALL; }
      else if (ch < 6) { WA_ALL; }
    } else {
      *(int4*)(drowB + 0)  = pv0;  *(int4*)(drowB + 8)  = pv1;
      *(int4*)(drowB + 16) = pv2;  *(int4*)(drowB + 24) = pv3;
      *(int4*)(drowB + 32) = pv4;  *(int4*)(drowB + 40) = pv5;
      if (!half) { *(int4*)(drowB + 48) = pv6; *(int4*)(drowB + 56) = pv7; }
    }
    __syncthreads();
    if (r < 13) {
      int rn = r + 1;
      int nki = rn >> 1, odd = rn & 1;
      if (wv < 2) {
        const ushort_t* pks = pkb + (size_t)nki * (961 * 112) + odd * 64 + ch * 8;
        if (!odd) { LA_ALL; }
        else if (ch < 6) { LA_ALL; }
      } else {
        int nkj0 = odd * 4;
        const int4* s0 = (const int4*)(splane + (size_t)(sbase + nki * W_ + nkj0) * 16);
        pv0 = s0[0]; pv1 = s0[1]; pv2 = s0[2]; pv3 = s0[3]; pv4 = s0[4]; pv5 = s0[5];
        if (!odd) { pv6 = s0[6]; pv7 = s0[7]; }
      }
    }
    if (!half) {
#pragma unroll
      for (int t = 0; t < 4; ++t) {
        bfv8 ah0 = *(const bfv8*)(sAh + aoff0 + t * 16);
        bfv8 al0 = *(const bfv8*)(sAl + aoff0 + t * 16);
        bfv8 ah1 = *(const bfv8*)(sAh + aoff1 + t * 16);
        bfv8 al1 = *(const bfv8*)(sAl + aoff1 + t * 16);
        bfv8 bh  = *(const bfv8*)(sBh + boff + t * 16);
        bfv8 bl  = *(const bfv8*)(sBl + boff + t * 16);
        acc0 = __builtin_amdgcn_mfma_f32_32x32x16_bf16(al0, bh, acc0, 0, 0, 0);
        acc0 = __builtin_amdgcn_mfma_f32_32x32x16_bf16(ah0, bl, acc0, 0, 0, 0);
        acc0 = __builtin_amdgcn_mfma_f32_32x32x16_bf16(ah0, bh, acc0, 0, 0, 0);
        acc1 = __builtin_amdgcn_mfma_f32_32x32x16_bf16(al1, bh, acc1, 0, 0, 0);
        acc1 = __builtin_amdgcn_mfma_f32_32x32x16_bf16(ah1, bl, acc1, 0, 0, 0);
        acc1 = __builtin_amdgcn_mfma_f32_32x32x16_bf16(ah1, bh, acc1, 0, 0, 0);
      }
    } else {
#pragma unroll
      for (int t = 0; t < 3; ++t) {
        bfv8 ah0 = *(const bfv8*)(sAh + aoff0 + t * 16);
        bfv8 al0 = *(const bfv8*)(sAl + aoff0 + t * 16);
        bfv8 ah1 = *(const bfv8*)(sAh + aoff1 + t * 16);
        bfv8 al1 = *(const bfv8*)(sAl + aoff1 + t * 16);
        bfv8 bh  = *(const bfv8*)(sBh + boff + t * 16);
        bfv8 bl  = *(const bfv8*)(sBl + boff + t * 16);
        acc0 = __builtin_amdgcn_mfma_f32_32x32x16_bf16(al0, bh, acc0, 0, 0, 0);
        acc0 = __builtin_amdgcn_mfma_f32_32x32x16_bf16(ah0, bl, acc0, 0, 0, 0);
        acc0 = __builtin_amdgcn_mfma_f32_32x32x16_bf16(ah0, bh, acc0, 0, 0, 0);
        acc1 = __builtin_amdgcn_mfma_f32_32x32x16_bf16(al1, bh, acc1, 0, 0, 0);
        acc1 = __builtin_amdgcn_mfma_f32_32x32x16_bf16(ah1, bl, acc1, 0, 0, 0);
        acc1 = __builtin_amdgcn_mfma_f32_32x32x16_bf16(ah1, bh, acc1, 0, 0, 0);
      }
    }
  }
#undef LA
#undef LA_ALL
#undef WA
#undef WA_ALL

  int nw = n0 + ((wv & 1) << 5) + fr;
  if (nw < L_) {
    int mw0 = m0 + mt * 32;
#pragma unroll
    for (int r = 0; r < 16; ++r) {
      int m = mw0 + (r & 3) + ((r >> 2) << 3) + ((lane >> 5) << 2);
      if (m < L_) Sc[(size_t)m * SROW + nw] = acc0[r];
    }
    int mw1 = m0 + (mt + 1) * 32;
#pragma unroll
    for (int r = 0; r < 16; ++r) {
      int m = mw1 + (r & 3) + ((r >> 2) << 3) + ((lane >> 5) << 2);
      if (m < L_) Sc[(size_t)m * SROW + nw] = acc1[r];
    }
  }
}

// -------- top-100 + softmax weights: 4 rows per block (1 wave each) --------------
__global__ __launch_bounds__(256) void k_topk(
    const float* __restrict__ scb, float* __restrict__ tkw, int* __restrict__ tkp,
    unsigned scstride_z)
{
  __shared__ float swv[4][TOPM];
  __shared__ int spx[4][TOPM];
  int tid = threadIdx.x;
  int wvi = tid >> 6, lane = tid & 63;
  int l = blockIdx.x * 4 + wvi;
  if (l > L_ - 1) l = L_ - 1;        // clamp: duplicate rows write identical data
  int bz = blockIdx.y;
  const float4* row4 = (const float4*)(scb + (size_t)bz * scstride_z + (size_t)l * SROW);
  int trow = (bz * L_ + l) * TKROW;

  unsigned k[16];
#pragma unroll
  for (int q = 0; q < 4; ++q) {
    float4 v = row4[q * 64 + lane];
    int ib = (q * 64 + lane) * 4;
    k[q * 4 + 0] = (ib + 0 < L_) ? fmap(v.x) : 0u;
    k[q * 4 + 1] = (ib + 1 < L_) ? fmap(v.y) : 0u;
    k[q * 4 + 2] = (ib + 2 < L_) ? fmap(v.z) : 0u;
    k[q * 4 + 3] = (ib + 3 < L_) ? fmap(v.w) : 0u;
  }

  unsigned mk = 0;
#pragma unroll
  for (int r = 0; r < 16; ++r) mk = max(mk, k[r]);
#pragma unroll
  for (int o = 32; o; o >>= 1) mk = max(mk, (unsigned)__shfl_down((int)mk, o));
  mk = (unsigned)__shfl((int)mk, 0);
  float vmax = unfmap(mk);

  unsigned alive = 0xFFFFu;
  unsigned prefix = 0; int base = 0;
  for (int bit = 30; bit >= 0; bit -= 2) {
    int c1 = 0, c2 = 0, c3 = 0;
#pragma unroll
    for (int r = 0; r < 16; ++r) {
      if ((alive >> r) & 1) {
        unsigned f = (k[r] >> bit) & 3u;
        c3 += (f == 3); c2 += (f >= 2); c1 += (f >= 1);
      }
    }
    int p = c3 | (c2 << 10) | (c1 << 20);
#pragma unroll
    for (int o = 32; o; o >>= 1) p += __shfl_down(p, o);
    p = __shfl(p, 0);
    int n3 = p & 1023, n2 = (p >> 10) & 1023, n1 = (p >> 20) & 1023;
    unsigned ch;
    if (base + n3 >= TOPM) ch = 3;
    else if (base + n2 >= TOPM) { ch = 2; base += n3; }
    else if (base + n1 >= TOPM) { ch = 1; base += n2; }
    else { ch = 0; base += n1; }
    prefix |= ch << bit;
#pragma unroll
    for (int r = 0; r < 16; ++r) {
      if ((alive >> r) & 1) {
        unsigned f = (k[r] >> bit) & 3u;
        if (f != ch) alive &= ~(1u << r);
      }
    }
  }
  int nA = base;
  int needT = TOPM - nA;

  int cA = 0, cT = 0;
#pragma unroll
  for (int r = 0; r < 16; ++r) { cA += (k[r] > prefix); cT += (k[r] == prefix); }
  int pk = cA | (cT << 16);
  int incl = pk;
#pragma unroll
  for (int o = 1; o < 64; o <<= 1) { int t = __shfl_up(incl, o); if (lane >= o) incl += t; }
  int excl = incl - pk;
  int tA = excl & 0xFFFF, tT = excl >> 16;

  float M = fmaxf(10.f * vmax, 0.f);
  float e0 = expf(-M);
  float z = 0.f;
#pragma unroll
  for (int r = 0; r < 16; ++r) {
    unsigned kk = k[r];
    int slot = -1;
    if (kk > prefix) slot = tA++;
    else if (kk == prefix) { if (tT < needT) slot = nA + tT; tT++; }
    if (slot >= 0) {
      float v = unfmap(kk);
      float wv = expf(10.f * v - M);
      swv[wvi][slot] = wv; z += wv;
      int gi = 256 * (r >> 2) + 4 * lane + (r & 3);
      int lh = gi / OH_, lw = gi - lh * OH_;
      spx[wvi][slot] = ((lh * ST) * W_ + lw * ST) * CI;
    }
  }
#pragma unroll
  for (int o = 32; o; o >>= 1) z += __shfl_down(z, o);
  z = __shfl(z, 0);
  float Z = z + (float)(L_ - TOPM) * e0;
  float invZ = 1.f / Z;
  float w0 = e0 / Z;
  __syncthreads();
#pragma unroll
  for (int s0 = 0; s0 < 2; ++s0) {
    int s = lane + 64 * s0;
    if (s < TOPM) {
      tkw[trow + s] = swv[wvi][s] * invZ - w0;
      tkp[trow + s] = spx[wvi][s];
    }
  }
  if (lane == 0) tkw[trow + TOPM] = w0;
}

// -------- PV gather (bf16 b3, uint4 full-line): 98 lanes x 8 channels ------------
__global__ __launch_bounds__(128) void k_pv(
    const float* __restrict__ tkw, const int* __restrict__ tkp,
    const ushort_t* __restrict__ b3, const float* __restrict__ s3,
    float* __restrict__ agb, int b0, unsigned agstride_z)
{
  int l = blockIdx.x, bz = blockIdx.y;
  int batch = b0 + bz;
  int trow = (bz * L_ + l) * TKROW;
  const ushort_t* B3 = b3 + (size_t)batch * HW * CI;
  const float* S3 = s3 + (size_t)batch * D_;
  float* agg = agb + (size_t)bz * agstride_z;
  int tid = threadIdx.x;
  if (tid >= 98) return;

  float w0 = tkw[trow + TOPM];
  int pos = tid >> 1;
  int c0 = (tid & 1) << 3;                 // 0 or 8
  int ki = pos / 7, kj = pos - (pos / 7) * 7;
  int poff = (ki * W_ + kj) * CI + c0;

  float a0 = 0.f, a1 = 0.f, a2 = 0.f, a3 = 0.f;
  float a4 = 0.f, a5 = 0.f, a6 = 0.f, a7 = 0.f;
  for (int j0 = 0; j0 < TOPM; j0 += 4) {
    float w_0 = tkw[trow + j0 + 0];
    float w_1 = tkw[trow + j0 + 1];
    float w_2 = tkw[trow + j0 + 2];
    float w_3 = tkw[trow + j0 + 3];
    int p_0 = tkp[trow + j0 + 0];
    int p_1 = tkp[trow + j0 + 1];
    int p_2 = tkp[trow + j0 + 2];
    int p_3 = tkp[trow + j0 + 3];
    const uint4 q0 = *(const uint4*)(B3 + p_0 + poff);
    const uint4 q1 = *(const uint4*)(B3 + p_1 + poff);
    const uint4 q2 = *(const uint4*)(B3 + p_2 + poff);
    const uint4 q3 = *(const uint4*)(B3 + p_3 + poff);
    a0 += w_0 * bflo(q0.x); a1 += w_0 * bfhi(q0.x); a2 += w_0 * bflo(q0.y); a3 += w_0 * bfhi(q0.y);
    a4 += w_0 * bflo(q0.z); a5 += w_0 * bfhi(q0.z); a6 += w_0 * bflo(q0.w); a7 += w_0 * bfhi(q0.w);
    a0 += w_1 * bflo(q1.x); a1 += w_1 * bfhi(q1.x); a2 += w_1 * bflo(q1.y); a3 += w_1 * bfhi(q1.y);
    a4 += w_1 * bflo(q1.z); a5 += w_1 * bfhi(q1.z); a6 += w_1 * bflo(q1.w); a7 += w_1 * bfhi(q1.w);
    a0 += w_2 * bflo(q2.x); a1 += w_2 * bfhi(q2.x); a2 += w_2 * bflo(q2.y); a3 += w_2 * bfhi(q2.y);
    a4 += w_2 * bflo(q2.z); a5 += w_2 * bfhi(q2.z); a6 += w_2 * bflo(q2.w); a7 += w_2 * bfhi(q2.w);
    a0 += w_3 * bflo(q3.x); a1 += w_3 * bfhi(q3.x); a2 += w_3 * bflo(q3.y); a3 += w_3 * bfhi(q3.y);
    a4 += w_3 * bflo(q3.z); a5 += w_3 * bfhi(q3.z); a6 += w_3 * bflo(q3.w); a7 += w_3 * bfhi(q3.w);
  }
  const float4 s40 = *(const float4*)(S3 + tid * 8);
  const float4 s41 = *(const float4*)(S3 + tid * 8 + 4);
  a0 += w0 * s40.x; a1 += w0 * s40.y; a2 += w0 * s40.z; a3 += w0 * s40.w;
  a4 += w0 * s41.x; a5 += w0 * s41.y; a6 += w0 * s41.z; a7 += w0 * s41.w;
  float* dst = agg + (size_t)l * D_ + tid * 8;
  *(float4*)(dst)     = make_float4(a0, a1, a2, a3);
  *(float4*)(dst + 4) = make_float4(a4, a5, a6, a7);
}

// -------- fold + mask divide + restore (16->64), batched -------------------------
__global__ __launch_bounds__(256) void k_fold(
    const int* __restrict__ flag, const float* __restrict__ ws,
    const float* __restrict__ agb, void* __restrict__ out,
    int b0, unsigned agstride_z)
{
  __shared__ float srw[CIN * CI];
  int tid = threadIdx.x;
  for (int i = tid; i < CIN * CI; i += 256) srw[i] = ws[RW_O + i];
  __syncthreads();

  int bz = blockIdx.y;
  int batch = b0 + bz;
  const float* agg = agb + (size_t)bz * agstride_z;

  int gid = blockIdx.x * 256 + tid;
  if (gid >= HW) return;
  int h = gid / W_;
  int w = gid % W_;

  int lh0 = (h >= KS - 1) ? ((h - (KS - 1) + (ST - 1)) >> 2) : 0;
  int lh1 = min(OH_ - 1, h >> 2);
  int lw0 = (w >= KS - 1) ? ((w - (KS - 1) + (ST - 1)) >> 2) : 0;
  int lw1 = min(OH_ - 1, w >> 2);

  float t[CI];
#pragma unroll
  for (int c = 0; c < CI; ++c) t[c] = 0.f;
  for (int lh = lh0; lh <= lh1; ++lh) {
    int ki = h - ST * lh;
    for (int lw = lw0; lw <= lw1; ++lw) {
      int kj = w - ST * lw;
      const float* pb = agg + (size_t)(lh * OH_ + lw) * D_ + (ki * KS + kj) * CI;
      float4 q0 = *(const float4*)(pb);
      float4 q1 = *(const float4*)(pb + 4);
      float4 q2 = *(const float4*)(pb + 8);
      float4 q3 = *(const float4*)(pb + 12);
      t[0] += q0.x; t[1] += q0.y; t[2] += q0.z; t[3] += q0.w;
      t[4] += q1.x; t[5] += q1.y; t[6] += q1.z; t[7] += q1.w;
      t[8] += q2.x; t[9] += q2.y; t[10] += q2.z; t[11] += q2.w;
      t[12] += q3.x; t[13] += q3.y; t[14] += q3.z; t[15] += q3.w;
    }
  }
  float cnt = (float)((lh1 - lh0 + 1) * (lw1 - lw0 + 1));
  float r[CI];
#pragma unroll
  for (int c = 0; c < CI; ++c) r[c] = t[c] / (cnt * ws[SM_O + c] + ws[SB_O + c] + 1e-8f);

  size_t ob = (size_t)batch * CIN * HW + (size_t)h * W_ + w;
  if (*flag) {
    float* of = (float*)out;
#pragma unroll
    for (int o = 0; o < CIN; ++o) {
      float s = ws[RB_O + o];
#pragma unroll
      for (int c = 0; c < CI; ++c) s += srw[o * CI + c] * r[c];
      of[ob + (size_t)o * HW] = s;
    }
  } else {
    bf16* of = (bf16*)out;
#pragma unroll
    for (int o = 0; o < CIN; ++o) {
      float s = ws[RB_O + o];
#pragma unroll
      for (int c = 0; c < CI; ++c) s += srw[o * CI + c] * r[c];
      of[ob + (size_t)o * HW] = __float2bfloat16(s);
    }
  }
}

extern "C" void kernel_launch(void* const* d_in, const int* in_sizes, int n_in,
                              void* d_out, int out_size, void* d_ws, size_t ws_size,
                              hipStream_t stream)
{
  const void* x    = d_in[0];
  const void* g_w  = d_in[1];
  const void* g_b  = d_in[2];
  const void* th_w = d_in[3];
  const void* th_b = d_in[4];
  const void* ph_w = d_in[5];
  const void* ph_b = d_in[6];
  const void* m_w  = d_in[7];
  const void* m_b  = d_in[8];
  const void* r_w  = d_in[9];
  const void* r_b  = d_in[10];

  float* W = (float*)d_ws;
  int* flag = (int*)d_ws;
  ushort_t* planes = (ushort_t*)(W + B1_O);
  ushort_t* b1h = planes;
  ushort_t* b1l = planes + (size_t)N1;
  ushort_t* b2h = planes + (size_t)2 * N1;
  ushort_t* b2l = planes + (size_t)3 * N1;
  ushort_t* b3  = planes + (size_t)4 * N1;   // bf16 plane, N1 ushorts
  float* s3 = W + S3_O;

  k_detect<<<1, 64, 0, stream>>>((const unsigned short*)x, flag);
  k_prep<<<1, 256, 0, stream>>>(flag, g_w, th_w, ph_w, g_b, th_b, ph_b,
                                m_w, m_b, r_w, r_b, W);

  if (ws_size >= FULL_BYTES) {
    ushort_t* xhh = (ushort_t*)(W + REG_O);    // bf16 hi/lo x planes, dead after conv
    ushort_t* xhl = xhh + (size_t)XHSZ;
    float* sc = W + REG_O;                     // 4 x SCSLOT, aliases x planes
    float* ag = W + REG_O + XHSZ;              // 4 x AGSZ
    ushort_t* pk = (ushort_t*)ag;              // PK aliases ag (dead until k_pv)
    float* tkw = W + B1_O + N1;                // b2h region (dead after k_score)
    int*   tkp = (int*)(W + B1_O + N1 + N1 / 2);
    k_hwc<<<dim3((B_ * HW + 63) / 64), 256, 0, stream>>>(flag, x, xhh, xhl);
    k_conv3<<<dim3((HW + 127) / 128, 1, B_), 256, 0, stream>>>(
        W, xhh, xhl, b1h, b1l, b2h, b2l, b3);
    k_pack<<<dim3(368, B_), 256, 0, stream>>>(b1h, b1l, pk, 0, PKSTR);
    k_colsum<<<dim3(B_, 49), 256, 0, stream>>>(b3, s3);
    k_score<<<dim3(16, 8, B_), 256, 0, stream>>>(b2h, b2l, pk, sc, 0, SCSLOT, PKSTR);
    k_topk<<<dim3((L_ + 3) / 4, B_), 256, 0, stream>>>(sc, tkw, tkp, SCSLOT);
    k_pv<<<dim3(L_, B_), 128, 0, stream>>>(tkw, tkp, b3, s3, ag, 0, AGSZ);
    k_fold<<<dim3(64, B_), 256, 0, stream>>>(flag, W, ag, d_out, 0, AGSZ);
  } else if (ws_size >= MID_BYTES) {
    ushort_t* xhh = (ushort_t*)(W + REG_O);
    ushort_t* xhl = xhh + (size_t)XHSZ;
    float* sc = W + REG_O;
    float* ag = W + REG_O + SCSLOT;
    ushort_t* pk = (ushort_t*)ag;              // PK shares the single ag slot
    k_hwc<<<dim3((B_ * HW + 63) / 64), 256, 0, stream>>>(flag, x, xhh, xhl);
    k_conv3<<<dim3((HW + 127) / 128, 1, B_), 256, 0, stream>>>(
        W, xhh, xhl, b1h, b1l, b2h, b2l, b3);
    k_colsum<<<dim3(B_, 49), 256, 0, stream>>>(b3, s3);
    for (int b = 0; b < B_; ++b) {
      float* tkw = W + B1_O + N1 + (size_t)b * (HW * CI / 2);
      int*   tkp = (int*)(W + B1_O + N1 + N1 / 2 + (size_t)b * (HW * CI / 2));
      k_pack<<<dim3(368, 1), 256, 0, stream>>>(b1h, b1l, pk, b, 0);
      k_score<<<dim3(16, 8, 1), 256, 0, stream>>>(b2h, b2l, pk, sc, b, 0, 0);
      k_topk<<<dim3((L_ + 3) / 4, 1), 256, 0, stream>>>(sc, tkw, tkp, 0);
      k_pv<<<dim3(L_, 1), 128, 0, stream>>>(tkw, tkp, b3, s3, ag, b, 0);
      k_fold<<<dim3(64, 1), 256, 0, stream>>>(flag, W, ag, d_out, b, 0);
    }
  } else {
    float* sc = W + REG_O;
    float* ag = W + REG_O + SCSLOT;
    ushort_t* pk = (ushort_t*)ag;
    k_convF<<<dim3(4, 16, B_), dim3(32, 8, 1), 0, stream>>>(
        flag, x, g_w, g_b, th_w, th_b, ph_w, ph_b, b1h, b1l, b2h, b2l, b3);
    k_colsum<<<dim3(B_, 49), 256, 0, stream>>>(b3, s3);
    for (int b = 0; b < B_; ++b) {
      float* tkw = W + B1_O + N1 + (size_t)b * (HW * CI / 2);
      int*   tkp = (int*)(W + B1_O + N1 + N1 / 2 + (size_t)b * (HW * CI / 2));
      k_pack<<<dim3(368, 1), 256, 0, stream>>>(b1h, b1l, pk, b, 0);
      k_score<<<dim3(16, 8, 1), 256, 0, stream>>>(b2h, b2l, pk, sc, b, 0, 0);
      k_topk<<<dim3((L_ + 3) / 4, 1), 256, 0, stream>>>(sc, tkw, tkp, 0);
      k_pv<<<dim3(L_, 1), 128, 0, stream>>>(tkw, tkp, b3, s3, ag, b, 0);
      k_fold<<<dim3(64, 1), 256, 0, stream>>>(flag, W, ag, d_out, b, 0);
    }
  }
}

// Round 5
// 285.136 us; speedup vs baseline: 1.5982x; 1.1227x over previous
//
#include <hip/hip_runtime.h>
#include <hip/hip_bf16.h>

typedef __hip_bfloat16 bf16;
typedef unsigned short ushort_t;
typedef __attribute__((ext_vector_type(8))) __bf16 bfv8;
typedef __attribute__((ext_vector_type(16))) float f32x16;

#define B_   4
#define CIN  64
#define CI   16
#define H_   127
#define W_   127
#define HW   (H_*W_)
#define KS   7
#define ST   4
#define OH_  31
#define L_   961
#define D_   784
#define TOPM 100

// ---- workspace layout (float offsets) ----
#define N1   1032256          // B*HW*CI elements (one conv-out array)
#define WG_O 4
#define WT_O (WG_O + 9216)
#define WP_O (WT_O + 1024)
#define BG_O (WP_O + 1024)
#define BT_O (BG_O + 16)
#define BP_O (BT_O + 16)
#define SM_O (BP_O + 16)
#define SB_O (SM_O + 16)
#define RW_O (SB_O + 16)
#define RB_O (RW_O + 1024)
#define B1_O 12448
// planes at B1_O: b1h,b1l,b2h,b2l each N1 ushorts (2*N1 floats); b3 bf16 N1 ushorts
#define S3_O (B1_O + 3*N1)
#define WB_O (S3_O + B_*D_)   // conv MFMA B: wBh + wBl = 36864 floats
#define REG_O (WB_O + 36864)
#define XHSZ 4129024          // B*HW*64 ushorts per x plane (2 planes = XHSZ floats)
#define SROW 964              // padded Sc row stride
#define SCSLOT 926464
#define AGSZ 753424
#define TKROW 112
#define SLST 72               // LDS row stride in ushorts (conflict-free, measured r8)
// PK: unfold-packed A operand. Per plane: 7 nki x 961 rows x 112 ushorts = 753424.
// Per batch (h+l): 1506848 ushorts = 753424 floats = exactly one AGSZ slot.
#define PKPLANE 753424
#define PKSTR   1506848

#define FULL_BYTES ((size_t)(REG_O + XHSZ + 4*AGSZ) * 4)   // ~41.1 MB
#define MID_BYTES  ((size_t)(REG_O + XHSZ) * 4)            // ~29.1 MB

__device__ __forceinline__ float bf2f(bf16 v) { return __bfloat162float(v); }
__device__ __forceinline__ float bflo(unsigned u) { return __uint_as_float(u << 16); }
__device__ __forceinline__ float bfhi(unsigned u) { return __uint_as_float(u & 0xFFFF0000u); }

template <typename T> struct Ld;
template <> struct Ld<float> {
  static __device__ __forceinline__ float f(const void* p, int i) { return ((const float*)p)[i]; }
};
template <> struct Ld<bf16> {
  static __device__ __forceinline__ float f(const void* p, int i) { return bf2f(((const bf16*)p)[i]); }
};

__device__ __forceinline__ unsigned fmap(float f) {
  unsigned u = __float_as_uint(f);
  return (u & 0x80000000u) ? ~u : (u | 0x80000000u);
}
__device__ __forceinline__ float unfmap(unsigned kk) {
  unsigned u = (kk & 0x80000000u) ? (kk & 0x7fffffffu) : ~kk;
  return __uint_as_float(u);
}

// RNE fp32 -> bf16 bits, and hi/lo split
__device__ __forceinline__ ushort_t f2bf(float x) {
  unsigned u = __float_as_uint(x);
  return (ushort_t)((u + 0x7FFFu + ((u >> 16) & 1u)) >> 16);
}
__device__ __forceinline__ void splitbf(float x, ushort_t& h, ushort_t& l) {
  h = f2bf(x);
  float hf = __uint_as_float(((unsigned)h) << 16);
  l = f2bf(x - hf);
}

// -------- dtype detector: flag=1 -> fp32 buffers, flag=0 -> bf16 -----------------
__global__ void k_detect(const unsigned short* __restrict__ xh, int* __restrict__ flag) {
  int tid = threadIdx.x;  // 64
  int c = 0;
#pragma unroll
  for (int j = 0; j < 2; ++j) {
    unsigned u = xh[tid * 2 + j];
    unsigned e = (u >> 7) & 0xFF;
    if (e >= 134) c++;
  }
#pragma unroll
  for (int o = 32; o; o >>= 1) c += __shfl_down(c, o);
  if (tid == 0) *flag = (c >= 8) ? 1 : 0;
}

// -------- weight prep: grid-parallel (was 1 block = 44.5us serial bottleneck) ----
// All outputs independent; grid-stride loops over 64 blocks. Writes disjoint.
#define LDW(ptr, i) (f ? ((const float*)(ptr))[i] : bf2f(((const bf16*)(ptr))[i]))
__global__ __launch_bounds__(256) void k_prep(
    const int* __restrict__ flag,
    const void* g_w, const void* t_w, const void* p_w,
    const void* g_b, const void* t_b, const void* p_b,
    const void* m_w, const void* m_b, const void* r_w, const void* r_b,
    float* __restrict__ ws)
{
  int f = *flag;
  int gid = blockIdx.x * 256 + threadIdx.x;
  int gs = gridDim.x * 256;
  for (int i = gid; i < 9216; i += gs) {
    int o = i & 15, t = i >> 4, c = t & 63, tap = t >> 6;
    ws[WG_O + i] = LDW(g_w, (o * 64 + c) * 9 + tap);
  }
  for (int i = gid; i < 1024; i += gs) {
    int o = i & 15, c = i >> 4;
    ws[WT_O + i] = LDW(t_w, o * 64 + c);
    ws[WP_O + i] = LDW(p_w, o * 64 + c);
  }
  if (gid < 16) {
    ws[BG_O + gid] = LDW(g_b, gid);
    ws[BT_O + gid] = LDW(t_b, gid);
    ws[BP_O + gid] = LDW(p_b, gid);
    float s = 0.f;
    for (int c = 0; c < 64; ++c) s += LDW(m_w, gid * 64 + c);
    ws[SM_O + gid] = s;
    ws[SB_O + gid] = LDW(m_b, gid);
  }
  for (int i = gid; i < 1024; i += gs) ws[RW_O + i] = LDW(r_w, i);
  if (gid >= 64 && gid < 128) ws[RB_O + gid - 64] = LDW(r_b, gid - 64);
  // conv MFMA B, split hi/lo: wB[tap][col64][c64]
  ushort_t* wBh = (ushort_t*)(ws + WB_O);
  ushort_t* wBl = wBh + 9 * 64 * 64;
  for (int i = gid; i < 9 * 64 * 64; i += gs) {
    int c = i & 63, t = i >> 6, col = t & 63, tap = t >> 6;
    float v = 0.f;
    if (col < 16) v = LDW(g_w, (col * 64 + c) * 9 + tap);
    else if (col < 32) { if (tap == 4) v = LDW(t_w, (col - 16) * 64 + c); }
    else if (col < 48) { if (tap == 4) v = LDW(p_w, (col - 32) * 64 + c); }
    ushort_t h, l; splitbf(v, h, l);
    wBh[i] = h; wBl[i] = l;
  }
}

// -------- x [B,64,H,W] -> HWC bf16 hi/lo planes ----------------------------------
__global__ __launch_bounds__(256) void k_hwc(
    const int* __restrict__ flag, const void* __restrict__ x,
    ushort_t* __restrict__ xhh, ushort_t* __restrict__ xhl)
{
  __shared__ float tile[64][65];
  int pix0 = blockIdx.x * 64;
  int tid = threadIdx.x;
  int g = tid >> 6, p = tid & 63;
  int pix = pix0 + p;
  bool ok = pix < B_ * HW;
  int bb = ok ? pix / HW : 0;
  int r  = ok ? pix - bb * HW : 0;
  if (*flag) {
    const float* xf = (const float*)x;
    for (int c = g * 16; c < g * 16 + 16; ++c)
      tile[p][c] = ok ? xf[((size_t)bb * CIN + c) * HW + r] : 0.f;
  } else {
    const bf16* xb = (const bf16*)x;
    for (int c = g * 16; c < g * 16 + 16; ++c)
      tile[p][c] = ok ? bf2f(xb[((size_t)bb * CIN + c) * HW + r]) : 0.f;
  }
  __syncthreads();
  int c2 = tid & 63, pg = tid >> 6;
  for (int k = 0; k < 16; ++k) {
    int p2 = pg * 16 + k;
    int pix2 = pix0 + p2;
    if (pix2 < B_ * HW) {
      ushort_t h, l; splitbf(tile[p2][c2], h, l);
      xhh[(size_t)pix2 * 64 + c2] = h;
      xhl[(size_t)pix2 * 64 + c2] = l;
    }
  }
}

// -------- unified split-bf16 MFMA conv, 128-pixel tile (round-0 verbatim) --------
__global__ __launch_bounds__(256) void k_conv3(
    const float* __restrict__ ws,
    const ushort_t* __restrict__ xhh, const ushort_t* __restrict__ xhl,
    ushort_t* __restrict__ b1h, ushort_t* __restrict__ b1l,
    ushort_t* __restrict__ b2h, ushort_t* __restrict__ b2l,
    ushort_t* __restrict__ b3)
{
  __shared__ ushort_t sAh[128 * SLST], sAl[128 * SLST];
  __shared__ ushort_t sBh[64 * SLST],  sBl[64 * SLST];
  int bz = blockIdx.z;
  int px0 = blockIdx.x * 128;
  int tid = threadIdx.x, lane = tid & 63, wv = tid >> 6;

  int pix0 = px0 + lane, pix1 = px0 + lane + 64;
  bool pok0 = pix0 < HW, pok1 = pix1 < HW;
  int ph0 = pok0 ? pix0 / W_ : 0, pw0 = pok0 ? pix0 - ph0 * W_ : 0;
  int ph1 = pok1 ? pix1 / W_ : 0, pw1 = pok1 ? pix1 - ph1 * W_ : 0;
  const ushort_t* xplane = ((wv == 0) ? xhh : xhl) + (size_t)bz * HW * 64;
  const ushort_t* wBh_ = (const ushort_t*)(ws + WB_O);
  const ushort_t* bsrc = (wv == 2) ? wBh_ : (wBh_ + 9 * 64 * 64);
  ushort_t* dplane = (wv == 0) ? sAh : (wv == 1) ? sAl : (wv == 2) ? sBh : sBl;
  ushort_t* drow0 = dplane + lane * SLST;
  ushort_t* drow1 = dplane + (lane + 64) * SLST;   // wv<2 only

  int fr = lane & 31, kh = (lane >> 5) << 3;
  int mt = (wv >> 1) << 1;
  int aoff0 = (mt * 32 + fr) * SLST + kh;
  int aoff1 = ((mt + 1) * 32 + fr) * SLST + kh;
  int boff  = (((wv & 1) << 5) + fr) * SLST + kh;

  f32x16 acc0 = {0.f,0.f,0.f,0.f,0.f,0.f,0.f,0.f,0.f,0.f,0.f,0.f,0.f,0.f,0.f,0.f};
  f32x16 acc1 = {0.f,0.f,0.f,0.f,0.f,0.f,0.f,0.f,0.f,0.f,0.f,0.f,0.f,0.f,0.f,0.f};
  const int4 z4 = make_int4(0, 0, 0, 0);
  int4 v0 = z4, v1 = z4, v2 = z4, v3 = z4, v4 = z4, v5 = z4, v6 = z4, v7 = z4;
  int4 u0 = z4, u1 = z4, u2 = z4, u3 = z4, u4 = z4, u5 = z4, u6 = z4, u7 = z4;

  // prefetch tap 0 (dh=-1, dw=-1)
  if (wv < 2) {
    int hh = ph0 - 1, ww = pw0 - 1;
    if (pok0 && hh >= 0 && ww >= 0) {
      const int4* s = (const int4*)(xplane + (size_t)(hh * W_ + ww) * 64);
      v0 = s[0]; v1 = s[1]; v2 = s[2]; v3 = s[3]; v4 = s[4]; v5 = s[5]; v6 = s[6]; v7 = s[7];
    }
    int hh1 = ph1 - 1, ww1 = pw1 - 1;
    if (pok1 && hh1 >= 0 && ww1 >= 0) {
      const int4* s = (const int4*)(xplane + (size_t)(hh1 * W_ + ww1) * 64);
      u0 = s[0]; u1 = s[1]; u2 = s[2]; u3 = s[3]; u4 = s[4]; u5 = s[5]; u6 = s[6]; u7 = s[7];
    }
  } else {
    const int4* s = (const int4*)(bsrc + (size_t)lane * 64);
    v0 = s[0]; v1 = s[1]; v2 = s[2]; v3 = s[3]; v4 = s[4]; v5 = s[5]; v6 = s[6]; v7 = s[7];
  }

  for (int r = 0; r < 9; ++r) {
    __syncthreads();
    *(int4*)(drow0 + 0)  = v0;  *(int4*)(drow0 + 8)  = v1;
    *(int4*)(drow0 + 16) = v2;  *(int4*)(drow0 + 24) = v3;
    *(int4*)(drow0 + 32) = v4;  *(int4*)(drow0 + 40) = v5;
    *(int4*)(drow0 + 48) = v6;  *(int4*)(drow0 + 56) = v7;
    if (wv < 2) {
      *(int4*)(drow1 + 0)  = u0;  *(int4*)(drow1 + 8)  = u1;
      *(int4*)(drow1 + 16) = u2;  *(int4*)(drow1 + 24) = u3;
      *(int4*)(drow1 + 32) = u4;  *(int4*)(drow1 + 40) = u5;
      *(int4*)(drow1 + 48) = u6;  *(int4*)(drow1 + 56) = u7;
    }
    __syncthreads();
    if (r < 8) {
      int rn = r + 1;
      int dh = rn / 3 - 1, dw = rn % 3 - 1;
      if (wv < 2) {
        int hh = ph0 + dh, ww = pw0 + dw;
        if (pok0 && (unsigned)hh < (unsigned)H_ && (unsigned)ww < (unsigned)W_) {
          const int4* s = (const int4*)(xplane + (size_t)(hh * W_ + ww) * 64);
          v0 = s[0]; v1 = s[1]; v2 = s[2]; v3 = s[3]; v4 = s[4]; v5 = s[5]; v6 = s[6]; v7 = s[7];
        } else {
          v0 = z4; v1 = z4; v2 = z4; v3 = z4; v4 = z4; v5 = z4; v6 = z4; v7 = z4;
        }
        int hh1 = ph1 + dh, ww1 = pw1 + dw;
        if (pok1 && (unsigned)hh1 < (unsigned)H_ && (unsigned)ww1 < (unsigned)W_) {
          const int4* s = (const int4*)(xplane + (size_t)(hh1 * W_ + ww1) * 64);
          u0 = s[0]; u1 = s[1]; u2 = s[2]; u3 = s[3]; u4 = s[4]; u5 = s[5]; u6 = s[6]; u7 = s[7];
        } else {
          u0 = z4; u1 = z4; u2 = z4; u3 = z4; u4 = z4; u5 = z4; u6 = z4; u7 = z4;
        }
      } else {
        const int4* s = (const int4*)(bsrc + ((size_t)rn * 64 + lane) * 64);
        v0 = s[0]; v1 = s[1]; v2 = s[2]; v3 = s[3]; v4 = s[4]; v5 = s[5]; v6 = s[6]; v7 = s[7];
      }
    }
#pragma unroll
    for (int t = 0; t < 4; ++t) {
      bfv8 ah0 = *(const bfv8*)(sAh + aoff0 + t * 16);
      bfv8 al0 = *(const bfv8*)(sAl + aoff0 + t * 16);
      bfv8 ah1 = *(const bfv8*)(sAh + aoff1 + t * 16);
      bfv8 al1 = *(const bfv8*)(sAl + aoff1 + t * 16);
      bfv8 bh  = *(const bfv8*)(sBh + boff + t * 16);
      bfv8 bl  = *(const bfv8*)(sBl + boff + t * 16);
      acc0 = __builtin_amdgcn_mfma_f32_32x32x16_bf16(al0, bh, acc0, 0, 0, 0);
      acc0 = __builtin_amdgcn_mfma_f32_32x32x16_bf16(ah0, bl, acc0, 0, 0, 0);
      acc0 = __builtin_amdgcn_mfma_f32_32x32x16_bf16(ah0, bh, acc0, 0, 0, 0);
      acc1 = __builtin_amdgcn_mfma_f32_32x32x16_bf16(al1, bh, acc1, 0, 0, 0);
      acc1 = __builtin_amdgcn_mfma_f32_32x32x16_bf16(ah1, bl, acc1, 0, 0, 0);
      acc1 = __builtin_amdgcn_mfma_f32_32x32x16_bf16(ah1, bh, acc1, 0, 0, 0);
    }
  }

  int nw = ((wv & 1) << 5) + fr;
#pragma unroll
  for (int s = 0; s < 2; ++s) {
    int mbase = (mt + s) * 32;
#pragma unroll
    for (int r = 0; r < 16; ++r) {
      int m = mbase + (r & 3) + ((r >> 2) << 3) + ((lane >> 5) << 2);
      int p2 = px0 + m;
      if (p2 >= HW) continue;
      size_t ob = ((size_t)bz * HW + p2) * 16;
      float val = s ? acc1[r] : acc0[r];
      if (nw < 16) {
        ushort_t h2, l2; splitbf(val + ws[BG_O + nw], h2, l2);
        b1h[ob + nw] = h2; b1l[ob + nw] = l2;
      } else if (nw < 32) {
        int o = nw - 16; ushort_t h2, l2; splitbf(val + ws[BT_O + o], h2, l2);
        b2h[ob + o] = h2; b2l[ob + o] = l2;
      } else if (nw < 48) {
        int o = nw - 32; b3[ob + o] = f2bf(val + ws[BP_O + o]);
      }
    }
  }
}

// -------- fallback conv (LOW tier), dtype-templated VALU -------------------------
template <typename T>
__device__ __forceinline__ void convF_body(
    const void* x, const void* g_w, const void* g_b,
    const void* t_w, const void* t_b, const void* p_w, const void* p_b,
    ushort_t* b1h, ushort_t* b1l, ushort_t* b2h, ushort_t* b2l, ushort_t* b3,
    float* sgw, float* stw, float* spw)
{
  int tid = threadIdx.y * 32 + threadIdx.x;
  for (int i = tid; i < CI * CIN * 9; i += 256) sgw[i] = Ld<T>::f(g_w, i);
  for (int i = tid; i < CI * CIN; i += 256) { stw[i] = Ld<T>::f(t_w, i); spw[i] = Ld<T>::f(p_w, i); }
  __syncthreads();

  int w = blockIdx.x * 32 + threadIdx.x;
  int h = blockIdx.y * 8 + threadIdx.y;
  int b = blockIdx.z;
  if (w >= W_ || h >= H_) return;

  float a1[CI], a2[CI], a3[CI];
#pragma unroll
  for (int o = 0; o < CI; ++o) { a1[o] = 0.f; a2[o] = 0.f; a3[o] = 0.f; }

  const size_t xb = (size_t)b * CIN * HW;
  for (int c = 0; c < CIN; ++c) {
    float xv[9];
#pragma unroll
    for (int dh = 0; dh < 3; ++dh) {
      int hh = h + dh - 1;
      bool rok = ((unsigned)hh < (unsigned)H_);
#pragma unroll
      for (int dw = 0; dw < 3; ++dw) {
        int ww = w + dw - 1;
        bool ok = rok && ((unsigned)ww < (unsigned)W_);
        xv[dh * 3 + dw] = ok ? Ld<T>::f(x, (int)(xb + (size_t)c * HW + hh * W_ + ww)) : 0.f;
      }
    }
    float xc = xv[4];
#pragma unroll
    for (int o = 0; o < CI; ++o) {
      const float* gg = &sgw[(o * CIN + c) * 9];
      float s = gg[0]*xv[0] + gg[1]*xv[1] + gg[2]*xv[2]
              + gg[3]*xv[3] + gg[4]*xv[4] + gg[5]*xv[5]
              + gg[6]*xv[6] + gg[7]*xv[7] + gg[8]*xv[8];
      a1[o] += s;
      a2[o] += stw[o * CIN + c] * xc;
      a3[o] += spw[o * CIN + c] * xc;
    }
  }
  size_t base = ((size_t)b * HW + h * W_ + w) * CI;
#pragma unroll
  for (int o = 0; o < CI; ++o) {
    float v1 = a1[o] + Ld<T>::f(g_b, o);
    float v2 = a2[o] + Ld<T>::f(t_b, o);
    ushort_t hh2, ll2;
    splitbf(v1, hh2, ll2); b1h[base + o] = hh2; b1l[base + o] = ll2;
    splitbf(v2, hh2, ll2); b2h[base + o] = hh2; b2l[base + o] = ll2;
    b3[base + o] = f2bf(a3[o] + Ld<T>::f(p_b, o));
  }
}

__global__ __launch_bounds__(256) void k_convF(
    const int* __restrict__ flag, const void* x,
    const void* g_w, const void* g_b, const void* t_w, const void* t_b,
    const void* p_w, const void* p_b,
    ushort_t* __restrict__ b1h, ushort_t* __restrict__ b1l,
    ushort_t* __restrict__ b2h, ushort_t* __restrict__ b2l,
    ushort_t* __restrict__ b3)
{
  __shared__ float sgw[CI * CIN * 9];
  __shared__ float stw[CI * CIN];
  __shared__ float spw[CI * CIN];
  if (*flag) convF_body<float>(x, g_w, g_b, t_w, t_b, p_w, p_b, b1h, b1l, b2h, b2l, b3, sgw, stw, spw);
  else       convF_body<bf16 >(x, g_w, g_b, t_w, t_b, p_w, p_b, b1h, b1l, b2h, b2l, b3, sgw, stw, spw);
}

// -------- S3[b, pos*16+c] = sum over patches of b3 (bf16 src, fp32 acc) ----------
__global__ __launch_bounds__(256) void k_colsum(const ushort_t* __restrict__ b3, float* __restrict__ S3)
{
  __shared__ float red[16][17];
  int b = blockIdx.x, pos = blockIdx.y;
  int ki = pos / 7, kj = pos % 7;
  int c = threadIdx.x & 15, chunk = threadIdx.x >> 4;
  const ushort_t* B3 = b3 + (size_t)b * HW * CI;
  float s = 0.f;
  for (int l = chunk; l < L_; l += 16) {
    int lh = l / OH_, lw = l % OH_;
    s += bflo((unsigned)B3[((lh * ST + ki) * W_ + lw * ST + kj) * CI + c]);
  }
  red[chunk][c] = s;
  __syncthreads();
  if (threadIdx.x < 16) {
    float t = 0.f;
#pragma unroll
    for (int k = 0; k < 16; ++k) t += red[k][threadIdx.x];
    S3[(b * 49 + pos) * 16 + threadIdx.x] = t;
  }
}

// -------- pack A operand: PK[plane][nki][row][112] = b1 patch-row segments -------
// Pure contiguous copy: 14 int4 per (row,nki) read, coalesced write. Exact bits.
__global__ __launch_bounds__(256) void k_pack(
    const ushort_t* __restrict__ b1h, const ushort_t* __restrict__ b1l,
    ushort_t* __restrict__ pk, int b0, unsigned pkstride_z)
{
  int idx = blockIdx.x * 256 + threadIdx.x;
  if (idx >= 961 * 98) return;
  int row = idx / 98, rem = idx - row * 98;
  int nki = rem / 14, q = rem - nki * 14;
  int slh = row / OH_, slw = row - slh * OH_;
  int src = ((slh * ST) * W_ + slw * ST + nki * W_) * 16 + q * 8;
  int dst = (nki * 961 + row) * 112 + q * 8;
  int batch = b0 + blockIdx.y;
  size_t poff = (size_t)batch * HW * CI;
  ushort_t* pkb = pk + (size_t)blockIdx.y * pkstride_z;
  *(int4*)(pkb + dst)           = *(const int4*)(b1h + poff + src);
  *(int4*)(pkb + PKPLANE + dst) = *(const int4*)(b1l + poff + src);
}

// -------- score GEMM via split-bf16 MFMA, 128x64 tile ----------------------------
// A staged cooperatively from PK (one base + imm offsets, named regs -> no spill,
// consecutive lanes contiguous -> ~3x fewer cache-line requests). B per-lane-row,
// LDS layout/MFMA/epilogue byte-identical to the 322us round-0 kernel.
__global__ __launch_bounds__(256) void k_score(
    const ushort_t* __restrict__ b2h, const ushort_t* __restrict__ b2l,
    const ushort_t* __restrict__ pk,
    float* __restrict__ scb, int b0, unsigned scstride_z, unsigned pkstride_z)
{
  __shared__ ushort_t sAh[128 * SLST], sAl[128 * SLST];
  __shared__ ushort_t sBh[64 * SLST],  sBl[64 * SLST];
  int batch = b0 + blockIdx.z;
  size_t poff_g = (size_t)batch * HW * CI;
  float* Sc = scb + (size_t)blockIdx.z * scstride_z;

  int tid = threadIdx.x;
  int m0 = blockIdx.y * 128, n0 = blockIdx.x * 64;
  int lane = tid & 63;
  int wv = tid >> 6;
  int grp = lane >> 3, ch = lane & 7;

  const ushort_t* pkb = pk + (size_t)blockIdx.z * pkstride_z + (size_t)(wv & 1) * PKPLANE;

  // B-side per-lane-row base (wv>=2)
  int srow = n0 + lane;  if (srow > L_ - 1) srow = L_ - 1;
  int slh = srow / OH_, slw = srow - slh * OH_;
  int sbase = (slh * ST) * W_ + slw * ST;
  const ushort_t* splane = (wv == 2) ? (b2h + poff_g) : (b2l + poff_g);
  ushort_t* dplane = (wv == 0) ? sAh : (wv == 1) ? sAl : (wv == 2) ? sBh : sBl;
  ushort_t* drowB = dplane + lane * SLST;

  int fr = lane & 31;
  int kh = (lane >> 5) << 3;
  int mt = (wv >> 1) << 1;                         // first m-subtile: 0 or 2
  int aoff0 = (mt * 32 + fr) * SLST + kh;
  int aoff1 = ((mt + 1) * 32 + fr) * SLST + kh;
  int boff  = (((wv & 1) << 5) + fr) * SLST + kh;

  f32x16 acc0 = {0.f,0.f,0.f,0.f,0.f,0.f,0.f,0.f,0.f,0.f,0.f,0.f,0.f,0.f,0.f,0.f};
  f32x16 acc1 = {0.f,0.f,0.f,0.f,0.f,0.f,0.f,0.f,0.f,0.f,0.f,0.f,0.f,0.f,0.f,0.f};

  int4 pv0, pv1, pv2, pv3, pv4, pv5, pv6, pv7;
  int4 pv8, pv9, pv10, pv11, pv12, pv13, pv14, pv15;

#define LA(j) pv##j = *(const int4*)(pks + (size_t)min(m0 + 8*j + grp, 960) * 112)
#define LA_ALL LA(0); LA(1); LA(2); LA(3); LA(4); LA(5); LA(6); LA(7); \
               LA(8); LA(9); LA(10); LA(11); LA(12); LA(13); LA(14); LA(15)
#define WA(j) *(int4*)(d0 + (j) * 8 * SLST) = pv##j
#define WA_ALL WA(0); WA(1); WA(2); WA(3); WA(4); WA(5); WA(6); WA(7); \
               WA(8); WA(9); WA(10); WA(11); WA(12); WA(13); WA(14); WA(15)

  // initial prefetch: rn=0 (nki=0, even)
  if (wv < 2) {
    const ushort_t* pks = pkb + ch * 8;
    LA_ALL;
  } else {
    const int4* s0 = (const int4*)(splane + (size_t)sbase * 16);
    pv0 = s0[0]; pv1 = s0[1]; pv2 = s0[2]; pv3 = s0[3];
    pv4 = s0[4]; pv5 = s0[5]; pv6 = s0[6]; pv7 = s0[7];
  }

  for (int r = 0; r < 14; ++r) {
    int half = r & 1;
    __syncthreads();
    if (wv < 2) {
      ushort_t* d0 = dplane + grp * SLST + ch * 8;
      if (!half) { WA_ALL; }
      else if (ch < 6) { WA_ALL; }
    } else {
      *(int4*)(drowB + 0)  = pv0;  *(int4*)(drowB + 8)  = pv1;
      *(int4*)(drowB + 16) = pv2;  *(int4*)(drowB + 24) = pv3;
      *(int4*)(drowB + 32) = pv4;  *(int4*)(drowB + 40) = pv5;
      if (!half) { *(int4*)(drowB + 48) = pv6; *(int4*)(drowB + 56) = pv7; }
    }
    __syncthreads();
    if (r < 13) {
      int rn = r + 1;
      int nki = rn >> 1, odd = rn & 1;
      if (wv < 2) {
        const ushort_t* pks = pkb + (size_t)nki * (961 * 112) + odd * 64 + ch * 8;
        if (!odd) { LA_ALL; }
        else if (ch < 6) { LA_ALL; }
      } else {
        int nkj0 = odd * 4;
        const int4* s0 = (const int4*)(splane + (size_t)(sbase + nki * W_ + nkj0) * 16);
        pv0 = s0[0]; pv1 = s0[1]; pv2 = s0[2]; pv3 = s0[3]; pv4 = s0[4]; pv5 = s0[5];
        if (!odd) { pv6 = s0[6]; pv7 = s0[7]; }
      }
    }
    if (!half) {
#pragma unroll
      for (int t = 0; t < 4; ++t) {
        bfv8 ah0 = *(const bfv8*)(sAh + aoff0 + t * 16);
        bfv8 al0 = *(const bfv8*)(sAl + aoff0 + t * 16);
        bfv8 ah1 = *(const bfv8*)(sAh + aoff1 + t * 16);
        bfv8 al1 = *(const bfv8*)(sAl + aoff1 + t * 16);
        bfv8 bh  = *(const bfv8*)(sBh + boff + t * 16);
        bfv8 bl  = *(const bfv8*)(sBl + boff + t * 16);
        acc0 = __builtin_amdgcn_mfma_f32_32x32x16_bf16(al0, bh, acc0, 0, 0, 0);
        acc0 = __builtin_amdgcn_mfma_f32_32x32x16_bf16(ah0, bl, acc0, 0, 0, 0);
        acc0 = __builtin_amdgcn_mfma_f32_32x32x16_bf16(ah0, bh, acc0, 0, 0, 0);
        acc1 = __builtin_amdgcn_mfma_f32_32x32x16_bf16(al1, bh, acc1, 0, 0, 0);
        acc1 = __builtin_amdgcn_mfma_f32_32x32x16_bf16(ah1, bl, acc1, 0, 0, 0);
        acc1 = __builtin_amdgcn_mfma_f32_32x32x16_bf16(ah1, bh, acc1, 0, 0, 0);
      }
    } else {
#pragma unroll
      for (int t = 0; t < 3; ++t) {
        bfv8 ah0 = *(const bfv8*)(sAh + aoff0 + t * 16);
        bfv8 al0 = *(const bfv8*)(sAl + aoff0 + t * 16);
        bfv8 ah1 = *(const bfv8*)(sAh + aoff1 + t * 16);
        bfv8 al1 = *(const bfv8*)(sAl + aoff1 + t * 16);
        bfv8 bh  = *(const bfv8*)(sBh + boff + t * 16);
        bfv8 bl  = *(const bfv8*)(sBl + boff + t * 16);
        acc0 = __builtin_amdgcn_mfma_f32_32x32x16_bf16(al0, bh, acc0, 0, 0, 0);
        acc0 = __builtin_amdgcn_mfma_f32_32x32x16_bf16(ah0, bl, acc0, 0, 0, 0);
        acc0 = __builtin_amdgcn_mfma_f32_32x32x16_bf16(ah0, bh, acc0, 0, 0, 0);
        acc1 = __builtin_amdgcn_mfma_f32_32x32x16_bf16(al1, bh, acc1, 0, 0, 0);
        acc1 = __builtin_amdgcn_mfma_f32_32x32x16_bf16(ah1, bl, acc1, 0, 0, 0);
        acc1 = __builtin_amdgcn_mfma_f32_32x32x16_bf16(ah1, bh, acc1, 0, 0, 0);
      }
    }
  }
#undef LA
#undef LA_ALL
#undef WA
#undef WA_ALL

  int nw = n0 + ((wv & 1) << 5) + fr;
  if (nw < L_) {
    int mw0 = m0 + mt * 32;
#pragma unroll
    for (int r = 0; r < 16; ++r) {
      int m = mw0 + (r & 3) + ((r >> 2) << 3) + ((lane >> 5) << 2);
      if (m < L_) Sc[(size_t)m * SROW + nw] = acc0[r];
    }
    int mw1 = m0 + (mt + 1) * 32;
#pragma unroll
    for (int r = 0; r < 16; ++r) {
      int m = mw1 + (r & 3) + ((r >> 2) << 3) + ((lane >> 5) << 2);
      if (m < L_) Sc[(size_t)m * SROW + nw] = acc1[r];
    }
  }
}

// -------- top-100 + softmax weights: 4 rows per block (1 wave each) --------------
__global__ __launch_bounds__(256) void k_topk(
    const float* __restrict__ scb, float* __restrict__ tkw, int* __restrict__ tkp,
    unsigned scstride_z)
{
  __shared__ float swv[4][TOPM];
  __shared__ int spx[4][TOPM];
  int tid = threadIdx.x;
  int wvi = tid >> 6, lane = tid & 63;
  int l = blockIdx.x * 4 + wvi;
  if (l > L_ - 1) l = L_ - 1;        // clamp: duplicate rows write identical data
  int bz = blockIdx.y;
  const float4* row4 = (const float4*)(scb + (size_t)bz * scstride_z + (size_t)l * SROW);
  int trow = (bz * L_ + l) * TKROW;

  unsigned k[16];
#pragma unroll
  for (int q = 0; q < 4; ++q) {
    float4 v = row4[q * 64 + lane];
    int ib = (q * 64 + lane) * 4;
    k[q * 4 + 0] = (ib + 0 < L_) ? fmap(v.x) : 0u;
    k[q * 4 + 1] = (ib + 1 < L_) ? fmap(v.y) : 0u;
    k[q * 4 + 2] = (ib + 2 < L_) ? fmap(v.z) : 0u;
    k[q * 4 + 3] = (ib + 3 < L_) ? fmap(v.w) : 0u;
  }

  unsigned mk = 0;
#pragma unroll
  for (int r = 0; r < 16; ++r) mk = max(mk, k[r]);
#pragma unroll
  for (int o = 32; o; o >>= 1) mk = max(mk, (unsigned)__shfl_down((int)mk, o));
  mk = (unsigned)__shfl((int)mk, 0);
  float vmax = unfmap(mk);

  unsigned alive = 0xFFFFu;
  unsigned prefix = 0; int base = 0;
  for (int bit = 30; bit >= 0; bit -= 2) {
    int c1 = 0, c2 = 0, c3 = 0;
#pragma unroll
    for (int r = 0; r < 16; ++r) {
      if ((alive >> r) & 1) {
        unsigned f = (k[r] >> bit) & 3u;
        c3 += (f == 3); c2 += (f >= 2); c1 += (f >= 1);
      }
    }
    int p = c3 | (c2 << 10) | (c1 << 20);
#pragma unroll
    for (int o = 32; o; o >>= 1) p += __shfl_down(p, o);
    p = __shfl(p, 0);
    int n3 = p & 1023, n2 = (p >> 10) & 1023, n1 = (p >> 20) & 1023;
    unsigned ch;
    if (base + n3 >= TOPM) ch = 3;
    else if (base + n2 >= TOPM) { ch = 2; base += n3; }
    else if (base + n1 >= TOPM) { ch = 1; base += n2; }
    else { ch = 0; base += n1; }
    prefix |= ch << bit;
#pragma unroll
    for (int r = 0; r < 16; ++r) {
      if ((alive >> r) & 1) {
        unsigned f = (k[r] >> bit) & 3u;
        if (f != ch) alive &= ~(1u << r);
      }
    }
  }
  int nA = base;
  int needT = TOPM - nA;

  int cA = 0, cT = 0;
#pragma unroll
  for (int r = 0; r < 16; ++r) { cA += (k[r] > prefix); cT += (k[r] == prefix); }
  int pk = cA | (cT << 16);
  int incl = pk;
#pragma unroll
  for (int o = 1; o < 64; o <<= 1) { int t = __shfl_up(incl, o); if (lane >= o) incl += t; }
  int excl = incl - pk;
  int tA = excl & 0xFFFF, tT = excl >> 16;

  float M = fmaxf(10.f * vmax, 0.f);
  float e0 = expf(-M);
  float z = 0.f;
#pragma unroll
  for (int r = 0; r < 16; ++r) {
    unsigned kk = k[r];
    int slot = -1;
    if (kk > prefix) slot = tA++;
    else if (kk == prefix) { if (tT < needT) slot = nA + tT; tT++; }
    if (slot >= 0) {
      float v = unfmap(kk);
      float wv = expf(10.f * v - M);
      swv[wvi][slot] = wv; z += wv;
      int gi = 256 * (r >> 2) + 4 * lane + (r & 3);
      int lh = gi / OH_, lw = gi - lh * OH_;
      spx[wvi][slot] = ((lh * ST) * W_ + lw * ST) * CI;
    }
  }
#pragma unroll
  for (int o = 32; o; o >>= 1) z += __shfl_down(z, o);
  z = __shfl(z, 0);
  float Z = z + (float)(L_ - TOPM) * e0;
  float invZ = 1.f / Z;
  float w0 = e0 / Z;
  __syncthreads();
#pragma unroll
  for (int s0 = 0; s0 < 2; ++s0) {
    int s = lane + 64 * s0;
    if (s < TOPM) {
      tkw[trow + s] = swv[wvi][s] * invZ - w0;
      tkp[trow + s] = spx[wvi][s];
    }
  }
  if (lane == 0) tkw[trow + TOPM] = w0;
}

// -------- PV gather (bf16 b3, uint4 full-line): 98 lanes x 8 channels ------------
__global__ __launch_bounds__(128) void k_pv(
    const float* __restrict__ tkw, const int* __restrict__ tkp,
    const ushort_t* __restrict__ b3, const float* __restrict__ s3,
    float* __restrict__ agb, int b0, unsigned agstride_z)
{
  int l = blockIdx.x, bz = blockIdx.y;
  int batch = b0 + bz;
  int trow = (bz * L_ + l) * TKROW;
  const ushort_t* B3 = b3 + (size_t)batch * HW * CI;
  const float* S3 = s3 + (size_t)batch * D_;
  float* agg = agb + (size_t)bz * agstride_z;
  int tid = threadIdx.x;
  if (tid >= 98) return;

  float w0 = tkw[trow + TOPM];
  int pos = tid >> 1;
  int c0 = (tid & 1) << 3;                 // 0 or 8
  int ki = pos / 7, kj = pos - (pos / 7) * 7;
  int poff = (ki * W_ + kj) * CI + c0;

  float a0 = 0.f, a1 = 0.f, a2 = 0.f, a3 = 0.f;
  float a4 = 0.f, a5 = 0.f, a6 = 0.f, a7 = 0.f;
  for (int j0 = 0; j0 < TOPM; j0 += 4) {
    float w_0 = tkw[trow + j0 + 0];
    float w_1 = tkw[trow + j0 + 1];
    float w_2 = tkw[trow + j0 + 2];
    float w_3 = tkw[trow + j0 + 3];
    int p_0 = tkp[trow + j0 + 0];
    int p_1 = tkp[trow + j0 + 1];
    int p_2 = tkp[trow + j0 + 2];
    int p_3 = tkp[trow + j0 + 3];
    const uint4 q0 = *(const uint4*)(B3 + p_0 + poff);
    const uint4 q1 = *(const uint4*)(B3 + p_1 + poff);
    const uint4 q2 = *(const uint4*)(B3 + p_2 + poff);
    const uint4 q3 = *(const uint4*)(B3 + p_3 + poff);
    a0 += w_0 * bflo(q0.x); a1 += w_0 * bfhi(q0.x); a2 += w_0 * bflo(q0.y); a3 += w_0 * bfhi(q0.y);
    a4 += w_0 * bflo(q0.z); a5 += w_0 * bfhi(q0.z); a6 += w_0 * bflo(q0.w); a7 += w_0 * bfhi(q0.w);
    a0 += w_1 * bflo(q1.x); a1 += w_1 * bfhi(q1.x); a2 += w_1 * bflo(q1.y); a3 += w_1 * bfhi(q1.y);
    a4 += w_1 * bflo(q1.z); a5 += w_1 * bfhi(q1.z); a6 += w_1 * bflo(q1.w); a7 += w_1 * bfhi(q1.w);
    a0 += w_2 * bflo(q2.x); a1 += w_2 * bfhi(q2.x); a2 += w_2 * bflo(q2.y); a3 += w_2 * bfhi(q2.y);
    a4 += w_2 * bflo(q2.z); a5 += w_2 * bfhi(q2.z); a6 += w_2 * bflo(q2.w); a7 += w_2 * bfhi(q2.w);
    a0 += w_3 * bflo(q3.x); a1 += w_3 * bfhi(q3.x); a2 += w_3 * bflo(q3.y); a3 += w_3 * bfhi(q3.y);
    a4 += w_3 * bflo(q3.z); a5 += w_3 * bfhi(q3.z); a6 += w_3 * bflo(q3.w); a7 += w_3 * bfhi(q3.w);
  }
  const float4 s40 = *(const float4*)(S3 + tid * 8);
  const float4 s41 = *(const float4*)(S3 + tid * 8 + 4);
  a0 += w0 * s40.x; a1 += w0 * s40.y; a2 += w0 * s40.z; a3 += w0 * s40.w;
  a4 += w0 * s41.x; a5 += w0 * s41.y; a6 += w0 * s41.z; a7 += w0 * s41.w;
  float* dst = agg + (size_t)l * D_ + tid * 8;
  *(float4*)(dst)     = make_float4(a0, a1, a2, a3);
  *(float4*)(dst + 4) = make_float4(a4, a5, a6, a7);
}

// -------- fold + mask divide + restore (16->64), batched -------------------------
__global__ __launch_bounds__(256) void k_fold(
    const int* __restrict__ flag, const float* __restrict__ ws,
    const float* __restrict__ agb, void* __restrict__ out,
    int b0, unsigned agstride_z)
{
  __shared__ float srw[CIN * CI];
  int tid = threadIdx.x;
  for (int i = tid; i < CIN * CI; i += 256) srw[i] = ws[RW_O + i];
  __syncthreads();

  int bz = blockIdx.y;
  int batch = b0 + bz;
  const float* agg = agb + (size_t)bz * agstride_z;

  int gid = blockIdx.x * 256 + tid;
  if (gid >= HW) return;
  int h = gid / W_;
  int w = gid % W_;

  int lh0 = (h >= KS - 1) ? ((h - (KS - 1) + (ST - 1)) >> 2) : 0;
  int lh1 = min(OH_ - 1, h >> 2);
  int lw0 = (w >= KS - 1) ? ((w - (KS - 1) + (ST - 1)) >> 2) : 0;
  int lw1 = min(OH_ - 1, w >> 2);

  float t[CI];
#pragma unroll
  for (int c = 0; c < CI; ++c) t[c] = 0.f;
  for (int lh = lh0; lh <= lh1; ++lh) {
    int ki = h - ST * lh;
    for (int lw = lw0; lw <= lw1; ++lw) {
      int kj = w - ST * lw;
      const float* pb = agg + (size_t)(lh * OH_ + lw) * D_ + (ki * KS + kj) * CI;
      float4 q0 = *(const float4*)(pb);
      float4 q1 = *(const float4*)(pb + 4);
      float4 q2 = *(const float4*)(pb + 8);
      float4 q3 = *(const float4*)(pb + 12);
      t[0] += q0.x; t[1] += q0.y; t[2] += q0.z; t[3] += q0.w;
      t[4] += q1.x; t[5] += q1.y; t[6] += q1.z; t[7] += q1.w;
      t[8] += q2.x; t[9] += q2.y; t[10] += q2.z; t[11] += q2.w;
      t[12] += q3.x; t[13] += q3.y; t[14] += q3.z; t[15] += q3.w;
    }
  }
  float cnt = (float)((lh1 - lh0 + 1) * (lw1 - lw0 + 1));
  float r[CI];
#pragma unroll
  for (int c = 0; c < CI; ++c) r[c] = t[c] / (cnt * ws[SM_O + c] + ws[SB_O + c] + 1e-8f);

  size_t ob = (size_t)batch * CIN * HW + (size_t)h * W_ + w;
  if (*flag) {
    float* of = (float*)out;
#pragma unroll
    for (int o = 0; o < CIN; ++o) {
      float s = ws[RB_O + o];
#pragma unroll
      for (int c = 0; c < CI; ++c) s += srw[o * CI + c] * r[c];
      of[ob + (size_t)o * HW] = s;
    }
  } else {
    bf16* of = (bf16*)out;
#pragma unroll
    for (int o = 0; o < CIN; ++o) {
      float s = ws[RB_O + o];
#pragma unroll
      for (int c = 0; c < CI; ++c) s += srw[o * CI + c] * r[c];
      of[ob + (size_t)o * HW] = __float2bfloat16(s);
    }
  }
}

extern "C" void kernel_launch(void* const* d_in, const int* in_sizes, int n_in,
                              void* d_out, int out_size, void* d_ws, size_t ws_size,
                              hipStream_t stream)
{
  const void* x    = d_in[0];
  const void* g_w  = d_in[1];
  const void* g_b  = d_in[2];
  const void* th_w = d_in[3];
  const void* th_b = d_in[4];
  const void* ph_w = d_in[5];
  const void* ph_b = d_in[6];
  const void* m_w  = d_in[7];
  const void* m_b  = d_in[8];
  const void* r_w  = d_in[9];
  const void* r_b  = d_in[10];

  float* W = (float*)d_ws;
  int* flag = (int*)d_ws;
  ushort_t* planes = (ushort_t*)(W + B1_O);
  ushort_t* b1h = planes;
  ushort_t* b1l = planes + (size_t)N1;
  ushort_t* b2h = planes + (size_t)2 * N1;
  ushort_t* b2l = planes + (size_t)3 * N1;
  ushort_t* b3  = planes + (size_t)4 * N1;   // bf16 plane, N1 ushorts
  float* s3 = W + S3_O;

  k_detect<<<1, 64, 0, stream>>>((const unsigned short*)x, flag);
  k_prep<<<64, 256, 0, stream>>>(flag, g_w, th_w, ph_w, g_b, th_b, ph_b,
                                 m_w, m_b, r_w, r_b, W);

  if (ws_size >= FULL_BYTES) {
    ushort_t* xhh = (ushort_t*)(W + REG_O);    // bf16 hi/lo x planes, dead after conv
    ushort_t* xhl = xhh + (size_t)XHSZ;
    float* sc = W + REG_O;                     // 4 x SCSLOT, aliases x planes
    float* ag = W + REG_O + XHSZ;              // 4 x AGSZ
    ushort_t* pk = (ushort_t*)ag;              // PK aliases ag (dead until k_pv)
    float* tkw = W + B1_O + N1;                // b2h region (dead after k_score)
    int*   tkp = (int*)(W + B1_O + N1 + N1 / 2);
    k_hwc<<<dim3((B_ * HW + 63) / 64), 256, 0, stream>>>(flag, x, xhh, xhl);
    k_conv3<<<dim3((HW + 127) / 128, 1, B_), 256, 0, stream>>>(
        W, xhh, xhl, b1h, b1l, b2h, b2l, b3);
    k_pack<<<dim3(368, B_), 256, 0, stream>>>(b1h, b1l, pk, 0, PKSTR);
    k_colsum<<<dim3(B_, 49), 256, 0, stream>>>(b3, s3);
    k_score<<<dim3(16, 8, B_), 256, 0, stream>>>(b2h, b2l, pk, sc, 0, SCSLOT, PKSTR);
    k_topk<<<dim3((L_ + 3) / 4, B_), 256, 0, stream>>>(sc, tkw, tkp, SCSLOT);
    k_pv<<<dim3(L_, B_), 128, 0, stream>>>(tkw, tkp, b3, s3, ag, 0, AGSZ);
    k_fold<<<dim3(64, B_), 256, 0, stream>>>(flag, W, ag, d_out, 0, AGSZ);
  } else if (ws_size >= MID_BYTES) {
    ushort_t* xhh = (ushort_t*)(W + REG_O);
    ushort_t* xhl = xhh + (size_t)XHSZ;
    float* sc = W + REG_O;
    float* ag = W + REG_O + SCSLOT;
    ushort_t* pk = (ushort_t*)ag;              // PK shares the single ag slot
    k_hwc<<<dim3((B_ * HW + 63) / 64), 256, 0, stream>>>(flag, x, xhh, xhl);
    k_conv3<<<dim3((HW + 127) / 128, 1, B_), 256, 0, stream>>>(
        W, xhh, xhl, b1h, b1l, b2h, b2l, b3);
    k_colsum<<<dim3(B_, 49), 256, 0, stream>>>(b3, s3);
    for (int b = 0; b < B_; ++b) {
      float* tkw = W + B1_O + N1 + (size_t)b * (HW * CI / 2);
      int*   tkp = (int*)(W + B1_O + N1 + N1 / 2 + (size_t)b * (HW * CI / 2));
      k_pack<<<dim3(368, 1), 256, 0, stream>>>(b1h, b1l, pk, b, 0);
      k_score<<<dim3(16, 8, 1), 256, 0, stream>>>(b2h, b2l, pk, sc, b, 0, 0);
      k_topk<<<dim3((L_ + 3) / 4, 1), 256, 0, stream>>>(sc, tkw, tkp, 0);
      k_pv<<<dim3(L_, 1), 128, 0, stream>>>(tkw, tkp, b3, s3, ag, b, 0);
      k_fold<<<dim3(64, 1), 256, 0, stream>>>(flag, W, ag, d_out, b, 0);
    }
  } else {
    float* sc = W + REG_O;
    float* ag = W + REG_O + SCSLOT;
    ushort_t* pk = (ushort_t*)ag;
    k_convF<<<dim3(4, 16, B_), dim3(32, 8, 1), 0, stream>>>(
        flag, x, g_w, g_b, th_w, th_b, ph_w, ph_b, b1h, b1l, b2h, b2l, b3);
    k_colsum<<<dim3(B_, 49), 256, 0, stream>>>(b3, s3);
    for (int b = 0; b < B_; ++b) {
      float* tkw = W + B1_O + N1 + (size_t)b * (HW * CI / 2);
      int*   tkp = (int*)(W + B1_O + N1 + N1 / 2 + (size_t)b * (HW * CI / 2));
      k_pack<<<dim3(368, 1), 256, 0, stream>>>(b1h, b1l, pk, b, 0);
      k_score<<<dim3(16, 8, 1), 256, 0, stream>>>(b2h, b2l, pk, sc, b, 0, 0);
      k_topk<<<dim3((L_ + 3) / 4, 1), 256, 0, stream>>>(sc, tkw, tkp, 0);
      k_pv<<<dim3(L_, 1), 128, 0, stream>>>(tkw, tkp, b3, s3, ag, b, 0);
      k_fold<<<dim3(64, 1), 256, 0, stream>>>(flag, W, ag, d_out, b, 0);
    }
  }
}

// Round 6
// 270.710 us; speedup vs baseline: 1.6833x; 1.0533x over previous
//
#include <hip/hip_runtime.h>
#include <hip/hip_bf16.h>

typedef __hip_bfloat16 bf16;
typedef unsigned short ushort_t;
typedef __attribute__((ext_vector_type(8))) __bf16 bfv8;
typedef __attribute__((ext_vector_type(16))) float f32x16;

#define B_   4
#define CIN  64
#define CI   16
#define H_   127
#define W_   127
#define HW   (H_*W_)
#define KS   7
#define ST   4
#define OH_  31
#define L_   961
#define D_   784
#define TOPM 100

// ---- workspace layout (float offsets) ----
#define N1   1032256          // B*HW*CI elements (one conv-out array)
#define WG_O 4
#define WT_O (WG_O + 9216)
#define WP_O (WT_O + 1024)
#define BG_O (WP_O + 1024)
#define BT_O (BG_O + 16)
#define BP_O (BT_O + 16)
#define SM_O (BP_O + 16)
#define SB_O (SM_O + 16)
#define RW_O (SB_O + 16)
#define RB_O (RW_O + 1024)
#define B1_O 12448
// planes at B1_O: b1h,b1l,b2h,b2l each N1 ushorts (2*N1 floats); b3 bf16 N1 ushorts
#define S3_O (B1_O + 3*N1)
#define WB_O (S3_O + B_*D_)   // conv MFMA B: wBh + wBl = 36864 floats
#define REG_O (WB_O + 36864)
#define XHSZ 4129024          // B*HW*64 ushorts per x plane (2 planes = XHSZ floats)
#define SROW 964              // padded Sc row stride
#define SCSLOT 926464
#define AGSZ 753424
#define TKROW 112
#define SLST 72               // LDS row stride in ushorts (conflict-free, measured r8)
// PK: unfold-packed A operand. Per plane: 7 nki x 961 rows x 112 ushorts = 753424.
// Per batch (h+l): 1506848 ushorts = 753424 floats = exactly one AGSZ slot.
#define PKPLANE 753424
#define PKSTR   1506848

#define FULL_BYTES ((size_t)(REG_O + XHSZ + 4*AGSZ) * 4)   // ~41.1 MB
#define MID_BYTES  ((size_t)(REG_O + XHSZ) * 4)            // ~29.1 MB

__device__ __forceinline__ float bf2f(bf16 v) { return __bfloat162float(v); }
__device__ __forceinline__ float bflo(unsigned u) { return __uint_as_float(u << 16); }
__device__ __forceinline__ float bfhi(unsigned u) { return __uint_as_float(u & 0xFFFF0000u); }

template <typename T> struct Ld;
template <> struct Ld<float> {
  static __device__ __forceinline__ float f(const void* p, int i) { return ((const float*)p)[i]; }
};
template <> struct Ld<bf16> {
  static __device__ __forceinline__ float f(const void* p, int i) { return bf2f(((const bf16*)p)[i]); }
};

__device__ __forceinline__ unsigned fmap(float f) {
  unsigned u = __float_as_uint(f);
  return (u & 0x80000000u) ? ~u : (u | 0x80000000u);
}
__device__ __forceinline__ float unfmap(unsigned kk) {
  unsigned u = (kk & 0x80000000u) ? (kk & 0x7fffffffu) : ~kk;
  return __uint_as_float(u);
}

// RNE fp32 -> bf16 bits, and hi/lo split
__device__ __forceinline__ ushort_t f2bf(float x) {
  unsigned u = __float_as_uint(x);
  return (ushort_t)((u + 0x7FFFu + ((u >> 16) & 1u)) >> 16);
}
__device__ __forceinline__ void splitbf(float x, ushort_t& h, ushort_t& l) {
  h = f2bf(x);
  float hf = __uint_as_float(((unsigned)h) << 16);
  l = f2bf(x - hf);
}

// -------- dtype detector: flag=1 -> fp32 buffers, flag=0 -> bf16 -----------------
__global__ void k_detect(const unsigned short* __restrict__ xh, int* __restrict__ flag) {
  int tid = threadIdx.x;  // 64
  int c = 0;
#pragma unroll
  for (int j = 0; j < 2; ++j) {
    unsigned u = xh[tid * 2 + j];
    unsigned e = (u >> 7) & 0xFF;
    if (e >= 134) c++;
  }
#pragma unroll
  for (int o = 32; o; o >>= 1) c += __shfl_down(c, o);
  if (tid == 0) *flag = (c >= 8) ? 1 : 0;
}

// -------- weight prep: grid-parallel (was 1 block = 44.5us serial bottleneck) ----
// All outputs independent; grid-stride loops over 64 blocks. Writes disjoint.
#define LDW(ptr, i) (f ? ((const float*)(ptr))[i] : bf2f(((const bf16*)(ptr))[i]))
__global__ __launch_bounds__(256) void k_prep(
    const int* __restrict__ flag,
    const void* g_w, const void* t_w, const void* p_w,
    const void* g_b, const void* t_b, const void* p_b,
    const void* m_w, const void* m_b, const void* r_w, const void* r_b,
    float* __restrict__ ws)
{
  int f = *flag;
  int gid = blockIdx.x * 256 + threadIdx.x;
  int gs = gridDim.x * 256;
  for (int i = gid; i < 9216; i += gs) {
    int o = i & 15, t = i >> 4, c = t & 63, tap = t >> 6;
    ws[WG_O + i] = LDW(g_w, (o * 64 + c) * 9 + tap);
  }
  for (int i = gid; i < 1024; i += gs) {
    int o = i & 15, c = i >> 4;
    ws[WT_O + i] = LDW(t_w, o * 64 + c);
    ws[WP_O + i] = LDW(p_w, o * 64 + c);
  }
  if (gid < 16) {
    ws[BG_O + gid] = LDW(g_b, gid);
    ws[BT_O + gid] = LDW(t_b, gid);
    ws[BP_O + gid] = LDW(p_b, gid);
    float s = 0.f;
    for (int c = 0; c < 64; ++c) s += LDW(m_w, gid * 64 + c);
    ws[SM_O + gid] = s;
    ws[SB_O + gid] = LDW(m_b, gid);
  }
  for (int i = gid; i < 1024; i += gs) ws[RW_O + i] = LDW(r_w, i);
  if (gid >= 64 && gid < 128) ws[RB_O + gid - 64] = LDW(r_b, gid - 64);
  // conv MFMA B, split hi/lo: wB[tap][col64][c64]
  ushort_t* wBh = (ushort_t*)(ws + WB_O);
  ushort_t* wBl = wBh + 9 * 64 * 64;
  for (int i = gid; i < 9 * 64 * 64; i += gs) {
    int c = i & 63, t = i >> 6, col = t & 63, tap = t >> 6;
    float v = 0.f;
    if (col < 16) v = LDW(g_w, (col * 64 + c) * 9 + tap);
    else if (col < 32) { if (tap == 4) v = LDW(t_w, (col - 16) * 64 + c); }
    else if (col < 48) { if (tap == 4) v = LDW(p_w, (col - 32) * 64 + c); }
    ushort_t h, l; splitbf(v, h, l);
    wBh[i] = h; wBl[i] = l;
  }
}

// -------- x [B,64,H,W] -> HWC bf16 hi/lo planes ----------------------------------
__global__ __launch_bounds__(256) void k_hwc(
    const int* __restrict__ flag, const void* __restrict__ x,
    ushort_t* __restrict__ xhh, ushort_t* __restrict__ xhl)
{
  __shared__ float tile[64][65];
  int pix0 = blockIdx.x * 64;
  int tid = threadIdx.x;
  int g = tid >> 6, p = tid & 63;
  int pix = pix0 + p;
  bool ok = pix < B_ * HW;
  int bb = ok ? pix / HW : 0;
  int r  = ok ? pix - bb * HW : 0;
  if (*flag) {
    const float* xf = (const float*)x;
    for (int c = g * 16; c < g * 16 + 16; ++c)
      tile[p][c] = ok ? xf[((size_t)bb * CIN + c) * HW + r] : 0.f;
  } else {
    const bf16* xb = (const bf16*)x;
    for (int c = g * 16; c < g * 16 + 16; ++c)
      tile[p][c] = ok ? bf2f(xb[((size_t)bb * CIN + c) * HW + r]) : 0.f;
  }
  __syncthreads();
  int c2 = tid & 63, pg = tid >> 6;
  for (int k = 0; k < 16; ++k) {
    int p2 = pg * 16 + k;
    int pix2 = pix0 + p2;
    if (pix2 < B_ * HW) {
      ushort_t h, l; splitbf(tile[p2][c2], h, l);
      xhh[(size_t)pix2 * 64 + c2] = h;
      xhl[(size_t)pix2 * 64 + c2] = l;
    }
  }
}

// -------- unified split-bf16 MFMA conv, 128-pixel tile (round-0 verbatim) --------
__global__ __launch_bounds__(256) void k_conv3(
    const float* __restrict__ ws,
    const ushort_t* __restrict__ xhh, const ushort_t* __restrict__ xhl,
    ushort_t* __restrict__ b1h, ushort_t* __restrict__ b1l,
    ushort_t* __restrict__ b2h, ushort_t* __restrict__ b2l,
    ushort_t* __restrict__ b3)
{
  __shared__ ushort_t sAh[128 * SLST], sAl[128 * SLST];
  __shared__ ushort_t sBh[64 * SLST],  sBl[64 * SLST];
  int bz = blockIdx.z;
  int px0 = blockIdx.x * 128;
  int tid = threadIdx.x, lane = tid & 63, wv = tid >> 6;

  int pix0 = px0 + lane, pix1 = px0 + lane + 64;
  bool pok0 = pix0 < HW, pok1 = pix1 < HW;
  int ph0 = pok0 ? pix0 / W_ : 0, pw0 = pok0 ? pix0 - ph0 * W_ : 0;
  int ph1 = pok1 ? pix1 / W_ : 0, pw1 = pok1 ? pix1 - ph1 * W_ : 0;
  const ushort_t* xplane = ((wv == 0) ? xhh : xhl) + (size_t)bz * HW * 64;
  const ushort_t* wBh_ = (const ushort_t*)(ws + WB_O);
  const ushort_t* bsrc = (wv == 2) ? wBh_ : (wBh_ + 9 * 64 * 64);
  ushort_t* dplane = (wv == 0) ? sAh : (wv == 1) ? sAl : (wv == 2) ? sBh : sBl;
  ushort_t* drow0 = dplane + lane * SLST;
  ushort_t* drow1 = dplane + (lane + 64) * SLST;   // wv<2 only

  int fr = lane & 31, kh = (lane >> 5) << 3;
  int mt = (wv >> 1) << 1;
  int aoff0 = (mt * 32 + fr) * SLST + kh;
  int aoff1 = ((mt + 1) * 32 + fr) * SLST + kh;
  int boff  = (((wv & 1) << 5) + fr) * SLST + kh;

  f32x16 acc0 = {0.f,0.f,0.f,0.f,0.f,0.f,0.f,0.f,0.f,0.f,0.f,0.f,0.f,0.f,0.f,0.f};
  f32x16 acc1 = {0.f,0.f,0.f,0.f,0.f,0.f,0.f,0.f,0.f,0.f,0.f,0.f,0.f,0.f,0.f,0.f};
  const int4 z4 = make_int4(0, 0, 0, 0);
  int4 v0 = z4, v1 = z4, v2 = z4, v3 = z4, v4 = z4, v5 = z4, v6 = z4, v7 = z4;
  int4 u0 = z4, u1 = z4, u2 = z4, u3 = z4, u4 = z4, u5 = z4, u6 = z4, u7 = z4;

  // prefetch tap 0 (dh=-1, dw=-1)
  if (wv < 2) {
    int hh = ph0 - 1, ww = pw0 - 1;
    if (pok0 && hh >= 0 && ww >= 0) {
      const int4* s = (const int4*)(xplane + (size_t)(hh * W_ + ww) * 64);
      v0 = s[0]; v1 = s[1]; v2 = s[2]; v3 = s[3]; v4 = s[4]; v5 = s[5]; v6 = s[6]; v7 = s[7];
    }
    int hh1 = ph1 - 1, ww1 = pw1 - 1;
    if (pok1 && hh1 >= 0 && ww1 >= 0) {
      const int4* s = (const int4*)(xplane + (size_t)(hh1 * W_ + ww1) * 64);
      u0 = s[0]; u1 = s[1]; u2 = s[2]; u3 = s[3]; u4 = s[4]; u5 = s[5]; u6 = s[6]; u7 = s[7];
    }
  } else {
    const int4* s = (const int4*)(bsrc + (size_t)lane * 64);
    v0 = s[0]; v1 = s[1]; v2 = s[2]; v3 = s[3]; v4 = s[4]; v5 = s[5]; v6 = s[6]; v7 = s[7];
  }

  for (int r = 0; r < 9; ++r) {
    __syncthreads();
    *(int4*)(drow0 + 0)  = v0;  *(int4*)(drow0 + 8)  = v1;
    *(int4*)(drow0 + 16) = v2;  *(int4*)(drow0 + 24) = v3;
    *(int4*)(drow0 + 32) = v4;  *(int4*)(drow0 + 40) = v5;
    *(int4*)(drow0 + 48) = v6;  *(int4*)(drow0 + 56) = v7;
    if (wv < 2) {
      *(int4*)(drow1 + 0)  = u0;  *(int4*)(drow1 + 8)  = u1;
      *(int4*)(drow1 + 16) = u2;  *(int4*)(drow1 + 24) = u3;
      *(int4*)(drow1 + 32) = u4;  *(int4*)(drow1 + 40) = u5;
      *(int4*)(drow1 + 48) = u6;  *(int4*)(drow1 + 56) = u7;
    }
    __syncthreads();
    if (r < 8) {
      int rn = r + 1;
      int dh = rn / 3 - 1, dw = rn % 3 - 1;
      if (wv < 2) {
        int hh = ph0 + dh, ww = pw0 + dw;
        if (pok0 && (unsigned)hh < (unsigned)H_ && (unsigned)ww < (unsigned)W_) {
          const int4* s = (const int4*)(xplane + (size_t)(hh * W_ + ww) * 64);
          v0 = s[0]; v1 = s[1]; v2 = s[2]; v3 = s[3]; v4 = s[4]; v5 = s[5]; v6 = s[6]; v7 = s[7];
        } else {
          v0 = z4; v1 = z4; v2 = z4; v3 = z4; v4 = z4; v5 = z4; v6 = z4; v7 = z4;
        }
        int hh1 = ph1 + dh, ww1 = pw1 + dw;
        if (pok1 && (unsigned)hh1 < (unsigned)H_ && (unsigned)ww1 < (unsigned)W_) {
          const int4* s = (const int4*)(xplane + (size_t)(hh1 * W_ + ww1) * 64);
          u0 = s[0]; u1 = s[1]; u2 = s[2]; u3 = s[3]; u4 = s[4]; u5 = s[5]; u6 = s[6]; u7 = s[7];
        } else {
          u0 = z4; u1 = z4; u2 = z4; u3 = z4; u4 = z4; u5 = z4; u6 = z4; u7 = z4;
        }
      } else {
        const int4* s = (const int4*)(bsrc + ((size_t)rn * 64 + lane) * 64);
        v0 = s[0]; v1 = s[1]; v2 = s[2]; v3 = s[3]; v4 = s[4]; v5 = s[5]; v6 = s[6]; v7 = s[7];
      }
    }
#pragma unroll
    for (int t = 0; t < 4; ++t) {
      bfv8 ah0 = *(const bfv8*)(sAh + aoff0 + t * 16);
      bfv8 al0 = *(const bfv8*)(sAl + aoff0 + t * 16);
      bfv8 ah1 = *(const bfv8*)(sAh + aoff1 + t * 16);
      bfv8 al1 = *(const bfv8*)(sAl + aoff1 + t * 16);
      bfv8 bh  = *(const bfv8*)(sBh + boff + t * 16);
      bfv8 bl  = *(const bfv8*)(sBl + boff + t * 16);
      acc0 = __builtin_amdgcn_mfma_f32_32x32x16_bf16(al0, bh, acc0, 0, 0, 0);
      acc0 = __builtin_amdgcn_mfma_f32_32x32x16_bf16(ah0, bl, acc0, 0, 0, 0);
      acc0 = __builtin_amdgcn_mfma_f32_32x32x16_bf16(ah0, bh, acc0, 0, 0, 0);
      acc1 = __builtin_amdgcn_mfma_f32_32x32x16_bf16(al1, bh, acc1, 0, 0, 0);
      acc1 = __builtin_amdgcn_mfma_f32_32x32x16_bf16(ah1, bl, acc1, 0, 0, 0);
      acc1 = __builtin_amdgcn_mfma_f32_32x32x16_bf16(ah1, bh, acc1, 0, 0, 0);
    }
  }

  int nw = ((wv & 1) << 5) + fr;
#pragma unroll
  for (int s = 0; s < 2; ++s) {
    int mbase = (mt + s) * 32;
#pragma unroll
    for (int r = 0; r < 16; ++r) {
      int m = mbase + (r & 3) + ((r >> 2) << 3) + ((lane >> 5) << 2);
      int p2 = px0 + m;
      if (p2 >= HW) continue;
      size_t ob = ((size_t)bz * HW + p2) * 16;
      float val = s ? acc1[r] : acc0[r];
      if (nw < 16) {
        ushort_t h2, l2; splitbf(val + ws[BG_O + nw], h2, l2);
        b1h[ob + nw] = h2; b1l[ob + nw] = l2;
      } else if (nw < 32) {
        int o = nw - 16; ushort_t h2, l2; splitbf(val + ws[BT_O + o], h2, l2);
        b2h[ob + o] = h2; b2l[ob + o] = l2;
      } else if (nw < 48) {
        int o = nw - 32; b3[ob + o] = f2bf(val + ws[BP_O + o]);
      }
    }
  }
}

// -------- fallback conv (LOW tier), dtype-templated VALU -------------------------
template <typename T>
__device__ __forceinline__ void convF_body(
    const void* x, const void* g_w, const void* g_b,
    const void* t_w, const void* t_b, const void* p_w, const void* p_b,
    ushort_t* b1h, ushort_t* b1l, ushort_t* b2h, ushort_t* b2l, ushort_t* b3,
    float* sgw, float* stw, float* spw)
{
  int tid = threadIdx.y * 32 + threadIdx.x;
  for (int i = tid; i < CI * CIN * 9; i += 256) sgw[i] = Ld<T>::f(g_w, i);
  for (int i = tid; i < CI * CIN; i += 256) { stw[i] = Ld<T>::f(t_w, i); spw[i] = Ld<T>::f(p_w, i); }
  __syncthreads();

  int w = blockIdx.x * 32 + threadIdx.x;
  int h = blockIdx.y * 8 + threadIdx.y;
  int b = blockIdx.z;
  if (w >= W_ || h >= H_) return;

  float a1[CI], a2[CI], a3[CI];
#pragma unroll
  for (int o = 0; o < CI; ++o) { a1[o] = 0.f; a2[o] = 0.f; a3[o] = 0.f; }

  const size_t xb = (size_t)b * CIN * HW;
  for (int c = 0; c < CIN; ++c) {
    float xv[9];
#pragma unroll
    for (int dh = 0; dh < 3; ++dh) {
      int hh = h + dh - 1;
      bool rok = ((unsigned)hh < (unsigned)H_);
#pragma unroll
      for (int dw = 0; dw < 3; ++dw) {
        int ww = w + dw - 1;
        bool ok = rok && ((unsigned)ww < (unsigned)W_);
        xv[dh * 3 + dw] = ok ? Ld<T>::f(x, (int)(xb + (size_t)c * HW + hh * W_ + ww)) : 0.f;
      }
    }
    float xc = xv[4];
#pragma unroll
    for (int o = 0; o < CI; ++o) {
      const float* gg = &sgw[(o * CIN + c) * 9];
      float s = gg[0]*xv[0] + gg[1]*xv[1] + gg[2]*xv[2]
              + gg[3]*xv[3] + gg[4]*xv[4] + gg[5]*xv[5]
              + gg[6]*xv[6] + gg[7]*xv[7] + gg[8]*xv[8];
      a1[o] += s;
      a2[o] += stw[o * CIN + c] * xc;
      a3[o] += spw[o * CIN + c] * xc;
    }
  }
  size_t base = ((size_t)b * HW + h * W_ + w) * CI;
#pragma unroll
  for (int o = 0; o < CI; ++o) {
    float v1 = a1[o] + Ld<T>::f(g_b, o);
    float v2 = a2[o] + Ld<T>::f(t_b, o);
    ushort_t hh2, ll2;
    splitbf(v1, hh2, ll2); b1h[base + o] = hh2; b1l[base + o] = ll2;
    splitbf(v2, hh2, ll2); b2h[base + o] = hh2; b2l[base + o] = ll2;
    b3[base + o] = f2bf(a3[o] + Ld<T>::f(p_b, o));
  }
}

__global__ __launch_bounds__(256) void k_convF(
    const int* __restrict__ flag, const void* x,
    const void* g_w, const void* g_b, const void* t_w, const void* t_b,
    const void* p_w, const void* p_b,
    ushort_t* __restrict__ b1h, ushort_t* __restrict__ b1l,
    ushort_t* __restrict__ b2h, ushort_t* __restrict__ b2l,
    ushort_t* __restrict__ b3)
{
  __shared__ float sgw[CI * CIN * 9];
  __shared__ float stw[CI * CIN];
  __shared__ float spw[CI * CIN];
  if (*flag) convF_body<float>(x, g_w, g_b, t_w, t_b, p_w, p_b, b1h, b1l, b2h, b2l, b3, sgw, stw, spw);
  else       convF_body<bf16 >(x, g_w, g_b, t_w, t_b, p_w, p_b, b1h, b1l, b2h, b2l, b3, sgw, stw, spw);
}

// -------- S3[b, pos*16+c] = sum over patches of b3 (bf16 src, fp32 acc) ----------
__global__ __launch_bounds__(256) void k_colsum(const ushort_t* __restrict__ b3, float* __restrict__ S3)
{
  __shared__ float red[16][17];
  int b = blockIdx.x, pos = blockIdx.y;
  int ki = pos / 7, kj = pos % 7;
  int c = threadIdx.x & 15, chunk = threadIdx.x >> 4;
  const ushort_t* B3 = b3 + (size_t)b * HW * CI;
  float s = 0.f;
  for (int l = chunk; l < L_; l += 16) {
    int lh = l / OH_, lw = l % OH_;
    s += bflo((unsigned)B3[((lh * ST + ki) * W_ + lw * ST + kj) * CI + c]);
  }
  red[chunk][c] = s;
  __syncthreads();
  if (threadIdx.x < 16) {
    float t = 0.f;
#pragma unroll
    for (int k = 0; k < 16; ++k) t += red[k][threadIdx.x];
    S3[(b * 49 + pos) * 16 + threadIdx.x] = t;
  }
}

// -------- pack A operand: PK[plane][nki][row][112] = b1 patch-row segments -------
// Pure contiguous copy: 14 int4 per (row,nki) read, coalesced write. Exact bits.
__global__ __launch_bounds__(256) void k_pack(
    const ushort_t* __restrict__ b1h, const ushort_t* __restrict__ b1l,
    ushort_t* __restrict__ pk, int b0, unsigned pkstride_z)
{
  int idx = blockIdx.x * 256 + threadIdx.x;
  if (idx >= 961 * 98) return;
  int row = idx / 98, rem = idx - row * 98;
  int nki = rem / 14, q = rem - nki * 14;
  int slh = row / OH_, slw = row - slh * OH_;
  int src = ((slh * ST) * W_ + slw * ST + nki * W_) * 16 + q * 8;
  int dst = (nki * 961 + row) * 112 + q * 8;
  int batch = b0 + blockIdx.y;
  size_t poff = (size_t)batch * HW * CI;
  ushort_t* pkb = pk + (size_t)blockIdx.y * pkstride_z;
  *(int4*)(pkb + dst)           = *(const int4*)(b1h + poff + src);
  *(int4*)(pkb + PKPLANE + dst) = *(const int4*)(b1l + poff + src);
}

// -------- score GEMM via split-bf16 MFMA, 128x64 tile ----------------------------
// A staged cooperatively from PK (one base + imm offsets, named regs -> no spill,
// consecutive lanes contiguous -> ~3x fewer cache-line requests). B per-lane-row,
// LDS layout/MFMA/epilogue byte-identical to the 322us round-0 kernel.
__global__ __launch_bounds__(256) void k_score(
    const ushort_t* __restrict__ b2h, const ushort_t* __restrict__ b2l,
    const ushort_t* __restrict__ pk,
    float* __restrict__ scb, int b0, unsigned scstride_z, unsigned pkstride_z)
{
  __shared__ ushort_t sAh[128 * SLST], sAl[128 * SLST];
  __shared__ ushort_t sBh[64 * SLST],  sBl[64 * SLST];
  int batch = b0 + blockIdx.z;
  size_t poff_g = (size_t)batch * HW * CI;
  float* Sc = scb + (size_t)blockIdx.z * scstride_z;

  int tid = threadIdx.x;
  int m0 = blockIdx.y * 128, n0 = blockIdx.x * 64;
  int lane = tid & 63;
  int wv = tid >> 6;
  int grp = lane >> 3, ch = lane & 7;

  const ushort_t* pkb = pk + (size_t)blockIdx.z * pkstride_z + (size_t)(wv & 1) * PKPLANE;

  // B-side per-lane-row base (wv>=2)
  int srow = n0 + lane;  if (srow > L_ - 1) srow = L_ - 1;
  int slh = srow / OH_, slw = srow - slh * OH_;
  int sbase = (slh * ST) * W_ + slw * ST;
  const ushort_t* splane = (wv == 2) ? (b2h + poff_g) : (b2l + poff_g);
  ushort_t* dplane = (wv == 0) ? sAh : (wv == 1) ? sAl : (wv == 2) ? sBh : sBl;
  ushort_t* drowB = dplane + lane * SLST;

  int fr = lane & 31;
  int kh = (lane >> 5) << 3;
  int mt = (wv >> 1) << 1;                         // first m-subtile: 0 or 2
  int aoff0 = (mt * 32 + fr) * SLST + kh;
  int aoff1 = ((mt + 1) * 32 + fr) * SLST + kh;
  int boff  = (((wv & 1) << 5) + fr) * SLST + kh;

  f32x16 acc0 = {0.f,0.f,0.f,0.f,0.f,0.f,0.f,0.f,0.f,0.f,0.f,0.f,0.f,0.f,0.f,0.f};
  f32x16 acc1 = {0.f,0.f,0.f,0.f,0.f,0.f,0.f,0.f,0.f,0.f,0.f,0.f,0.f,0.f,0.f,0.f};

  int4 pv0, pv1, pv2, pv3, pv4, pv5, pv6, pv7;
  int4 pv8, pv9, pv10, pv11, pv12, pv13, pv14, pv15;

#define LA(j) pv##j = *(const int4*)(pks + (size_t)min(m0 + 8*j + grp, 960) * 112)
#define LA_ALL LA(0); LA(1); LA(2); LA(3); LA(4); LA(5); LA(6); LA(7); \
               LA(8); LA(9); LA(10); LA(11); LA(12); LA(13); LA(14); LA(15)
#define WA(j) *(int4*)(d0 + (j) * 8 * SLST) = pv##j
#define WA_ALL WA(0); WA(1); WA(2); WA(3); WA(4); WA(5); WA(6); WA(7); \
               WA(8); WA(9); WA(10); WA(11); WA(12); WA(13); WA(14); WA(15)

  // initial prefetch: rn=0 (nki=0, even)
  if (wv < 2) {
    const ushort_t* pks = pkb + ch * 8;
    LA_ALL;
  } else {
    const int4* s0 = (const int4*)(splane + (size_t)sbase * 16);
    pv0 = s0[0]; pv1 = s0[1]; pv2 = s0[2]; pv3 = s0[3];
    pv4 = s0[4]; pv5 = s0[5]; pv6 = s0[6]; pv7 = s0[7];
  }

  for (int r = 0; r < 14; ++r) {
    int half = r & 1;
    __syncthreads();
    if (wv < 2) {
      ushort_t* d0 = dplane + grp * SLST + ch * 8;
      if (!half) { WA_ALL; }
      else if (ch < 6) { WA_ALL; }
    } else {
      *(int4*)(drowB + 0)  = pv0;  *(int4*)(drowB + 8)  = pv1;
      *(int4*)(drowB + 16) = pv2;  *(int4*)(drowB + 24) = pv3;
      *(int4*)(drowB + 32) = pv4;  *(int4*)(drowB + 40) = pv5;
      if (!half) { *(int4*)(drowB + 48) = pv6; *(int4*)(drowB + 56) = pv7; }
    }
    __syncthreads();
    if (r < 13) {
      int rn = r + 1;
      int nki = rn >> 1, odd = rn & 1;
      if (wv < 2) {
        const ushort_t* pks = pkb + (size_t)nki * (961 * 112) + odd * 64 + ch * 8;
        if (!odd) { LA_ALL; }
        else if (ch < 6) { LA_ALL; }
      } else {
        int nkj0 = odd * 4;
        const int4* s0 = (const int4*)(splane + (size_t)(sbase + nki * W_ + nkj0) * 16);
        pv0 = s0[0]; pv1 = s0[1]; pv2 = s0[2]; pv3 = s0[3]; pv4 = s0[4]; pv5 = s0[5];
        if (!odd) { pv6 = s0[6]; pv7 = s0[7]; }
      }
    }
    if (!half) {
#pragma unroll
      for (int t = 0; t < 4; ++t) {
        bfv8 ah0 = *(const bfv8*)(sAh + aoff0 + t * 16);
        bfv8 al0 = *(const bfv8*)(sAl + aoff0 + t * 16);
        bfv8 ah1 = *(const bfv8*)(sAh + aoff1 + t * 16);
        bfv8 al1 = *(const bfv8*)(sAl + aoff1 + t * 16);
        bfv8 bh  = *(const bfv8*)(sBh + boff + t * 16);
        bfv8 bl  = *(const bfv8*)(sBl + boff + t * 16);
        acc0 = __builtin_amdgcn_mfma_f32_32x32x16_bf16(al0, bh, acc0, 0, 0, 0);
        acc0 = __builtin_amdgcn_mfma_f32_32x32x16_bf16(ah0, bl, acc0, 0, 0, 0);
        acc0 = __builtin_amdgcn_mfma_f32_32x32x16_bf16(ah0, bh, acc0, 0, 0, 0);
        acc1 = __builtin_amdgcn_mfma_f32_32x32x16_bf16(al1, bh, acc1, 0, 0, 0);
        acc1 = __builtin_amdgcn_mfma_f32_32x32x16_bf16(ah1, bl, acc1, 0, 0, 0);
        acc1 = __builtin_amdgcn_mfma_f32_32x32x16_bf16(ah1, bh, acc1, 0, 0, 0);
      }
    } else {
#pragma unroll
      for (int t = 0; t < 3; ++t) {
        bfv8 ah0 = *(const bfv8*)(sAh + aoff0 + t * 16);
        bfv8 al0 = *(const bfv8*)(sAl + aoff0 + t * 16);
        bfv8 ah1 = *(const bfv8*)(sAh + aoff1 + t * 16);
        bfv8 al1 = *(const bfv8*)(sAl + aoff1 + t * 16);
        bfv8 bh  = *(const bfv8*)(sBh + boff + t * 16);
        bfv8 bl  = *(const bfv8*)(sBl + boff + t * 16);
        acc0 = __builtin_amdgcn_mfma_f32_32x32x16_bf16(al0, bh, acc0, 0, 0, 0);
        acc0 = __builtin_amdgcn_mfma_f32_32x32x16_bf16(ah0, bl, acc0, 0, 0, 0);
        acc0 = __builtin_amdgcn_mfma_f32_32x32x16_bf16(ah0, bh, acc0, 0, 0, 0);
        acc1 = __builtin_amdgcn_mfma_f32_32x32x16_bf16(al1, bh, acc1, 0, 0, 0);
        acc1 = __builtin_amdgcn_mfma_f32_32x32x16_bf16(ah1, bl, acc1, 0, 0, 0);
        acc1 = __builtin_amdgcn_mfma_f32_32x32x16_bf16(ah1, bh, acc1, 0, 0, 0);
      }
    }
  }
#undef LA
#undef LA_ALL
#undef WA
#undef WA_ALL

  int nw = n0 + ((wv & 1) << 5) + fr;
  if (nw < L_) {
    int mw0 = m0 + mt * 32;
#pragma unroll
    for (int r = 0; r < 16; ++r) {
      int m = mw0 + (r & 3) + ((r >> 2) << 3) + ((lane >> 5) << 2);
      if (m < L_) Sc[(size_t)m * SROW + nw] = acc0[r];
    }
    int mw1 = m0 + (mt + 1) * 32;
#pragma unroll
    for (int r = 0; r < 16; ++r) {
      int m = mw1 + (r & 3) + ((r >> 2) << 3) + ((lane >> 5) << 2);
      if (m < L_) Sc[(size_t)m * SROW + nw] = acc1[r];
    }
  }
}

// -------- top-100 + softmax weights: 4 rows per block (1 wave each) --------------
// Ballot-radix: counts via v_cmp->SGPR + s_bcnt1 (SALU pipe), no shfl reduces.
// Retired keys are zeroed in a working copy kk[] (digit-0 keys contribute nothing
// to c1/c2/c3, provably equivalent to the alive-mask). k[] preserved for ties.
__global__ __launch_bounds__(256) void k_topk(
    const float* __restrict__ scb, float* __restrict__ tkw, int* __restrict__ tkp,
    unsigned scstride_z)
{
  __shared__ float swv[4][TOPM];
  __shared__ int spx[4][TOPM];
  int tid = threadIdx.x;
  int wvi = tid >> 6, lane = tid & 63;
  int l = blockIdx.x * 4 + wvi;
  if (l > L_ - 1) l = L_ - 1;        // clamp: duplicate rows write identical data
  int bz = blockIdx.y;
  const float4* row4 = (const float4*)(scb + (size_t)bz * scstride_z + (size_t)l * SROW);
  int trow = (bz * L_ + l) * TKROW;

  unsigned k[16];
#pragma unroll
  for (int q = 0; q < 4; ++q) {
    float4 v = row4[q * 64 + lane];
    int ib = (q * 64 + lane) * 4;
    k[q * 4 + 0] = (ib + 0 < L_) ? fmap(v.x) : 0u;
    k[q * 4 + 1] = (ib + 1 < L_) ? fmap(v.y) : 0u;
    k[q * 4 + 2] = (ib + 2 < L_) ? fmap(v.z) : 0u;
    k[q * 4 + 3] = (ib + 3 < L_) ? fmap(v.w) : 0u;
  }

  unsigned mk = 0;
#pragma unroll
  for (int r = 0; r < 16; ++r) mk = max(mk, k[r]);
#pragma unroll
  for (int o = 32; o; o >>= 1) mk = max(mk, (unsigned)__shfl_down((int)mk, o));
  mk = (unsigned)__shfl((int)mk, 0);
  float vmax = unfmap(mk);

  // working copy; zeroed keys are retired (contribute 0 to all counts)
  unsigned kk[16];
#pragma unroll
  for (int r = 0; r < 16; ++r) kk[r] = k[r];

  unsigned prefix = 0; int base = 0;
  for (int bit = 30; bit >= 0; bit -= 2) {
    int n3 = 0, n2 = 0, n1 = 0;
#pragma unroll
    for (int r = 0; r < 16; ++r) {
      unsigned f = (kk[r] >> bit) & 3u;
      n3 += (int)__popcll(__ballot(f == 3u));
      n2 += (int)__popcll(__ballot(f >= 2u));
      n1 += (int)__popcll(__ballot(f >= 1u));
    }
    unsigned ch;
    if (base + n3 >= TOPM) ch = 3;
    else if (base + n2 >= TOPM) { ch = 2; base += n3; }
    else if (base + n1 >= TOPM) { ch = 1; base += n2; }
    else { ch = 0; base += n1; }
    prefix |= ch << bit;
#pragma unroll
    for (int r = 0; r < 16; ++r) {
      unsigned f = (kk[r] >> bit) & 3u;
      kk[r] = (f == ch) ? kk[r] : 0u;
    }
  }
  int nA = base;
  int needT = TOPM - nA;

  int cA = 0, cT = 0;
#pragma unroll
  for (int r = 0; r < 16; ++r) { cA += (k[r] > prefix); cT += (k[r] == prefix); }
  int pk = cA | (cT << 16);
  int incl = pk;
#pragma unroll
  for (int o = 1; o < 64; o <<= 1) { int t = __shfl_up(incl, o); if (lane >= o) incl += t; }
  int excl = incl - pk;
  int tA = excl & 0xFFFF, tT = excl >> 16;

  float M = fmaxf(10.f * vmax, 0.f);
  float e0 = __expf(-M);
  float z = 0.f;
#pragma unroll
  for (int r = 0; r < 16; ++r) {
    unsigned kr = k[r];
    int slot = -1;
    if (kr > prefix) slot = tA++;
    else if (kr == prefix) { if (tT < needT) slot = nA + tT; tT++; }
    if (slot >= 0) {
      float v = unfmap(kr);
      float wv = __expf(10.f * v - M);
      swv[wvi][slot] = wv; z += wv;
      int gi = 256 * (r >> 2) + 4 * lane + (r & 3);
      int lh = gi / OH_, lw = gi - lh * OH_;
      spx[wvi][slot] = ((lh * ST) * W_ + lw * ST) * CI;
    }
  }
#pragma unroll
  for (int o = 32; o; o >>= 1) z += __shfl_down(z, o);
  z = __shfl(z, 0);
  float Z = z + (float)(L_ - TOPM) * e0;
  float invZ = 1.f / Z;
  float w0 = e0 / Z;
  __syncthreads();
#pragma unroll
  for (int s0 = 0; s0 < 2; ++s0) {
    int s = lane + 64 * s0;
    if (s < TOPM) {
      tkw[trow + s] = swv[wvi][s] * invZ - w0;
      tkp[trow + s] = spx[wvi][s];
    }
  }
  if (lane == 0) tkw[trow + TOPM] = w0;
}

// -------- PV gather (bf16 b3, uint4 full-line): 98 lanes x 8 channels ------------
__global__ __launch_bounds__(128) void k_pv(
    const float* __restrict__ tkw, const int* __restrict__ tkp,
    const ushort_t* __restrict__ b3, const float* __restrict__ s3,
    float* __restrict__ agb, int b0, unsigned agstride_z)
{
  int l = blockIdx.x, bz = blockIdx.y;
  int batch = b0 + bz;
  int trow = (bz * L_ + l) * TKROW;
  const ushort_t* B3 = b3 + (size_t)batch * HW * CI;
  const float* S3 = s3 + (size_t)batch * D_;
  float* agg = agb + (size_t)bz * agstride_z;
  int tid = threadIdx.x;
  if (tid >= 98) return;

  float w0 = tkw[trow + TOPM];
  int pos = tid >> 1;
  int c0 = (tid & 1) << 3;                 // 0 or 8
  int ki = pos / 7, kj = pos - (pos / 7) * 7;
  int poff = (ki * W_ + kj) * CI + c0;

  float a0 = 0.f, a1 = 0.f, a2 = 0.f, a3 = 0.f;
  float a4 = 0.f, a5 = 0.f, a6 = 0.f, a7 = 0.f;
  for (int j0 = 0; j0 < TOPM; j0 += 4) {
    float w_0 = tkw[trow + j0 + 0];
    float w_1 = tkw[trow + j0 + 1];
    float w_2 = tkw[trow + j0 + 2];
    float w_3 = tkw[trow + j0 + 3];
    int p_0 = tkp[trow + j0 + 0];
    int p_1 = tkp[trow + j0 + 1];
    int p_2 = tkp[trow + j0 + 2];
    int p_3 = tkp[trow + j0 + 3];
    const uint4 q0 = *(const uint4*)(B3 + p_0 + poff);
    const uint4 q1 = *(const uint4*)(B3 + p_1 + poff);
    const uint4 q2 = *(const uint4*)(B3 + p_2 + poff);
    const uint4 q3 = *(const uint4*)(B3 + p_3 + poff);
    a0 += w_0 * bflo(q0.x); a1 += w_0 * bfhi(q0.x); a2 += w_0 * bflo(q0.y); a3 += w_0 * bfhi(q0.y);
    a4 += w_0 * bflo(q0.z); a5 += w_0 * bfhi(q0.z); a6 += w_0 * bflo(q0.w); a7 += w_0 * bfhi(q0.w);
    a0 += w_1 * bflo(q1.x); a1 += w_1 * bfhi(q1.x); a2 += w_1 * bflo(q1.y); a3 += w_1 * bfhi(q1.y);
    a4 += w_1 * bflo(q1.z); a5 += w_1 * bfhi(q1.z); a6 += w_1 * bflo(q1.w); a7 += w_1 * bfhi(q1.w);
    a0 += w_2 * bflo(q2.x); a1 += w_2 * bfhi(q2.x); a2 += w_2 * bflo(q2.y); a3 += w_2 * bfhi(q2.y);
    a4 += w_2 * bflo(q2.z); a5 += w_2 * bfhi(q2.z); a6 += w_2 * bflo(q2.w); a7 += w_2 * bfhi(q2.w);
    a0 += w_3 * bflo(q3.x); a1 += w_3 * bfhi(q3.x); a2 += w_3 * bflo(q3.y); a3 += w_3 * bfhi(q3.y);
    a4 += w_3 * bflo(q3.z); a5 += w_3 * bfhi(q3.z); a6 += w_3 * bflo(q3.w); a7 += w_3 * bfhi(q3.w);
  }
  const float4 s40 = *(const float4*)(S3 + tid * 8);
  const float4 s41 = *(const float4*)(S3 + tid * 8 + 4);
  a0 += w0 * s40.x; a1 += w0 * s40.y; a2 += w0 * s40.z; a3 += w0 * s40.w;
  a4 += w0 * s41.x; a5 += w0 * s41.y; a6 += w0 * s41.z; a7 += w0 * s41.w;
  float* dst = agg + (size_t)l * D_ + tid * 8;
  *(float4*)(dst)     = make_float4(a0, a1, a2, a3);
  *(float4*)(dst + 4) = make_float4(a4, a5, a6, a7);
}

// -------- fold + mask divide + restore (16->64), batched -------------------------
__global__ __launch_bounds__(256) void k_fold(
    const int* __restrict__ flag, const float* __restrict__ ws,
    const float* __restrict__ agb, void* __restrict__ out,
    int b0, unsigned agstride_z)
{
  __shared__ float srw[CIN * CI];
  int tid = threadIdx.x;
  for (int i = tid; i < CIN * CI; i += 256) srw[i] = ws[RW_O + i];
  __syncthreads();

  int bz = blockIdx.y;
  int batch = b0 + bz;
  const float* agg = agb + (size_t)bz * agstride_z;

  int gid = blockIdx.x * 256 + tid;
  if (gid >= HW) return;
  int h = gid / W_;
  int w = gid % W_;

  int lh0 = (h >= KS - 1) ? ((h - (KS - 1) + (ST - 1)) >> 2) : 0;
  int lh1 = min(OH_ - 1, h >> 2);
  int lw0 = (w >= KS - 1) ? ((w - (KS - 1) + (ST - 1)) >> 2) : 0;
  int lw1 = min(OH_ - 1, w >> 2);

  float t[CI];
#pragma unroll
  for (int c = 0; c < CI; ++c) t[c] = 0.f;
  for (int lh = lh0; lh <= lh1; ++lh) {
    int ki = h - ST * lh;
    for (int lw = lw0; lw <= lw1; ++lw) {
      int kj = w - ST * lw;
      const float* pb = agg + (size_t)(lh * OH_ + lw) * D_ + (ki * KS + kj) * CI;
      float4 q0 = *(const float4*)(pb);
      float4 q1 = *(const float4*)(pb + 4);
      float4 q2 = *(const float4*)(pb + 8);
      float4 q3 = *(const float4*)(pb + 12);
      t[0] += q0.x; t[1] += q0.y; t[2] += q0.z; t[3] += q0.w;
      t[4] += q1.x; t[5] += q1.y; t[6] += q1.z; t[7] += q1.w;
      t[8] += q2.x; t[9] += q2.y; t[10] += q2.z; t[11] += q2.w;
      t[12] += q3.x; t[13] += q3.y; t[14] += q3.z; t[15] += q3.w;
    }
  }
  float cnt = (float)((lh1 - lh0 + 1) * (lw1 - lw0 + 1));
  float r[CI];
#pragma unroll
  for (int c = 0; c < CI; ++c) r[c] = t[c] / (cnt * ws[SM_O + c] + ws[SB_O + c] + 1e-8f);

  size_t ob = (size_t)batch * CIN * HW + (size_t)h * W_ + w;
  if (*flag) {
    float* of = (float*)out;
#pragma unroll
    for (int o = 0; o < CIN; ++o) {
      float s = ws[RB_O + o];
#pragma unroll
      for (int c = 0; c < CI; ++c) s += srw[o * CI + c] * r[c];
      of[ob + (size_t)o * HW] = s;
    }
  } else {
    bf16* of = (bf16*)out;
#pragma unroll
    for (int o = 0; o < CIN; ++o) {
      float s = ws[RB_O + o];
#pragma unroll
      for (int c = 0; c < CI; ++c) s += srw[o * CI + c] * r[c];
      of[ob + (size_t)o * HW] = __float2bfloat16(s);
    }
  }
}

extern "C" void kernel_launch(void* const* d_in, const int* in_sizes, int n_in,
                              void* d_out, int out_size, void* d_ws, size_t ws_size,
                              hipStream_t stream)
{
  const void* x    = d_in[0];
  const void* g_w  = d_in[1];
  const void* g_b  = d_in[2];
  const void* th_w = d_in[3];
  const void* th_b = d_in[4];
  const void* ph_w = d_in[5];
  const void* ph_b = d_in[6];
  const void* m_w  = d_in[7];
  const void* m_b  = d_in[8];
  const void* r_w  = d_in[9];
  const void* r_b  = d_in[10];

  float* W = (float*)d_ws;
  int* flag = (int*)d_ws;
  ushort_t* planes = (ushort_t*)(W + B1_O);
  ushort_t* b1h = planes;
  ushort_t* b1l = planes + (size_t)N1;
  ushort_t* b2h = planes + (size_t)2 * N1;
  ushort_t* b2l = planes + (size_t)3 * N1;
  ushort_t* b3  = planes + (size_t)4 * N1;   // bf16 plane, N1 ushorts
  float* s3 = W + S3_O;

  k_detect<<<1, 64, 0, stream>>>((const unsigned short*)x, flag);
  k_prep<<<64, 256, 0, stream>>>(flag, g_w, th_w, ph_w, g_b, th_b, ph_b,
                                 m_w, m_b, r_w, r_b, W);

  if (ws_size >= FULL_BYTES) {
    ushort_t* xhh = (ushort_t*)(W + REG_O);    // bf16 hi/lo x planes, dead after conv
    ushort_t* xhl = xhh + (size_t)XHSZ;
    float* sc = W + REG_O;                     // 4 x SCSLOT, aliases x planes
    float* ag = W + REG_O + XHSZ;              // 4 x AGSZ
    ushort_t* pk = (ushort_t*)ag;              // PK aliases ag (dead until k_pv)
    float* tkw = W + B1_O + N1;                // b2h region (dead after k_score)
    int*   tkp = (int*)(W + B1_O + N1 + N1 / 2);
    k_hwc<<<dim3((B_ * HW + 63) / 64), 256, 0, stream>>>(flag, x, xhh, xhl);
    k_conv3<<<dim3((HW + 127) / 128, 1, B_), 256, 0, stream>>>(
        W, xhh, xhl, b1h, b1l, b2h, b2l, b3);
    k_pack<<<dim3(368, B_), 256, 0, stream>>>(b1h, b1l, pk, 0, PKSTR);
    k_colsum<<<dim3(B_, 49), 256, 0, stream>>>(b3, s3);
    k_score<<<dim3(16, 8, B_), 256, 0, stream>>>(b2h, b2l, pk, sc, 0, SCSLOT, PKSTR);
    k_topk<<<dim3((L_ + 3) / 4, B_), 256, 0, stream>>>(sc, tkw, tkp, SCSLOT);
    k_pv<<<dim3(L_, B_), 128, 0, stream>>>(tkw, tkp, b3, s3, ag, 0, AGSZ);
    k_fold<<<dim3(64, B_), 256, 0, stream>>>(flag, W, ag, d_out, 0, AGSZ);
  } else if (ws_size >= MID_BYTES) {
    ushort_t* xhh = (ushort_t*)(W + REG_O);
    ushort_t* xhl = xhh + (size_t)XHSZ;
    float* sc = W + REG_O;
    float* ag = W + REG_O + SCSLOT;
    ushort_t* pk = (ushort_t*)ag;              // PK shares the single ag slot
    k_hwc<<<dim3((B_ * HW + 63) / 64), 256, 0, stream>>>(flag, x, xhh, xhl);
    k_conv3<<<dim3((HW + 127) / 128, 1, B_), 256, 0, stream>>>(
        W, xhh, xhl, b1h, b1l, b2h, b2l, b3);
    k_colsum<<<dim3(B_, 49), 256, 0, stream>>>(b3, s3);
    for (int b = 0; b < B_; ++b) {
      float* tkw = W + B1_O + N1 + (size_t)b * (HW * CI / 2);
      int*   tkp = (int*)(W + B1_O + N1 + N1 / 2 + (size_t)b * (HW * CI / 2));
      k_pack<<<dim3(368, 1), 256, 0, stream>>>(b1h, b1l, pk, b, 0);
      k_score<<<dim3(16, 8, 1), 256, 0, stream>>>(b2h, b2l, pk, sc, b, 0, 0);
      k_topk<<<dim3((L_ + 3) / 4, 1), 256, 0, stream>>>(sc, tkw, tkp, 0);
      k_pv<<<dim3(L_, 1), 128, 0, stream>>>(tkw, tkp, b3, s3, ag, b, 0);
      k_fold<<<dim3(64, 1), 256, 0, stream>>>(flag, W, ag, d_out, b, 0);
    }
  } else {
    float* sc = W + REG_O;
    float* ag = W + REG_O + SCSLOT;
    ushort_t* pk = (ushort_t*)ag;
    k_convF<<<dim3(4, 16, B_), dim3(32, 8, 1), 0, stream>>>(
        flag, x, g_w, g_b, th_w, th_b, ph_w, ph_b, b1h, b1l, b2h, b2l, b3);
    k_colsum<<<dim3(B_, 49), 256, 0, stream>>>(b3, s3);
    for (int b = 0; b < B_; ++b) {
      float* tkw = W + B1_O + N1 + (size_t)b * (HW * CI / 2);
      int*   tkp = (int*)(W + B1_O + N1 + N1 / 2 + (size_t)b * (HW * CI / 2));
      k_pack<<<dim3(368, 1), 256, 0, stream>>>(b1h, b1l, pk, b, 0);
      k_score<<<dim3(16, 8, 1), 256, 0, stream>>>(b2h, b2l, pk, sc, b, 0, 0);
      k_topk<<<dim3((L_ + 3) / 4, 1), 256, 0, stream>>>(sc, tkw, tkp, 0);
      k_pv<<<dim3(L_, 1), 128, 0, stream>>>(tkw, tkp, b3, s3, ag, b, 0);
      k_fold<<<dim3(64, 1), 256, 0, stream>>>(flag, W, ag, d_out, b, 0);
    }
  }
}

// Round 7
// 262.835 us; speedup vs baseline: 1.7338x; 1.0300x over previous
//
#include <hip/hip_runtime.h>
#include <hip/hip_bf16.h>

typedef __hip_bfloat16 bf16;
typedef unsigned short ushort_t;
typedef __attribute__((ext_vector_type(8))) __bf16 bfv8;
typedef __attribute__((ext_vector_type(16))) float f32x16;

#define B_   4
#define CIN  64
#define CI   16
#define H_   127
#define W_   127
#define HW   (H_*W_)
#define KS   7
#define ST   4
#define OH_  31
#define L_   961
#define D_   784
#define TOPM 100

// ---- workspace layout (float offsets) ----
#define N1   1032256          // B*HW*CI elements (one conv-out array)
#define WG_O 4
#define WT_O (WG_O + 9216)
#define WP_O (WT_O + 1024)
#define BG_O (WP_O + 1024)
#define BT_O (BG_O + 16)
#define BP_O (BT_O + 16)
#define SM_O (BP_O + 16)
#define SB_O (SM_O + 16)
#define RW_O (SB_O + 16)
#define RB_O (RW_O + 1024)
#define B1_O 12448
// planes at B1_O: b1h,b1l,b2h,b2l each N1 ushorts (2*N1 floats); b3 bf16 N1 ushorts
#define S3_O (B1_O + 3*N1)
#define WB_O (S3_O + B_*D_)   // conv MFMA B: wBh + wBl = 36864 floats
#define REG_O (WB_O + 36864)
#define XHSZ 4129024          // legacy ag-region offset anchor (floats)
#define SROW 964              // padded Sc row stride
#define SCSLOT 926464
#define AGSZ 753424
#define TKROW 112
#define SLST 72               // LDS row stride in ushorts (conflict-free, measured r8)
// PK: unfold-packed A operand. Per plane: 7 nki x 961 rows x 112 ushorts = 753424.
#define PKPLANE 753424
#define PKSTR   1506848
// padded x planes: 129x129 pixels x 64 ch, zero borders -> conv3 has NO bounds logic
#define PADW 129
#define PADPIX (PADW*PADW)            // 16641
#define XPB  (PADPIX*64)              // ushorts per batch-plane = 1,065,024
#define XPU  ((size_t)B_ * XPB)       // ushorts per plane (all batches) = 4,260,096
// both planes = 2*XPU ushorts = XPU floats = 4,260,096 floats from REG_O.
// FULL tier: overlaps ag/pk first 131,072 floats -> OK, pk written after conv3.

#define FULL_BYTES ((size_t)(REG_O + XHSZ + 4*AGSZ) * 4)   // ~41.1 MB (unchanged)
#define MID_BYTES  ((size_t)(REG_O + 4260096) * 4)         // ~29.6 MB

__device__ __forceinline__ float bf2f(bf16 v) { return __bfloat162float(v); }
__device__ __forceinline__ float bflo(unsigned u) { return __uint_as_float(u << 16); }
__device__ __forceinline__ float bfhi(unsigned u) { return __uint_as_float(u & 0xFFFF0000u); }

template <typename T> struct Ld;
template <> struct Ld<float> {
  static __device__ __forceinline__ float f(const void* p, int i) { return ((const float*)p)[i]; }
};
template <> struct Ld<bf16> {
  static __device__ __forceinline__ float f(const void* p, int i) { return bf2f(((const bf16*)p)[i]); }
};

__device__ __forceinline__ unsigned fmap(float f) {
  unsigned u = __float_as_uint(f);
  return (u & 0x80000000u) ? ~u : (u | 0x80000000u);
}
__device__ __forceinline__ float unfmap(unsigned kk) {
  unsigned u = (kk & 0x80000000u) ? (kk & 0x7fffffffu) : ~kk;
  return __uint_as_float(u);
}

// RNE fp32 -> bf16 bits, and hi/lo split
__device__ __forceinline__ ushort_t f2bf(float x) {
  unsigned u = __float_as_uint(x);
  return (ushort_t)((u + 0x7FFFu + ((u >> 16) & 1u)) >> 16);
}
__device__ __forceinline__ void splitbf(float x, ushort_t& h, ushort_t& l) {
  h = f2bf(x);
  float hf = __uint_as_float(((unsigned)h) << 16);
  l = f2bf(x - hf);
}

// -------- dtype detector: flag=1 -> fp32 buffers, flag=0 -> bf16 -----------------
__global__ void k_detect(const unsigned short* __restrict__ xh, int* __restrict__ flag) {
  int tid = threadIdx.x;  // 64
  int c = 0;
#pragma unroll
  for (int j = 0; j < 2; ++j) {
    unsigned u = xh[tid * 2 + j];
    unsigned e = (u >> 7) & 0xFF;
    if (e >= 134) c++;
  }
#pragma unroll
  for (int o = 32; o; o >>= 1) c += __shfl_down(c, o);
  if (tid == 0) *flag = (c >= 8) ? 1 : 0;
}

// -------- weight prep: grid-parallel -------------------------------------------
#define LDW(ptr, i) (f ? ((const float*)(ptr))[i] : bf2f(((const bf16*)(ptr))[i]))
__global__ __launch_bounds__(256) void k_prep(
    const int* __restrict__ flag,
    const void* g_w, const void* t_w, const void* p_w,
    const void* g_b, const void* t_b, const void* p_b,
    const void* m_w, const void* m_b, const void* r_w, const void* r_b,
    float* __restrict__ ws)
{
  int f = *flag;
  int gid = blockIdx.x * 256 + threadIdx.x;
  int gs = gridDim.x * 256;
  for (int i = gid; i < 9216; i += gs) {
    int o = i & 15, t = i >> 4, c = t & 63, tap = t >> 6;
    ws[WG_O + i] = LDW(g_w, (o * 64 + c) * 9 + tap);
  }
  for (int i = gid; i < 1024; i += gs) {
    int o = i & 15, c = i >> 4;
    ws[WT_O + i] = LDW(t_w, o * 64 + c);
    ws[WP_O + i] = LDW(p_w, o * 64 + c);
  }
  if (gid < 16) {
    ws[BG_O + gid] = LDW(g_b, gid);
    ws[BT_O + gid] = LDW(t_b, gid);
    ws[BP_O + gid] = LDW(p_b, gid);
    float s = 0.f;
    for (int c = 0; c < 64; ++c) s += LDW(m_w, gid * 64 + c);
    ws[SM_O + gid] = s;
    ws[SB_O + gid] = LDW(m_b, gid);
  }
  for (int i = gid; i < 1024; i += gs) ws[RW_O + i] = LDW(r_w, i);
  if (gid >= 64 && gid < 128) ws[RB_O + gid - 64] = LDW(r_b, gid - 64);
  // conv MFMA B, split hi/lo: wB[tap][col64][c64]
  ushort_t* wBh = (ushort_t*)(ws + WB_O);
  ushort_t* wBl = wBh + 9 * 64 * 64;
  for (int i = gid; i < 9 * 64 * 64; i += gs) {
    int c = i & 63, t = i >> 6, col = t & 63, tap = t >> 6;
    float v = 0.f;
    if (col < 16) v = LDW(g_w, (col * 64 + c) * 9 + tap);
    else if (col < 32) { if (tap == 4) v = LDW(t_w, (col - 16) * 64 + c); }
    else if (col < 48) { if (tap == 4) v = LDW(p_w, (col - 32) * 64 + c); }
    ushort_t h, l; splitbf(v, h, l);
    wBh[i] = h; wBl[i] = l;
  }
}

// -------- zero the padded-plane borders (512 cells/batch, both planes) ----------
__global__ __launch_bounds__(256) void k_zpad(ushort_t* __restrict__ xhh,
                                              ushort_t* __restrict__ xhl)
{
  int idx = blockIdx.x * 256 + threadIdx.x;   // 4*512*8 = 16384 int4 writes/plane
  if (idx >= B_ * 512 * 8) return;
  int q = idx & 7, t = idx >> 3;
  int bp = t & 511, bb = t >> 9;
  int pp;
  if (bp < 129) pp = bp;                              // top row
  else if (bp < 258) pp = 128 * PADW + (bp - 129);    // bottom row
  else if (bp < 385) pp = (bp - 257) * PADW;          // left col rows 1..127
  else pp = (bp - 384) * PADW + 128;                  // right col rows 1..127
  size_t off = ((size_t)bb * PADPIX + pp) * 64 + q * 8;
  const int4 z = make_int4(0, 0, 0, 0);
  *(int4*)(xhh + off) = z;
  *(int4*)(xhl + off) = z;
}

// -------- x [B,64,H,W] -> padded HWC bf16 hi/lo planes ---------------------------
__global__ __launch_bounds__(256) void k_hwc(
    const int* __restrict__ flag, const void* __restrict__ x,
    ushort_t* __restrict__ xhh, ushort_t* __restrict__ xhl)
{
  __shared__ float tile[64][65];
  int pix0 = blockIdx.x * 64;
  int tid = threadIdx.x;
  int g = tid >> 6, p = tid & 63;
  int pix = pix0 + p;
  bool ok = pix < B_ * HW;
  int bb = ok ? pix / HW : 0;
  int r  = ok ? pix - bb * HW : 0;
  if (*flag) {
    const float* xf = (const float*)x;
    for (int c = g * 16; c < g * 16 + 16; ++c)
      tile[p][c] = ok ? xf[((size_t)bb * CIN + c) * HW + r] : 0.f;
  } else {
    const bf16* xb = (const bf16*)x;
    for (int c = g * 16; c < g * 16 + 16; ++c)
      tile[p][c] = ok ? bf2f(xb[((size_t)bb * CIN + c) * HW + r]) : 0.f;
  }
  __syncthreads();
  int c2 = tid & 63, pg = tid >> 6;
  // incremental (bb2,h2,w2) tracking: 2 divisions per thread total
  int pix2 = pix0 + pg * 16;
  int bb2 = pix2 / HW, r2 = pix2 - bb2 * HW;
  int h2 = r2 / W_, w2 = r2 - h2 * W_;
  for (int k = 0; k < 16; ++k) {
    if (pix2 + k < B_ * HW) {
      ushort_t h, l; splitbf(tile[pg * 16 + k][c2], h, l);
      size_t off = ((size_t)bb2 * PADPIX + (size_t)(h2 + 1) * PADW + (w2 + 1)) * 64 + c2;
      xhh[off] = h;
      xhl[off] = l;
    }
    if (++w2 == W_) { w2 = 0; if (++h2 == H_) { h2 = 0; ++bb2; } }
  }
}

// -------- split-bf16 MFMA conv, one output row per block, contiguous staging -----
// Tile = row h (127 pixels + 1 dead). Padded zero-border planes -> taps are pure
// contiguous loads: ONE base + immediate offsets, named regs (r4 k_score recipe).
// Accumulation order identical to round-0 -> bitwise-identical outputs.
__global__ __launch_bounds__(256) void k_conv3(
    const float* __restrict__ ws,
    const ushort_t* __restrict__ xhh, const ushort_t* __restrict__ xhl,
    ushort_t* __restrict__ b1h, ushort_t* __restrict__ b1l,
    ushort_t* __restrict__ b2h, ushort_t* __restrict__ b2l,
    ushort_t* __restrict__ b3)
{
  __shared__ ushort_t sAh[128 * SLST], sAl[128 * SLST];
  __shared__ ushort_t sBh[64 * SLST],  sBl[64 * SLST];
  int bz = blockIdx.z;
  int h = blockIdx.x;                       // output row
  int tid = threadIdx.x, lane = tid & 63, wv = tid >> 6;
  int grp = lane >> 3, ch = lane & 7;

  const ushort_t* xplane = ((wv == 0) ? xhh : xhl) + (size_t)bz * XPB;
  const ushort_t* wBh_ = (const ushort_t*)(ws + WB_O);
  const ushort_t* bsrc = (wv == 2) ? wBh_ : (wBh_ + 9 * 64 * 64);
  ushort_t* dplane = (wv == 0) ? sAh : (wv == 1) ? sAl : (wv == 2) ? sBh : sBl;

  int fr = lane & 31, kh = (lane >> 5) << 3;
  int mt = (wv >> 1) << 1;
  int aoff0 = (mt * 32 + fr) * SLST + kh;
  int aoff1 = ((mt + 1) * 32 + fr) * SLST + kh;
  int boff  = (((wv & 1) << 5) + fr) * SLST + kh;

  f32x16 acc0 = {0.f,0.f,0.f,0.f,0.f,0.f,0.f,0.f,0.f,0.f,0.f,0.f,0.f,0.f,0.f,0.f};
  f32x16 acc1 = {0.f,0.f,0.f,0.f,0.f,0.f,0.f,0.f,0.f,0.f,0.f,0.f,0.f,0.f,0.f,0.f};

  int4 pv0, pv1, pv2, pv3, pv4, pv5, pv6, pv7;
  int4 pv8, pv9, pv10, pv11, pv12, pv13, pv14, pv15;

#define LC(j) pv##j = *(const int4*)(src + (j) * 512)
#define LC_A  LC(0); LC(1); LC(2); LC(3); LC(4); LC(5); LC(6); LC(7); \
              LC(8); LC(9); LC(10); LC(11); LC(12); LC(13); LC(14); LC(15)
#define LC_W  LC(0); LC(1); LC(2); LC(3); LC(4); LC(5); LC(6); LC(7)
#define WC(j) *(int4*)(d0 + (j) * 8 * SLST) = pv##j
#define WC_A  WC(0); WC(1); WC(2); WC(3); WC(4); WC(5); WC(6); WC(7); \
              WC(8); WC(9); WC(10); WC(11); WC(12); WC(13); WC(14); WC(15)
#define WC_W  WC(0); WC(1); WC(2); WC(3); WC(4); WC(5); WC(6); WC(7)

  // prefetch tap 0 (dh=-1, dw=-1): padded row h, col 0
  if (wv < 2) {
    const ushort_t* src = xplane + (size_t)h * (PADW * 64) + grp * 64 + ch * 8;
    LC_A;
  } else {
    const ushort_t* src = bsrc + grp * 64 + ch * 8;
    LC_W;
  }

  for (int r = 0; r < 9; ++r) {
    __syncthreads();
    {
      ushort_t* d0 = dplane + grp * SLST + ch * 8;
      if (wv < 2) { WC_A; } else { WC_W; }
    }
    __syncthreads();
    if (r < 8) {
      int rn = r + 1;
      int dh = rn / 3 - 1, dw = rn % 3 - 1;
      if (wv < 2) {
        const ushort_t* src = xplane
            + ((size_t)(h + 1 + dh) * PADW + (1 + dw)) * 64 + grp * 64 + ch * 8;
        LC_A;
      } else {
        const ushort_t* src = bsrc + rn * 4096 + grp * 64 + ch * 8;
        LC_W;
      }
    }
#pragma unroll
    for (int t = 0; t < 4; ++t) {
      bfv8 ah0 = *(const bfv8*)(sAh + aoff0 + t * 16);
      bfv8 al0 = *(const bfv8*)(sAl + aoff0 + t * 16);
      bfv8 ah1 = *(const bfv8*)(sAh + aoff1 + t * 16);
      bfv8 al1 = *(const bfv8*)(sAl + aoff1 + t * 16);
      bfv8 bh  = *(const bfv8*)(sBh + boff + t * 16);
      bfv8 bl  = *(const bfv8*)(sBl + boff + t * 16);
      acc0 = __builtin_amdgcn_mfma_f32_32x32x16_bf16(al0, bh, acc0, 0, 0, 0);
      acc0 = __builtin_amdgcn_mfma_f32_32x32x16_bf16(ah0, bl, acc0, 0, 0, 0);
      acc0 = __builtin_amdgcn_mfma_f32_32x32x16_bf16(ah0, bh, acc0, 0, 0, 0);
      acc1 = __builtin_amdgcn_mfma_f32_32x32x16_bf16(al1, bh, acc1, 0, 0, 0);
      acc1 = __builtin_amdgcn_mfma_f32_32x32x16_bf16(ah1, bl, acc1, 0, 0, 0);
      acc1 = __builtin_amdgcn_mfma_f32_32x32x16_bf16(ah1, bh, acc1, 0, 0, 0);
    }
  }
#undef LC
#undef LC_A
#undef LC_W
#undef WC
#undef WC_A
#undef WC_W

  int nw = ((wv & 1) << 5) + fr;
#pragma unroll
  for (int s = 0; s < 2; ++s) {
    int mbase = (mt + s) * 32;
#pragma unroll
    for (int r = 0; r < 16; ++r) {
      int m = mbase + (r & 3) + ((r >> 2) << 3) + ((lane >> 5) << 2);
      if (m >= W_) continue;                 // dead 128th pixel of the row tile
      int p2 = h * W_ + m;
      size_t ob = ((size_t)bz * HW + p2) * 16;
      float val = s ? acc1[r] : acc0[r];
      if (nw < 16) {
        ushort_t h2, l2; splitbf(val + ws[BG_O + nw], h2, l2);
        b1h[ob + nw] = h2; b1l[ob + nw] = l2;
      } else if (nw < 32) {
        int o = nw - 16; ushort_t h2, l2; splitbf(val + ws[BT_O + o], h2, l2);
        b2h[ob + o] = h2; b2l[ob + o] = l2;
      } else if (nw < 48) {
        int o = nw - 32; b3[ob + o] = f2bf(val + ws[BP_O + o]);
      }
    }
  }
}

// -------- fallback conv (LOW tier), dtype-templated VALU -------------------------
template <typename T>
__device__ __forceinline__ void convF_body(
    const void* x, const void* g_w, const void* g_b,
    const void* t_w, const void* t_b, const void* p_w, const void* p_b,
    ushort_t* b1h, ushort_t* b1l, ushort_t* b2h, ushort_t* b2l, ushort_t* b3,
    float* sgw, float* stw, float* spw)
{
  int tid = threadIdx.y * 32 + threadIdx.x;
  for (int i = tid; i < CI * CIN * 9; i += 256) sgw[i] = Ld<T>::f(g_w, i);
  for (int i = tid; i < CI * CIN; i += 256) { stw[i] = Ld<T>::f(t_w, i); spw[i] = Ld<T>::f(p_w, i); }
  __syncthreads();

  int w = blockIdx.x * 32 + threadIdx.x;
  int h = blockIdx.y * 8 + threadIdx.y;
  int b = blockIdx.z;
  if (w >= W_ || h >= H_) return;

  float a1[CI], a2[CI], a3[CI];
#pragma unroll
  for (int o = 0; o < CI; ++o) { a1[o] = 0.f; a2[o] = 0.f; a3[o] = 0.f; }

  const size_t xb = (size_t)b * CIN * HW;
  for (int c = 0; c < CIN; ++c) {
    float xv[9];
#pragma unroll
    for (int dh = 0; dh < 3; ++dh) {
      int hh = h + dh - 1;
      bool rok = ((unsigned)hh < (unsigned)H_);
#pragma unroll
      for (int dw = 0; dw < 3; ++dw) {
        int ww = w + dw - 1;
        bool ok = rok && ((unsigned)ww < (unsigned)W_);
        xv[dh * 3 + dw] = ok ? Ld<T>::f(x, (int)(xb + (size_t)c * HW + hh * W_ + ww)) : 0.f;
      }
    }
    float xc = xv[4];
#pragma unroll
    for (int o = 0; o < CI; ++o) {
      const float* gg = &sgw[(o * CIN + c) * 9];
      float s = gg[0]*xv[0] + gg[1]*xv[1] + gg[2]*xv[2]
              + gg[3]*xv[3] + gg[4]*xv[4] + gg[5]*xv[5]
              + gg[6]*xv[6] + gg[7]*xv[7] + gg[8]*xv[8];
      a1[o] += s;
      a2[o] += stw[o * CIN + c] * xc;
      a3[o] += spw[o * CIN + c] * xc;
    }
  }
  size_t base = ((size_t)b * HW + h * W_ + w) * CI;
#pragma unroll
  for (int o = 0; o < CI; ++o) {
    float v1 = a1[o] + Ld<T>::f(g_b, o);
    float v2 = a2[o] + Ld<T>::f(t_b, o);
    ushort_t hh2, ll2;
    splitbf(v1, hh2, ll2); b1h[base + o] = hh2; b1l[base + o] = ll2;
    splitbf(v2, hh2, ll2); b2h[base + o] = hh2; b2l[base + o] = ll2;
    b3[base + o] = f2bf(a3[o] + Ld<T>::f(p_b, o));
  }
}

__global__ __launch_bounds__(256) void k_convF(
    const int* __restrict__ flag, const void* x,
    const void* g_w, const void* g_b, const void* t_w, const void* t_b,
    const void* p_w, const void* p_b,
    ushort_t* __restrict__ b1h, ushort_t* __restrict__ b1l,
    ushort_t* __restrict__ b2h, ushort_t* __restrict__ b2l,
    ushort_t* __restrict__ b3)
{
  __shared__ float sgw[CI * CIN * 9];
  __shared__ float stw[CI * CIN];
  __shared__ float spw[CI * CIN];
  if (*flag) convF_body<float>(x, g_w, g_b, t_w, t_b, p_w, p_b, b1h, b1l, b2h, b2l, b3, sgw, stw, spw);
  else       convF_body<bf16 >(x, g_w, g_b, t_w, t_b, p_w, p_b, b1h, b1l, b2h, b2l, b3, sgw, stw, spw);
}

// -------- S3[b, pos*16+c] = sum over patches of b3 (bf16 src, fp32 acc) ----------
__global__ __launch_bounds__(256) void k_colsum(const ushort_t* __restrict__ b3, float* __restrict__ S3)
{
  __shared__ float red[16][17];
  int b = blockIdx.x, pos = blockIdx.y;
  int ki = pos / 7, kj = pos % 7;
  int c = threadIdx.x & 15, chunk = threadIdx.x >> 4;
  const ushort_t* B3 = b3 + (size_t)b * HW * CI;
  float s = 0.f;
  for (int l = chunk; l < L_; l += 16) {
    int lh = l / OH_, lw = l % OH_;
    s += bflo((unsigned)B3[((lh * ST + ki) * W_ + lw * ST + kj) * CI + c]);
  }
  red[chunk][c] = s;
  __syncthreads();
  if (threadIdx.x < 16) {
    float t = 0.f;
#pragma unroll
    for (int k = 0; k < 16; ++k) t += red[k][threadIdx.x];
    S3[(b * 49 + pos) * 16 + threadIdx.x] = t;
  }
}

// -------- pack A operand: PK[plane][nki][row][112] = b1 patch-row segments -------
__global__ __launch_bounds__(256) void k_pack(
    const ushort_t* __restrict__ b1h, const ushort_t* __restrict__ b1l,
    ushort_t* __restrict__ pk, int b0, unsigned pkstride_z)
{
  int idx = blockIdx.x * 256 + threadIdx.x;
  if (idx >= 961 * 98) return;
  int row = idx / 98, rem = idx - row * 98;
  int nki = rem / 14, q = rem - nki * 14;
  int slh = row / OH_, slw = row - slh * OH_;
  int src = ((slh * ST) * W_ + slw * ST + nki * W_) * 16 + q * 8;
  int dst = (nki * 961 + row) * 112 + q * 8;
  int batch = b0 + blockIdx.y;
  size_t poff = (size_t)batch * HW * CI;
  ushort_t* pkb = pk + (size_t)blockIdx.y * pkstride_z;
  *(int4*)(pkb + dst)           = *(const int4*)(b1h + poff + src);
  *(int4*)(pkb + PKPLANE + dst) = *(const int4*)(b1l + poff + src);
}

// -------- score GEMM via split-bf16 MFMA, 128x64 tile (r4-verified) --------------
__global__ __launch_bounds__(256) void k_score(
    const ushort_t* __restrict__ b2h, const ushort_t* __restrict__ b2l,
    const ushort_t* __restrict__ pk,
    float* __restrict__ scb, int b0, unsigned scstride_z, unsigned pkstride_z)
{
  __shared__ ushort_t sAh[128 * SLST], sAl[128 * SLST];
  __shared__ ushort_t sBh[64 * SLST],  sBl[64 * SLST];
  int batch = b0 + blockIdx.z;
  size_t poff_g = (size_t)batch * HW * CI;
  float* Sc = scb + (size_t)blockIdx.z * scstride_z;

  int tid = threadIdx.x;
  int m0 = blockIdx.y * 128, n0 = blockIdx.x * 64;
  int lane = tid & 63;
  int wv = tid >> 6;
  int grp = lane >> 3, ch = lane & 7;

  const ushort_t* pkb = pk + (size_t)blockIdx.z * pkstride_z + (size_t)(wv & 1) * PKPLANE;

  // B-side per-lane-row base (wv>=2)
  int srow = n0 + lane;  if (srow > L_ - 1) srow = L_ - 1;
  int slh = srow / OH_, slw = srow - slh * OH_;
  int sbase = (slh * ST) * W_ + slw * ST;
  const ushort_t* splane = (wv == 2) ? (b2h + poff_g) : (b2l + poff_g);
  ushort_t* dplane = (wv == 0) ? sAh : (wv == 1) ? sAl : (wv == 2) ? sBh : sBl;
  ushort_t* drowB = dplane + lane * SLST;

  int fr = lane & 31;
  int kh = (lane >> 5) << 3;
  int mt = (wv >> 1) << 1;                         // first m-subtile: 0 or 2
  int aoff0 = (mt * 32 + fr) * SLST + kh;
  int aoff1 = ((mt + 1) * 32 + fr) * SLST + kh;
  int boff  = (((wv & 1) << 5) + fr) * SLST + kh;

  f32x16 acc0 = {0.f,0.f,0.f,0.f,0.f,0.f,0.f,0.f,0.f,0.f,0.f,0.f,0.f,0.f,0.f,0.f};
  f32x16 acc1 = {0.f,0.f,0.f,0.f,0.f,0.f,0.f,0.f,0.f,0.f,0.f,0.f,0.f,0.f,0.f,0.f};

  int4 pv0, pv1, pv2, pv3, pv4, pv5, pv6, pv7;
  int4 pv8, pv9, pv10, pv11, pv12, pv13, pv14, pv15;

#define LA(j) pv##j = *(const int4*)(pks + (size_t)min(m0 + 8*j + grp, 960) * 112)
#define LA_ALL LA(0); LA(1); LA(2); LA(3); LA(4); LA(5); LA(6); LA(7); \
               LA(8); LA(9); LA(10); LA(11); LA(12); LA(13); LA(14); LA(15)
#define WA(j) *(int4*)(d0 + (j) * 8 * SLST) = pv##j
#define WA_ALL WA(0); WA(1); WA(2); WA(3); WA(4); WA(5); WA(6); WA(7); \
               WA(8); WA(9); WA(10); WA(11); WA(12); WA(13); WA(14); WA(15)

  // initial prefetch: rn=0 (nki=0, even)
  if (wv < 2) {
    const ushort_t* pks = pkb + ch * 8;
    LA_ALL;
  } else {
    const int4* s0 = (const int4*)(splane + (size_t)sbase * 16);
    pv0 = s0[0]; pv1 = s0[1]; pv2 = s0[2]; pv3 = s0[3];
    pv4 = s0[4]; pv5 = s0[5]; pv6 = s0[6]; pv7 = s0[7];
  }

  for (int r = 0; r < 14; ++r) {
    int half = r & 1;
    __syncthreads();
    if (wv < 2) {
      ushort_t* d0 = dplane + grp * SLST + ch * 8;
      if (!half) { WA_ALL; }
      else if (ch < 6) { WA_ALL; }
    } else {
      *(int4*)(drowB + 0)  = pv0;  *(int4*)(drowB + 8)  = pv1;
      *(int4*)(drowB + 16) = pv2;  *(int4*)(drowB + 24) = pv3;
      *(int4*)(drowB + 32) = pv4;  *(int4*)(drowB + 40) = pv5;
      if (!half) { *(int4*)(drowB + 48) = pv6; *(int4*)(drowB + 56) = pv7; }
    }
    __syncthreads();
    if (r < 13) {
      int rn = r + 1;
      int nki = rn >> 1, odd = rn & 1;
      if (wv < 2) {
        const ushort_t* pks = pkb + (size_t)nki * (961 * 112) + odd * 64 + ch * 8;
        if (!odd) { LA_ALL; }
        else if (ch < 6) { LA_ALL; }
      } else {
        int nkj0 = odd * 4;
        const int4* s0 = (const int4*)(splane + (size_t)(sbase + nki * W_ + nkj0) * 16);
        pv0 = s0[0]; pv1 = s0[1]; pv2 = s0[2]; pv3 = s0[3]; pv4 = s0[4]; pv5 = s0[5];
        if (!odd) { pv6 = s0[6]; pv7 = s0[7]; }
      }
    }
    if (!half) {
#pragma unroll
      for (int t = 0; t < 4; ++t) {
        bfv8 ah0 = *(const bfv8*)(sAh + aoff0 + t * 16);
        bfv8 al0 = *(const bfv8*)(sAl + aoff0 + t * 16);
        bfv8 ah1 = *(const bfv8*)(sAh + aoff1 + t * 16);
        bfv8 al1 = *(const bfv8*)(sAl + aoff1 + t * 16);
        bfv8 bh  = *(const bfv8*)(sBh + boff + t * 16);
        bfv8 bl  = *(const bfv8*)(sBl + boff + t * 16);
        acc0 = __builtin_amdgcn_mfma_f32_32x32x16_bf16(al0, bh, acc0, 0, 0, 0);
        acc0 = __builtin_amdgcn_mfma_f32_32x32x16_bf16(ah0, bl, acc0, 0, 0, 0);
        acc0 = __builtin_amdgcn_mfma_f32_32x32x16_bf16(ah0, bh, acc0, 0, 0, 0);
        acc1 = __builtin_amdgcn_mfma_f32_32x32x16_bf16(al1, bh, acc1, 0, 0, 0);
        acc1 = __builtin_amdgcn_mfma_f32_32x32x16_bf16(ah1, bl, acc1, 0, 0, 0);
        acc1 = __builtin_amdgcn_mfma_f32_32x32x16_bf16(ah1, bh, acc1, 0, 0, 0);
      }
    } else {
#pragma unroll
      for (int t = 0; t < 3; ++t) {
        bfv8 ah0 = *(const bfv8*)(sAh + aoff0 + t * 16);
        bfv8 al0 = *(const bfv8*)(sAl + aoff0 + t * 16);
        bfv8 ah1 = *(const bfv8*)(sAh + aoff1 + t * 16);
        bfv8 al1 = *(const bfv8*)(sAl + aoff1 + t * 16);
        bfv8 bh  = *(const bfv8*)(sBh + boff + t * 16);
        bfv8 bl  = *(const bfv8*)(sBl + boff + t * 16);
        acc0 = __builtin_amdgcn_mfma_f32_32x32x16_bf16(al0, bh, acc0, 0, 0, 0);
        acc0 = __builtin_amdgcn_mfma_f32_32x32x16_bf16(ah0, bl, acc0, 0, 0, 0);
        acc0 = __builtin_amdgcn_mfma_f32_32x32x16_bf16(ah0, bh, acc0, 0, 0, 0);
        acc1 = __builtin_amdgcn_mfma_f32_32x32x16_bf16(al1, bh, acc1, 0, 0, 0);
        acc1 = __builtin_amdgcn_mfma_f32_32x32x16_bf16(ah1, bl, acc1, 0, 0, 0);
        acc1 = __builtin_amdgcn_mfma_f32_32x32x16_bf16(ah1, bh, acc1, 0, 0, 0);
      }
    }
  }
#undef LA
#undef LA_ALL
#undef WA
#undef WA_ALL

  int nw = n0 + ((wv & 1) << 5) + fr;
  if (nw < L_) {
    int mw0 = m0 + mt * 32;
#pragma unroll
    for (int r = 0; r < 16; ++r) {
      int m = mw0 + (r & 3) + ((r >> 2) << 3) + ((lane >> 5) << 2);
      if (m < L_) Sc[(size_t)m * SROW + nw] = acc0[r];
    }
    int mw1 = m0 + (mt + 1) * 32;
#pragma unroll
    for (int r = 0; r < 16; ++r) {
      int m = mw1 + (r & 3) + ((r >> 2) << 3) + ((lane >> 5) << 2);
      if (m < L_) Sc[(size_t)m * SROW + nw] = acc1[r];
    }
  }
}

// -------- top-100 + softmax weights: ballot-radix (r6-verified) ------------------
__global__ __launch_bounds__(256) void k_topk(
    const float* __restrict__ scb, float* __restrict__ tkw, int* __restrict__ tkp,
    unsigned scstride_z)
{
  __shared__ float swv[4][TOPM];
  __shared__ int spx[4][TOPM];
  int tid = threadIdx.x;
  int wvi = tid >> 6, lane = tid & 63;
  int l = blockIdx.x * 4 + wvi;
  if (l > L_ - 1) l = L_ - 1;        // clamp: duplicate rows write identical data
  int bz = blockIdx.y;
  const float4* row4 = (const float4*)(scb + (size_t)bz * scstride_z + (size_t)l * SROW);
  int trow = (bz * L_ + l) * TKROW;

  unsigned k[16];
#pragma unroll
  for (int q = 0; q < 4; ++q) {
    float4 v = row4[q * 64 + lane];
    int ib = (q * 64 + lane) * 4;
    k[q * 4 + 0] = (ib + 0 < L_) ? fmap(v.x) : 0u;
    k[q * 4 + 1] = (ib + 1 < L_) ? fmap(v.y) : 0u;
    k[q * 4 + 2] = (ib + 2 < L_) ? fmap(v.z) : 0u;
    k[q * 4 + 3] = (ib + 3 < L_) ? fmap(v.w) : 0u;
  }

  unsigned mk = 0;
#pragma unroll
  for (int r = 0; r < 16; ++r) mk = max(mk, k[r]);
#pragma unroll
  for (int o = 32; o; o >>= 1) mk = max(mk, (unsigned)__shfl_down((int)mk, o));
  mk = (unsigned)__shfl((int)mk, 0);
  float vmax = unfmap(mk);

  unsigned kk[16];
#pragma unroll
  for (int r = 0; r < 16; ++r) kk[r] = k[r];

  unsigned prefix = 0; int base = 0;
  for (int bit = 30; bit >= 0; bit -= 2) {
    int n3 = 0, n2 = 0, n1 = 0;
#pragma unroll
    for (int r = 0; r < 16; ++r) {
      unsigned f = (kk[r] >> bit) & 3u;
      n3 += (int)__popcll(__ballot(f == 3u));
      n2 += (int)__popcll(__ballot(f >= 2u));
      n1 += (int)__popcll(__ballot(f >= 1u));
    }
    unsigned ch;
    if (base + n3 >= TOPM) ch = 3;
    else if (base + n2 >= TOPM) { ch = 2; base += n3; }
    else if (base + n1 >= TOPM) { ch = 1; base += n2; }
    else { ch = 0; base += n1; }
    prefix |= ch << bit;
#pragma unroll
    for (int r = 0; r < 16; ++r) {
      unsigned f = (kk[r] >> bit) & 3u;
      kk[r] = (f == ch) ? kk[r] : 0u;
    }
  }
  int nA = base;
  int needT = TOPM - nA;

  int cA = 0, cT = 0;
#pragma unroll
  for (int r = 0; r < 16; ++r) { cA += (k[r] > prefix); cT += (k[r] == prefix); }
  int pk = cA | (cT << 16);
  int incl = pk;
#pragma unroll
  for (int o = 1; o < 64; o <<= 1) { int t = __shfl_up(incl, o); if (lane >= o) incl += t; }
  int excl = incl - pk;
  int tA = excl & 0xFFFF, tT = excl >> 16;

  float M = fmaxf(10.f * vmax, 0.f);
  float e0 = __expf(-M);
  float z = 0.f;
#pragma unroll
  for (int r = 0; r < 16; ++r) {
    unsigned kr = k[r];
    int slot = -1;
    if (kr > prefix) slot = tA++;
    else if (kr == prefix) { if (tT < needT) slot = nA + tT; tT++; }
    if (slot >= 0) {
      float v = unfmap(kr);
      float wv = __expf(10.f * v - M);
      swv[wvi][slot] = wv; z += wv;
      int gi = 256 * (r >> 2) + 4 * lane + (r & 3);
      int lh = gi / OH_, lw = gi - lh * OH_;
      spx[wvi][slot] = ((lh * ST) * W_ + lw * ST) * CI;
    }
  }
#pragma unroll
  for (int o = 32; o; o >>= 1) z += __shfl_down(z, o);
  z = __shfl(z, 0);
  float Z = z + (float)(L_ - TOPM) * e0;
  float invZ = 1.f / Z;
  float w0 = e0 / Z;
  __syncthreads();
#pragma unroll
  for (int s0 = 0; s0 < 2; ++s0) {
    int s = lane + 64 * s0;
    if (s < TOPM) {
      tkw[trow + s] = swv[wvi][s] * invZ - w0;
      tkp[trow + s] = spx[wvi][s];
    }
  }
  if (lane == 0) tkw[trow + TOPM] = w0;
}

// -------- PV gather (bf16 b3, uint4 full-line): 98 lanes x 8 channels ------------
__global__ __launch_bounds__(128) void k_pv(
    const float* __restrict__ tkw, const int* __restrict__ tkp,
    const ushort_t* __restrict__ b3, const float* __restrict__ s3,
    float* __restrict__ agb, int b0, unsigned agstride_z)
{
  int l = blockIdx.x, bz = blockIdx.y;
  int batch = b0 + bz;
  int trow = (bz * L_ + l) * TKROW;
  const ushort_t* B3 = b3 + (size_t)batch * HW * CI;
  const float* S3 = s3 + (size_t)batch * D_;
  float* agg = agb + (size_t)bz * agstride_z;
  int tid = threadIdx.x;
  if (tid >= 98) return;

  float w0 = tkw[trow + TOPM];
  int pos = tid >> 1;
  int c0 = (tid & 1) << 3;                 // 0 or 8
  int ki = pos / 7, kj = pos - (pos / 7) * 7;
  int poff = (ki * W_ + kj) * CI + c0;

  float a0 = 0.f, a1 = 0.f, a2 = 0.f, a3 = 0.f;
  float a4 = 0.f, a5 = 0.f, a6 = 0.f, a7 = 0.f;
  for (int j0 = 0; j0 < TOPM; j0 += 4) {
    float w_0 = tkw[trow + j0 + 0];
    float w_1 = tkw[trow + j0 + 1];
    float w_2 = tkw[trow + j0 + 2];
    float w_3 = tkw[trow + j0 + 3];
    int p_0 = tkp[trow + j0 + 0];
    int p_1 = tkp[trow + j0 + 1];
    int p_2 = tkp[trow + j0 + 2];
    int p_3 = tkp[trow + j0 + 3];
    const uint4 q0 = *(const uint4*)(B3 + p_0 + poff);
    const uint4 q1 = *(const uint4*)(B3 + p_1 + poff);
    const uint4 q2 = *(const uint4*)(B3 + p_2 + poff);
    const uint4 q3 = *(const uint4*)(B3 + p_3 + poff);
    a0 += w_0 * bflo(q0.x); a1 += w_0 * bfhi(q0.x); a2 += w_0 * bflo(q0.y); a3 += w_0 * bfhi(q0.y);
    a4 += w_0 * bflo(q0.z); a5 += w_0 * bfhi(q0.z); a6 += w_0 * bflo(q0.w); a7 += w_0 * bfhi(q0.w);
    a0 += w_1 * bflo(q1.x); a1 += w_1 * bfhi(q1.x); a2 += w_1 * bflo(q1.y); a3 += w_1 * bfhi(q1.y);
    a4 += w_1 * bflo(q1.z); a5 += w_1 * bfhi(q1.z); a6 += w_1 * bflo(q1.w); a7 += w_1 * bfhi(q1.w);
    a0 += w_2 * bflo(q2.x); a1 += w_2 * bfhi(q2.x); a2 += w_2 * bflo(q2.y); a3 += w_2 * bfhi(q2.y);
    a4 += w_2 * bflo(q2.z); a5 += w_2 * bfhi(q2.z); a6 += w_2 * bflo(q2.w); a7 += w_2 * bfhi(q2.w);
    a0 += w_3 * bflo(q3.x); a1 += w_3 * bfhi(q3.x); a2 += w_3 * bflo(q3.y); a3 += w_3 * bfhi(q3.y);
    a4 += w_3 * bflo(q3.z); a5 += w_3 * bfhi(q3.z); a6 += w_3 * bflo(q3.w); a7 += w_3 * bfhi(q3.w);
  }
  const float4 s40 = *(const float4*)(S3 + tid * 8);
  const float4 s41 = *(const float4*)(S3 + tid * 8 + 4);
  a0 += w0 * s40.x; a1 += w0 * s40.y; a2 += w0 * s40.z; a3 += w0 * s40.w;
  a4 += w0 * s41.x; a5 += w0 * s41.y; a6 += w0 * s41.z; a7 += w0 * s41.w;
  float* dst = agg + (size_t)l * D_ + tid * 8;
  *(float4*)(dst)     = make_float4(a0, a1, a2, a3);
  *(float4*)(dst + 4) = make_float4(a4, a5, a6, a7);
}

// -------- fold + mask divide + restore (16->64), batched -------------------------
__global__ __launch_bounds__(256) void k_fold(
    const int* __restrict__ flag, const float* __restrict__ ws,
    const float* __restrict__ agb, void* __restrict__ out,
    int b0, unsigned agstride_z)
{
  __shared__ float srw[CIN * CI];
  int tid = threadIdx.x;
  for (int i = tid; i < CIN * CI; i += 256) srw[i] = ws[RW_O + i];
  __syncthreads();

  int bz = blockIdx.y;
  int batch = b0 + bz;
  const float* agg = agb + (size_t)bz * agstride_z;

  int gid = blockIdx.x * 256 + tid;
  if (gid >= HW) return;
  int h = gid / W_;
  int w = gid % W_;

  int lh0 = (h >= KS - 1) ? ((h - (KS - 1) + (ST - 1)) >> 2) : 0;
  int lh1 = min(OH_ - 1, h >> 2);
  int lw0 = (w >= KS - 1) ? ((w - (KS - 1) + (ST - 1)) >> 2) : 0;
  int lw1 = min(OH_ - 1, w >> 2);

  float t[CI];
#pragma unroll
  for (int c = 0; c < CI; ++c) t[c] = 0.f;
  for (int lh = lh0; lh <= lh1; ++lh) {
    int ki = h - ST * lh;
    for (int lw = lw0; lw <= lw1; ++lw) {
      int kj = w - ST * lw;
      const float* pb = agg + (size_t)(lh * OH_ + lw) * D_ + (ki * KS + kj) * CI;
      float4 q0 = *(const float4*)(pb);
      float4 q1 = *(const float4*)(pb + 4);
      float4 q2 = *(const float4*)(pb + 8);
      float4 q3 = *(const float4*)(pb + 12);
      t[0] += q0.x; t[1] += q0.y; t[2] += q0.z; t[3] += q0.w;
      t[4] += q1.x; t[5] += q1.y; t[6] += q1.z; t[7] += q1.w;
      t[8] += q2.x; t[9] += q2.y; t[10] += q2.z; t[11] += q2.w;
      t[12] += q3.x; t[13] += q3.y; t[14] += q3.z; t[15] += q3.w;
    }
  }
  float cnt = (float)((lh1 - lh0 + 1) * (lw1 - lw0 + 1));
  float r[CI];
#pragma unroll
  for (int c = 0; c < CI; ++c) r[c] = t[c] / (cnt * ws[SM_O + c] + ws[SB_O + c] + 1e-8f);

  size_t ob = (size_t)batch * CIN * HW + (size_t)h * W_ + w;
  if (*flag) {
    float* of = (float*)out;
#pragma unroll
    for (int o = 0; o < CIN; ++o) {
      float s = ws[RB_O + o];
#pragma unroll
      for (int c = 0; c < CI; ++c) s += srw[o * CI + c] * r[c];
      of[ob + (size_t)o * HW] = s;
    }
  } else {
    bf16* of = (bf16*)out;
#pragma unroll
    for (int o = 0; o < CIN; ++o) {
      float s = ws[RB_O + o];
#pragma unroll
      for (int c = 0; c < CI; ++c) s += srw[o * CI + c] * r[c];
      of[ob + (size_t)o * HW] = __float2bfloat16(s);
    }
  }
}

extern "C" void kernel_launch(void* const* d_in, const int* in_sizes, int n_in,
                              void* d_out, int out_size, void* d_ws, size_t ws_size,
                              hipStream_t stream)
{
  const void* x    = d_in[0];
  const void* g_w  = d_in[1];
  const void* g_b  = d_in[2];
  const void* th_w = d_in[3];
  const void* th_b = d_in[4];
  const void* ph_w = d_in[5];
  const void* ph_b = d_in[6];
  const void* m_w  = d_in[7];
  const void* m_b  = d_in[8];
  const void* r_w  = d_in[9];
  const void* r_b  = d_in[10];

  float* W = (float*)d_ws;
  int* flag = (int*)d_ws;
  ushort_t* planes = (ushort_t*)(W + B1_O);
  ushort_t* b1h = planes;
  ushort_t* b1l = planes + (size_t)N1;
  ushort_t* b2h = planes + (size_t)2 * N1;
  ushort_t* b2l = planes + (size_t)3 * N1;
  ushort_t* b3  = planes + (size_t)4 * N1;   // bf16 plane, N1 ushorts
  float* s3 = W + S3_O;

  k_detect<<<1, 64, 0, stream>>>((const unsigned short*)x, flag);
  k_prep<<<64, 256, 0, stream>>>(flag, g_w, th_w, ph_w, g_b, th_b, ph_b,
                                 m_w, m_b, r_w, r_b, W);

  if (ws_size >= FULL_BYTES) {
    ushort_t* xhh = (ushort_t*)(W + REG_O);    // padded planes, dead after conv
    ushort_t* xhl = xhh + XPU;
    float* sc = W + REG_O;                     // 4 x SCSLOT, aliases x planes
    float* ag = W + REG_O + XHSZ;              // 4 x AGSZ (planes overlap head; pk after conv)
    ushort_t* pk = (ushort_t*)ag;              // PK aliases ag (dead until k_pv)
    float* tkw = W + B1_O + N1;                // b2h region (dead after k_score)
    int*   tkp = (int*)(W + B1_O + N1 + N1 / 2);
    k_zpad<<<64, 256, 0, stream>>>(xhh, xhl);
    k_hwc<<<dim3((B_ * HW + 63) / 64), 256, 0, stream>>>(flag, x, xhh, xhl);
    k_conv3<<<dim3(H_, 1, B_), 256, 0, stream>>>(
        W, xhh, xhl, b1h, b1l, b2h, b2l, b3);
    k_pack<<<dim3(368, B_), 256, 0, stream>>>(b1h, b1l, pk, 0, PKSTR);
    k_colsum<<<dim3(B_, 49), 256, 0, stream>>>(b3, s3);
    k_score<<<dim3(16, 8, B_), 256, 0, stream>>>(b2h, b2l, pk, sc, 0, SCSLOT, PKSTR);
    k_topk<<<dim3((L_ + 3) / 4, B_), 256, 0, stream>>>(sc, tkw, tkp, SCSLOT);
    k_pv<<<dim3(L_, B_), 128, 0, stream>>>(tkw, tkp, b3, s3, ag, 0, AGSZ);
    k_fold<<<dim3(64, B_), 256, 0, stream>>>(flag, W, ag, d_out, 0, AGSZ);
  } else if (ws_size >= MID_BYTES) {
    ushort_t* xhh = (ushort_t*)(W + REG_O);
    ushort_t* xhl = xhh + XPU;
    float* sc = W + REG_O;
    float* ag = W + REG_O + SCSLOT;
    ushort_t* pk = (ushort_t*)ag;              // PK shares the single ag slot
    k_zpad<<<64, 256, 0, stream>>>(xhh, xhl);
    k_hwc<<<dim3((B_ * HW + 63) / 64), 256, 0, stream>>>(flag, x, xhh, xhl);
    k_conv3<<<dim3(H_, 1, B_), 256, 0, stream>>>(
        W, xhh, xhl, b1h, b1l, b2h, b2l, b3);
    k_colsum<<<dim3(B_, 49), 256, 0, stream>>>(b3, s3);
    for (int b = 0; b < B_; ++b) {
      float* tkw = W + B1_O + N1 + (size_t)b * (HW * CI / 2);
      int*   tkp = (int*)(W + B1_O + N1 + N1 / 2 + (size_t)b * (HW * CI / 2));
      k_pack<<<dim3(368, 1), 256, 0, stream>>>(b1h, b1l, pk, b, 0);
      k_score<<<dim3(16, 8, 1), 256, 0, stream>>>(b2h, b2l, pk, sc, b, 0, 0);
      k_topk<<<dim3((L_ + 3) / 4, 1), 256, 0, stream>>>(sc, tkw, tkp, 0);
      k_pv<<<dim3(L_, 1), 128, 0, stream>>>(tkw, tkp, b3, s3, ag, b, 0);
      k_fold<<<dim3(64, 1), 256, 0, stream>>>(flag, W, ag, d_out, b, 0);
    }
  } else {
    float* sc = W + REG_O;
    float* ag = W + REG_O + SCSLOT;
    ushort_t* pk = (ushort_t*)ag;
    k_convF<<<dim3(4, 16, B_), dim3(32, 8, 1), 0, stream>>>(
        flag, x, g_w, g_b, th_w, th_b, ph_w, ph_b, b1h, b1l, b2h, b2l, b3);
    k_colsum<<<dim3(B_, 49), 256, 0, stream>>>(b3, s3);
    for (int b = 0; b < B_; ++b) {
      float* tkw = W + B1_O + N1 + (size_t)b * (HW * CI / 2);
      int*   tkp = (int*)(W + B1_O + N1 + N1 / 2 + (size_t)b * (HW * CI / 2));
      k_pack<<<dim3(368, 1), 256, 0, stream>>>(b1h, b1l, pk, b, 0);
      k_score<<<dim3(16, 8, 1), 256, 0, stream>>>(b2h, b2l, pk, sc, b, 0, 0);
      k_topk<<<dim3((L_ + 3) / 4, 1), 256, 0, stream>>>(sc, tkw, tkp, 0);
      k_pv<<<dim3(L_, 1), 128, 0, stream>>>(tkw, tkp, b3, s3, ag, b, 0);
      k_fold<<<dim3(64, 1), 256, 0, stream>>>(flag, W, ag, d_out, b, 0);
    }
  }
}

// Round 8
// 255.642 us; speedup vs baseline: 1.7826x; 1.0281x over previous
//
#include <hip/hip_runtime.h>
#include <hip/hip_bf16.h>

typedef __hip_bfloat16 bf16;
typedef unsigned short ushort_t;
typedef __attribute__((ext_vector_type(8))) __bf16 bfv8;
typedef __attribute__((ext_vector_type(16))) float f32x16;

#define B_   4
#define CIN  64
#define CI   16
#define H_   127
#define W_   127
#define HW   (H_*W_)
#define KS   7
#define ST   4
#define OH_  31
#define L_   961
#define D_   784
#define TOPM 100

// ---- workspace layout (float offsets) ----
#define N1   1032256          // B*HW*CI elements (one conv-out array)
#define WG_O 4
#define WT_O (WG_O + 9216)
#define WP_O (WT_O + 1024)
#define BG_O (WP_O + 1024)
#define BT_O (BG_O + 16)
#define BP_O (BT_O + 16)
#define SM_O (BP_O + 16)
#define SB_O (SM_O + 16)
#define RW_O (SB_O + 16)
#define RB_O (RW_O + 1024)
#define B1_O 12448
// planes at B1_O: b1h,b1l,b2h,b2l each N1 ushorts (2*N1 floats); b3 bf16 N1 ushorts
#define S3_O (B1_O + 3*N1)
#define WB_O (S3_O + B_*D_)   // conv MFMA B: wBh + wBl = 36864 floats
#define REG_O (WB_O + 36864)
#define SROW 964              // padded Sc row stride
#define SCSLOT 926464
#define AGSZ 753424
#define TKROW 112
#define SLST 72               // LDS row stride in ushorts (conflict-free, measured r8)
// PK: unfold-packed A operand. Per plane: 7 nki x 961 rows x 112 ushorts = 753424.
#define PKPLANE 753424
#define PKSTR   1506848
// padded x planes: 129x129 pixels x 64 ch, zero borders -> conv3 has NO bounds logic
#define PADW 129
#define PADPIX (PADW*PADW)            // 16641
#define XPB  (PADPIX*64)              // ushorts per batch-plane = 1,065,024
#define XPU  ((size_t)B_ * XPB)       // ushorts per plane (all batches) = 4,260,096
#define PLANES_FL 4260096             // floats spanned by both padded planes
// FULL tier: PK lives AFTER the planes (conv3 writes PK while reading planes).
#define PK_O (REG_O + PLANES_FL)      // 4*PKSTR ushorts = 3,013,696 floats; ag aliases

#define FULL_BYTES ((size_t)(PK_O + 3013696) * 4)          // ~41.7 MB (ws is 256 MiB)
#define MID_BYTES  ((size_t)(REG_O + PLANES_FL) * 4)       // ~29.6 MB

__device__ __forceinline__ float bf2f(bf16 v) { return __bfloat162float(v); }
__device__ __forceinline__ float bflo(unsigned u) { return __uint_as_float(u << 16); }
__device__ __forceinline__ float bfhi(unsigned u) { return __uint_as_float(u & 0xFFFF0000u); }

template <typename T> struct Ld;
template <> struct Ld<float> {
  static __device__ __forceinline__ float f(const void* p, int i) { return ((const float*)p)[i]; }
};
template <> struct Ld<bf16> {
  static __device__ __forceinline__ float f(const void* p, int i) { return bf2f(((const bf16*)p)[i]); }
};

__device__ __forceinline__ unsigned fmap(float f) {
  unsigned u = __float_as_uint(f);
  return (u & 0x80000000u) ? ~u : (u | 0x80000000u);
}
__device__ __forceinline__ float unfmap(unsigned kk) {
  unsigned u = (kk & 0x80000000u) ? (kk & 0x7fffffffu) : ~kk;
  return __uint_as_float(u);
}

// RNE fp32 -> bf16 bits, and hi/lo split
__device__ __forceinline__ ushort_t f2bf(float x) {
  unsigned u = __float_as_uint(x);
  return (ushort_t)((u + 0x7FFFu + ((u >> 16) & 1u)) >> 16);
}
__device__ __forceinline__ void splitbf(float x, ushort_t& h, ushort_t& l) {
  h = f2bf(x);
  float hf = __uint_as_float(((unsigned)h) << 16);
  l = f2bf(x - hf);
}

// -------- weight prep: grid-parallel; inline dtype detect; fused border zpad -----
#define LDW(ptr, i) (f ? ((const float*)(ptr))[i] : bf2f(((const bf16*)(ptr))[i]))
__global__ __launch_bounds__(256) void k_prep(
    const void* __restrict__ x,
    const void* g_w, const void* t_w, const void* p_w,
    const void* g_b, const void* t_b, const void* p_b,
    const void* m_w, const void* m_b, const void* r_w, const void* r_b,
    float* __restrict__ ws,
    ushort_t* __restrict__ xhh, ushort_t* __restrict__ xhl)
{
  // inline dtype detect (per block; wave 0 reduces, LDS broadcast)
  __shared__ int sflag;
  {
    const unsigned short* xh = (const unsigned short*)x;
    if (threadIdx.x < 64) {
      int c = 0;
#pragma unroll
      for (int j = 0; j < 2; ++j) {
        unsigned u = xh[threadIdx.x * 2 + j];
        unsigned e = (u >> 7) & 0xFF;
        if (e >= 134) c++;
      }
#pragma unroll
      for (int o = 32; o; o >>= 1) c += __shfl_down(c, o);
      if (threadIdx.x == 0) sflag = (c >= 8) ? 1 : 0;
    }
  }
  __syncthreads();
  int f = sflag;
  if (blockIdx.x == 0 && threadIdx.x == 0) *(int*)ws = f;   // publish for downstream

  int gid = blockIdx.x * 256 + threadIdx.x;
  int gs = gridDim.x * 256;
  for (int i = gid; i < 9216; i += gs) {
    int o = i & 15, t = i >> 4, c = t & 63, tap = t >> 6;
    ws[WG_O + i] = LDW(g_w, (o * 64 + c) * 9 + tap);
  }
  for (int i = gid; i < 1024; i += gs) {
    int o = i & 15, c = i >> 4;
    ws[WT_O + i] = LDW(t_w, o * 64 + c);
    ws[WP_O + i] = LDW(p_w, o * 64 + c);
  }
  if (gid < 16) {
    ws[BG_O + gid] = LDW(g_b, gid);
    ws[BT_O + gid] = LDW(t_b, gid);
    ws[BP_O + gid] = LDW(p_b, gid);
    float s = 0.f;
    for (int c = 0; c < 64; ++c) s += LDW(m_w, gid * 64 + c);
    ws[SM_O + gid] = s;
    ws[SB_O + gid] = LDW(m_b, gid);
  }
  for (int i = gid; i < 1024; i += gs) ws[RW_O + i] = LDW(r_w, i);
  if (gid >= 64 && gid < 128) ws[RB_O + gid - 64] = LDW(r_b, gid - 64);
  // conv MFMA B, split hi/lo: wB[tap][col64][c64]
  ushort_t* wBh = (ushort_t*)(ws + WB_O);
  ushort_t* wBl = wBh + 9 * 64 * 64;
  for (int i = gid; i < 9 * 64 * 64; i += gs) {
    int c = i & 63, t = i >> 6, col = t & 63, tap = t >> 6;
    float v = 0.f;
    if (col < 16) v = LDW(g_w, (col * 64 + c) * 9 + tap);
    else if (col < 32) { if (tap == 4) v = LDW(t_w, (col - 16) * 64 + c); }
    else if (col < 48) { if (tap == 4) v = LDW(p_w, (col - 32) * 64 + c); }
    ushort_t h, l; splitbf(v, h, l);
    wBh[i] = h; wBl[i] = l;
  }
  // fused border zpad for the padded planes (FULL/MID tiers)
  if (xhh) {
    const int4 z = make_int4(0, 0, 0, 0);
    for (int idx = gid; idx < B_ * 512 * 8; idx += gs) {
      int q = idx & 7, t = idx >> 3;
      int bp = t & 511, bb = t >> 9;
      int pp;
      if (bp < 129) pp = bp;                              // top row
      else if (bp < 258) pp = 128 * PADW + (bp - 129);    // bottom row
      else if (bp < 385) pp = (bp - 257) * PADW;          // left col rows 1..127
      else pp = (bp - 384) * PADW + 128;                  // right col rows 1..127
      size_t off = ((size_t)bb * PADPIX + pp) * 64 + q * 8;
      *(int4*)(xhh + off) = z;
      *(int4*)(xhl + off) = z;
    }
  }
}

// -------- x [B,64,H,W] -> padded HWC bf16 hi/lo planes ---------------------------
__global__ __launch_bounds__(256) void k_hwc(
    const int* __restrict__ flag, const void* __restrict__ x,
    ushort_t* __restrict__ xhh, ushort_t* __restrict__ xhl)
{
  __shared__ float tile[64][65];
  int pix0 = blockIdx.x * 64;
  int tid = threadIdx.x;
  int g = tid >> 6, p = tid & 63;
  int pix = pix0 + p;
  bool ok = pix < B_ * HW;
  int bb = ok ? pix / HW : 0;
  int r  = ok ? pix - bb * HW : 0;
  if (*flag) {
    const float* xf = (const float*)x;
    for (int c = g * 16; c < g * 16 + 16; ++c)
      tile[p][c] = ok ? xf[((size_t)bb * CIN + c) * HW + r] : 0.f;
  } else {
    const bf16* xb = (const bf16*)x;
    for (int c = g * 16; c < g * 16 + 16; ++c)
      tile[p][c] = ok ? bf2f(xb[((size_t)bb * CIN + c) * HW + r]) : 0.f;
  }
  __syncthreads();
  int c2 = tid & 63, pg = tid >> 6;
  // incremental (bb2,h2,w2) tracking: 2 divisions per thread total
  int pix2 = pix0 + pg * 16;
  int bb2 = pix2 / HW, r2 = pix2 - bb2 * HW;
  int h2 = r2 / W_, w2 = r2 - h2 * W_;
  for (int k = 0; k < 16; ++k) {
    if (pix2 + k < B_ * HW) {
      ushort_t h, l; splitbf(tile[pg * 16 + k][c2], h, l);
      size_t off = ((size_t)bb2 * PADPIX + (size_t)(h2 + 1) * PADW + (w2 + 1)) * 64 + c2;
      xhh[off] = h;
      xhl[off] = l;
    }
    if (++w2 == W_) { w2 = 0; if (++h2 == H_) { h2 = 0; ++bb2; } }
  }
}

// -------- split-bf16 MFMA conv, one output row per block, contiguous staging -----
// pk != nullptr (FULL): epilogue stages b1 in LDS and writes PK directly
// (bit-identical to old b1-write + k_pack copy); b1h/b1l never materialize.
__global__ __launch_bounds__(256) void k_conv3(
    const float* __restrict__ ws,
    const ushort_t* __restrict__ xhh, const ushort_t* __restrict__ xhl,
    ushort_t* __restrict__ b1h, ushort_t* __restrict__ b1l,
    ushort_t* __restrict__ b2h, ushort_t* __restrict__ b2l,
    ushort_t* __restrict__ b3, ushort_t* __restrict__ pk)
{
  __shared__ ushort_t sAh[128 * SLST], sAl[128 * SLST];
  __shared__ ushort_t sBh[64 * SLST],  sBl[64 * SLST];
  int bz = blockIdx.z;
  int h = blockIdx.x;                       // output row
  int tid = threadIdx.x, lane = tid & 63, wv = tid >> 6;
  int grp = lane >> 3, ch = lane & 7;

  const ushort_t* xplane = ((wv == 0) ? xhh : xhl) + (size_t)bz * XPB;
  const ushort_t* wBh_ = (const ushort_t*)(ws + WB_O);
  const ushort_t* bsrc = (wv == 2) ? wBh_ : (wBh_ + 9 * 64 * 64);
  ushort_t* dplane = (wv == 0) ? sAh : (wv == 1) ? sAl : (wv == 2) ? sBh : sBl;

  int fr = lane & 31, kh = (lane >> 5) << 3;
  int mt = (wv >> 1) << 1;
  int aoff0 = (mt * 32 + fr) * SLST + kh;
  int aoff1 = ((mt + 1) * 32 + fr) * SLST + kh;
  int boff  = (((wv & 1) << 5) + fr) * SLST + kh;

  f32x16 acc0 = {0.f,0.f,0.f,0.f,0.f,0.f,0.f,0.f,0.f,0.f,0.f,0.f,0.f,0.f,0.f,0.f};
  f32x16 acc1 = {0.f,0.f,0.f,0.f,0.f,0.f,0.f,0.f,0.f,0.f,0.f,0.f,0.f,0.f,0.f,0.f};

  int4 pv0, pv1, pv2, pv3, pv4, pv5, pv6, pv7;
  int4 pv8, pv9, pv10, pv11, pv12, pv13, pv14, pv15;

#define LC(j) pv##j = *(const int4*)(src + (j) * 512)
#define LC_A  LC(0); LC(1); LC(2); LC(3); LC(4); LC(5); LC(6); LC(7); \
              LC(8); LC(9); LC(10); LC(11); LC(12); LC(13); LC(14); LC(15)
#define LC_W  LC(0); LC(1); LC(2); LC(3); LC(4); LC(5); LC(6); LC(7)
#define WC(j) *(int4*)(d0 + (j) * 8 * SLST) = pv##j
#define WC_A  WC(0); WC(1); WC(2); WC(3); WC(4); WC(5); WC(6); WC(7); \
              WC(8); WC(9); WC(10); WC(11); WC(12); WC(13); WC(14); WC(15)
#define WC_W  WC(0); WC(1); WC(2); WC(3); WC(4); WC(5); WC(6); WC(7)

  // prefetch tap 0 (dh=-1, dw=-1): padded row h, col 0
  if (wv < 2) {
    const ushort_t* src = xplane + (size_t)h * (PADW * 64) + grp * 64 + ch * 8;
    LC_A;
  } else {
    const ushort_t* src = bsrc + grp * 64 + ch * 8;
    LC_W;
  }

  for (int r = 0; r < 9; ++r) {
    __syncthreads();
    {
      ushort_t* d0 = dplane + grp * SLST + ch * 8;
      if (wv < 2) { WC_A; } else { WC_W; }
    }
    __syncthreads();
    if (r < 8) {
      int rn = r + 1;
      int dh = rn / 3 - 1, dw = rn % 3 - 1;
      if (wv < 2) {
        const ushort_t* src = xplane
            + ((size_t)(h + 1 + dh) * PADW + (1 + dw)) * 64 + grp * 64 + ch * 8;
        LC_A;
      } else {
        const ushort_t* src = bsrc + rn * 4096 + grp * 64 + ch * 8;
        LC_W;
      }
    }
#pragma unroll
    for (int t = 0; t < 4; ++t) {
      bfv8 ah0 = *(const bfv8*)(sAh + aoff0 + t * 16);
      bfv8 al0 = *(const bfv8*)(sAl + aoff0 + t * 16);
      bfv8 ah1 = *(const bfv8*)(sAh + aoff1 + t * 16);
      bfv8 al1 = *(const bfv8*)(sAl + aoff1 + t * 16);
      bfv8 bh  = *(const bfv8*)(sBh + boff + t * 16);
      bfv8 bl  = *(const bfv8*)(sBl + boff + t * 16);
      acc0 = __builtin_amdgcn_mfma_f32_32x32x16_bf16(al0, bh, acc0, 0, 0, 0);
      acc0 = __builtin_amdgcn_mfma_f32_32x32x16_bf16(ah0, bl, acc0, 0, 0, 0);
      acc0 = __builtin_amdgcn_mfma_f32_32x32x16_bf16(ah0, bh, acc0, 0, 0, 0);
      acc1 = __builtin_amdgcn_mfma_f32_32x32x16_bf16(al1, bh, acc1, 0, 0, 0);
      acc1 = __builtin_amdgcn_mfma_f32_32x32x16_bf16(ah1, bl, acc1, 0, 0, 0);
      acc1 = __builtin_amdgcn_mfma_f32_32x32x16_bf16(ah1, bh, acc1, 0, 0, 0);
    }
  }
#undef LC
#undef LC_A
#undef LC_W
#undef WC
#undef WC_A
#undef WC_W

  int nw = ((wv & 1) << 5) + fr;
  if (pk) {
    // ---- PK-direct epilogue ----
    __syncthreads();                     // main-loop LDS reads done
    ushort_t* sb1h = sAh;                // [128][16]
    ushort_t* sb1l = sAl;
#pragma unroll
    for (int s = 0; s < 2; ++s) {
      int mbase = (mt + s) * 32;
#pragma unroll
      for (int r = 0; r < 16; ++r) {
        int m = mbase + (r & 3) + ((r >> 2) << 3) + ((lane >> 5) << 2);
        float val = s ? acc1[r] : acc0[r];
        if (nw < 16) {
          ushort_t h2, l2; splitbf(val + ws[BG_O + nw], h2, l2);
          sb1h[m * 16 + nw] = h2; sb1l[m * 16 + nw] = l2;
        } else if (m < W_) {
          size_t ob = ((size_t)bz * HW + h * W_ + m) * 16;
          if (nw < 32) {
            int o = nw - 16; ushort_t h2, l2; splitbf(val + ws[BT_O + o], h2, l2);
            b2h[ob + o] = h2; b2l[ob + o] = l2;
          } else if (nw < 48) {
            int o = nw - 32; b3[ob + o] = f2bf(val + ws[BP_O + o]);
          }
        }
      }
    }
    __syncthreads();
    // cooperative PK write: each valid slh owns 31 slw segments x 14 int4 / plane
    ushort_t* pkb = pk + (size_t)bz * PKSTR;
    int slh_lo = (h >= 6) ? ((h - 3) >> 2) : 0;       // ceil((h-6)/4)
    int slh_hi = h >> 2; if (slh_hi > 30) slh_hi = 30;
    for (int slh = slh_lo; slh <= slh_hi; ++slh) {
      int nki = h - 4 * slh;                          // in [0,6]
      size_t rb = ((size_t)nki * 961 + slh * 31) * 112;
      for (int t = tid; t < 31 * 14; t += 256) {
        int slw = t / 14, q = t - slw * 14;
        int m = slw * 4 + (q >> 1);                   // pixel w (<=126)
        int c0 = (q & 1) << 3;
        int4 vh = *(int4*)(sb1h + m * 16 + c0);
        int4 vl = *(int4*)(sb1l + m * 16 + c0);
        size_t doff = rb + (size_t)slw * 112 + q * 8;
        *(int4*)(pkb + doff)           = vh;
        *(int4*)(pkb + PKPLANE + doff) = vl;
      }
    }
  } else {
    // ---- legacy epilogue (MID tier; k_pack consumes b1) ----
#pragma unroll
    for (int s = 0; s < 2; ++s) {
      int mbase = (mt + s) * 32;
#pragma unroll
      for (int r = 0; r < 16; ++r) {
        int m = mbase + (r & 3) + ((r >> 2) << 3) + ((lane >> 5) << 2);
        if (m >= W_) continue;
        size_t ob = ((size_t)bz * HW + h * W_ + m) * 16;
        float val = s ? acc1[r] : acc0[r];
        if (nw < 16) {
          ushort_t h2, l2; splitbf(val + ws[BG_O + nw], h2, l2);
          b1h[ob + nw] = h2; b1l[ob + nw] = l2;
        } else if (nw < 32) {
          int o = nw - 16; ushort_t h2, l2; splitbf(val + ws[BT_O + o], h2, l2);
          b2h[ob + o] = h2; b2l[ob + o] = l2;
        } else if (nw < 48) {
          int o = nw - 32; b3[ob + o] = f2bf(val + ws[BP_O + o]);
        }
      }
    }
  }
}

// -------- fallback conv (LOW tier), dtype-templated VALU -------------------------
template <typename T>
__device__ __forceinline__ void convF_body(
    const void* x, const void* g_w, const void* g_b,
    const void* t_w, const void* t_b, const void* p_w, const void* p_b,
    ushort_t* b1h, ushort_t* b1l, ushort_t* b2h, ushort_t* b2l, ushort_t* b3,
    float* sgw, float* stw, float* spw)
{
  int tid = threadIdx.y * 32 + threadIdx.x;
  for (int i = tid; i < CI * CIN * 9; i += 256) sgw[i] = Ld<T>::f(g_w, i);
  for (int i = tid; i < CI * CIN; i += 256) { stw[i] = Ld<T>::f(t_w, i); spw[i] = Ld<T>::f(p_w, i); }
  __syncthreads();

  int w = blockIdx.x * 32 + threadIdx.x;
  int h = blockIdx.y * 8 + threadIdx.y;
  int b = blockIdx.z;
  if (w >= W_ || h >= H_) return;

  float a1[CI], a2[CI], a3[CI];
#pragma unroll
  for (int o = 0; o < CI; ++o) { a1[o] = 0.f; a2[o] = 0.f; a3[o] = 0.f; }

  const size_t xb = (size_t)b * CIN * HW;
  for (int c = 0; c < CIN; ++c) {
    float xv[9];
#pragma unroll
    for (int dh = 0; dh < 3; ++dh) {
      int hh = h + dh - 1;
      bool rok = ((unsigned)hh < (unsigned)H_);
#pragma unroll
      for (int dw = 0; dw < 3; ++dw) {
        int ww = w + dw - 1;
        bool ok = rok && ((unsigned)ww < (unsigned)W_);
        xv[dh * 3 + dw] = ok ? Ld<T>::f(x, (int)(xb + (size_t)c * HW + hh * W_ + ww)) : 0.f;
      }
    }
    float xc = xv[4];
#pragma unroll
    for (int o = 0; o < CI; ++o) {
      const float* gg = &sgw[(o * CIN + c) * 9];
      float s = gg[0]*xv[0] + gg[1]*xv[1] + gg[2]*xv[2]
              + gg[3]*xv[3] + gg[4]*xv[4] + gg[5]*xv[5]
              + gg[6]*xv[6] + gg[7]*xv[7] + gg[8]*xv[8];
      a1[o] += s;
      a2[o] += stw[o * CIN + c] * xc;
      a3[o] += spw[o * CIN + c] * xc;
    }
  }
  size_t base = ((size_t)b * HW + h * W_ + w) * CI;
#pragma unroll
  for (int o = 0; o < CI; ++o) {
    float v1 = a1[o] + Ld<T>::f(g_b, o);
    float v2 = a2[o] + Ld<T>::f(t_b, o);
    ushort_t hh2, ll2;
    splitbf(v1, hh2, ll2); b1h[base + o] = hh2; b1l[base + o] = ll2;
    splitbf(v2, hh2, ll2); b2h[base + o] = hh2; b2l[base + o] = ll2;
    b3[base + o] = f2bf(a3[o] + Ld<T>::f(p_b, o));
  }
}

__global__ __launch_bounds__(256) void k_convF(
    const int* __restrict__ flag, const void* x,
    const void* g_w, const void* g_b, const void* t_w, const void* t_b,
    const void* p_w, const void* p_b,
    ushort_t* __restrict__ b1h, ushort_t* __restrict__ b1l,
    ushort_t* __restrict__ b2h, ushort_t* __restrict__ b2l,
    ushort_t* __restrict__ b3)
{
  __shared__ float sgw[CI * CIN * 9];
  __shared__ float stw[CI * CIN];
  __shared__ float spw[CI * CIN];
  if (*flag) convF_body<float>(x, g_w, g_b, t_w, t_b, p_w, p_b, b1h, b1l, b2h, b2l, b3, sgw, stw, spw);
  else       convF_body<bf16 >(x, g_w, g_b, t_w, t_b, p_w, p_b, b1h, b1l, b2h, b2l, b3, sgw, stw, spw);
}

// -------- S3[b, pos*16+c] = sum over patches of b3 (bf16 src, fp32 acc) ----------
__global__ __launch_bounds__(256) void k_colsum(const ushort_t* __restrict__ b3, float* __restrict__ S3)
{
  __shared__ float red[16][17];
  int b = blockIdx.x, pos = blockIdx.y;
  int ki = pos / 7, kj = pos % 7;
  int c = threadIdx.x & 15, chunk = threadIdx.x >> 4;
  const ushort_t* B3 = b3 + (size_t)b * HW * CI;
  float s = 0.f;
  for (int l = chunk; l < L_; l += 16) {
    int lh = l / OH_, lw = l % OH_;
    s += bflo((unsigned)B3[((lh * ST + ki) * W_ + lw * ST + kj) * CI + c]);
  }
  red[chunk][c] = s;
  __syncthreads();
  if (threadIdx.x < 16) {
    float t = 0.f;
#pragma unroll
    for (int k = 0; k < 16; ++k) t += red[k][threadIdx.x];
    S3[(b * 49 + pos) * 16 + threadIdx.x] = t;
  }
}

// -------- pack A operand (MID/LOW tiers only): PK from b1 ------------------------
__global__ __launch_bounds__(256) void k_pack(
    const ushort_t* __restrict__ b1h, const ushort_t* __restrict__ b1l,
    ushort_t* __restrict__ pk, int b0, unsigned pkstride_z)
{
  int idx = blockIdx.x * 256 + threadIdx.x;
  if (idx >= 961 * 98) return;
  int row = idx / 98, rem = idx - row * 98;
  int nki = rem / 14, q = rem - nki * 14;
  int slh = row / OH_, slw = row - slh * OH_;
  int src = ((slh * ST) * W_ + slw * ST + nki * W_) * 16 + q * 8;
  int dst = (nki * 961 + row) * 112 + q * 8;
  int batch = b0 + blockIdx.y;
  size_t poff = (size_t)batch * HW * CI;
  ushort_t* pkb = pk + (size_t)blockIdx.y * pkstride_z;
  *(int4*)(pkb + dst)           = *(const int4*)(b1h + poff + src);
  *(int4*)(pkb + PKPLANE + dst) = *(const int4*)(b1l + poff + src);
}

// -------- score GEMM via split-bf16 MFMA, 128x64 tile (r4-verified) --------------
__global__ __launch_bounds__(256) void k_score(
    const ushort_t* __restrict__ b2h, const ushort_t* __restrict__ b2l,
    const ushort_t* __restrict__ pk,
    float* __restrict__ scb, int b0, unsigned scstride_z, unsigned pkstride_z)
{
  __shared__ ushort_t sAh[128 * SLST], sAl[128 * SLST];
  __shared__ ushort_t sBh[64 * SLST],  sBl[64 * SLST];
  int batch = b0 + blockIdx.z;
  size_t poff_g = (size_t)batch * HW * CI;
  float* Sc = scb + (size_t)blockIdx.z * scstride_z;

  int tid = threadIdx.x;
  int m0 = blockIdx.y * 128, n0 = blockIdx.x * 64;
  int lane = tid & 63;
  int wv = tid >> 6;
  int grp = lane >> 3, ch = lane & 7;

  const ushort_t* pkb = pk + (size_t)blockIdx.z * pkstride_z + (size_t)(wv & 1) * PKPLANE;

  // B-side per-lane-row base (wv>=2)
  int srow = n0 + lane;  if (srow > L_ - 1) srow = L_ - 1;
  int slh = srow / OH_, slw = srow - slh * OH_;
  int sbase = (slh * ST) * W_ + slw * ST;
  const ushort_t* splane = (wv == 2) ? (b2h + poff_g) : (b2l + poff_g);
  ushort_t* dplane = (wv == 0) ? sAh : (wv == 1) ? sAl : (wv == 2) ? sBh : sBl;
  ushort_t* drowB = dplane + lane * SLST;

  int fr = lane & 31;
  int kh = (lane >> 5) << 3;
  int mt = (wv >> 1) << 1;                         // first m-subtile: 0 or 2
  int aoff0 = (mt * 32 + fr) * SLST + kh;
  int aoff1 = ((mt + 1) * 32 + fr) * SLST + kh;
  int boff  = (((wv & 1) << 5) + fr) * SLST + kh;

  f32x16 acc0 = {0.f,0.f,0.f,0.f,0.f,0.f,0.f,0.f,0.f,0.f,0.f,0.f,0.f,0.f,0.f,0.f};
  f32x16 acc1 = {0.f,0.f,0.f,0.f,0.f,0.f,0.f,0.f,0.f,0.f,0.f,0.f,0.f,0.f,0.f,0.f};

  int4 pv0, pv1, pv2, pv3, pv4, pv5, pv6, pv7;
  int4 pv8, pv9, pv10, pv11, pv12, pv13, pv14, pv15;

#define LA(j) pv##j = *(const int4*)(pks + (size_t)min(m0 + 8*j + grp, 960) * 112)
#define LA_ALL LA(0); LA(1); LA(2); LA(3); LA(4); LA(5); LA(6); LA(7); \
               LA(8); LA(9); LA(10); LA(11); LA(12); LA(13); LA(14); LA(15)
#define WA(j) *(int4*)(d0 + (j) * 8 * SLST) = pv##j
#define WA_ALL WA(0); WA(1); WA(2); WA(3); WA(4); WA(5); WA(6); WA(7); \
               WA(8); WA(9); WA(10); WA(11); WA(12); WA(13); WA(14); WA(15)

  // initial prefetch: rn=0 (nki=0, even)
  if (wv < 2) {
    const ushort_t* pks = pkb + ch * 8;
    LA_ALL;
  } else {
    const int4* s0 = (const int4*)(splane + (size_t)sbase * 16);
    pv0 = s0[0]; pv1 = s0[1]; pv2 = s0[2]; pv3 = s0[3];
    pv4 = s0[4]; pv5 = s0[5]; pv6 = s0[6]; pv7 = s0[7];
  }

  for (int r = 0; r < 14; ++r) {
    int half = r & 1;
    __syncthreads();
    if (wv < 2) {
      ushort_t* d0 = dplane + grp * SLST + ch * 8;
      if (!half) { WA_ALL; }
      else if (ch < 6) { WA_ALL; }
    } else {
      *(int4*)(drowB + 0)  = pv0;  *(int4*)(drowB + 8)  = pv1;
      *(int4*)(drowB + 16) = pv2;  *(int4*)(drowB + 24) = pv3;
      *(int4*)(drowB + 32) = pv4;  *(int4*)(drowB + 40) = pv5;
      if (!half) { *(int4*)(drowB + 48) = pv6; *(int4*)(drowB + 56) = pv7; }
    }
    __syncthreads();
    if (r < 13) {
      int rn = r + 1;
      int nki = rn >> 1, odd = rn & 1;
      if (wv < 2) {
        const ushort_t* pks = pkb + (size_t)nki * (961 * 112) + odd * 64 + ch * 8;
        if (!odd) { LA_ALL; }
        else if (ch < 6) { LA_ALL; }
      } else {
        int nkj0 = odd * 4;
        const int4* s0 = (const int4*)(splane + (size_t)(sbase + nki * W_ + nkj0) * 16);
        pv0 = s0[0]; pv1 = s0[1]; pv2 = s0[2]; pv3 = s0[3]; pv4 = s0[4]; pv5 = s0[5];
        if (!odd) { pv6 = s0[6]; pv7 = s0[7]; }
      }
    }
    if (!half) {
#pragma unroll
      for (int t = 0; t < 4; ++t) {
        bfv8 ah0 = *(const bfv8*)(sAh + aoff0 + t * 16);
        bfv8 al0 = *(const bfv8*)(sAl + aoff0 + t * 16);
        bfv8 ah1 = *(const bfv8*)(sAh + aoff1 + t * 16);
        bfv8 al1 = *(const bfv8*)(sAl + aoff1 + t * 16);
        bfv8 bh  = *(const bfv8*)(sBh + boff + t * 16);
        bfv8 bl  = *(const bfv8*)(sBl + boff + t * 16);
        acc0 = __builtin_amdgcn_mfma_f32_32x32x16_bf16(al0, bh, acc0, 0, 0, 0);
        acc0 = __builtin_amdgcn_mfma_f32_32x32x16_bf16(ah0, bl, acc0, 0, 0, 0);
        acc0 = __builtin_amdgcn_mfma_f32_32x32x16_bf16(ah0, bh, acc0, 0, 0, 0);
        acc1 = __builtin_amdgcn_mfma_f32_32x32x16_bf16(al1, bh, acc1, 0, 0, 0);
        acc1 = __builtin_amdgcn_mfma_f32_32x32x16_bf16(ah1, bl, acc1, 0, 0, 0);
        acc1 = __builtin_amdgcn_mfma_f32_32x32x16_bf16(ah1, bh, acc1, 0, 0, 0);
      }
    } else {
#pragma unroll
      for (int t = 0; t < 3; ++t) {
        bfv8 ah0 = *(const bfv8*)(sAh + aoff0 + t * 16);
        bfv8 al0 = *(const bfv8*)(sAl + aoff0 + t * 16);
        bfv8 ah1 = *(const bfv8*)(sAh + aoff1 + t * 16);
        bfv8 al1 = *(const bfv8*)(sAl + aoff1 + t * 16);
        bfv8 bh  = *(const bfv8*)(sBh + boff + t * 16);
        bfv8 bl  = *(const bfv8*)(sBl + boff + t * 16);
        acc0 = __builtin_amdgcn_mfma_f32_32x32x16_bf16(al0, bh, acc0, 0, 0, 0);
        acc0 = __builtin_amdgcn_mfma_f32_32x32x16_bf16(ah0, bl, acc0, 0, 0, 0);
        acc0 = __builtin_amdgcn_mfma_f32_32x32x16_bf16(ah0, bh, acc0, 0, 0, 0);
        acc1 = __builtin_amdgcn_mfma_f32_32x32x16_bf16(al1, bh, acc1, 0, 0, 0);
        acc1 = __builtin_amdgcn_mfma_f32_32x32x16_bf16(ah1, bl, acc1, 0, 0, 0);
        acc1 = __builtin_amdgcn_mfma_f32_32x32x16_bf16(ah1, bh, acc1, 0, 0, 0);
      }
    }
  }
#undef LA
#undef LA_ALL
#undef WA
#undef WA_ALL

  int nw = n0 + ((wv & 1) << 5) + fr;
  if (nw < L_) {
    int mw0 = m0 + mt * 32;
#pragma unroll
    for (int r = 0; r < 16; ++r) {
      int m = mw0 + (r & 3) + ((r >> 2) << 3) + ((lane >> 5) << 2);
      if (m < L_) Sc[(size_t)m * SROW + nw] = acc0[r];
    }
    int mw1 = m0 + (mt + 1) * 32;
#pragma unroll
    for (int r = 0; r < 16; ++r) {
      int m = mw1 + (r & 3) + ((r >> 2) << 3) + ((lane >> 5) << 2);
      if (m < L_) Sc[(size_t)m * SROW + nw] = acc1[r];
    }
  }
}

// -------- top-100 + softmax weights: ballot-radix (r6-verified) ------------------
__global__ __launch_bounds__(256) void k_topk(
    const float* __restrict__ scb, float* __restrict__ tkw, int* __restrict__ tkp,
    unsigned scstride_z)
{
  __shared__ float swv[4][TOPM];
  __shared__ int spx[4][TOPM];
  int tid = threadIdx.x;
  int wvi = tid >> 6, lane = tid & 63;
  int l = blockIdx.x * 4 + wvi;
  if (l > L_ - 1) l = L_ - 1;        // clamp: duplicate rows write identical data
  int bz = blockIdx.y;
  const float4* row4 = (const float4*)(scb + (size_t)bz * scstride_z + (size_t)l * SROW);
  int trow = (bz * L_ + l) * TKROW;

  unsigned k[16];
#pragma unroll
  for (int q = 0; q < 4; ++q) {
    float4 v = row4[q * 64 + lane];
    int ib = (q * 64 + lane) * 4;
    k[q * 4 + 0] = (ib + 0 < L_) ? fmap(v.x) : 0u;
    k[q * 4 + 1] = (ib + 1 < L_) ? fmap(v.y) : 0u;
    k[q * 4 + 2] = (ib + 2 < L_) ? fmap(v.z) : 0u;
    k[q * 4 + 3] = (ib + 3 < L_) ? fmap(v.w) : 0u;
  }

  unsigned mk = 0;
#pragma unroll
  for (int r = 0; r < 16; ++r) mk = max(mk, k[r]);
#pragma unroll
  for (int o = 32; o; o >>= 1) mk = max(mk, (unsigned)__shfl_down((int)mk, o));
  mk = (unsigned)__shfl((int)mk, 0);
  float vmax = unfmap(mk);

  unsigned kk[16];
#pragma unroll
  for (int r = 0; r < 16; ++r) kk[r] = k[r];

  unsigned prefix = 0; int base = 0;
  for (int bit = 30; bit >= 0; bit -= 2) {
    int n3 = 0, n2 = 0, n1 = 0;
#pragma unroll
    for (int r = 0; r < 16; ++r) {
      unsigned f = (kk[r] >> bit) & 3u;
      n3 += (int)__popcll(__ballot(f == 3u));
      n2 += (int)__popcll(__ballot(f >= 2u));
      n1 += (int)__popcll(__ballot(f >= 1u));
    }
    unsigned ch;
    if (base + n3 >= TOPM) ch = 3;
    else if (base + n2 >= TOPM) { ch = 2; base += n3; }
    else if (base + n1 >= TOPM) { ch = 1; base += n2; }
    else { ch = 0; base += n1; }
    prefix |= ch << bit;
#pragma unroll
    for (int r = 0; r < 16; ++r) {
      unsigned f = (kk[r] >> bit) & 3u;
      kk[r] = (f == ch) ? kk[r] : 0u;
    }
  }
  int nA = base;
  int needT = TOPM - nA;

  int cA = 0, cT = 0;
#pragma unroll
  for (int r = 0; r < 16; ++r) { cA += (k[r] > prefix); cT += (k[r] == prefix); }
  int pk = cA | (cT << 16);
  int incl = pk;
#pragma unroll
  for (int o = 1; o < 64; o <<= 1) { int t = __shfl_up(incl, o); if (lane >= o) incl += t; }
  int excl = incl - pk;
  int tA = excl & 0xFFFF, tT = excl >> 16;

  float M = fmaxf(10.f * vmax, 0.f);
  float e0 = __expf(-M);
  float z = 0.f;
#pragma unroll
  for (int r = 0; r < 16; ++r) {
    unsigned kr = k[r];
    int slot = -1;
    if (kr > prefix) slot = tA++;
    else if (kr == prefix) { if (tT < needT) slot = nA + tT; tT++; }
    if (slot >= 0) {
      float v = unfmap(kr);
      float wv = __expf(10.f * v - M);
      swv[wvi][slot] = wv; z += wv;
      int gi = 256 * (r >> 2) + 4 * lane + (r & 3);
      int lh = gi / OH_, lw = gi - lh * OH_;
      spx[wvi][slot] = ((lh * ST) * W_ + lw * ST) * CI;
    }
  }
#pragma unroll
  for (int o = 32; o; o >>= 1) z += __shfl_down(z, o);
  z = __shfl(z, 0);
  float Z = z + (float)(L_ - TOPM) * e0;
  float invZ = 1.f / Z;
  float w0 = e0 / Z;
  __syncthreads();
#pragma unroll
  for (int s0 = 0; s0 < 2; ++s0) {
    int s = lane + 64 * s0;
    if (s < TOPM) {
      tkw[trow + s] = swv[wvi][s] * invZ - w0;
      tkp[trow + s] = spx[wvi][s];
    }
  }
  if (lane == 0) tkw[trow + TOPM] = w0;
}

// -------- PV gather (bf16 b3, uint4 full-line): 98 lanes x 8 channels ------------
__global__ __launch_bounds__(128) void k_pv(
    const float* __restrict__ tkw, const int* __restrict__ tkp,
    const ushort_t* __restrict__ b3, const float* __restrict__ s3,
    float* __restrict__ agb, int b0, unsigned agstride_z)
{
  int l = blockIdx.x, bz = blockIdx.y;
  int batch = b0 + bz;
  int trow = (bz * L_ + l) * TKROW;
  const ushort_t* B3 = b3 + (size_t)batch * HW * CI;
  const float* S3 = s3 + (size_t)batch * D_;
  float* agg = agb + (size_t)bz * agstride_z;
  int tid = threadIdx.x;
  if (tid >= 98) return;

  float w0 = tkw[trow + TOPM];
  int pos = tid >> 1;
  int c0 = (tid & 1) << 3;                 // 0 or 8
  int ki = pos / 7, kj = pos - (pos / 7) * 7;
  int poff = (ki * W_ + kj) * CI + c0;

  float a0 = 0.f, a1 = 0.f, a2 = 0.f, a3 = 0.f;
  float a4 = 0.f, a5 = 0.f, a6 = 0.f, a7 = 0.f;
  for (int j0 = 0; j0 < TOPM; j0 += 4) {
    float w_0 = tkw[trow + j0 + 0];
    float w_1 = tkw[trow + j0 + 1];
    float w_2 = tkw[trow + j0 + 2];
    float w_3 = tkw[trow + j0 + 3];
    int p_0 = tkp[trow + j0 + 0];
    int p_1 = tkp[trow + j0 + 1];
    int p_2 = tkp[trow + j0 + 2];
    int p_3 = tkp[trow + j0 + 3];
    const uint4 q0 = *(const uint4*)(B3 + p_0 + poff);
    const uint4 q1 = *(const uint4*)(B3 + p_1 + poff);
    const uint4 q2 = *(const uint4*)(B3 + p_2 + poff);
    const uint4 q3 = *(const uint4*)(B3 + p_3 + poff);
    a0 += w_0 * bflo(q0.x); a1 += w_0 * bfhi(q0.x); a2 += w_0 * bflo(q0.y); a3 += w_0 * bfhi(q0.y);
    a4 += w_0 * bflo(q0.z); a5 += w_0 * bfhi(q0.z); a6 += w_0 * bflo(q0.w); a7 += w_0 * bfhi(q0.w);
    a0 += w_1 * bflo(q1.x); a1 += w_1 * bfhi(q1.x); a2 += w_1 * bflo(q1.y); a3 += w_1 * bfhi(q1.y);
    a4 += w_1 * bflo(q1.z); a5 += w_1 * bfhi(q1.z); a6 += w_1 * bflo(q1.w); a7 += w_1 * bfhi(q1.w);
    a0 += w_2 * bflo(q2.x); a1 += w_2 * bfhi(q2.x); a2 += w_2 * bflo(q2.y); a3 += w_2 * bfhi(q2.y);
    a4 += w_2 * bflo(q2.z); a5 += w_2 * bfhi(q2.z); a6 += w_2 * bflo(q2.w); a7 += w_2 * bfhi(q2.w);
    a0 += w_3 * bflo(q3.x); a1 += w_3 * bfhi(q3.x); a2 += w_3 * bflo(q3.y); a3 += w_3 * bfhi(q3.y);
    a4 += w_3 * bflo(q3.z); a5 += w_3 * bfhi(q3.z); a6 += w_3 * bflo(q3.w); a7 += w_3 * bfhi(q3.w);
  }
  const float4 s40 = *(const float4*)(S3 + tid * 8);
  const float4 s41 = *(const float4*)(S3 + tid * 8 + 4);
  a0 += w0 * s40.x; a1 += w0 * s40.y; a2 += w0 * s40.z; a3 += w0 * s40.w;
  a4 += w0 * s41.x; a5 += w0 * s41.y; a6 += w0 * s41.z; a7 += w0 * s41.w;
  float* dst = agg + (size_t)l * D_ + tid * 8;
  *(float4*)(dst)     = make_float4(a0, a1, a2, a3);
  *(float4*)(dst + 4) = make_float4(a4, a5, a6, a7);
}

// -------- fold + mask divide + restore (16->64), batched -------------------------
__global__ __launch_bounds__(256) void k_fold(
    const int* __restrict__ flag, const float* __restrict__ ws,
    const float* __restrict__ agb, void* __restrict__ out,
    int b0, unsigned agstride_z)
{
  __shared__ float srw[CIN * CI];
  int tid = threadIdx.x;
  for (int i = tid; i < CIN * CI; i += 256) srw[i] = ws[RW_O + i];
  __syncthreads();

  int bz = blockIdx.y;
  int batch = b0 + bz;
  const float* agg = agb + (size_t)bz * agstride_z;

  int gid = blockIdx.x * 256 + tid;
  if (gid >= HW) return;
  int h = gid / W_;
  int w = gid % W_;

  int lh0 = (h >= KS - 1) ? ((h - (KS - 1) + (ST - 1)) >> 2) : 0;
  int lh1 = min(OH_ - 1, h >> 2);
  int lw0 = (w >= KS - 1) ? ((w - (KS - 1) + (ST - 1)) >> 2) : 0;
  int lw1 = min(OH_ - 1, w >> 2);

  float t[CI];
#pragma unroll
  for (int c = 0; c < CI; ++c) t[c] = 0.f;
  for (int lh = lh0; lh <= lh1; ++lh) {
    int ki = h - ST * lh;
    for (int lw = lw0; lw <= lw1; ++lw) {
      int kj = w - ST * lw;
      const float* pb = agg + (size_t)(lh * OH_ + lw) * D_ + (ki * KS + kj) * CI;
      float4 q0 = *(const float4*)(pb);
      float4 q1 = *(const float4*)(pb + 4);
      float4 q2 = *(const float4*)(pb + 8);
      float4 q3 = *(const float4*)(pb + 12);
      t[0] += q0.x; t[1] += q0.y; t[2] += q0.z; t[3] += q0.w;
      t[4] += q1.x; t[5] += q1.y; t[6] += q1.z; t[7] += q1.w;
      t[8] += q2.x; t[9] += q2.y; t[10] += q2.z; t[11] += q2.w;
      t[12] += q3.x; t[13] += q3.y; t[14] += q3.z; t[15] += q3.w;
    }
  }
  float cnt = (float)((lh1 - lh0 + 1) * (lw1 - lw0 + 1));
  float r[CI];
#pragma unroll
  for (int c = 0; c < CI; ++c) r[c] = t[c] / (cnt * ws[SM_O + c] + ws[SB_O + c] + 1e-8f);

  size_t ob = (size_t)batch * CIN * HW + (size_t)h * W_ + w;
  if (*flag) {
    float* of = (float*)out;
#pragma unroll
    for (int o = 0; o < CIN; ++o) {
      float s = ws[RB_O + o];
#pragma unroll
      for (int c = 0; c < CI; ++c) s += srw[o * CI + c] * r[c];
      of[ob + (size_t)o * HW] = s;
    }
  } else {
    bf16* of = (bf16*)out;
#pragma unroll
    for (int o = 0; o < CIN; ++o) {
      float s = ws[RB_O + o];
#pragma unroll
      for (int c = 0; c < CI; ++c) s += srw[o * CI + c] * r[c];
      of[ob + (size_t)o * HW] = __float2bfloat16(s);
    }
  }
}

extern "C" void kernel_launch(void* const* d_in, const int* in_sizes, int n_in,
                              void* d_out, int out_size, void* d_ws, size_t ws_size,
                              hipStream_t stream)
{
  const void* x    = d_in[0];
  const void* g_w  = d_in[1];
  const void* g_b  = d_in[2];
  const void* th_w = d_in[3];
  const void* th_b = d_in[4];
  const void* ph_w = d_in[5];
  const void* ph_b = d_in[6];
  const void* m_w  = d_in[7];
  const void* m_b  = d_in[8];
  const void* r_w  = d_in[9];
  const void* r_b  = d_in[10];

  float* W = (float*)d_ws;
  int* flag = (int*)d_ws;
  ushort_t* planes = (ushort_t*)(W + B1_O);
  ushort_t* b1h = planes;
  ushort_t* b1l = planes + (size_t)N1;
  ushort_t* b2h = planes + (size_t)2 * N1;
  ushort_t* b2l = planes + (size_t)3 * N1;
  ushort_t* b3  = planes + (size_t)4 * N1;   // bf16 plane, N1 ushorts
  float* s3 = W + S3_O;

  if (ws_size >= FULL_BYTES) {
    ushort_t* xhh = (ushort_t*)(W + REG_O);    // padded planes, dead after conv
    ushort_t* xhl = xhh + XPU;
    float* sc = W + REG_O;                     // 4 x SCSLOT, aliases x planes
    ushort_t* pk = (ushort_t*)(W + PK_O);      // after planes (conv writes PK live)
    float* ag = W + PK_O;                      // aliases pk (pv after score)
    float* tkw = W + B1_O + N1;                // b2h region (dead after k_score)
    int*   tkp = (int*)(W + B1_O + N1 + N1 / 2);
    k_prep<<<64, 256, 0, stream>>>(x, g_w, th_w, ph_w, g_b, th_b, ph_b,
                                   m_w, m_b, r_w, r_b, W, xhh, xhl);
    k_hwc<<<dim3((B_ * HW + 63) / 64), 256, 0, stream>>>(flag, x, xhh, xhl);
    k_conv3<<<dim3(H_, 1, B_), 256, 0, stream>>>(
        W, xhh, xhl, b1h, b1l, b2h, b2l, b3, pk);
    k_colsum<<<dim3(B_, 49), 256, 0, stream>>>(b3, s3);
    k_score<<<dim3(16, 8, B_), 256, 0, stream>>>(b2h, b2l, pk, sc, 0, SCSLOT, PKSTR);
    k_topk<<<dim3((L_ + 3) / 4, B_), 256, 0, stream>>>(sc, tkw, tkp, SCSLOT);
    k_pv<<<dim3(L_, B_), 128, 0, stream>>>(tkw, tkp, b3, s3, ag, 0, AGSZ);
    k_fold<<<dim3(64, B_), 256, 0, stream>>>(flag, W, ag, d_out, 0, AGSZ);
  } else if (ws_size >= MID_BYTES) {
    ushort_t* xhh = (ushort_t*)(W + REG_O);
    ushort_t* xhl = xhh + XPU;
    float* sc = W + REG_O;
    float* ag = W + REG_O + SCSLOT;
    ushort_t* pk = (ushort_t*)ag;              // PK shares the single ag slot
    k_prep<<<64, 256, 0, stream>>>(x, g_w, th_w, ph_w, g_b, th_b, ph_b,
                                   m_w, m_b, r_w, r_b, W, xhh, xhl);
    k_hwc<<<dim3((B_ * HW + 63) / 64), 256, 0, stream>>>(flag, x, xhh, xhl);
    k_conv3<<<dim3(H_, 1, B_), 256, 0, stream>>>(
        W, xhh, xhl, b1h, b1l, b2h, b2l, b3, (ushort_t*)nullptr);
    k_colsum<<<dim3(B_, 49), 256, 0, stream>>>(b3, s3);
    for (int b = 0; b < B_; ++b) {
      float* tkw = W + B1_O + N1 + (size_t)b * (HW * CI / 2);
      int*   tkp = (int*)(W + B1_O + N1 + N1 / 2 + (size_t)b * (HW * CI / 2));
      k_pack<<<dim3(368, 1), 256, 0, stream>>>(b1h, b1l, pk, b, 0);
      k_score<<<dim3(16, 8, 1), 256, 0, stream>>>(b2h, b2l, pk, sc, b, 0, 0);
      k_topk<<<dim3((L_ + 3) / 4, 1), 256, 0, stream>>>(sc, tkw, tkp, 0);
      k_pv<<<dim3(L_, 1), 128, 0, stream>>>(tkw, tkp, b3, s3, ag, b, 0);
      k_fold<<<dim3(64, 1), 256, 0, stream>>>(flag, W, ag, d_out, b, 0);
    }
  } else {
    float* sc = W + REG_O;
    float* ag = W + REG_O + SCSLOT;
    ushort_t* pk = (ushort_t*)ag;
    k_prep<<<64, 256, 0, stream>>>(x, g_w, th_w, ph_w, g_b, th_b, ph_b,
                                   m_w, m_b, r_w, r_b, W,
                                   (ushort_t*)nullptr, (ushort_t*)nullptr);
    k_convF<<<dim3(4, 16, B_), dim3(32, 8, 1), 0, stream>>>(
        flag, x, g_w, g_b, th_w, th_b, ph_w, ph_b, b1h, b1l, b2h, b2l, b3);
    k_colsum<<<dim3(B_, 49), 256, 0, stream>>>(b3, s3);
    for (int b = 0; b < B_; ++b) {
      float* tkw = W + B1_O + N1 + (size_t)b * (HW * CI / 2);
      int*   tkp = (int*)(W + B1_O + N1 + N1 / 2 + (size_t)b * (HW * CI / 2));
      k_pack<<<dim3(368, 1), 256, 0, stream>>>(b1h, b1l, pk, b, 0);
      k_score<<<dim3(16, 8, 1), 256, 0, stream>>>(b2h, b2l, pk, sc, b, 0, 0);
      k_topk<<<dim3((L_ + 3) / 4, 1), 256, 0, stream>>>(sc, tkw, tkp, 0);
      k_pv<<<dim3(L_, 1), 128, 0, stream>>>(tkw, tkp, b3, s3, ag, b, 0);
      k_fold<<<dim3(64, 1), 256, 0, stream>>>(flag, W, ag, d_out, b, 0);
    }
  }
}

// Round 9
// 247.747 us; speedup vs baseline: 1.8394x; 1.0319x over previous
//
#include <hip/hip_runtime.h>
#include <hip/hip_bf16.h>

typedef __hip_bfloat16 bf16;
typedef unsigned short ushort_t;
typedef __attribute__((ext_vector_type(8))) __bf16 bfv8;
typedef __attribute__((ext_vector_type(16))) float f32x16;

#define B_   4
#define CIN  64
#define CI   16
#define H_   127
#define W_   127
#define HW   (H_*W_)
#define KS   7
#define ST   4
#define OH_  31
#define L_   961
#define D_   784
#define TOPM 100

// ---- workspace layout (float offsets) ----
#define N1   1032256          // B*HW*CI elements (one conv-out array)
#define WG_O 4
#define WT_O (WG_O + 9216)
#define WP_O (WT_O + 1024)
#define BG_O (WP_O + 1024)
#define BT_O (BG_O + 16)
#define BP_O (BT_O + 16)
#define SM_O (BP_O + 16)
#define SB_O (SM_O + 16)
#define RW_O (SB_O + 16)
#define RB_O (RW_O + 1024)
#define B1_O 12448
// planes at B1_O: b1h,b1l,b2h,b2l each N1 ushorts (2*N1 floats); b3 bf16 N1 ushorts
#define S3_O (B1_O + 3*N1)
#define WB_O (S3_O + B_*D_)   // conv MFMA B: wBh + wBl = 36864 floats
#define REG_O (WB_O + 36864)
#define SROW 964              // padded Sc row stride
#define SCSLOT 926464
#define AGSZ 753424
#define SLST 72               // LDS row stride in ushorts (conflict-free, measured r8)
// PK: unfold-packed operands. Per plane: 7 nki x 961 rows x 112 ushorts = 753424.
#define PKPLANE 753424
#define PKSTR   1506848
// padded x planes: 129x129 pixels x 64 ch, zero borders -> conv3 has NO bounds logic
#define PADW 129
#define PADPIX (PADW*PADW)            // 16641
#define XPB  (PADPIX*64)              // ushorts per batch-plane = 1,065,024
#define XPU  ((size_t)B_ * XPB)       // ushorts per plane (all batches) = 4,260,096
#define PLANES_FL 4260096             // floats spanned by both padded planes
// FULL tier: PK1/PK2 after the planes (conv3 writes them while reading planes).
#define PK_O  (REG_O + PLANES_FL)     // PK1: 4*PKSTR ushorts = 3,013,696 floats
#define PK2_O (PK_O + 3013696)        // PK2 (b2 operand), same size

#define FULL_BYTES ((size_t)(PK2_O + 3013696) * 4)         // ~53.7 MB (ws is 256 MiB)
#define MID_BYTES  ((size_t)(REG_O + PLANES_FL) * 4)       // ~29.6 MB

__device__ __forceinline__ float bf2f(bf16 v) { return __bfloat162float(v); }
__device__ __forceinline__ float bflo(unsigned u) { return __uint_as_float(u << 16); }
__device__ __forceinline__ float bfhi(unsigned u) { return __uint_as_float(u & 0xFFFF0000u); }

template <typename T> struct Ld;
template <> struct Ld<float> {
  static __device__ __forceinline__ float f(const void* p, int i) { return ((const float*)p)[i]; }
};
template <> struct Ld<bf16> {
  static __device__ __forceinline__ float f(const void* p, int i) { return bf2f(((const bf16*)p)[i]); }
};

__device__ __forceinline__ unsigned fmap(float f) {
  unsigned u = __float_as_uint(f);
  return (u & 0x80000000u) ? ~u : (u | 0x80000000u);
}
__device__ __forceinline__ float unfmap(unsigned kk) {
  unsigned u = (kk & 0x80000000u) ? (kk & 0x7fffffffu) : ~kk;
  return __uint_as_float(u);
}

// RNE fp32 -> bf16 bits, and hi/lo split
__device__ __forceinline__ ushort_t f2bf(float x) {
  unsigned u = __float_as_uint(x);
  return (ushort_t)((u + 0x7FFFu + ((u >> 16) & 1u)) >> 16);
}
__device__ __forceinline__ void splitbf(float x, ushort_t& h, ushort_t& l) {
  h = f2bf(x);
  float hf = __uint_as_float(((unsigned)h) << 16);
  l = f2bf(x - hf);
}

// -------- weight prep + inline dtype detect + border zpad + fused HWC ------------
#define LDW(ptr, i) (f ? ((const float*)(ptr))[i] : bf2f(((const bf16*)(ptr))[i]))
__global__ __launch_bounds__(256) void k_prep(
    const void* __restrict__ x,
    const void* g_w, const void* t_w, const void* p_w,
    const void* g_b, const void* t_b, const void* p_b,
    const void* m_w, const void* m_b, const void* r_w, const void* r_b,
    float* __restrict__ ws,
    ushort_t* __restrict__ xhh, ushort_t* __restrict__ xhl)
{
  __shared__ int sflag;
  __shared__ float tile[64][65];
  // inline dtype detect (per block; wave 0 reduces, LDS broadcast)
  {
    const unsigned short* xh = (const unsigned short*)x;
    if (threadIdx.x < 64) {
      int c = 0;
#pragma unroll
      for (int j = 0; j < 2; ++j) {
        unsigned u = xh[threadIdx.x * 2 + j];
        unsigned e = (u >> 7) & 0xFF;
        if (e >= 134) c++;
      }
#pragma unroll
      for (int o = 32; o; o >>= 1) c += __shfl_down(c, o);
      if (threadIdx.x == 0) sflag = (c >= 8) ? 1 : 0;
    }
  }
  __syncthreads();
  int f = sflag;
  if (blockIdx.x == 0 && threadIdx.x == 0) *(int*)ws = f;   // publish for downstream

  int gid = blockIdx.x * 256 + threadIdx.x;
  int gs = gridDim.x * 256;
  for (int i = gid; i < 9216; i += gs) {
    int o = i & 15, t = i >> 4, c = t & 63, tap = t >> 6;
    ws[WG_O + i] = LDW(g_w, (o * 64 + c) * 9 + tap);
  }
  for (int i = gid; i < 1024; i += gs) {
    int o = i & 15, c = i >> 4;
    ws[WT_O + i] = LDW(t_w, o * 64 + c);
    ws[WP_O + i] = LDW(p_w, o * 64 + c);
  }
  if (gid < 16) {
    ws[BG_O + gid] = LDW(g_b, gid);
    ws[BT_O + gid] = LDW(t_b, gid);
    ws[BP_O + gid] = LDW(p_b, gid);
    float s = 0.f;
    for (int c = 0; c < 64; ++c) s += LDW(m_w, gid * 64 + c);
    ws[SM_O + gid] = s;
    ws[SB_O + gid] = LDW(m_b, gid);
  }
  for (int i = gid; i < 1024; i += gs) ws[RW_O + i] = LDW(r_w, i);
  if (gid >= 64 && gid < 128) ws[RB_O + gid - 64] = LDW(r_b, gid - 64);
  // conv MFMA B, split hi/lo: wB[tap][col64][c64]
  ushort_t* wBh = (ushort_t*)(ws + WB_O);
  ushort_t* wBl = wBh + 9 * 64 * 64;
  for (int i = gid; i < 9 * 64 * 64; i += gs) {
    int c = i & 63, t = i >> 6, col = t & 63, tap = t >> 6;
    float v = 0.f;
    if (col < 16) v = LDW(g_w, (col * 64 + c) * 9 + tap);
    else if (col < 32) { if (tap == 4) v = LDW(t_w, (col - 16) * 64 + c); }
    else if (col < 48) { if (tap == 4) v = LDW(p_w, (col - 32) * 64 + c); }
    ushort_t h, l; splitbf(v, h, l);
    wBh[i] = h; wBl[i] = l;
  }
  if (xhh) {
    // fused border zpad
    const int4 z = make_int4(0, 0, 0, 0);
    for (int idx = gid; idx < B_ * 512 * 8; idx += gs) {
      int q = idx & 7, t = idx >> 3;
      int bp = t & 511, bb = t >> 9;
      int pp;
      if (bp < 129) pp = bp;                              // top row
      else if (bp < 258) pp = 128 * PADW + (bp - 129);    // bottom row
      else if (bp < 385) pp = (bp - 257) * PADW;          // left col rows 1..127
      else pp = (bp - 384) * PADW + 128;                  // right col rows 1..127
      size_t off = ((size_t)bb * PADPIX + pp) * 64 + q * 8;
      *(int4*)(xhh + off) = z;
      *(int4*)(xhl + off) = z;
    }
    // fused HWC transpose into padded planes (one 64-pixel tile per block)
    int pix0 = blockIdx.x * 64;
    if (pix0 < B_ * HW) {
      int g = threadIdx.x >> 6, p = threadIdx.x & 63;
      int pix = pix0 + p;
      bool ok = pix < B_ * HW;
      int bb = ok ? pix / HW : 0;
      int r  = ok ? pix - bb * HW : 0;
      if (f) {
        const float* xf = (const float*)x;
        for (int c = g * 16; c < g * 16 + 16; ++c)
          tile[p][c] = ok ? xf[((size_t)bb * CIN + c) * HW + r] : 0.f;
      } else {
        const bf16* xb = (const bf16*)x;
        for (int c = g * 16; c < g * 16 + 16; ++c)
          tile[p][c] = ok ? bf2f(xb[((size_t)bb * CIN + c) * HW + r]) : 0.f;
      }
      __syncthreads();
      int c2 = threadIdx.x & 63, pg = threadIdx.x >> 6;
      int pix2 = pix0 + pg * 16;
      int bb2 = pix2 / HW, r2 = pix2 - bb2 * HW;
      int h2 = r2 / W_, w2 = r2 - h2 * W_;
      for (int k = 0; k < 16; ++k) {
        if (pix2 + k < B_ * HW) {
          ushort_t h, l; splitbf(tile[pg * 16 + k][c2], h, l);
          size_t off = ((size_t)bb2 * PADPIX + (size_t)(h2 + 1) * PADW + (w2 + 1)) * 64 + c2;
          xhh[off] = h;
          xhl[off] = l;
        }
        if (++w2 == W_) { w2 = 0; if (++h2 == H_) { h2 = 0; ++bb2; } }
      }
    }
  }
}

// -------- split-bf16 MFMA conv, one output row per block, contiguous staging -----
// pk != nullptr (FULL): epilogue stages b1 AND b2 in LDS and writes PK1/PK2
// directly (bit-identical values); b1/b2 planes never materialize.
__global__ __launch_bounds__(256) void k_conv3(
    const float* __restrict__ ws,
    const ushort_t* __restrict__ xhh, const ushort_t* __restrict__ xhl,
    ushort_t* __restrict__ b1h, ushort_t* __restrict__ b1l,
    ushort_t* __restrict__ b2h, ushort_t* __restrict__ b2l,
    ushort_t* __restrict__ b3, ushort_t* __restrict__ pk, ushort_t* __restrict__ pk2)
{
  __shared__ ushort_t sAh[128 * SLST], sAl[128 * SLST];
  __shared__ ushort_t sBh[64 * SLST],  sBl[64 * SLST];
  int bz = blockIdx.z;
  int h = blockIdx.x;                       // output row
  int tid = threadIdx.x, lane = tid & 63, wv = tid >> 6;
  int grp = lane >> 3, ch = lane & 7;

  const ushort_t* xplane = ((wv == 0) ? xhh : xhl) + (size_t)bz * XPB;
  const ushort_t* wBh_ = (const ushort_t*)(ws + WB_O);
  const ushort_t* bsrc = (wv == 2) ? wBh_ : (wBh_ + 9 * 64 * 64);
  ushort_t* dplane = (wv == 0) ? sAh : (wv == 1) ? sAl : (wv == 2) ? sBh : sBl;

  int fr = lane & 31, kh = (lane >> 5) << 3;
  int mt = (wv >> 1) << 1;
  int aoff0 = (mt * 32 + fr) * SLST + kh;
  int aoff1 = ((mt + 1) * 32 + fr) * SLST + kh;
  int boff  = (((wv & 1) << 5) + fr) * SLST + kh;

  f32x16 acc0 = {0.f,0.f,0.f,0.f,0.f,0.f,0.f,0.f,0.f,0.f,0.f,0.f,0.f,0.f,0.f,0.f};
  f32x16 acc1 = {0.f,0.f,0.f,0.f,0.f,0.f,0.f,0.f,0.f,0.f,0.f,0.f,0.f,0.f,0.f,0.f};

  int4 pv0, pv1, pv2, pv3, pv4, pv5, pv6, pv7;
  int4 pv8, pv9, pv10, pv11, pv12, pv13, pv14, pv15;

#define LC(j) pv##j = *(const int4*)(src + (j) * 512)
#define LC_A  LC(0); LC(1); LC(2); LC(3); LC(4); LC(5); LC(6); LC(7); \
              LC(8); LC(9); LC(10); LC(11); LC(12); LC(13); LC(14); LC(15)
#define LC_W  LC(0); LC(1); LC(2); LC(3); LC(4); LC(5); LC(6); LC(7)
#define WC(j) *(int4*)(d0 + (j) * 8 * SLST) = pv##j
#define WC_A  WC(0); WC(1); WC(2); WC(3); WC(4); WC(5); WC(6); WC(7); \
              WC(8); WC(9); WC(10); WC(11); WC(12); WC(13); WC(14); WC(15)
#define WC_W  WC(0); WC(1); WC(2); WC(3); WC(4); WC(5); WC(6); WC(7)

  // prefetch tap 0 (dh=-1, dw=-1): padded row h, col 0
  if (wv < 2) {
    const ushort_t* src = xplane + (size_t)h * (PADW * 64) + grp * 64 + ch * 8;
    LC_A;
  } else {
    const ushort_t* src = bsrc + grp * 64 + ch * 8;
    LC_W;
  }

  for (int r = 0; r < 9; ++r) {
    __syncthreads();
    {
      ushort_t* d0 = dplane + grp * SLST + ch * 8;
      if (wv < 2) { WC_A; } else { WC_W; }
    }
    __syncthreads();
    if (r < 8) {
      int rn = r + 1;
      int dh = rn / 3 - 1, dw = rn % 3 - 1;
      if (wv < 2) {
        const ushort_t* src = xplane
            + ((size_t)(h + 1 + dh) * PADW + (1 + dw)) * 64 + grp * 64 + ch * 8;
        LC_A;
      } else {
        const ushort_t* src = bsrc + rn * 4096 + grp * 64 + ch * 8;
        LC_W;
      }
    }
#pragma unroll
    for (int t = 0; t < 4; ++t) {
      bfv8 ah0 = *(const bfv8*)(sAh + aoff0 + t * 16);
      bfv8 al0 = *(const bfv8*)(sAl + aoff0 + t * 16);
      bfv8 ah1 = *(const bfv8*)(sAh + aoff1 + t * 16);
      bfv8 al1 = *(const bfv8*)(sAl + aoff1 + t * 16);
      bfv8 bh  = *(const bfv8*)(sBh + boff + t * 16);
      bfv8 bl  = *(const bfv8*)(sBl + boff + t * 16);
      acc0 = __builtin_amdgcn_mfma_f32_32x32x16_bf16(al0, bh, acc0, 0, 0, 0);
      acc0 = __builtin_amdgcn_mfma_f32_32x32x16_bf16(ah0, bl, acc0, 0, 0, 0);
      acc0 = __builtin_amdgcn_mfma_f32_32x32x16_bf16(ah0, bh, acc0, 0, 0, 0);
      acc1 = __builtin_amdgcn_mfma_f32_32x32x16_bf16(al1, bh, acc1, 0, 0, 0);
      acc1 = __builtin_amdgcn_mfma_f32_32x32x16_bf16(ah1, bl, acc1, 0, 0, 0);
      acc1 = __builtin_amdgcn_mfma_f32_32x32x16_bf16(ah1, bh, acc1, 0, 0, 0);
    }
  }
#undef LC
#undef LC_A
#undef LC_W
#undef WC
#undef WC_A
#undef WC_W

  int nw = ((wv & 1) << 5) + fr;
  if (pk) {
    // ---- PK-direct epilogue (b1 -> PK1, b2 -> PK2) ----
    __syncthreads();                     // main-loop LDS reads done
    ushort_t* sb1h = sAh;                // [128][16]
    ushort_t* sb1l = sAl;
    ushort_t* sb2h = sBh;                // [128][16] (fits in 64*SLST=4608)
    ushort_t* sb2l = sBl;
#pragma unroll
    for (int s = 0; s < 2; ++s) {
      int mbase = (mt + s) * 32;
#pragma unroll
      for (int r = 0; r < 16; ++r) {
        int m = mbase + (r & 3) + ((r >> 2) << 3) + ((lane >> 5) << 2);
        float val = s ? acc1[r] : acc0[r];
        if (nw < 16) {
          ushort_t h2, l2; splitbf(val + ws[BG_O + nw], h2, l2);
          sb1h[m * 16 + nw] = h2; sb1l[m * 16 + nw] = l2;
        } else if (nw < 32) {
          int o = nw - 16; ushort_t h2, l2; splitbf(val + ws[BT_O + o], h2, l2);
          sb2h[m * 16 + o] = h2; sb2l[m * 16 + o] = l2;
        } else if (nw < 48) {
          if (m < W_) {
            size_t ob = ((size_t)bz * HW + h * W_ + m) * 16;
            int o = nw - 32; b3[ob + o] = f2bf(val + ws[BP_O + o]);
          }
        }
      }
    }
    __syncthreads();
    // cooperative PK write: each valid slh owns 31 slw segments x 14 int4 / plane
    ushort_t* pk1b = pk  + (size_t)bz * PKSTR;
    ushort_t* pk2b = pk2 + (size_t)bz * PKSTR;
    int slh_lo = (h >= 6) ? ((h - 3) >> 2) : 0;       // ceil((h-6)/4)
    int slh_hi = h >> 2; if (slh_hi > 30) slh_hi = 30;
    for (int slh = slh_lo; slh <= slh_hi; ++slh) {
      int nki = h - 4 * slh;                          // in [0,6]
      size_t rb = ((size_t)nki * 961 + slh * 31) * 112;
      for (int t = tid; t < 31 * 14; t += 256) {
        int slw = t / 14, q = t - slw * 14;
        int m = slw * 4 + (q >> 1);                   // pixel w (<=126)
        int c0 = (q & 1) << 3;
        size_t doff = rb + (size_t)slw * 112 + q * 8;
        *(int4*)(pk1b + doff)           = *(int4*)(sb1h + m * 16 + c0);
        *(int4*)(pk1b + PKPLANE + doff) = *(int4*)(sb1l + m * 16 + c0);
        *(int4*)(pk2b + doff)           = *(int4*)(sb2h + m * 16 + c0);
        *(int4*)(pk2b + PKPLANE + doff) = *(int4*)(sb2l + m * 16 + c0);
      }
    }
  } else {
    // ---- legacy epilogue (MID tier; k_pack consumes b1/b2) ----
#pragma unroll
    for (int s = 0; s < 2; ++s) {
      int mbase = (mt + s) * 32;
#pragma unroll
      for (int r = 0; r < 16; ++r) {
        int m = mbase + (r & 3) + ((r >> 2) << 3) + ((lane >> 5) << 2);
        if (m >= W_) continue;
        size_t ob = ((size_t)bz * HW + h * W_ + m) * 16;
        float val = s ? acc1[r] : acc0[r];
        if (nw < 16) {
          ushort_t h2, l2; splitbf(val + ws[BG_O + nw], h2, l2);
          b1h[ob + nw] = h2; b1l[ob + nw] = l2;
        } else if (nw < 32) {
          int o = nw - 16; ushort_t h2, l2; splitbf(val + ws[BT_O + o], h2, l2);
          b2h[ob + o] = h2; b2l[ob + o] = l2;
        } else if (nw < 48) {
          int o = nw - 32; b3[ob + o] = f2bf(val + ws[BP_O + o]);
        }
      }
    }
  }
}

// -------- fallback conv (LOW tier), dtype-templated VALU -------------------------
template <typename T>
__device__ __forceinline__ void convF_body(
    const void* x, const void* g_w, const void* g_b,
    const void* t_w, const void* t_b, const void* p_w, const void* p_b,
    ushort_t* b1h, ushort_t* b1l, ushort_t* b2h, ushort_t* b2l, ushort_t* b3,
    float* sgw, float* stw, float* spw)
{
  int tid = threadIdx.y * 32 + threadIdx.x;
  for (int i = tid; i < CI * CIN * 9; i += 256) sgw[i] = Ld<T>::f(g_w, i);
  for (int i = tid; i < CI * CIN; i += 256) { stw[i] = Ld<T>::f(t_w, i); spw[i] = Ld<T>::f(p_w, i); }
  __syncthreads();

  int w = blockIdx.x * 32 + threadIdx.x;
  int h = blockIdx.y * 8 + threadIdx.y;
  int b = blockIdx.z;
  if (w >= W_ || h >= H_) return;

  float a1[CI], a2[CI], a3[CI];
#pragma unroll
  for (int o = 0; o < CI; ++o) { a1[o] = 0.f; a2[o] = 0.f; a3[o] = 0.f; }

  const size_t xb = (size_t)b * CIN * HW;
  for (int c = 0; c < CIN; ++c) {
    float xv[9];
#pragma unroll
    for (int dh = 0; dh < 3; ++dh) {
      int hh = h + dh - 1;
      bool rok = ((unsigned)hh < (unsigned)H_);
#pragma unroll
      for (int dw = 0; dw < 3; ++dw) {
        int ww = w + dw - 1;
        bool ok = rok && ((unsigned)ww < (unsigned)W_);
        xv[dh * 3 + dw] = ok ? Ld<T>::f(x, (int)(xb + (size_t)c * HW + hh * W_ + ww)) : 0.f;
      }
    }
    float xc = xv[4];
#pragma unroll
    for (int o = 0; o < CI; ++o) {
      const float* gg = &sgw[(o * CIN + c) * 9];
      float s = gg[0]*xv[0] + gg[1]*xv[1] + gg[2]*xv[2]
              + gg[3]*xv[3] + gg[4]*xv[4] + gg[5]*xv[5]
              + gg[6]*xv[6] + gg[7]*xv[7] + gg[8]*xv[8];
      a1[o] += s;
      a2[o] += stw[o * CIN + c] * xc;
      a3[o] += spw[o * CIN + c] * xc;
    }
  }
  size_t base = ((size_t)b * HW + h * W_ + w) * CI;
#pragma unroll
  for (int o = 0; o < CI; ++o) {
    float v1 = a1[o] + Ld<T>::f(g_b, o);
    float v2 = a2[o] + Ld<T>::f(t_b, o);
    ushort_t hh2, ll2;
    splitbf(v1, hh2, ll2); b1h[base + o] = hh2; b1l[base + o] = ll2;
    splitbf(v2, hh2, ll2); b2h[base + o] = hh2; b2l[base + o] = ll2;
    b3[base + o] = f2bf(a3[o] + Ld<T>::f(p_b, o));
  }
}

__global__ __launch_bounds__(256) void k_convF(
    const int* __restrict__ flag, const void* x,
    const void* g_w, const void* g_b, const void* t_w, const void* t_b,
    const void* p_w, const void* p_b,
    ushort_t* __restrict__ b1h, ushort_t* __restrict__ b1l,
    ushort_t* __restrict__ b2h, ushort_t* __restrict__ b2l,
    ushort_t* __restrict__ b3)
{
  __shared__ float sgw[CI * CIN * 9];
  __shared__ float stw[CI * CIN];
  __shared__ float spw[CI * CIN];
  if (*flag) convF_body<float>(x, g_w, g_b, t_w, t_b, p_w, p_b, b1h, b1l, b2h, b2l, b3, sgw, stw, spw);
  else       convF_body<bf16 >(x, g_w, g_b, t_w, t_b, p_w, p_b, b1h, b1l, b2h, b2l, b3, sgw, stw, spw);
}

// -------- S3[b, pos*16+c] = sum over patches of b3 (bf16 src, fp32 acc) ----------
__global__ __launch_bounds__(256) void k_colsum(const ushort_t* __restrict__ b3, float* __restrict__ S3)
{
  __shared__ float red[16][17];
  int b = blockIdx.x, pos = blockIdx.y;
  int ki = pos / 7, kj = pos % 7;
  int c = threadIdx.x & 15, chunk = threadIdx.x >> 4;
  const ushort_t* B3 = b3 + (size_t)b * HW * CI;
  float s = 0.f;
  for (int l = chunk; l < L_; l += 16) {
    int lh = l / OH_, lw = l % OH_;
    s += bflo((unsigned)B3[((lh * ST + ki) * W_ + lw * ST + kj) * CI + c]);
  }
  red[chunk][c] = s;
  __syncthreads();
  if (threadIdx.x < 16) {
    float t = 0.f;
#pragma unroll
    for (int k = 0; k < 16; ++k) t += red[k][threadIdx.x];
    S3[(b * 49 + pos) * 16 + threadIdx.x] = t;
  }
}

// -------- pack operands (MID/LOW tiers): PK1 from b1, PK2 from b2 ----------------
__global__ __launch_bounds__(256) void k_pack(
    const ushort_t* __restrict__ b1h, const ushort_t* __restrict__ b1l,
    const ushort_t* __restrict__ b2h, const ushort_t* __restrict__ b2l,
    ushort_t* __restrict__ pk, ushort_t* __restrict__ pk2,
    int b0, unsigned pkstride_z)
{
  int idx = blockIdx.x * 256 + threadIdx.x;
  if (idx >= 2 * 961 * 98) return;
  int sel = (idx >= 961 * 98);
  int i2 = sel ? idx - 961 * 98 : idx;
  int row = i2 / 98, rem = i2 - row * 98;
  int nki = rem / 14, q = rem - nki * 14;
  int slh = row / OH_, slw = row - slh * OH_;
  int src = ((slh * ST) * W_ + slw * ST + nki * W_) * 16 + q * 8;
  int dst = (nki * 961 + row) * 112 + q * 8;
  int batch = b0 + blockIdx.y;
  size_t poff = (size_t)batch * HW * CI;
  const ushort_t* sh = sel ? b2h : b1h;
  const ushort_t* sl = sel ? b2l : b1l;
  ushort_t* pkb = (sel ? pk2 : pk) + (size_t)blockIdx.y * pkstride_z;
  *(int4*)(pkb + dst)           = *(const int4*)(sh + poff + src);
  *(int4*)(pkb + PKPLANE + dst) = *(const int4*)(sl + poff + src);
}

// -------- score GEMM via split-bf16 MFMA, 128x64 tile, both operands from PK -----
__global__ __launch_bounds__(256) void k_score(
    const ushort_t* __restrict__ pk, const ushort_t* __restrict__ pk2,
    float* __restrict__ scb, unsigned scstride_z, unsigned pkstride_z)
{
  __shared__ ushort_t sAh[128 * SLST], sAl[128 * SLST];
  __shared__ ushort_t sBh[64 * SLST],  sBl[64 * SLST];
  float* Sc = scb + (size_t)blockIdx.z * scstride_z;

  int tid = threadIdx.x;
  int m0 = blockIdx.y * 128, n0 = blockIdx.x * 64;
  int lane = tid & 63;
  int wv = tid >> 6;
  int grp = lane >> 3, ch = lane & 7;

  const ushort_t* pka = ((wv < 2) ? pk : pk2)
      + (size_t)blockIdx.z * pkstride_z + (size_t)(wv & 1) * PKPLANE;
  int base_mn = (wv < 2) ? m0 : n0;

  ushort_t* dplane = (wv == 0) ? sAh : (wv == 1) ? sAl : (wv == 2) ? sBh : sBl;

  int fr = lane & 31;
  int kh = (lane >> 5) << 3;
  int mt = (wv >> 1) << 1;                         // first m-subtile: 0 or 2
  int aoff0 = (mt * 32 + fr) * SLST + kh;
  int aoff1 = ((mt + 1) * 32 + fr) * SLST + kh;
  int boff  = (((wv & 1) << 5) + fr) * SLST + kh;

  f32x16 acc0 = {0.f,0.f,0.f,0.f,0.f,0.f,0.f,0.f,0.f,0.f,0.f,0.f,0.f,0.f,0.f,0.f};
  f32x16 acc1 = {0.f,0.f,0.f,0.f,0.f,0.f,0.f,0.f,0.f,0.f,0.f,0.f,0.f,0.f,0.f,0.f};

  int4 pv0, pv1, pv2, pv3, pv4, pv5, pv6, pv7;
  int4 pv8, pv9, pv10, pv11, pv12, pv13, pv14, pv15;

#define LA(j) pv##j = *(const int4*)(pks + (size_t)min(base_mn + 8*(j) + grp, 960) * 112)
#define LA_A LA(0); LA(1); LA(2); LA(3); LA(4); LA(5); LA(6); LA(7); \
             LA(8); LA(9); LA(10); LA(11); LA(12); LA(13); LA(14); LA(15)
#define LA_B LA(0); LA(1); LA(2); LA(3); LA(4); LA(5); LA(6); LA(7)
#define WA(j) *(int4*)(d0 + (j) * 8 * SLST) = pv##j
#define WA_A WA(0); WA(1); WA(2); WA(3); WA(4); WA(5); WA(6); WA(7); \
             WA(8); WA(9); WA(10); WA(11); WA(12); WA(13); WA(14); WA(15)
#define WA_B WA(0); WA(1); WA(2); WA(3); WA(4); WA(5); WA(6); WA(7)

  // initial prefetch: rn=0 (nki=0, even)
  {
    const ushort_t* pks = pka + ch * 8;
    if (wv < 2) { LA_A; } else { LA_B; }
  }

  for (int r = 0; r < 14; ++r) {
    int half = r & 1;
    __syncthreads();
    {
      ushort_t* d0 = dplane + grp * SLST + ch * 8;
      if (!half || ch < 6) { if (wv < 2) { WA_A; } else { WA_B; } }
    }
    __syncthreads();
    if (r < 13) {
      int rn = r + 1;
      int nki = rn >> 1, odd = rn & 1;
      const ushort_t* pks = pka + (size_t)nki * (961 * 112) + odd * 64 + ch * 8;
      if (!odd || ch < 6) { if (wv < 2) { LA_A; } else { LA_B; } }
    }
    if (!half) {
#pragma unroll
      for (int t = 0; t < 4; ++t) {
        bfv8 ah0 = *(const bfv8*)(sAh + aoff0 + t * 16);
        bfv8 al0 = *(const bfv8*)(sAl + aoff0 + t * 16);
        bfv8 ah1 = *(const bfv8*)(sAh + aoff1 + t * 16);
        bfv8 al1 = *(const bfv8*)(sAl + aoff1 + t * 16);
        bfv8 bh  = *(const bfv8*)(sBh + boff + t * 16);
        bfv8 bl  = *(const bfv8*)(sBl + boff + t * 16);
        acc0 = __builtin_amdgcn_mfma_f32_32x32x16_bf16(al0, bh, acc0, 0, 0, 0);
        acc0 = __builtin_amdgcn_mfma_f32_32x32x16_bf16(ah0, bl, acc0, 0, 0, 0);
        acc0 = __builtin_amdgcn_mfma_f32_32x32x16_bf16(ah0, bh, acc0, 0, 0, 0);
        acc1 = __builtin_amdgcn_mfma_f32_32x32x16_bf16(al1, bh, acc1, 0, 0, 0);
        acc1 = __builtin_amdgcn_mfma_f32_32x32x16_bf16(ah1, bl, acc1, 0, 0, 0);
        acc1 = __builtin_amdgcn_mfma_f32_32x32x16_bf16(ah1, bh, acc1, 0, 0, 0);
      }
    } else {
#pragma unroll
      for (int t = 0; t < 3; ++t) {
        bfv8 ah0 = *(const bfv8*)(sAh + aoff0 + t * 16);
        bfv8 al0 = *(const bfv8*)(sAl + aoff0 + t * 16);
        bfv8 ah1 = *(const bfv8*)(sAh + aoff1 + t * 16);
        bfv8 al1 = *(const bfv8*)(sAl + aoff1 + t * 16);
        bfv8 bh  = *(const bfv8*)(sBh + boff + t * 16);
        bfv8 bl  = *(const bfv8*)(sBl + boff + t * 16);
        acc0 = __builtin_amdgcn_mfma_f32_32x32x16_bf16(al0, bh, acc0, 0, 0, 0);
        acc0 = __builtin_amdgcn_mfma_f32_32x32x16_bf16(ah0, bl, acc0, 0, 0, 0);
        acc0 = __builtin_amdgcn_mfma_f32_32x32x16_bf16(ah0, bh, acc0, 0, 0, 0);
        acc1 = __builtin_amdgcn_mfma_f32_32x32x16_bf16(al1, bh, acc1, 0, 0, 0);
        acc1 = __builtin_amdgcn_mfma_f32_32x32x16_bf16(ah1, bl, acc1, 0, 0, 0);
        acc1 = __builtin_amdgcn_mfma_f32_32x32x16_bf16(ah1, bh, acc1, 0, 0, 0);
      }
    }
  }
#undef LA
#undef LA_A
#undef LA_B
#undef WA
#undef WA_A
#undef WA_B

  int nw = n0 + ((wv & 1) << 5) + fr;
  if (nw < L_) {
    int mw0 = m0 + mt * 32;
#pragma unroll
    for (int r = 0; r < 16; ++r) {
      int m = mw0 + (r & 3) + ((r >> 2) << 3) + ((lane >> 5) << 2);
      if (m < L_) Sc[(size_t)m * SROW + nw] = acc0[r];
    }
    int mw1 = m0 + (mt + 1) * 32;
#pragma unroll
    for (int r = 0; r < 16; ++r) {
      int m = mw1 + (r & 3) + ((r >> 2) << 3) + ((lane >> 5) << 2);
      if (m < L_) Sc[(size_t)m * SROW + nw] = acc1[r];
    }
  }
}

// -------- fused top-100 softmax (wave 0, ballot-radix) + PV gather ---------------
__global__ __launch_bounds__(128) void k_tkpv(
    const float* __restrict__ scb,
    const ushort_t* __restrict__ b3, const float* __restrict__ s3,
    float* __restrict__ agb, int b0, unsigned scstride_z, unsigned agstride_z)
{
  __shared__ float swv[TOPM];
  __shared__ int spx[TOPM];
  __shared__ float sw0, sinvZ;
  int l = blockIdx.x, bz = blockIdx.y;
  int tid = threadIdx.x;

  if (tid < 64) {
    int lane = tid;
    const float4* row4 = (const float4*)(scb + (size_t)bz * scstride_z + (size_t)l * SROW);

    unsigned k[16];
#pragma unroll
    for (int q = 0; q < 4; ++q) {
      float4 v = row4[q * 64 + lane];
      int ib = (q * 64 + lane) * 4;
      k[q * 4 + 0] = (ib + 0 < L_) ? fmap(v.x) : 0u;
      k[q * 4 + 1] = (ib + 1 < L_) ? fmap(v.y) : 0u;
      k[q * 4 + 2] = (ib + 2 < L_) ? fmap(v.z) : 0u;
      k[q * 4 + 3] = (ib + 3 < L_) ? fmap(v.w) : 0u;
    }

    unsigned mk = 0;
#pragma unroll
    for (int r = 0; r < 16; ++r) mk = max(mk, k[r]);
#pragma unroll
    for (int o = 32; o; o >>= 1) mk = max(mk, (unsigned)__shfl_down((int)mk, o));
    mk = (unsigned)__shfl((int)mk, 0);
    float vmax = unfmap(mk);

    unsigned kk[16];
#pragma unroll
    for (int r = 0; r < 16; ++r) kk[r] = k[r];

    unsigned prefix = 0; int base = 0;
    for (int bit = 30; bit >= 0; bit -= 2) {
      int n3 = 0, n2 = 0, n1 = 0;
#pragma unroll
      for (int r = 0; r < 16; ++r) {
        unsigned f = (kk[r] >> bit) & 3u;
        n3 += (int)__popcll(__ballot(f == 3u));
        n2 += (int)__popcll(__ballot(f >= 2u));
        n1 += (int)__popcll(__ballot(f >= 1u));
      }
      unsigned ch;
      if (base + n3 >= TOPM) ch = 3;
      else if (base + n2 >= TOPM) { ch = 2; base += n3; }
      else if (base + n1 >= TOPM) { ch = 1; base += n2; }
      else { ch = 0; base += n1; }
      prefix |= ch << bit;
#pragma unroll
      for (int r = 0; r < 16; ++r) {
        unsigned f = (kk[r] >> bit) & 3u;
        kk[r] = (f == ch) ? kk[r] : 0u;
      }
    }
    int nA = base;
    int needT = TOPM - nA;

    int cA = 0, cT = 0;
#pragma unroll
    for (int r = 0; r < 16; ++r) { cA += (k[r] > prefix); cT += (k[r] == prefix); }
    int pkc = cA | (cT << 16);
    int incl = pkc;
#pragma unroll
    for (int o = 1; o < 64; o <<= 1) { int t = __shfl_up(incl, o); if (lane >= o) incl += t; }
    int excl = incl - pkc;
    int tA = excl & 0xFFFF, tT = excl >> 16;

    float M = fmaxf(10.f * vmax, 0.f);
    float e0 = __expf(-M);
    float z = 0.f;
#pragma unroll
    for (int r = 0; r < 16; ++r) {
      unsigned kr = k[r];
      int slot = -1;
      if (kr > prefix) slot = tA++;
      else if (kr == prefix) { if (tT < needT) slot = nA + tT; tT++; }
      if (slot >= 0) {
        float v = unfmap(kr);
        float wv = __expf(10.f * v - M);
        swv[slot] = wv; z += wv;
        int gi = 256 * (r >> 2) + 4 * lane + (r & 3);
        int lh = gi / OH_, lw = gi - lh * OH_;
        spx[slot] = ((lh * ST) * W_ + lw * ST) * CI;
      }
    }
#pragma unroll
    for (int o = 32; o; o >>= 1) z += __shfl_down(z, o);
    z = __shfl(z, 0);
    float Z = z + (float)(L_ - TOPM) * e0;
    if (lane == 0) { sinvZ = 1.f / Z; sw0 = e0 / Z; }
  }
  __syncthreads();
  if (tid < TOPM) swv[tid] = swv[tid] * sinvZ - sw0;
  __syncthreads();

  // ---- PV phase (98 lanes x 8 channels) ----
  if (tid >= 98) return;
  int batch = b0 + bz;
  const ushort_t* B3 = b3 + (size_t)batch * HW * CI;
  const float* S3 = s3 + (size_t)batch * D_;
  float* agg = agb + (size_t)bz * agstride_z;

  float w0 = sw0;
  int pos = tid >> 1;
  int c0 = (tid & 1) << 3;                 // 0 or 8
  int ki = pos / 7, kj = pos - (pos / 7) * 7;
  int poff = (ki * W_ + kj) * CI + c0;

  float a0 = 0.f, a1 = 0.f, a2 = 0.f, a3 = 0.f;
  float a4 = 0.f, a5 = 0.f, a6 = 0.f, a7 = 0.f;
  for (int j0 = 0; j0 < TOPM; j0 += 4) {
    float w_0 = swv[j0 + 0];
    float w_1 = swv[j0 + 1];
    float w_2 = swv[j0 + 2];
    float w_3 = swv[j0 + 3];
    int p_0 = spx[j0 + 0];
    int p_1 = spx[j0 + 1];
    int p_2 = spx[j0 + 2];
    int p_3 = spx[j0 + 3];
    const uint4 q0 = *(const uint4*)(B3 + p_0 + poff);
    const uint4 q1 = *(const uint4*)(B3 + p_1 + poff);
    const uint4 q2 = *(const uint4*)(B3 + p_2 + poff);
    const uint4 q3 = *(const uint4*)(B3 + p_3 + poff);
    a0 += w_0 * bflo(q0.x); a1 += w_0 * bfhi(q0.x); a2 += w_0 * bflo(q0.y); a3 += w_0 * bfhi(q0.y);
    a4 += w_0 * bflo(q0.z); a5 += w_0 * bfhi(q0.z); a6 += w_0 * bflo(q0.w); a7 += w_0 * bfhi(q0.w);
    a0 += w_1 * bflo(q1.x); a1 += w_1 * bfhi(q1.x); a2 += w_1 * bflo(q1.y); a3 += w_1 * bfhi(q1.y);
    a4 += w_1 * bflo(q1.z); a5 += w_1 * bfhi(q1.z); a6 += w_1 * bflo(q1.w); a7 += w_1 * bfhi(q1.w);
    a0 += w_2 * bflo(q2.x); a1 += w_2 * bfhi(q2.x); a2 += w_2 * bflo(q2.y); a3 += w_2 * bfhi(q2.y);
    a4 += w_2 * bflo(q2.z); a5 += w_2 * bfhi(q2.z); a6 += w_2 * bflo(q2.w); a7 += w_2 * bfhi(q2.w);
    a0 += w_3 * bflo(q3.x); a1 += w_3 * bfhi(q3.x); a2 += w_3 * bflo(q3.y); a3 += w_3 * bfhi(q3.y);
    a4 += w_3 * bflo(q3.z); a5 += w_3 * bfhi(q3.z); a6 += w_3 * bflo(q3.w); a7 += w_3 * bfhi(q3.w);
  }
  const float4 s40 = *(const float4*)(S3 + tid * 8);
  const float4 s41 = *(const float4*)(S3 + tid * 8 + 4);
  a0 += w0 * s40.x; a1 += w0 * s40.y; a2 += w0 * s40.z; a3 += w0 * s40.w;
  a4 += w0 * s41.x; a5 += w0 * s41.y; a6 += w0 * s41.z; a7 += w0 * s41.w;
  float* dst = agg + (size_t)l * D_ + tid * 8;
  *(float4*)(dst)     = make_float4(a0, a1, a2, a3);
  *(float4*)(dst + 4) = make_float4(a4, a5, a6, a7);
}

// -------- fold + mask divide + restore (16->64), batched -------------------------
__global__ __launch_bounds__(256) void k_fold(
    const int* __restrict__ flag, const float* __restrict__ ws,
    const float* __restrict__ agb, void* __restrict__ out,
    int b0, unsigned agstride_z)
{
  __shared__ float srw[CIN * CI];
  int tid = threadIdx.x;
  for (int i = tid; i < CIN * CI; i += 256) srw[i] = ws[RW_O + i];
  __syncthreads();

  int bz = blockIdx.y;
  int batch = b0 + bz;
  const float* agg = agb + (size_t)bz * agstride_z;

  int gid = blockIdx.x * 256 + tid;
  if (gid >= HW) return;
  int h = gid / W_;
  int w = gid % W_;

  int lh0 = (h >= KS - 1) ? ((h - (KS - 1) + (ST - 1)) >> 2) : 0;
  int lh1 = min(OH_ - 1, h >> 2);
  int lw0 = (w >= KS - 1) ? ((w - (KS - 1) + (ST - 1)) >> 2) : 0;
  int lw1 = min(OH_ - 1, w >> 2);

  float t[CI];
#pragma unroll
  for (int c = 0; c < CI; ++c) t[c] = 0.f;
  for (int lh = lh0; lh <= lh1; ++lh) {
    int ki = h - ST * lh;
    for (int lw = lw0; lw <= lw1; ++lw) {
      int kj = w - ST * lw;
      const float* pb = agg + (size_t)(lh * OH_ + lw) * D_ + (ki * KS + kj) * CI;
      float4 q0 = *(const float4*)(pb);
      float4 q1 = *(const float4*)(pb + 4);
      float4 q2 = *(const float4*)(pb + 8);
      float4 q3 = *(const float4*)(pb + 12);
      t[0] += q0.x; t[1] += q0.y; t[2] += q0.z; t[3] += q0.w;
      t[4] += q1.x; t[5] += q1.y; t[6] += q1.z; t[7] += q1.w;
      t[8] += q2.x; t[9] += q2.y; t[10] += q2.z; t[11] += q2.w;
      t[12] += q3.x; t[13] += q3.y; t[14] += q3.z; t[15] += q3.w;
    }
  }
  float cnt = (float)((lh1 - lh0 + 1) * (lw1 - lw0 + 1));
  float r[CI];
#pragma unroll
  for (int c = 0; c < CI; ++c) r[c] = t[c] / (cnt * ws[SM_O + c] + ws[SB_O + c] + 1e-8f);

  size_t ob = (size_t)batch * CIN * HW + (size_t)h * W_ + w;
  if (*flag) {
    float* of = (float*)out;
#pragma unroll
    for (int o = 0; o < CIN; ++o) {
      float s = ws[RB_O + o];
#pragma unroll
      for (int c = 0; c < CI; ++c) s += srw[o * CI + c] * r[c];
      of[ob + (size_t)o * HW] = s;
    }
  } else {
    bf16* of = (bf16*)out;
#pragma unroll
    for (int o = 0; o < CIN; ++o) {
      float s = ws[RB_O + o];
#pragma unroll
      for (int c = 0; c < CI; ++c) s += srw[o * CI + c] * r[c];
      of[ob + (size_t)o * HW] = __float2bfloat16(s);
    }
  }
}

extern "C" void kernel_launch(void* const* d_in, const int* in_sizes, int n_in,
                              void* d_out, int out_size, void* d_ws, size_t ws_size,
                              hipStream_t stream)
{
  const void* x    = d_in[0];
  const void* g_w  = d_in[1];
  const void* g_b  = d_in[2];
  const void* th_w = d_in[3];
  const void* th_b = d_in[4];
  const void* ph_w = d_in[5];
  const void* ph_b = d_in[6];
  const void* m_w  = d_in[7];
  const void* m_b  = d_in[8];
  const void* r_w  = d_in[9];
  const void* r_b  = d_in[10];

  float* W = (float*)d_ws;
  int* flag = (int*)d_ws;
  ushort_t* planes = (ushort_t*)(W + B1_O);
  ushort_t* b1h = planes;
  ushort_t* b1l = planes + (size_t)N1;
  ushort_t* b2h = planes + (size_t)2 * N1;
  ushort_t* b2l = planes + (size_t)3 * N1;
  ushort_t* b3  = planes + (size_t)4 * N1;   // bf16 plane, N1 ushorts
  float* s3 = W + S3_O;

  if (ws_size >= FULL_BYTES) {
    ushort_t* xhh = (ushort_t*)(W + REG_O);    // padded planes, dead after conv
    ushort_t* xhl = xhh + XPU;
    float* sc = W + REG_O;                     // 4 x SCSLOT, aliases dead planes
    ushort_t* pk  = (ushort_t*)(W + PK_O);
    ushort_t* pk2 = (ushort_t*)(W + PK2_O);
    float* ag = W + PK_O;                      // aliases PK1 (dead after k_score)
    k_prep<<<dim3((B_ * HW + 63) / 64), 256, 0, stream>>>(
        x, g_w, th_w, ph_w, g_b, th_b, ph_b, m_w, m_b, r_w, r_b, W, xhh, xhl);
    k_conv3<<<dim3(H_, 1, B_), 256, 0, stream>>>(
        W, xhh, xhl, b1h, b1l, b2h, b2l, b3, pk, pk2);
    k_colsum<<<dim3(B_, 49), 256, 0, stream>>>(b3, s3);
    k_score<<<dim3(16, 8, B_), 256, 0, stream>>>(pk, pk2, sc, SCSLOT, PKSTR);
    k_tkpv<<<dim3(L_, B_), 128, 0, stream>>>(sc, b3, s3, ag, 0, SCSLOT, AGSZ);
    k_fold<<<dim3(64, B_), 256, 0, stream>>>(flag, W, ag, d_out, 0, AGSZ);
  } else if (ws_size >= MID_BYTES) {
    ushort_t* xhh = (ushort_t*)(W + REG_O);
    ushort_t* xhl = xhh + XPU;
    float* sc = W + REG_O;
    float* ag = W + REG_O + SCSLOT;
    ushort_t* pk  = (ushort_t*)ag;             // PK1 shares the ag slot
    ushort_t* pk2 = pk + (size_t)PKSTR;        // PK2 right after (within planes region)
    k_prep<<<dim3((B_ * HW + 63) / 64), 256, 0, stream>>>(
        x, g_w, th_w, ph_w, g_b, th_b, ph_b, m_w, m_b, r_w, r_b, W, xhh, xhl);
    k_conv3<<<dim3(H_, 1, B_), 256, 0, stream>>>(
        W, xhh, xhl, b1h, b1l, b2h, b2l, b3, (ushort_t*)nullptr, (ushort_t*)nullptr);
    k_colsum<<<dim3(B_, 49), 256, 0, stream>>>(b3, s3);
    for (int b = 0; b < B_; ++b) {
      k_pack<<<dim3(736, 1), 256, 0, stream>>>(b1h, b1l, b2h, b2l, pk, pk2, b, 0);
      k_score<<<dim3(16, 8, 1), 256, 0, stream>>>(pk, pk2, sc, 0, 0);
      k_tkpv<<<dim3(L_, 1), 128, 0, stream>>>(sc, b3, s3, ag, b, 0, 0);
      k_fold<<<dim3(64, 1), 256, 0, stream>>>(flag, W, ag, d_out, b, 0);
    }
  } else {
    float* sc = W + REG_O;
    float* ag = W + REG_O + SCSLOT;
    ushort_t* pk  = (ushort_t*)ag;
    ushort_t* pk2 = pk + (size_t)PKSTR;
    k_prep<<<64, 256, 0, stream>>>(
        x, g_w, th_w, ph_w, g_b, th_b, ph_b, m_w, m_b, r_w, r_b, W,
        (ushort_t*)nullptr, (ushort_t*)nullptr);
    k_convF<<<dim3(4, 16, B_), dim3(32, 8, 1), 0, stream>>>(
        flag, x, g_w, g_b, th_w, th_b, ph_w, ph_b, b1h, b1l, b2h, b2l, b3);
    k_colsum<<<dim3(B_, 49), 256, 0, stream>>>(b3, s3);
    for (int b = 0; b < B_; ++b) {
      k_pack<<<dim3(736, 1), 256, 0, stream>>>(b1h, b1l, b2h, b2l, pk, pk2, b, 0);
      k_score<<<dim3(16, 8, 1), 256, 0, stream>>>(pk, pk2, sc, 0, 0);
      k_tkpv<<<dim3(L_, 1), 128, 0, stream>>>(sc, b3, s3, ag, b, 0, 0);
      k_fold<<<dim3(64, 1), 256, 0, stream>>>(flag, W, ag, d_out, b, 0);
    }
  }
}

// Round 10
// 241.258 us; speedup vs baseline: 1.8888x; 1.0269x over previous
//
#include <hip/hip_runtime.h>
#include <hip/hip_bf16.h>

typedef __hip_bfloat16 bf16;
typedef unsigned short ushort_t;
typedef __attribute__((ext_vector_type(8))) __bf16 bfv8;
typedef __attribute__((ext_vector_type(16))) float f32x16;

#define B_   4
#define CIN  64
#define CI   16
#define H_   127
#define W_   127
#define HW   (H_*W_)
#define KS   7
#define ST   4
#define OH_  31
#define L_   961
#define D_   784
#define TOPM 100

// ---- workspace layout (float offsets) ----
#define N1   1032256          // B*HW*CI elements (one conv-out array)
#define WG_O 4
#define WT_O (WG_O + 9216)
#define WP_O (WT_O + 1024)
#define BG_O (WP_O + 1024)
#define BT_O (BG_O + 16)
#define BP_O (BT_O + 16)
#define SM_O (BP_O + 16)
#define SB_O (SM_O + 16)
#define RW_O (SB_O + 16)
#define RB_O (RW_O + 1024)
#define B1_O 12448
// planes at B1_O: b1h,b1l,b2h,b2l each N1 ushorts (2*N1 floats); b3 bf16 N1 ushorts
#define S3_O (B1_O + 3*N1)
#define WB_O (S3_O + B_*D_)   // conv MFMA B: wBh + wBl = 36864 floats
#define REG_O (WB_O + 36864)
#define SROW 964              // padded Sc row stride
#define SCSLOT 926464
#define AGSZ 753424
#define SLST 72               // LDS row stride in ushorts (conflict-free, measured r8)
// PK: unfold-packed operands. Per plane: 7 nki x 961 rows x 112 ushorts = 753424.
#define PKPLANE 753424
#define PKSTR   1506848
// padded x planes: 129x129 pixels x 64 ch, zero borders -> conv3 has NO bounds logic
#define PADW 129
#define PADPIX (PADW*PADW)            // 16641
#define XPB  (PADPIX*64)              // ushorts per batch-plane = 1,065,024
#define XPU  ((size_t)B_ * XPB)       // ushorts per plane (all batches) = 4,260,096
#define PLANES_FL 4260096             // floats spanned by both padded planes
// FULL tier: PK1/PK2 after the planes (conv3 writes them while reading planes).
#define PK_O  (REG_O + PLANES_FL)     // PK1: 4*PKSTR ushorts = 3,013,696 floats
#define PK2_O (PK_O + 3013696)        // PK2 (b2 operand), same size

#define FULL_BYTES ((size_t)(PK2_O + 3013696) * 4)         // ~53.7 MB (ws is 256 MiB)
#define MID_BYTES  ((size_t)(REG_O + PLANES_FL) * 4)       // ~29.6 MB

__device__ __forceinline__ float bf2f(bf16 v) { return __bfloat162float(v); }
__device__ __forceinline__ float bflo(unsigned u) { return __uint_as_float(u << 16); }
__device__ __forceinline__ float bfhi(unsigned u) { return __uint_as_float(u & 0xFFFF0000u); }

template <typename T> struct Ld;
template <> struct Ld<float> {
  static __device__ __forceinline__ float f(const void* p, int i) { return ((const float*)p)[i]; }
};
template <> struct Ld<bf16> {
  static __device__ __forceinline__ float f(const void* p, int i) { return bf2f(((const bf16*)p)[i]); }
};

__device__ __forceinline__ unsigned fmap(float f) {
  unsigned u = __float_as_uint(f);
  return (u & 0x80000000u) ? ~u : (u | 0x80000000u);
}
__device__ __forceinline__ float unfmap(unsigned kk) {
  unsigned u = (kk & 0x80000000u) ? (kk & 0x7fffffffu) : ~kk;
  return __uint_as_float(u);
}

// RNE fp32 -> bf16 bits, and hi/lo split
__device__ __forceinline__ ushort_t f2bf(float x) {
  unsigned u = __float_as_uint(x);
  return (ushort_t)((u + 0x7FFFu + ((u >> 16) & 1u)) >> 16);
}
__device__ __forceinline__ void splitbf(float x, ushort_t& h, ushort_t& l) {
  h = f2bf(x);
  float hf = __uint_as_float(((unsigned)h) << 16);
  l = f2bf(x - hf);
}

// -------- weight prep + inline dtype detect + border zpad + fused HWC ------------
#define LDW(ptr, i) (f ? ((const float*)(ptr))[i] : bf2f(((const bf16*)(ptr))[i]))
__global__ __launch_bounds__(256) void k_prep(
    const void* __restrict__ x,
    const void* g_w, const void* t_w, const void* p_w,
    const void* g_b, const void* t_b, const void* p_b,
    const void* m_w, const void* m_b, const void* r_w, const void* r_b,
    float* __restrict__ ws,
    ushort_t* __restrict__ xhh, ushort_t* __restrict__ xhl)
{
  __shared__ int sflag;
  __shared__ float tile[64][65];
  // inline dtype detect (per block; wave 0 reduces, LDS broadcast)
  {
    const unsigned short* xh = (const unsigned short*)x;
    if (threadIdx.x < 64) {
      int c = 0;
#pragma unroll
      for (int j = 0; j < 2; ++j) {
        unsigned u = xh[threadIdx.x * 2 + j];
        unsigned e = (u >> 7) & 0xFF;
        if (e >= 134) c++;
      }
#pragma unroll
      for (int o = 32; o; o >>= 1) c += __shfl_down(c, o);
      if (threadIdx.x == 0) sflag = (c >= 8) ? 1 : 0;
    }
  }
  __syncthreads();
  int f = sflag;
  if (blockIdx.x == 0 && threadIdx.x == 0) *(int*)ws = f;   // publish for downstream

  int gid = blockIdx.x * 256 + threadIdx.x;
  int gs = gridDim.x * 256;
  for (int i = gid; i < 9216; i += gs) {
    int o = i & 15, t = i >> 4, c = t & 63, tap = t >> 6;
    ws[WG_O + i] = LDW(g_w, (o * 64 + c) * 9 + tap);
  }
  for (int i = gid; i < 1024; i += gs) {
    int o = i & 15, c = i >> 4;
    ws[WT_O + i] = LDW(t_w, o * 64 + c);
    ws[WP_O + i] = LDW(p_w, o * 64 + c);
  }
  if (gid < 16) {
    ws[BG_O + gid] = LDW(g_b, gid);
    ws[BT_O + gid] = LDW(t_b, gid);
    ws[BP_O + gid] = LDW(p_b, gid);
    float s = 0.f;
    for (int c = 0; c < 64; ++c) s += LDW(m_w, gid * 64 + c);
    ws[SM_O + gid] = s;
    ws[SB_O + gid] = LDW(m_b, gid);
  }
  for (int i = gid; i < 1024; i += gs) ws[RW_O + i] = LDW(r_w, i);
  if (gid >= 64 && gid < 128) ws[RB_O + gid - 64] = LDW(r_b, gid - 64);
  // conv MFMA B, split hi/lo: wB[tap][col64][c64]
  ushort_t* wBh = (ushort_t*)(ws + WB_O);
  ushort_t* wBl = wBh + 9 * 64 * 64;
  for (int i = gid; i < 9 * 64 * 64; i += gs) {
    int c = i & 63, t = i >> 6, col = t & 63, tap = t >> 6;
    float v = 0.f;
    if (col < 16) v = LDW(g_w, (col * 64 + c) * 9 + tap);
    else if (col < 32) { if (tap == 4) v = LDW(t_w, (col - 16) * 64 + c); }
    else if (col < 48) { if (tap == 4) v = LDW(p_w, (col - 32) * 64 + c); }
    ushort_t h, l; splitbf(v, h, l);
    wBh[i] = h; wBl[i] = l;
  }
  if (xhh) {
    // fused border zpad
    const int4 z = make_int4(0, 0, 0, 0);
    for (int idx = gid; idx < B_ * 512 * 8; idx += gs) {
      int q = idx & 7, t = idx >> 3;
      int bp = t & 511, bb = t >> 9;
      int pp;
      if (bp < 129) pp = bp;                              // top row
      else if (bp < 258) pp = 128 * PADW + (bp - 129);    // bottom row
      else if (bp < 385) pp = (bp - 257) * PADW;          // left col rows 1..127
      else pp = (bp - 384) * PADW + 128;                  // right col rows 1..127
      size_t off = ((size_t)bb * PADPIX + pp) * 64 + q * 8;
      *(int4*)(xhh + off) = z;
      *(int4*)(xhl + off) = z;
    }
    // fused HWC transpose into padded planes (one 64-pixel tile per block)
    int pix0 = blockIdx.x * 64;
    if (pix0 < B_ * HW) {
      int g = threadIdx.x >> 6, p = threadIdx.x & 63;
      int pix = pix0 + p;
      bool ok = pix < B_ * HW;
      int bb = ok ? pix / HW : 0;
      int r  = ok ? pix - bb * HW : 0;
      if (f) {
        const float* xf = (const float*)x;
        for (int c = g * 16; c < g * 16 + 16; ++c)
          tile[p][c] = ok ? xf[((size_t)bb * CIN + c) * HW + r] : 0.f;
      } else {
        const bf16* xb = (const bf16*)x;
        for (int c = g * 16; c < g * 16 + 16; ++c)
          tile[p][c] = ok ? bf2f(xb[((size_t)bb * CIN + c) * HW + r]) : 0.f;
      }
      __syncthreads();
      int c2 = threadIdx.x & 63, pg = threadIdx.x >> 6;
      int pix2 = pix0 + pg * 16;
      int bb2 = pix2 / HW, r2 = pix2 - bb2 * HW;
      int h2 = r2 / W_, w2 = r2 - h2 * W_;
      for (int k = 0; k < 16; ++k) {
        if (pix2 + k < B_ * HW) {
          ushort_t h, l; splitbf(tile[pg * 16 + k][c2], h, l);
          size_t off = ((size_t)bb2 * PADPIX + (size_t)(h2 + 1) * PADW + (w2 + 1)) * 64 + c2;
          xhh[off] = h;
          xhl[off] = l;
        }
        if (++w2 == W_) { w2 = 0; if (++h2 == H_) { h2 = 0; ++bb2; } }
      }
    }
  }
}

// -------- split-bf16 MFMA conv, one output row per block, contiguous staging -----
// pk != nullptr (FULL): epilogue stages b1 AND b2 in LDS and writes PK1/PK2
// directly (bit-identical values); b1/b2 planes never materialize.
__global__ __launch_bounds__(256) void k_conv3(
    const float* __restrict__ ws,
    const ushort_t* __restrict__ xhh, const ushort_t* __restrict__ xhl,
    ushort_t* __restrict__ b1h, ushort_t* __restrict__ b1l,
    ushort_t* __restrict__ b2h, ushort_t* __restrict__ b2l,
    ushort_t* __restrict__ b3, ushort_t* __restrict__ pk, ushort_t* __restrict__ pk2)
{
  __shared__ ushort_t sAh[128 * SLST], sAl[128 * SLST];
  __shared__ ushort_t sBh[64 * SLST],  sBl[64 * SLST];
  int bz = blockIdx.z;
  int h = blockIdx.x;                       // output row
  int tid = threadIdx.x, lane = tid & 63, wv = tid >> 6;
  int grp = lane >> 3, ch = lane & 7;

  const ushort_t* xplane = ((wv == 0) ? xhh : xhl) + (size_t)bz * XPB;
  const ushort_t* wBh_ = (const ushort_t*)(ws + WB_O);
  const ushort_t* bsrc = (wv == 2) ? wBh_ : (wBh_ + 9 * 64 * 64);
  ushort_t* dplane = (wv == 0) ? sAh : (wv == 1) ? sAl : (wv == 2) ? sBh : sBl;

  int fr = lane & 31, kh = (lane >> 5) << 3;
  int mt = (wv >> 1) << 1;
  int aoff0 = (mt * 32 + fr) * SLST + kh;
  int aoff1 = ((mt + 1) * 32 + fr) * SLST + kh;
  int boff  = (((wv & 1) << 5) + fr) * SLST + kh;

  f32x16 acc0 = {0.f,0.f,0.f,0.f,0.f,0.f,0.f,0.f,0.f,0.f,0.f,0.f,0.f,0.f,0.f,0.f};
  f32x16 acc1 = {0.f,0.f,0.f,0.f,0.f,0.f,0.f,0.f,0.f,0.f,0.f,0.f,0.f,0.f,0.f,0.f};

  int4 pv0, pv1, pv2, pv3, pv4, pv5, pv6, pv7;
  int4 pv8, pv9, pv10, pv11, pv12, pv13, pv14, pv15;

#define LC(j) pv##j = *(const int4*)(src + (j) * 512)
#define LC_A  LC(0); LC(1); LC(2); LC(3); LC(4); LC(5); LC(6); LC(7); \
              LC(8); LC(9); LC(10); LC(11); LC(12); LC(13); LC(14); LC(15)
#define LC_W  LC(0); LC(1); LC(2); LC(3); LC(4); LC(5); LC(6); LC(7)
#define WC(j) *(int4*)(d0 + (j) * 8 * SLST) = pv##j
#define WC_A  WC(0); WC(1); WC(2); WC(3); WC(4); WC(5); WC(6); WC(7); \
              WC(8); WC(9); WC(10); WC(11); WC(12); WC(13); WC(14); WC(15)
#define WC_W  WC(0); WC(1); WC(2); WC(3); WC(4); WC(5); WC(6); WC(7)

  // prefetch tap 0 (dh=-1, dw=-1): padded row h, col 0
  if (wv < 2) {
    const ushort_t* src = xplane + (size_t)h * (PADW * 64) + grp * 64 + ch * 8;
    LC_A;
  } else {
    const ushort_t* src = bsrc + grp * 64 + ch * 8;
    LC_W;
  }

  for (int r = 0; r < 9; ++r) {
    __syncthreads();
    {
      ushort_t* d0 = dplane + grp * SLST + ch * 8;
      if (wv < 2) { WC_A; } else { WC_W; }
    }
    __syncthreads();
    if (r < 8) {
      int rn = r + 1;
      int dh = rn / 3 - 1, dw = rn % 3 - 1;
      if (wv < 2) {
        const ushort_t* src = xplane
            + ((size_t)(h + 1 + dh) * PADW + (1 + dw)) * 64 + grp * 64 + ch * 8;
        LC_A;
      } else {
        const ushort_t* src = bsrc + rn * 4096 + grp * 64 + ch * 8;
        LC_W;
      }
    }
#pragma unroll
    for (int t = 0; t < 4; ++t) {
      bfv8 ah0 = *(const bfv8*)(sAh + aoff0 + t * 16);
      bfv8 al0 = *(const bfv8*)(sAl + aoff0 + t * 16);
      bfv8 ah1 = *(const bfv8*)(sAh + aoff1 + t * 16);
      bfv8 al1 = *(const bfv8*)(sAl + aoff1 + t * 16);
      bfv8 bh  = *(const bfv8*)(sBh + boff + t * 16);
      bfv8 bl  = *(const bfv8*)(sBl + boff + t * 16);
      acc0 = __builtin_amdgcn_mfma_f32_32x32x16_bf16(al0, bh, acc0, 0, 0, 0);
      acc0 = __builtin_amdgcn_mfma_f32_32x32x16_bf16(ah0, bl, acc0, 0, 0, 0);
      acc0 = __builtin_amdgcn_mfma_f32_32x32x16_bf16(ah0, bh, acc0, 0, 0, 0);
      acc1 = __builtin_amdgcn_mfma_f32_32x32x16_bf16(al1, bh, acc1, 0, 0, 0);
      acc1 = __builtin_amdgcn_mfma_f32_32x32x16_bf16(ah1, bl, acc1, 0, 0, 0);
      acc1 = __builtin_amdgcn_mfma_f32_32x32x16_bf16(ah1, bh, acc1, 0, 0, 0);
    }
  }
#undef LC
#undef LC_A
#undef LC_W
#undef WC
#undef WC_A
#undef WC_W

  int nw = ((wv & 1) << 5) + fr;
  if (pk) {
    // ---- PK-direct epilogue (b1 -> PK1, b2 -> PK2) ----
    __syncthreads();                     // main-loop LDS reads done
    ushort_t* sb1h = sAh;                // [128][16]
    ushort_t* sb1l = sAl;
    ushort_t* sb2h = sBh;                // [128][16] (fits in 64*SLST=4608)
    ushort_t* sb2l = sBl;
#pragma unroll
    for (int s = 0; s < 2; ++s) {
      int mbase = (mt + s) * 32;
#pragma unroll
      for (int r = 0; r < 16; ++r) {
        int m = mbase + (r & 3) + ((r >> 2) << 3) + ((lane >> 5) << 2);
        float val = s ? acc1[r] : acc0[r];
        if (nw < 16) {
          ushort_t h2, l2; splitbf(val + ws[BG_O + nw], h2, l2);
          sb1h[m * 16 + nw] = h2; sb1l[m * 16 + nw] = l2;
        } else if (nw < 32) {
          int o = nw - 16; ushort_t h2, l2; splitbf(val + ws[BT_O + o], h2, l2);
          sb2h[m * 16 + o] = h2; sb2l[m * 16 + o] = l2;
        } else if (nw < 48) {
          if (m < W_) {
            size_t ob = ((size_t)bz * HW + h * W_ + m) * 16;
            int o = nw - 32; b3[ob + o] = f2bf(val + ws[BP_O + o]);
          }
        }
      }
    }
    __syncthreads();
    // cooperative PK write: each valid slh owns 31 slw segments x 14 int4 / plane
    ushort_t* pk1b = pk  + (size_t)bz * PKSTR;
    ushort_t* pk2b = pk2 + (size_t)bz * PKSTR;
    int slh_lo = (h >= 6) ? ((h - 3) >> 2) : 0;       // ceil((h-6)/4)
    int slh_hi = h >> 2; if (slh_hi > 30) slh_hi = 30;
    for (int slh = slh_lo; slh <= slh_hi; ++slh) {
      int nki = h - 4 * slh;                          // in [0,6]
      size_t rb = ((size_t)nki * 961 + slh * 31) * 112;
      for (int t = tid; t < 31 * 14; t += 256) {
        int slw = t / 14, q = t - slw * 14;
        int m = slw * 4 + (q >> 1);                   // pixel w (<=126)
        int c0 = (q & 1) << 3;
        size_t doff = rb + (size_t)slw * 112 + q * 8;
        *(int4*)(pk1b + doff)           = *(int4*)(sb1h + m * 16 + c0);
        *(int4*)(pk1b + PKPLANE + doff) = *(int4*)(sb1l + m * 16 + c0);
        *(int4*)(pk2b + doff)           = *(int4*)(sb2h + m * 16 + c0);
        *(int4*)(pk2b + PKPLANE + doff) = *(int4*)(sb2l + m * 16 + c0);
      }
    }
  } else {
    // ---- legacy epilogue (MID tier; k_pack consumes b1/b2) ----
#pragma unroll
    for (int s = 0; s < 2; ++s) {
      int mbase = (mt + s) * 32;
#pragma unroll
      for (int r = 0; r < 16; ++r) {
        int m = mbase + (r & 3) + ((r >> 2) << 3) + ((lane >> 5) << 2);
        if (m >= W_) continue;
        size_t ob = ((size_t)bz * HW + h * W_ + m) * 16;
        float val = s ? acc1[r] : acc0[r];
        if (nw < 16) {
          ushort_t h2, l2; splitbf(val + ws[BG_O + nw], h2, l2);
          b1h[ob + nw] = h2; b1l[ob + nw] = l2;
        } else if (nw < 32) {
          int o = nw - 16; ushort_t h2, l2; splitbf(val + ws[BT_O + o], h2, l2);
          b2h[ob + o] = h2; b2l[ob + o] = l2;
        } else if (nw < 48) {
          int o = nw - 32; b3[ob + o] = f2bf(val + ws[BP_O + o]);
        }
      }
    }
  }
}

// -------- fallback conv (LOW tier), dtype-templated VALU -------------------------
template <typename T>
__device__ __forceinline__ void convF_body(
    const void* x, const void* g_w, const void* g_b,
    const void* t_w, const void* t_b, const void* p_w, const void* p_b,
    ushort_t* b1h, ushort_t* b1l, ushort_t* b2h, ushort_t* b2l, ushort_t* b3,
    float* sgw, float* stw, float* spw)
{
  int tid = threadIdx.y * 32 + threadIdx.x;
  for (int i = tid; i < CI * CIN * 9; i += 256) sgw[i] = Ld<T>::f(g_w, i);
  for (int i = tid; i < CI * CIN; i += 256) { stw[i] = Ld<T>::f(t_w, i); spw[i] = Ld<T>::f(p_w, i); }
  __syncthreads();

  int w = blockIdx.x * 32 + threadIdx.x;
  int h = blockIdx.y * 8 + threadIdx.y;
  int b = blockIdx.z;
  if (w >= W_ || h >= H_) return;

  float a1[CI], a2[CI], a3[CI];
#pragma unroll
  for (int o = 0; o < CI; ++o) { a1[o] = 0.f; a2[o] = 0.f; a3[o] = 0.f; }

  const size_t xb = (size_t)b * CIN * HW;
  for (int c = 0; c < CIN; ++c) {
    float xv[9];
#pragma unroll
    for (int dh = 0; dh < 3; ++dh) {
      int hh = h + dh - 1;
      bool rok = ((unsigned)hh < (unsigned)H_);
#pragma unroll
      for (int dw = 0; dw < 3; ++dw) {
        int ww = w + dw - 1;
        bool ok = rok && ((unsigned)ww < (unsigned)W_);
        xv[dh * 3 + dw] = ok ? Ld<T>::f(x, (int)(xb + (size_t)c * HW + hh * W_ + ww)) : 0.f;
      }
    }
    float xc = xv[4];
#pragma unroll
    for (int o = 0; o < CI; ++o) {
      const float* gg = &sgw[(o * CIN + c) * 9];
      float s = gg[0]*xv[0] + gg[1]*xv[1] + gg[2]*xv[2]
              + gg[3]*xv[3] + gg[4]*xv[4] + gg[5]*xv[5]
              + gg[6]*xv[6] + gg[7]*xv[7] + gg[8]*xv[8];
      a1[o] += s;
      a2[o] += stw[o * CIN + c] * xc;
      a3[o] += spw[o * CIN + c] * xc;
    }
  }
  size_t base = ((size_t)b * HW + h * W_ + w) * CI;
#pragma unroll
  for (int o = 0; o < CI; ++o) {
    float v1 = a1[o] + Ld<T>::f(g_b, o);
    float v2 = a2[o] + Ld<T>::f(t_b, o);
    ushort_t hh2, ll2;
    splitbf(v1, hh2, ll2); b1h[base + o] = hh2; b1l[base + o] = ll2;
    splitbf(v2, hh2, ll2); b2h[base + o] = hh2; b2l[base + o] = ll2;
    b3[base + o] = f2bf(a3[o] + Ld<T>::f(p_b, o));
  }
}

__global__ __launch_bounds__(256) void k_convF(
    const int* __restrict__ flag, const void* x,
    const void* g_w, const void* g_b, const void* t_w, const void* t_b,
    const void* p_w, const void* p_b,
    ushort_t* __restrict__ b1h, ushort_t* __restrict__ b1l,
    ushort_t* __restrict__ b2h, ushort_t* __restrict__ b2l,
    ushort_t* __restrict__ b3)
{
  __shared__ float sgw[CI * CIN * 9];
  __shared__ float stw[CI * CIN];
  __shared__ float spw[CI * CIN];
  if (*flag) convF_body<float>(x, g_w, g_b, t_w, t_b, p_w, p_b, b1h, b1l, b2h, b2l, b3, sgw, stw, spw);
  else       convF_body<bf16 >(x, g_w, g_b, t_w, t_b, p_w, p_b, b1h, b1l, b2h, b2l, b3, sgw, stw, spw);
}

// -------- S3[b, pos*16+c] = sum over patches of b3 (bf16 src, fp32 acc) ----------
__global__ __launch_bounds__(256) void k_colsum(const ushort_t* __restrict__ b3, float* __restrict__ S3)
{
  __shared__ float red[16][17];
  int b = blockIdx.x, pos = blockIdx.y;
  int ki = pos / 7, kj = pos % 7;
  int c = threadIdx.x & 15, chunk = threadIdx.x >> 4;
  const ushort_t* B3 = b3 + (size_t)b * HW * CI;
  float s = 0.f;
  for (int l = chunk; l < L_; l += 16) {
    int lh = l / OH_, lw = l % OH_;
    s += bflo((unsigned)B3[((lh * ST + ki) * W_ + lw * ST + kj) * CI + c]);
  }
  red[chunk][c] = s;
  __syncthreads();
  if (threadIdx.x < 16) {
    float t = 0.f;
#pragma unroll
    for (int k = 0; k < 16; ++k) t += red[k][threadIdx.x];
    S3[(b * 49 + pos) * 16 + threadIdx.x] = t;
  }
}

// -------- pack operands (MID/LOW tiers): PK1 from b1, PK2 from b2 ----------------
__global__ __launch_bounds__(256) void k_pack(
    const ushort_t* __restrict__ b1h, const ushort_t* __restrict__ b1l,
    const ushort_t* __restrict__ b2h, const ushort_t* __restrict__ b2l,
    ushort_t* __restrict__ pk, ushort_t* __restrict__ pk2,
    int b0, unsigned pkstride_z)
{
  int idx = blockIdx.x * 256 + threadIdx.x;
  if (idx >= 2 * 961 * 98) return;
  int sel = (idx >= 961 * 98);
  int i2 = sel ? idx - 961 * 98 : idx;
  int row = i2 / 98, rem = i2 - row * 98;
  int nki = rem / 14, q = rem - nki * 14;
  int slh = row / OH_, slw = row - slh * OH_;
  int src = ((slh * ST) * W_ + slw * ST + nki * W_) * 16 + q * 8;
  int dst = (nki * 961 + row) * 112 + q * 8;
  int batch = b0 + blockIdx.y;
  size_t poff = (size_t)batch * HW * CI;
  const ushort_t* sh = sel ? b2h : b1h;
  const ushort_t* sl = sel ? b2l : b1l;
  ushort_t* pkb = (sel ? pk2 : pk) + (size_t)blockIdx.y * pkstride_z;
  *(int4*)(pkb + dst)           = *(const int4*)(sh + poff + src);
  *(int4*)(pkb + PKPLANE + dst) = *(const int4*)(sl + poff + src);
}

// -------- score GEMM via split-bf16 MFMA, 128x64 tile, both operands from PK -----
__global__ __launch_bounds__(256) void k_score(
    const ushort_t* __restrict__ pk, const ushort_t* __restrict__ pk2,
    float* __restrict__ scb, unsigned scstride_z, unsigned pkstride_z)
{
  __shared__ ushort_t sAh[128 * SLST], sAl[128 * SLST];
  __shared__ ushort_t sBh[64 * SLST],  sBl[64 * SLST];
  float* Sc = scb + (size_t)blockIdx.z * scstride_z;

  int tid = threadIdx.x;
  int m0 = blockIdx.y * 128, n0 = blockIdx.x * 64;
  int lane = tid & 63;
  int wv = tid >> 6;
  int grp = lane >> 3, ch = lane & 7;

  const ushort_t* pka = ((wv < 2) ? pk : pk2)
      + (size_t)blockIdx.z * pkstride_z + (size_t)(wv & 1) * PKPLANE;
  int base_mn = (wv < 2) ? m0 : n0;

  ushort_t* dplane = (wv == 0) ? sAh : (wv == 1) ? sAl : (wv == 2) ? sBh : sBl;

  int fr = lane & 31;
  int kh = (lane >> 5) << 3;
  int mt = (wv >> 1) << 1;                         // first m-subtile: 0 or 2
  int aoff0 = (mt * 32 + fr) * SLST + kh;
  int aoff1 = ((mt + 1) * 32 + fr) * SLST + kh;
  int boff  = (((wv & 1) << 5) + fr) * SLST + kh;

  f32x16 acc0 = {0.f,0.f,0.f,0.f,0.f,0.f,0.f,0.f,0.f,0.f,0.f,0.f,0.f,0.f,0.f,0.f};
  f32x16 acc1 = {0.f,0.f,0.f,0.f,0.f,0.f,0.f,0.f,0.f,0.f,0.f,0.f,0.f,0.f,0.f,0.f};

  int4 pv0, pv1, pv2, pv3, pv4, pv5, pv6, pv7;
  int4 pv8, pv9, pv10, pv11, pv12, pv13, pv14, pv15;

#define LA(j) pv##j = *(const int4*)(pks + (size_t)min(base_mn + 8*(j) + grp, 960) * 112)
#define LA_A LA(0); LA(1); LA(2); LA(3); LA(4); LA(5); LA(6); LA(7); \
             LA(8); LA(9); LA(10); LA(11); LA(12); LA(13); LA(14); LA(15)
#define LA_B LA(0); LA(1); LA(2); LA(3); LA(4); LA(5); LA(6); LA(7)
#define WA(j) *(int4*)(d0 + (j) * 8 * SLST) = pv##j
#define WA_A WA(0); WA(1); WA(2); WA(3); WA(4); WA(5); WA(6); WA(7); \
             WA(8); WA(9); WA(10); WA(11); WA(12); WA(13); WA(14); WA(15)
#define WA_B WA(0); WA(1); WA(2); WA(3); WA(4); WA(5); WA(6); WA(7)

  // initial prefetch: rn=0 (nki=0, even)
  {
    const ushort_t* pks = pka + ch * 8;
    if (wv < 2) { LA_A; } else { LA_B; }
  }

  for (int r = 0; r < 14; ++r) {
    int half = r & 1;
    __syncthreads();
    {
      ushort_t* d0 = dplane + grp * SLST + ch * 8;
      if (!half || ch < 6) { if (wv < 2) { WA_A; } else { WA_B; } }
    }
    __syncthreads();
    if (r < 13) {
      int rn = r + 1;
      int nki = rn >> 1, odd = rn & 1;
      const ushort_t* pks = pka + (size_t)nki * (961 * 112) + odd * 64 + ch * 8;
      if (!odd || ch < 6) { if (wv < 2) { LA_A; } else { LA_B; } }
    }
    if (!half) {
#pragma unroll
      for (int t = 0; t < 4; ++t) {
        bfv8 ah0 = *(const bfv8*)(sAh + aoff0 + t * 16);
        bfv8 al0 = *(const bfv8*)(sAl + aoff0 + t * 16);
        bfv8 ah1 = *(const bfv8*)(sAh + aoff1 + t * 16);
        bfv8 al1 = *(const bfv8*)(sAl + aoff1 + t * 16);
        bfv8 bh  = *(const bfv8*)(sBh + boff + t * 16);
        bfv8 bl  = *(const bfv8*)(sBl + boff + t * 16);
        acc0 = __builtin_amdgcn_mfma_f32_32x32x16_bf16(al0, bh, acc0, 0, 0, 0);
        acc0 = __builtin_amdgcn_mfma_f32_32x32x16_bf16(ah0, bl, acc0, 0, 0, 0);
        acc0 = __builtin_amdgcn_mfma_f32_32x32x16_bf16(ah0, bh, acc0, 0, 0, 0);
        acc1 = __builtin_amdgcn_mfma_f32_32x32x16_bf16(al1, bh, acc1, 0, 0, 0);
        acc1 = __builtin_amdgcn_mfma_f32_32x32x16_bf16(ah1, bl, acc1, 0, 0, 0);
        acc1 = __builtin_amdgcn_mfma_f32_32x32x16_bf16(ah1, bh, acc1, 0, 0, 0);
      }
    } else {
#pragma unroll
      for (int t = 0; t < 3; ++t) {
        bfv8 ah0 = *(const bfv8*)(sAh + aoff0 + t * 16);
        bfv8 al0 = *(const bfv8*)(sAl + aoff0 + t * 16);
        bfv8 ah1 = *(const bfv8*)(sAh + aoff1 + t * 16);
        bfv8 al1 = *(const bfv8*)(sAl + aoff1 + t * 16);
        bfv8 bh  = *(const bfv8*)(sBh + boff + t * 16);
        bfv8 bl  = *(const bfv8*)(sBl + boff + t * 16);
        acc0 = __builtin_amdgcn_mfma_f32_32x32x16_bf16(al0, bh, acc0, 0, 0, 0);
        acc0 = __builtin_amdgcn_mfma_f32_32x32x16_bf16(ah0, bl, acc0, 0, 0, 0);
        acc0 = __builtin_amdgcn_mfma_f32_32x32x16_bf16(ah0, bh, acc0, 0, 0, 0);
        acc1 = __builtin_amdgcn_mfma_f32_32x32x16_bf16(al1, bh, acc1, 0, 0, 0);
        acc1 = __builtin_amdgcn_mfma_f32_32x32x16_bf16(ah1, bl, acc1, 0, 0, 0);
        acc1 = __builtin_amdgcn_mfma_f32_32x32x16_bf16(ah1, bh, acc1, 0, 0, 0);
      }
    }
  }
#undef LA
#undef LA_A
#undef LA_B
#undef WA
#undef WA_A
#undef WA_B

  int nw = n0 + ((wv & 1) << 5) + fr;
  if (nw < L_) {
    int mw0 = m0 + mt * 32;
#pragma unroll
    for (int r = 0; r < 16; ++r) {
      int m = mw0 + (r & 3) + ((r >> 2) << 3) + ((lane >> 5) << 2);
      if (m < L_) Sc[(size_t)m * SROW + nw] = acc0[r];
    }
    int mw1 = m0 + (mt + 1) * 32;
#pragma unroll
    for (int r = 0; r < 16; ++r) {
      int m = mw1 + (r & 3) + ((r >> 2) << 3) + ((lane >> 5) << 2);
      if (m < L_) Sc[(size_t)m * SROW + nw] = acc1[r];
    }
  }
}

// -------- fused top-100 softmax + PV: 4 rows/block, radix on ALL 4 waves ---------
// Radix phase: wave wvi does row l0+wvi (structure of the r6-verified k_topk).
// PV phase: 2 rows concurrently (lanes 0..195), 2 passes. Bit-identical math.
__global__ __launch_bounds__(256) void k_tkpv(
    const float* __restrict__ scb,
    const ushort_t* __restrict__ b3, const float* __restrict__ s3,
    float* __restrict__ agb, int b0, unsigned scstride_z, unsigned agstride_z)
{
  __shared__ float swv[4][TOPM];
  __shared__ int spx[4][TOPM];
  __shared__ float sw0[4], sinvZ[4];
  int tid = threadIdx.x;
  int wvi = tid >> 6, lane = tid & 63;
  int l0 = blockIdx.x * 4;
  int l = l0 + wvi;
  if (l > L_ - 1) l = L_ - 1;        // clamp: duplicate rows produce identical data
  int bz = blockIdx.y;

  // ---- radix top-100 phase (per wave, one row) ----
  {
    const float4* row4 = (const float4*)(scb + (size_t)bz * scstride_z + (size_t)l * SROW);
    unsigned k[16];
#pragma unroll
    for (int q = 0; q < 4; ++q) {
      float4 v = row4[q * 64 + lane];
      int ib = (q * 64 + lane) * 4;
      k[q * 4 + 0] = (ib + 0 < L_) ? fmap(v.x) : 0u;
      k[q * 4 + 1] = (ib + 1 < L_) ? fmap(v.y) : 0u;
      k[q * 4 + 2] = (ib + 2 < L_) ? fmap(v.z) : 0u;
      k[q * 4 + 3] = (ib + 3 < L_) ? fmap(v.w) : 0u;
    }

    unsigned mk = 0;
#pragma unroll
    for (int r = 0; r < 16; ++r) mk = max(mk, k[r]);
#pragma unroll
    for (int o = 32; o; o >>= 1) mk = max(mk, (unsigned)__shfl_down((int)mk, o));
    mk = (unsigned)__shfl((int)mk, 0);
    float vmax = unfmap(mk);

    unsigned kk[16];
#pragma unroll
    for (int r = 0; r < 16; ++r) kk[r] = k[r];

    unsigned prefix = 0; int base = 0;
    for (int bit = 30; bit >= 0; bit -= 2) {
      int n3 = 0, n2 = 0, n1 = 0;
#pragma unroll
      for (int r = 0; r < 16; ++r) {
        unsigned f = (kk[r] >> bit) & 3u;
        n3 += (int)__popcll(__ballot(f == 3u));
        n2 += (int)__popcll(__ballot(f >= 2u));
        n1 += (int)__popcll(__ballot(f >= 1u));
      }
      unsigned ch;
      if (base + n3 >= TOPM) ch = 3;
      else if (base + n2 >= TOPM) { ch = 2; base += n3; }
      else if (base + n1 >= TOPM) { ch = 1; base += n2; }
      else { ch = 0; base += n1; }
      prefix |= ch << bit;
#pragma unroll
      for (int r = 0; r < 16; ++r) {
        unsigned f = (kk[r] >> bit) & 3u;
        kk[r] = (f == ch) ? kk[r] : 0u;
      }
    }
    int nA = base;
    int needT = TOPM - nA;

    int cA = 0, cT = 0;
#pragma unroll
    for (int r = 0; r < 16; ++r) { cA += (k[r] > prefix); cT += (k[r] == prefix); }
    int pkc = cA | (cT << 16);
    int incl = pkc;
#pragma unroll
    for (int o = 1; o < 64; o <<= 1) { int t = __shfl_up(incl, o); if (lane >= o) incl += t; }
    int excl = incl - pkc;
    int tA = excl & 0xFFFF, tT = excl >> 16;

    float M = fmaxf(10.f * vmax, 0.f);
    float e0 = __expf(-M);
    float z = 0.f;
#pragma unroll
    for (int r = 0; r < 16; ++r) {
      unsigned kr = k[r];
      int slot = -1;
      if (kr > prefix) slot = tA++;
      else if (kr == prefix) { if (tT < needT) slot = nA + tT; tT++; }
      if (slot >= 0) {
        float v = unfmap(kr);
        float wv = __expf(10.f * v - M);
        swv[wvi][slot] = wv; z += wv;
        int gi = 256 * (r >> 2) + 4 * lane + (r & 3);
        int lh = gi / OH_, lw = gi - lh * OH_;
        spx[wvi][slot] = ((lh * ST) * W_ + lw * ST) * CI;
      }
    }
#pragma unroll
    for (int o = 32; o; o >>= 1) z += __shfl_down(z, o);
    z = __shfl(z, 0);
    float Z = z + (float)(L_ - TOPM) * e0;
    if (lane == 0) { sinvZ[wvi] = 1.f / Z; sw0[wvi] = e0 / Z; }
  }
  __syncthreads();
  for (int i = tid; i < 4 * TOPM; i += 256) {
    int rr = i / TOPM, s = i - rr * TOPM;
    swv[rr][s] = swv[rr][s] * sinvZ[rr] - sw0[rr];
  }
  __syncthreads();

  // ---- PV phase: lanes 0..195 cover 2 rows per pass, 2 passes ----
  if (tid >= 196) return;
  int batch = b0 + bz;
  const ushort_t* B3 = b3 + (size_t)batch * HW * CI;
  const float* S3 = s3 + (size_t)batch * D_;
  float* agg = agb + (size_t)bz * agstride_z;

  int sub = tid / 98;
  int t98 = tid - sub * 98;
  int pos = t98 >> 1;
  int c0 = (t98 & 1) << 3;                 // 0 or 8
  int ki = pos / 7, kj = pos - (pos / 7) * 7;
  int poff = (ki * W_ + kj) * CI + c0;
  const float4 s40 = *(const float4*)(S3 + t98 * 8);
  const float4 s41 = *(const float4*)(S3 + t98 * 8 + 4);

  for (int p = 0; p < 2; ++p) {
    int rr = p * 2 + sub;
    int lr = l0 + rr;
    if (lr > L_ - 1) lr = L_ - 1;          // duplicate rows write identical data
    float w0 = sw0[rr];
    float a0 = 0.f, a1 = 0.f, a2 = 0.f, a3 = 0.f;
    float a4 = 0.f, a5 = 0.f, a6 = 0.f, a7 = 0.f;
    for (int j0 = 0; j0 < TOPM; j0 += 4) {
      float w_0 = swv[rr][j0 + 0];
      float w_1 = swv[rr][j0 + 1];
      float w_2 = swv[rr][j0 + 2];
      float w_3 = swv[rr][j0 + 3];
      int p_0 = spx[rr][j0 + 0];
      int p_1 = spx[rr][j0 + 1];
      int p_2 = spx[rr][j0 + 2];
      int p_3 = spx[rr][j0 + 3];
      const uint4 q0 = *(const uint4*)(B3 + p_0 + poff);
      const uint4 q1 = *(const uint4*)(B3 + p_1 + poff);
      const uint4 q2 = *(const uint4*)(B3 + p_2 + poff);
      const uint4 q3 = *(const uint4*)(B3 + p_3 + poff);
      a0 += w_0 * bflo(q0.x); a1 += w_0 * bfhi(q0.x); a2 += w_0 * bflo(q0.y); a3 += w_0 * bfhi(q0.y);
      a4 += w_0 * bflo(q0.z); a5 += w_0 * bfhi(q0.z); a6 += w_0 * bflo(q0.w); a7 += w_0 * bfhi(q0.w);
      a0 += w_1 * bflo(q1.x); a1 += w_1 * bfhi(q1.x); a2 += w_1 * bflo(q1.y); a3 += w_1 * bfhi(q1.y);
      a4 += w_1 * bflo(q1.z); a5 += w_1 * bfhi(q1.z); a6 += w_1 * bflo(q1.w); a7 += w_1 * bfhi(q1.w);
      a0 += w_2 * bflo(q2.x); a1 += w_2 * bfhi(q2.x); a2 += w_2 * bflo(q2.y); a3 += w_2 * bfhi(q2.y);
      a4 += w_2 * bflo(q2.z); a5 += w_2 * bfhi(q2.z); a6 += w_2 * bflo(q2.w); a7 += w_2 * bfhi(q2.w);
      a0 += w_3 * bflo(q3.x); a1 += w_3 * bfhi(q3.x); a2 += w_3 * bflo(q3.y); a3 += w_3 * bfhi(q3.y);
      a4 += w_3 * bflo(q3.z); a5 += w_3 * bfhi(q3.z); a6 += w_3 * bflo(q3.w); a7 += w_3 * bfhi(q3.w);
    }
    a0 += w0 * s40.x; a1 += w0 * s40.y; a2 += w0 * s40.z; a3 += w0 * s40.w;
    a4 += w0 * s41.x; a5 += w0 * s41.y; a6 += w0 * s41.z; a7 += w0 * s41.w;
    float* dst = agg + (size_t)lr * D_ + t98 * 8;
    *(float4*)(dst)     = make_float4(a0, a1, a2, a3);
    *(float4*)(dst + 4) = make_float4(a4, a5, a6, a7);
  }
}

// -------- fold + mask divide + restore (16->64), batched -------------------------
__global__ __launch_bounds__(256) void k_fold(
    const int* __restrict__ flag, const float* __restrict__ ws,
    const float* __restrict__ agb, void* __restrict__ out,
    int b0, unsigned agstride_z)
{
  __shared__ float srw[CIN * CI];
  int tid = threadIdx.x;
  for (int i = tid; i < CIN * CI; i += 256) srw[i] = ws[RW_O + i];
  __syncthreads();

  int bz = blockIdx.y;
  int batch = b0 + bz;
  const float* agg = agb + (size_t)bz * agstride_z;

  int gid = blockIdx.x * 256 + tid;
  if (gid >= HW) return;
  int h = gid / W_;
  int w = gid % W_;

  int lh0 = (h >= KS - 1) ? ((h - (KS - 1) + (ST - 1)) >> 2) : 0;
  int lh1 = min(OH_ - 1, h >> 2);
  int lw0 = (w >= KS - 1) ? ((w - (KS - 1) + (ST - 1)) >> 2) : 0;
  int lw1 = min(OH_ - 1, w >> 2);

  float t[CI];
#pragma unroll
  for (int c = 0; c < CI; ++c) t[c] = 0.f;
  for (int lh = lh0; lh <= lh1; ++lh) {
    int ki = h - ST * lh;
    for (int lw = lw0; lw <= lw1; ++lw) {
      int kj = w - ST * lw;
      const float* pb = agg + (size_t)(lh * OH_ + lw) * D_ + (ki * KS + kj) * CI;
      float4 q0 = *(const float4*)(pb);
      float4 q1 = *(const float4*)(pb + 4);
      float4 q2 = *(const float4*)(pb + 8);
      float4 q3 = *(const float4*)(pb + 12);
      t[0] += q0.x; t[1] += q0.y; t[2] += q0.z; t[3] += q0.w;
      t[4] += q1.x; t[5] += q1.y; t[6] += q1.z; t[7] += q1.w;
      t[8] += q2.x; t[9] += q2.y; t[10] += q2.z; t[11] += q2.w;
      t[12] += q3.x; t[13] += q3.y; t[14] += q3.z; t[15] += q3.w;
    }
  }
  float cnt = (float)((lh1 - lh0 + 1) * (lw1 - lw0 + 1));
  float r[CI];
#pragma unroll
  for (int c = 0; c < CI; ++c) r[c] = t[c] / (cnt * ws[SM_O + c] + ws[SB_O + c] + 1e-8f);

  size_t ob = (size_t)batch * CIN * HW + (size_t)h * W_ + w;
  if (*flag) {
    float* of = (float*)out;
#pragma unroll
    for (int o = 0; o < CIN; ++o) {
      float s = ws[RB_O + o];
#pragma unroll
      for (int c = 0; c < CI; ++c) s += srw[o * CI + c] * r[c];
      of[ob + (size_t)o * HW] = s;
    }
  } else {
    bf16* of = (bf16*)out;
#pragma unroll
    for (int o = 0; o < CIN; ++o) {
      float s = ws[RB_O + o];
#pragma unroll
      for (int c = 0; c < CI; ++c) s += srw[o * CI + c] * r[c];
      of[ob + (size_t)o * HW] = __float2bfloat16(s);
    }
  }
}

extern "C" void kernel_launch(void* const* d_in, const int* in_sizes, int n_in,
                              void* d_out, int out_size, void* d_ws, size_t ws_size,
                              hipStream_t stream)
{
  const void* x    = d_in[0];
  const void* g_w  = d_in[1];
  const void* g_b  = d_in[2];
  const void* th_w = d_in[3];
  const void* th_b = d_in[4];
  const void* ph_w = d_in[5];
  const void* ph_b = d_in[6];
  const void* m_w  = d_in[7];
  const void* m_b  = d_in[8];
  const void* r_w  = d_in[9];
  const void* r_b  = d_in[10];

  float* W = (float*)d_ws;
  int* flag = (int*)d_ws;
  ushort_t* planes = (ushort_t*)(W + B1_O);
  ushort_t* b1h = planes;
  ushort_t* b1l = planes + (size_t)N1;
  ushort_t* b2h = planes + (size_t)2 * N1;
  ushort_t* b2l = planes + (size_t)3 * N1;
  ushort_t* b3  = planes + (size_t)4 * N1;   // bf16 plane, N1 ushorts
  float* s3 = W + S3_O;

  if (ws_size >= FULL_BYTES) {
    ushort_t* xhh = (ushort_t*)(W + REG_O);    // padded planes, dead after conv
    ushort_t* xhl = xhh + XPU;
    float* sc = W + REG_O;                     // 4 x SCSLOT, aliases dead planes
    ushort_t* pk  = (ushort_t*)(W + PK_O);
    ushort_t* pk2 = (ushort_t*)(W + PK2_O);
    float* ag = W + PK_O;                      // aliases PK1 (dead after k_score)
    k_prep<<<dim3((B_ * HW + 63) / 64), 256, 0, stream>>>(
        x, g_w, th_w, ph_w, g_b, th_b, ph_b, m_w, m_b, r_w, r_b, W, xhh, xhl);
    k_conv3<<<dim3(H_, 1, B_), 256, 0, stream>>>(
        W, xhh, xhl, b1h, b1l, b2h, b2l, b3, pk, pk2);
    k_colsum<<<dim3(B_, 49), 256, 0, stream>>>(b3, s3);
    k_score<<<dim3(16, 8, B_), 256, 0, stream>>>(pk, pk2, sc, SCSLOT, PKSTR);
    k_tkpv<<<dim3((L_ + 3) / 4, B_), 256, 0, stream>>>(sc, b3, s3, ag, 0, SCSLOT, AGSZ);
    k_fold<<<dim3(64, B_), 256, 0, stream>>>(flag, W, ag, d_out, 0, AGSZ);
  } else if (ws_size >= MID_BYTES) {
    ushort_t* xhh = (ushort_t*)(W + REG_O);
    ushort_t* xhl = xhh + XPU;
    float* sc = W + REG_O;
    float* ag = W + REG_O + SCSLOT;
    ushort_t* pk  = (ushort_t*)ag;             // PK1 shares the ag slot
    ushort_t* pk2 = pk + (size_t)PKSTR;        // PK2 right after (within planes region)
    k_prep<<<dim3((B_ * HW + 63) / 64), 256, 0, stream>>>(
        x, g_w, th_w, ph_w, g_b, th_b, ph_b, m_w, m_b, r_w, r_b, W, xhh, xhl);
    k_conv3<<<dim3(H_, 1, B_), 256, 0, stream>>>(
        W, xhh, xhl, b1h, b1l, b2h, b2l, b3, (ushort_t*)nullptr, (ushort_t*)nullptr);
    k_colsum<<<dim3(B_, 49), 256, 0, stream>>>(b3, s3);
    for (int b = 0; b < B_; ++b) {
      k_pack<<<dim3(736, 1), 256, 0, stream>>>(b1h, b1l, b2h, b2l, pk, pk2, b, 0);
      k_score<<<dim3(16, 8, 1), 256, 0, stream>>>(pk, pk2, sc, 0, 0);
      k_tkpv<<<dim3((L_ + 3) / 4, 1), 256, 0, stream>>>(sc, b3, s3, ag, b, 0, 0);
      k_fold<<<dim3(64, 1), 256, 0, stream>>>(flag, W, ag, d_out, b, 0);
    }
  } else {
    float* sc = W + REG_O;
    float* ag = W + REG_O + SCSLOT;
    ushort_t* pk  = (ushort_t*)ag;
    ushort_t* pk2 = pk + (size_t)PKSTR;
    k_prep<<<64, 256, 0, stream>>>(
        x, g_w, th_w, ph_w, g_b, th_b, ph_b, m_w, m_b, r_w, r_b, W,
        (ushort_t*)nullptr, (ushort_t*)nullptr);
    k_convF<<<dim3(4, 16, B_), dim3(32, 8, 1), 0, stream>>>(
        flag, x, g_w, g_b, th_w, th_b, ph_w, ph_b, b1h, b1l, b2h, b2l, b3);
    k_colsum<<<dim3(B_, 49), 256, 0, stream>>>(b3, s3);
    for (int b = 0; b < B_; ++b) {
      k_pack<<<dim3(736, 1), 256, 0, stream>>>(b1h, b1l, b2h, b2l, pk, pk2, b, 0);
      k_score<<<dim3(16, 8, 1), 256, 0, stream>>>(pk, pk2, sc, 0, 0);
      k_tkpv<<<dim3((L_ + 3) / 4, 1), 256, 0, stream>>>(sc, b3, s3, ag, b, 0, 0);
      k_fold<<<dim3(64, 1), 256, 0, stream>>>(flag, W, ag, d_out, b, 0);
    }
  }
}

// Round 11
// 238.823 us; speedup vs baseline: 1.9081x; 1.0102x over previous
//
#include <hip/hip_runtime.h>
#include <hip/hip_bf16.h>

typedef __hip_bfloat16 bf16;
typedef unsigned short ushort_t;
typedef __attribute__((ext_vector_type(8))) __bf16 bfv8;
typedef __attribute__((ext_vector_type(16))) float f32x16;

#define B_   4
#define CIN  64
#define CI   16
#define H_   127
#define W_   127
#define HW   (H_*W_)
#define KS   7
#define ST   4
#define OH_  31
#define L_   961
#define D_   784
#define TOPM 100

// ---- workspace layout (float offsets) ----
#define N1   1032256          // B*HW*CI elements (one conv-out array)
#define WG_O 4
#define WT_O (WG_O + 9216)
#define WP_O (WT_O + 1024)
#define BG_O (WP_O + 1024)
#define BT_O (BG_O + 16)
#define BP_O (BT_O + 16)
#define SM_O (BP_O + 16)
#define SB_O (SM_O + 16)
#define RW_O (SB_O + 16)
#define RB_O (RW_O + 1024)
#define B1_O 12448
// planes at B1_O: b1h,b1l,b2h,b2l each N1 ushorts (2*N1 floats); b3 bf16 N1 ushorts
#define S3_O (B1_O + 3*N1)
#define WB_O (S3_O + B_*D_)   // conv MFMA B: wBh + wBl = 36864 floats
#define REG_O (WB_O + 36864)
#define SROW 964              // padded Sc row stride
#define SCSLOT 926464
#define AGSZ 753424
#define SLST 72               // LDS row stride in ushorts (conflict-free, measured r8)
// PK: unfold-packed operands. Per plane: 7 nki x 961 rows x 112 ushorts = 753424.
#define PKPLANE 753424
#define PKSTR   1506848
// padded x planes: 129x129 pixels x 64 ch, zero borders -> conv3 has NO bounds logic
#define PADW 129
#define PADPIX (PADW*PADW)            // 16641
#define XPB  (PADPIX*64)              // ushorts per batch-plane = 1,065,024
#define XPU  ((size_t)B_ * XPB)       // ushorts per plane (all batches) = 4,260,096
#define PLANES_FL 4260096             // floats spanned by both padded planes
// FULL tier: PK1/PK2 after the planes (conv3 writes them while reading planes).
#define PK_O  (REG_O + PLANES_FL)     // PK1: 4*PKSTR ushorts = 3,013,696 floats
#define PK2_O (PK_O + 3013696)        // PK2 (b2 operand), same size

#define FULL_BYTES ((size_t)(PK2_O + 3013696) * 4)         // ~53.7 MB (ws is 256 MiB)
#define MID_BYTES  ((size_t)(REG_O + PLANES_FL) * 4)       // ~29.6 MB

__device__ __forceinline__ float bf2f(bf16 v) { return __bfloat162float(v); }
__device__ __forceinline__ float bflo(unsigned u) { return __uint_as_float(u << 16); }
__device__ __forceinline__ float bfhi(unsigned u) { return __uint_as_float(u & 0xFFFF0000u); }

template <typename T> struct Ld;
template <> struct Ld<float> {
  static __device__ __forceinline__ float f(const void* p, int i) { return ((const float*)p)[i]; }
};
template <> struct Ld<bf16> {
  static __device__ __forceinline__ float f(const void* p, int i) { return bf2f(((const bf16*)p)[i]); }
};

__device__ __forceinline__ unsigned fmap(float f) {
  unsigned u = __float_as_uint(f);
  return (u & 0x80000000u) ? ~u : (u | 0x80000000u);
}
__device__ __forceinline__ float unfmap(unsigned kk) {
  unsigned u = (kk & 0x80000000u) ? (kk & 0x7fffffffu) : ~kk;
  return __uint_as_float(u);
}

// RNE fp32 -> bf16 bits, and hi/lo split
__device__ __forceinline__ ushort_t f2bf(float x) {
  unsigned u = __float_as_uint(x);
  return (ushort_t)((u + 0x7FFFu + ((u >> 16) & 1u)) >> 16);
}
__device__ __forceinline__ void splitbf(float x, ushort_t& h, ushort_t& l) {
  h = f2bf(x);
  float hf = __uint_as_float(((unsigned)h) << 16);
  l = f2bf(x - hf);
}

// -------- weight prep + inline dtype detect + border zpad + fused HWC ------------
#define LDW(ptr, i) (f ? ((const float*)(ptr))[i] : bf2f(((const bf16*)(ptr))[i]))
__global__ __launch_bounds__(256) void k_prep(
    const void* __restrict__ x,
    const void* g_w, const void* t_w, const void* p_w,
    const void* g_b, const void* t_b, const void* p_b,
    const void* m_w, const void* m_b, const void* r_w, const void* r_b,
    float* __restrict__ ws,
    ushort_t* __restrict__ xhh, ushort_t* __restrict__ xhl)
{
  __shared__ int sflag;
  __shared__ float tile[64][65];
  // inline dtype detect (per block; wave 0 reduces, LDS broadcast)
  {
    const unsigned short* xh = (const unsigned short*)x;
    if (threadIdx.x < 64) {
      int c = 0;
#pragma unroll
      for (int j = 0; j < 2; ++j) {
        unsigned u = xh[threadIdx.x * 2 + j];
        unsigned e = (u >> 7) & 0xFF;
        if (e >= 134) c++;
      }
#pragma unroll
      for (int o = 32; o; o >>= 1) c += __shfl_down(c, o);
      if (threadIdx.x == 0) sflag = (c >= 8) ? 1 : 0;
    }
  }
  __syncthreads();
  int f = sflag;
  if (blockIdx.x == 0 && threadIdx.x == 0) *(int*)ws = f;   // publish for downstream

  int gid = blockIdx.x * 256 + threadIdx.x;
  int gs = gridDim.x * 256;
  for (int i = gid; i < 9216; i += gs) {
    int o = i & 15, t = i >> 4, c = t & 63, tap = t >> 6;
    ws[WG_O + i] = LDW(g_w, (o * 64 + c) * 9 + tap);
  }
  for (int i = gid; i < 1024; i += gs) {
    int o = i & 15, c = i >> 4;
    ws[WT_O + i] = LDW(t_w, o * 64 + c);
    ws[WP_O + i] = LDW(p_w, o * 64 + c);
  }
  if (gid < 16) {
    ws[BG_O + gid] = LDW(g_b, gid);
    ws[BT_O + gid] = LDW(t_b, gid);
    ws[BP_O + gid] = LDW(p_b, gid);
    float s = 0.f;
    for (int c = 0; c < 64; ++c) s += LDW(m_w, gid * 64 + c);
    ws[SM_O + gid] = s;
    ws[SB_O + gid] = LDW(m_b, gid);
  }
  for (int i = gid; i < 1024; i += gs) ws[RW_O + i] = LDW(r_w, i);
  if (gid >= 64 && gid < 128) ws[RB_O + gid - 64] = LDW(r_b, gid - 64);
  // conv MFMA B, split hi/lo: wB[tap][col64][c64]
  ushort_t* wBh = (ushort_t*)(ws + WB_O);
  ushort_t* wBl = wBh + 9 * 64 * 64;
  for (int i = gid; i < 9 * 64 * 64; i += gs) {
    int c = i & 63, t = i >> 6, col = t & 63, tap = t >> 6;
    float v = 0.f;
    if (col < 16) v = LDW(g_w, (col * 64 + c) * 9 + tap);
    else if (col < 32) { if (tap == 4) v = LDW(t_w, (col - 16) * 64 + c); }
    else if (col < 48) { if (tap == 4) v = LDW(p_w, (col - 32) * 64 + c); }
    ushort_t h, l; splitbf(v, h, l);
    wBh[i] = h; wBl[i] = l;
  }
  if (xhh) {
    // fused border zpad
    const int4 z = make_int4(0, 0, 0, 0);
    for (int idx = gid; idx < B_ * 512 * 8; idx += gs) {
      int q = idx & 7, t = idx >> 3;
      int bp = t & 511, bb = t >> 9;
      int pp;
      if (bp < 129) pp = bp;                              // top row
      else if (bp < 258) pp = 128 * PADW + (bp - 129);    // bottom row
      else if (bp < 385) pp = (bp - 257) * PADW;          // left col rows 1..127
      else pp = (bp - 384) * PADW + 128;                  // right col rows 1..127
      size_t off = ((size_t)bb * PADPIX + pp) * 64 + q * 8;
      *(int4*)(xhh + off) = z;
      *(int4*)(xhl + off) = z;
    }
    // fused HWC transpose into padded planes (one 64-pixel tile per block)
    int pix0 = blockIdx.x * 64;
    if (pix0 < B_ * HW) {
      int g = threadIdx.x >> 6, p = threadIdx.x & 63;
      int pix = pix0 + p;
      bool ok = pix < B_ * HW;
      int bb = ok ? pix / HW : 0;
      int r  = ok ? pix - bb * HW : 0;
      if (f) {
        const float* xf = (const float*)x;
        for (int c = g * 16; c < g * 16 + 16; ++c)
          tile[p][c] = ok ? xf[((size_t)bb * CIN + c) * HW + r] : 0.f;
      } else {
        const bf16* xb = (const bf16*)x;
        for (int c = g * 16; c < g * 16 + 16; ++c)
          tile[p][c] = ok ? bf2f(xb[((size_t)bb * CIN + c) * HW + r]) : 0.f;
      }
      __syncthreads();
      int c2 = threadIdx.x & 63, pg = threadIdx.x >> 6;
      int pix2 = pix0 + pg * 16;
      int bb2 = pix2 / HW, r2 = pix2 - bb2 * HW;
      int h2 = r2 / W_, w2 = r2 - h2 * W_;
      for (int k = 0; k < 16; ++k) {
        if (pix2 + k < B_ * HW) {
          ushort_t h, l; splitbf(tile[pg * 16 + k][c2], h, l);
          size_t off = ((size_t)bb2 * PADPIX + (size_t)(h2 + 1) * PADW + (w2 + 1)) * 64 + c2;
          xhh[off] = h;
          xhl[off] = l;
        }
        if (++w2 == W_) { w2 = 0; if (++h2 == H_) { h2 = 0; ++bb2; } }
      }
    }
  }
}

// -------- split-bf16 MFMA conv, one output row per block, contiguous staging -----
// pk != nullptr (FULL): epilogue stages b1 AND b2 in LDS and writes PK1/PK2
// directly (bit-identical values); b1/b2 planes never materialize.
__global__ __launch_bounds__(256) void k_conv3(
    const float* __restrict__ ws,
    const ushort_t* __restrict__ xhh, const ushort_t* __restrict__ xhl,
    ushort_t* __restrict__ b1h, ushort_t* __restrict__ b1l,
    ushort_t* __restrict__ b2h, ushort_t* __restrict__ b2l,
    ushort_t* __restrict__ b3, ushort_t* __restrict__ pk, ushort_t* __restrict__ pk2)
{
  __shared__ ushort_t sAh[128 * SLST], sAl[128 * SLST];
  __shared__ ushort_t sBh[64 * SLST],  sBl[64 * SLST];
  int bz = blockIdx.z;
  int h = blockIdx.x;                       // output row
  int tid = threadIdx.x, lane = tid & 63, wv = tid >> 6;
  int grp = lane >> 3, ch = lane & 7;

  const ushort_t* xplane = ((wv == 0) ? xhh : xhl) + (size_t)bz * XPB;
  const ushort_t* wBh_ = (const ushort_t*)(ws + WB_O);
  const ushort_t* bsrc = (wv == 2) ? wBh_ : (wBh_ + 9 * 64 * 64);
  ushort_t* dplane = (wv == 0) ? sAh : (wv == 1) ? sAl : (wv == 2) ? sBh : sBl;

  int fr = lane & 31, kh = (lane >> 5) << 3;
  int mt = (wv >> 1) << 1;
  int aoff0 = (mt * 32 + fr) * SLST + kh;
  int aoff1 = ((mt + 1) * 32 + fr) * SLST + kh;
  int boff  = (((wv & 1) << 5) + fr) * SLST + kh;

  f32x16 acc0 = {0.f,0.f,0.f,0.f,0.f,0.f,0.f,0.f,0.f,0.f,0.f,0.f,0.f,0.f,0.f,0.f};
  f32x16 acc1 = {0.f,0.f,0.f,0.f,0.f,0.f,0.f,0.f,0.f,0.f,0.f,0.f,0.f,0.f,0.f,0.f};

  int4 pv0, pv1, pv2, pv3, pv4, pv5, pv6, pv7;
  int4 pv8, pv9, pv10, pv11, pv12, pv13, pv14, pv15;

#define LC(j) pv##j = *(const int4*)(src + (j) * 512)
#define LC_A  LC(0); LC(1); LC(2); LC(3); LC(4); LC(5); LC(6); LC(7); \
              LC(8); LC(9); LC(10); LC(11); LC(12); LC(13); LC(14); LC(15)
#define LC_W  LC(0); LC(1); LC(2); LC(3); LC(4); LC(5); LC(6); LC(7)
#define WC(j) *(int4*)(d0 + (j) * 8 * SLST) = pv##j
#define WC_A  WC(0); WC(1); WC(2); WC(3); WC(4); WC(5); WC(6); WC(7); \
              WC(8); WC(9); WC(10); WC(11); WC(12); WC(13); WC(14); WC(15)
#define WC_W  WC(0); WC(1); WC(2); WC(3); WC(4); WC(5); WC(6); WC(7)

  // prefetch tap 0 (dh=-1, dw=-1): padded row h, col 0
  if (wv < 2) {
    const ushort_t* src = xplane + (size_t)h * (PADW * 64) + grp * 64 + ch * 8;
    LC_A;
  } else {
    const ushort_t* src = bsrc + grp * 64 + ch * 8;
    LC_W;
  }

  for (int r = 0; r < 9; ++r) {
    __syncthreads();
    {
      ushort_t* d0 = dplane + grp * SLST + ch * 8;
      if (wv < 2) { WC_A; } else { WC_W; }
    }
    __syncthreads();
    if (r < 8) {
      int rn = r + 1;
      int dh = rn / 3 - 1, dw = rn % 3 - 1;
      if (wv < 2) {
        const ushort_t* src = xplane
            + ((size_t)(h + 1 + dh) * PADW + (1 + dw)) * 64 + grp * 64 + ch * 8;
        LC_A;
      } else {
        const ushort_t* src = bsrc + rn * 4096 + grp * 64 + ch * 8;
        LC_W;
      }
    }
#pragma unroll
    for (int t = 0; t < 4; ++t) {
      bfv8 ah0 = *(const bfv8*)(sAh + aoff0 + t * 16);
      bfv8 al0 = *(const bfv8*)(sAl + aoff0 + t * 16);
      bfv8 ah1 = *(const bfv8*)(sAh + aoff1 + t * 16);
      bfv8 al1 = *(const bfv8*)(sAl + aoff1 + t * 16);
      bfv8 bh  = *(const bfv8*)(sBh + boff + t * 16);
      bfv8 bl  = *(const bfv8*)(sBl + boff + t * 16);
      acc0 = __builtin_amdgcn_mfma_f32_32x32x16_bf16(al0, bh, acc0, 0, 0, 0);
      acc0 = __builtin_amdgcn_mfma_f32_32x32x16_bf16(ah0, bl, acc0, 0, 0, 0);
      acc0 = __builtin_amdgcn_mfma_f32_32x32x16_bf16(ah0, bh, acc0, 0, 0, 0);
      acc1 = __builtin_amdgcn_mfma_f32_32x32x16_bf16(al1, bh, acc1, 0, 0, 0);
      acc1 = __builtin_amdgcn_mfma_f32_32x32x16_bf16(ah1, bl, acc1, 0, 0, 0);
      acc1 = __builtin_amdgcn_mfma_f32_32x32x16_bf16(ah1, bh, acc1, 0, 0, 0);
    }
  }
#undef LC
#undef LC_A
#undef LC_W
#undef WC
#undef WC_A
#undef WC_W

  int nw = ((wv & 1) << 5) + fr;
  if (pk) {
    // ---- PK-direct epilogue (b1 -> PK1, b2 -> PK2) ----
    __syncthreads();                     // main-loop LDS reads done
    ushort_t* sb1h = sAh;                // [128][16]
    ushort_t* sb1l = sAl;
    ushort_t* sb2h = sBh;                // [128][16] (fits in 64*SLST=4608)
    ushort_t* sb2l = sBl;
#pragma unroll
    for (int s = 0; s < 2; ++s) {
      int mbase = (mt + s) * 32;
#pragma unroll
      for (int r = 0; r < 16; ++r) {
        int m = mbase + (r & 3) + ((r >> 2) << 3) + ((lane >> 5) << 2);
        float val = s ? acc1[r] : acc0[r];
        if (nw < 16) {
          ushort_t h2, l2; splitbf(val + ws[BG_O + nw], h2, l2);
          sb1h[m * 16 + nw] = h2; sb1l[m * 16 + nw] = l2;
        } else if (nw < 32) {
          int o = nw - 16; ushort_t h2, l2; splitbf(val + ws[BT_O + o], h2, l2);
          sb2h[m * 16 + o] = h2; sb2l[m * 16 + o] = l2;
        } else if (nw < 48) {
          if (m < W_) {
            size_t ob = ((size_t)bz * HW + h * W_ + m) * 16;
            int o = nw - 32; b3[ob + o] = f2bf(val + ws[BP_O + o]);
          }
        }
      }
    }
    __syncthreads();
    // cooperative PK write: each valid slh owns 31 slw segments x 14 int4 / plane
    ushort_t* pk1b = pk  + (size_t)bz * PKSTR;
    ushort_t* pk2b = pk2 + (size_t)bz * PKSTR;
    int slh_lo = (h >= 6) ? ((h - 3) >> 2) : 0;       // ceil((h-6)/4)
    int slh_hi = h >> 2; if (slh_hi > 30) slh_hi = 30;
    for (int slh = slh_lo; slh <= slh_hi; ++slh) {
      int nki = h - 4 * slh;                          // in [0,6]
      size_t rb = ((size_t)nki * 961 + slh * 31) * 112;
      for (int t = tid; t < 31 * 14; t += 256) {
        int slw = t / 14, q = t - slw * 14;
        int m = slw * 4 + (q >> 1);                   // pixel w (<=126)
        int c0 = (q & 1) << 3;
        size_t doff = rb + (size_t)slw * 112 + q * 8;
        *(int4*)(pk1b + doff)           = *(int4*)(sb1h + m * 16 + c0);
        *(int4*)(pk1b + PKPLANE + doff) = *(int4*)(sb1l + m * 16 + c0);
        *(int4*)(pk2b + doff)           = *(int4*)(sb2h + m * 16 + c0);
        *(int4*)(pk2b + PKPLANE + doff) = *(int4*)(sb2l + m * 16 + c0);
      }
    }
  } else {
    // ---- legacy epilogue (MID tier; k_pack consumes b1/b2) ----
#pragma unroll
    for (int s = 0; s < 2; ++s) {
      int mbase = (mt + s) * 32;
#pragma unroll
      for (int r = 0; r < 16; ++r) {
        int m = mbase + (r & 3) + ((r >> 2) << 3) + ((lane >> 5) << 2);
        if (m >= W_) continue;
        size_t ob = ((size_t)bz * HW + h * W_ + m) * 16;
        float val = s ? acc1[r] : acc0[r];
        if (nw < 16) {
          ushort_t h2, l2; splitbf(val + ws[BG_O + nw], h2, l2);
          b1h[ob + nw] = h2; b1l[ob + nw] = l2;
        } else if (nw < 32) {
          int o = nw - 16; ushort_t h2, l2; splitbf(val + ws[BT_O + o], h2, l2);
          b2h[ob + o] = h2; b2l[ob + o] = l2;
        } else if (nw < 48) {
          int o = nw - 32; b3[ob + o] = f2bf(val + ws[BP_O + o]);
        }
      }
    }
  }
}

// -------- fallback conv (LOW tier), dtype-templated VALU -------------------------
template <typename T>
__device__ __forceinline__ void convF_body(
    const void* x, const void* g_w, const void* g_b,
    const void* t_w, const void* t_b, const void* p_w, const void* p_b,
    ushort_t* b1h, ushort_t* b1l, ushort_t* b2h, ushort_t* b2l, ushort_t* b3,
    float* sgw, float* stw, float* spw)
{
  int tid = threadIdx.y * 32 + threadIdx.x;
  for (int i = tid; i < CI * CIN * 9; i += 256) sgw[i] = Ld<T>::f(g_w, i);
  for (int i = tid; i < CI * CIN; i += 256) { stw[i] = Ld<T>::f(t_w, i); spw[i] = Ld<T>::f(p_w, i); }
  __syncthreads();

  int w = blockIdx.x * 32 + threadIdx.x;
  int h = blockIdx.y * 8 + threadIdx.y;
  int b = blockIdx.z;
  if (w >= W_ || h >= H_) return;

  float a1[CI], a2[CI], a3[CI];
#pragma unroll
  for (int o = 0; o < CI; ++o) { a1[o] = 0.f; a2[o] = 0.f; a3[o] = 0.f; }

  const size_t xb = (size_t)b * CIN * HW;
  for (int c = 0; c < CIN; ++c) {
    float xv[9];
#pragma unroll
    for (int dh = 0; dh < 3; ++dh) {
      int hh = h + dh - 1;
      bool rok = ((unsigned)hh < (unsigned)H_);
#pragma unroll
      for (int dw = 0; dw < 3; ++dw) {
        int ww = w + dw - 1;
        bool ok = rok && ((unsigned)ww < (unsigned)W_);
        xv[dh * 3 + dw] = ok ? Ld<T>::f(x, (int)(xb + (size_t)c * HW + hh * W_ + ww)) : 0.f;
      }
    }
    float xc = xv[4];
#pragma unroll
    for (int o = 0; o < CI; ++o) {
      const float* gg = &sgw[(o * CIN + c) * 9];
      float s = gg[0]*xv[0] + gg[1]*xv[1] + gg[2]*xv[2]
              + gg[3]*xv[3] + gg[4]*xv[4] + gg[5]*xv[5]
              + gg[6]*xv[6] + gg[7]*xv[7] + gg[8]*xv[8];
      a1[o] += s;
      a2[o] += stw[o * CIN + c] * xc;
      a3[o] += spw[o * CIN + c] * xc;
    }
  }
  size_t base = ((size_t)b * HW + h * W_ + w) * CI;
#pragma unroll
  for (int o = 0; o < CI; ++o) {
    float v1 = a1[o] + Ld<T>::f(g_b, o);
    float v2 = a2[o] + Ld<T>::f(t_b, o);
    ushort_t hh2, ll2;
    splitbf(v1, hh2, ll2); b1h[base + o] = hh2; b1l[base + o] = ll2;
    splitbf(v2, hh2, ll2); b2h[base + o] = hh2; b2l[base + o] = ll2;
    b3[base + o] = f2bf(a3[o] + Ld<T>::f(p_b, o));
  }
}

__global__ __launch_bounds__(256) void k_convF(
    const int* __restrict__ flag, const void* x,
    const void* g_w, const void* g_b, const void* t_w, const void* t_b,
    const void* p_w, const void* p_b,
    ushort_t* __restrict__ b1h, ushort_t* __restrict__ b1l,
    ushort_t* __restrict__ b2h, ushort_t* __restrict__ b2l,
    ushort_t* __restrict__ b3)
{
  __shared__ float sgw[CI * CIN * 9];
  __shared__ float stw[CI * CIN];
  __shared__ float spw[CI * CIN];
  if (*flag) convF_body<float>(x, g_w, g_b, t_w, t_b, p_w, p_b, b1h, b1l, b2h, b2l, b3, sgw, stw, spw);
  else       convF_body<bf16 >(x, g_w, g_b, t_w, t_b, p_w, p_b, b1h, b1l, b2h, b2l, b3, sgw, stw, spw);
}

// -------- S3[b, pos*16+c] = sum over patches of b3 (bf16 src, fp32 acc) ----------
__global__ __launch_bounds__(256) void k_colsum(const ushort_t* __restrict__ b3, float* __restrict__ S3)
{
  __shared__ float red[16][17];
  int b = blockIdx.x, pos = blockIdx.y;
  int ki = pos / 7, kj = pos % 7;
  int c = threadIdx.x & 15, chunk = threadIdx.x >> 4;
  const ushort_t* B3 = b3 + (size_t)b * HW * CI;
  float s = 0.f;
  for (int l = chunk; l < L_; l += 16) {
    int lh = l / OH_, lw = l % OH_;
    s += bflo((unsigned)B3[((lh * ST + ki) * W_ + lw * ST + kj) * CI + c]);
  }
  red[chunk][c] = s;
  __syncthreads();
  if (threadIdx.x < 16) {
    float t = 0.f;
#pragma unroll
    for (int k = 0; k < 16; ++k) t += red[k][threadIdx.x];
    S3[(b * 49 + pos) * 16 + threadIdx.x] = t;
  }
}

// -------- pack operands (MID/LOW tiers): PK1 from b1, PK2 from b2 ----------------
__global__ __launch_bounds__(256) void k_pack(
    const ushort_t* __restrict__ b1h, const ushort_t* __restrict__ b1l,
    const ushort_t* __restrict__ b2h, const ushort_t* __restrict__ b2l,
    ushort_t* __restrict__ pk, ushort_t* __restrict__ pk2,
    int b0, unsigned pkstride_z)
{
  int idx = blockIdx.x * 256 + threadIdx.x;
  if (idx >= 2 * 961 * 98) return;
  int sel = (idx >= 961 * 98);
  int i2 = sel ? idx - 961 * 98 : idx;
  int row = i2 / 98, rem = i2 - row * 98;
  int nki = rem / 14, q = rem - nki * 14;
  int slh = row / OH_, slw = row - slh * OH_;
  int src = ((slh * ST) * W_ + slw * ST + nki * W_) * 16 + q * 8;
  int dst = (nki * 961 + row) * 112 + q * 8;
  int batch = b0 + blockIdx.y;
  size_t poff = (size_t)batch * HW * CI;
  const ushort_t* sh = sel ? b2h : b1h;
  const ushort_t* sl = sel ? b2l : b1l;
  ushort_t* pkb = (sel ? pk2 : pk) + (size_t)blockIdx.y * pkstride_z;
  *(int4*)(pkb + dst)           = *(const int4*)(sh + poff + src);
  *(int4*)(pkb + PKPLANE + dst) = *(const int4*)(sl + poff + src);
}

// -------- score GEMM via split-bf16 MFMA, 128x64 tile, both operands from PK -----
__global__ __launch_bounds__(256) void k_score(
    const ushort_t* __restrict__ pk, const ushort_t* __restrict__ pk2,
    float* __restrict__ scb, unsigned scstride_z, unsigned pkstride_z)
{
  __shared__ ushort_t sAh[128 * SLST], sAl[128 * SLST];
  __shared__ ushort_t sBh[64 * SLST],  sBl[64 * SLST];
  float* Sc = scb + (size_t)blockIdx.z * scstride_z;

  int tid = threadIdx.x;
  int m0 = blockIdx.y * 128, n0 = blockIdx.x * 64;
  int lane = tid & 63;
  int wv = tid >> 6;
  int grp = lane >> 3, ch = lane & 7;

  const ushort_t* pka = ((wv < 2) ? pk : pk2)
      + (size_t)blockIdx.z * pkstride_z + (size_t)(wv & 1) * PKPLANE;
  int base_mn = (wv < 2) ? m0 : n0;

  ushort_t* dplane = (wv == 0) ? sAh : (wv == 1) ? sAl : (wv == 2) ? sBh : sBl;

  int fr = lane & 31;
  int kh = (lane >> 5) << 3;
  int mt = (wv >> 1) << 1;                         // first m-subtile: 0 or 2
  int aoff0 = (mt * 32 + fr) * SLST + kh;
  int aoff1 = ((mt + 1) * 32 + fr) * SLST + kh;
  int boff  = (((wv & 1) << 5) + fr) * SLST + kh;

  f32x16 acc0 = {0.f,0.f,0.f,0.f,0.f,0.f,0.f,0.f,0.f,0.f,0.f,0.f,0.f,0.f,0.f,0.f};
  f32x16 acc1 = {0.f,0.f,0.f,0.f,0.f,0.f,0.f,0.f,0.f,0.f,0.f,0.f,0.f,0.f,0.f,0.f};

  int4 pv0, pv1, pv2, pv3, pv4, pv5, pv6, pv7;
  int4 pv8, pv9, pv10, pv11, pv12, pv13, pv14, pv15;

#define LA(j) pv##j = *(const int4*)(pks + (size_t)min(base_mn + 8*(j) + grp, 960) * 112)
#define LA_A LA(0); LA(1); LA(2); LA(3); LA(4); LA(5); LA(6); LA(7); \
             LA(8); LA(9); LA(10); LA(11); LA(12); LA(13); LA(14); LA(15)
#define LA_B LA(0); LA(1); LA(2); LA(3); LA(4); LA(5); LA(6); LA(7)
#define WA(j) *(int4*)(d0 + (j) * 8 * SLST) = pv##j
#define WA_A WA(0); WA(1); WA(2); WA(3); WA(4); WA(5); WA(6); WA(7); \
             WA(8); WA(9); WA(10); WA(11); WA(12); WA(13); WA(14); WA(15)
#define WA_B WA(0); WA(1); WA(2); WA(3); WA(4); WA(5); WA(6); WA(7)

  // initial prefetch: rn=0 (nki=0, even)
  {
    const ushort_t* pks = pka + ch * 8;
    if (wv < 2) { LA_A; } else { LA_B; }
  }

  for (int r = 0; r < 14; ++r) {
    int half = r & 1;
    __syncthreads();
    {
      ushort_t* d0 = dplane + grp * SLST + ch * 8;
      if (!half || ch < 6) { if (wv < 2) { WA_A; } else { WA_B; } }
    }
    __syncthreads();
    if (r < 13) {
      int rn = r + 1;
      int nki = rn >> 1, odd = rn & 1;
      const ushort_t* pks = pka + (size_t)nki * (961 * 112) + odd * 64 + ch * 8;
      if (!odd || ch < 6) { if (wv < 2) { LA_A; } else { LA_B; } }
    }
    if (!half) {
#pragma unroll
      for (int t = 0; t < 4; ++t) {
        bfv8 ah0 = *(const bfv8*)(sAh + aoff0 + t * 16);
        bfv8 al0 = *(const bfv8*)(sAl + aoff0 + t * 16);
        bfv8 ah1 = *(const bfv8*)(sAh + aoff1 + t * 16);
        bfv8 al1 = *(const bfv8*)(sAl + aoff1 + t * 16);
        bfv8 bh  = *(const bfv8*)(sBh + boff + t * 16);
        bfv8 bl  = *(const bfv8*)(sBl + boff + t * 16);
        acc0 = __builtin_amdgcn_mfma_f32_32x32x16_bf16(al0, bh, acc0, 0, 0, 0);
        acc0 = __builtin_amdgcn_mfma_f32_32x32x16_bf16(ah0, bl, acc0, 0, 0, 0);
        acc0 = __builtin_amdgcn_mfma_f32_32x32x16_bf16(ah0, bh, acc0, 0, 0, 0);
        acc1 = __builtin_amdgcn_mfma_f32_32x32x16_bf16(al1, bh, acc1, 0, 0, 0);
        acc1 = __builtin_amdgcn_mfma_f32_32x32x16_bf16(ah1, bl, acc1, 0, 0, 0);
        acc1 = __builtin_amdgcn_mfma_f32_32x32x16_bf16(ah1, bh, acc1, 0, 0, 0);
      }
    } else {
#pragma unroll
      for (int t = 0; t < 3; ++t) {
        bfv8 ah0 = *(const bfv8*)(sAh + aoff0 + t * 16);
        bfv8 al0 = *(const bfv8*)(sAl + aoff0 + t * 16);
        bfv8 ah1 = *(const bfv8*)(sAh + aoff1 + t * 16);
        bfv8 al1 = *(const bfv8*)(sAl + aoff1 + t * 16);
        bfv8 bh  = *(const bfv8*)(sBh + boff + t * 16);
        bfv8 bl  = *(const bfv8*)(sBl + boff + t * 16);
        acc0 = __builtin_amdgcn_mfma_f32_32x32x16_bf16(al0, bh, acc0, 0, 0, 0);
        acc0 = __builtin_amdgcn_mfma_f32_32x32x16_bf16(ah0, bl, acc0, 0, 0, 0);
        acc0 = __builtin_amdgcn_mfma_f32_32x32x16_bf16(ah0, bh, acc0, 0, 0, 0);
        acc1 = __builtin_amdgcn_mfma_f32_32x32x16_bf16(al1, bh, acc1, 0, 0, 0);
        acc1 = __builtin_amdgcn_mfma_f32_32x32x16_bf16(ah1, bl, acc1, 0, 0, 0);
        acc1 = __builtin_amdgcn_mfma_f32_32x32x16_bf16(ah1, bh, acc1, 0, 0, 0);
      }
    }
  }
#undef LA
#undef LA_A
#undef LA_B
#undef WA
#undef WA_A
#undef WA_B

  int nw = n0 + ((wv & 1) << 5) + fr;
  if (nw < L_) {
    int mw0 = m0 + mt * 32;
#pragma unroll
    for (int r = 0; r < 16; ++r) {
      int m = mw0 + (r & 3) + ((r >> 2) << 3) + ((lane >> 5) << 2);
      if (m < L_) Sc[(size_t)m * SROW + nw] = acc0[r];
    }
    int mw1 = m0 + (mt + 1) * 32;
#pragma unroll
    for (int r = 0; r < 16; ++r) {
      int m = mw1 + (r & 3) + ((r >> 2) << 3) + ((lane >> 5) << 2);
      if (m < L_) Sc[(size_t)m * SROW + nw] = acc1[r];
    }
  }
}

// -------- fused top-100 softmax + PV: 4 rows/block, dual-row interleaved PV ------
// Radix phase: wave wvi does row l0+wvi (r6-verified structure).
// PV phase: lanes 0..195 hold TWO rows' accumulators (rrA=sub, rrB=2+sub) and
// issue 8 gathers/iter -> 2x memory-level parallelism. Per-row accumulation
// order identical to the serial 2-pass version -> bit-identical output.
__global__ __launch_bounds__(256) void k_tkpv(
    const float* __restrict__ scb,
    const ushort_t* __restrict__ b3, const float* __restrict__ s3,
    float* __restrict__ agb, int b0, unsigned scstride_z, unsigned agstride_z)
{
  __shared__ float swv[4][TOPM];
  __shared__ int spx[4][TOPM];
  __shared__ float sw0[4], sinvZ[4];
  int tid = threadIdx.x;
  int wvi = tid >> 6, lane = tid & 63;
  int l0 = blockIdx.x * 4;
  int l = l0 + wvi;
  if (l > L_ - 1) l = L_ - 1;        // clamp: duplicate rows produce identical data
  int bz = blockIdx.y;

  // ---- radix top-100 phase (per wave, one row) ----
  {
    const float4* row4 = (const float4*)(scb + (size_t)bz * scstride_z + (size_t)l * SROW);
    unsigned k[16];
#pragma unroll
    for (int q = 0; q < 4; ++q) {
      float4 v = row4[q * 64 + lane];
      int ib = (q * 64 + lane) * 4;
      k[q * 4 + 0] = (ib + 0 < L_) ? fmap(v.x) : 0u;
      k[q * 4 + 1] = (ib + 1 < L_) ? fmap(v.y) : 0u;
      k[q * 4 + 2] = (ib + 2 < L_) ? fmap(v.z) : 0u;
      k[q * 4 + 3] = (ib + 3 < L_) ? fmap(v.w) : 0u;
    }

    unsigned mk = 0;
#pragma unroll
    for (int r = 0; r < 16; ++r) mk = max(mk, k[r]);
#pragma unroll
    for (int o = 32; o; o >>= 1) mk = max(mk, (unsigned)__shfl_down((int)mk, o));
    mk = (unsigned)__shfl((int)mk, 0);
    float vmax = unfmap(mk);

    unsigned kk[16];
#pragma unroll
    for (int r = 0; r < 16; ++r) kk[r] = k[r];

    unsigned prefix = 0; int base = 0;
    for (int bit = 30; bit >= 0; bit -= 2) {
      int n3 = 0, n2 = 0, n1 = 0;
#pragma unroll
      for (int r = 0; r < 16; ++r) {
        unsigned f = (kk[r] >> bit) & 3u;
        n3 += (int)__popcll(__ballot(f == 3u));
        n2 += (int)__popcll(__ballot(f >= 2u));
        n1 += (int)__popcll(__ballot(f >= 1u));
      }
      unsigned ch;
      if (base + n3 >= TOPM) ch = 3;
      else if (base + n2 >= TOPM) { ch = 2; base += n3; }
      else if (base + n1 >= TOPM) { ch = 1; base += n2; }
      else { ch = 0; base += n1; }
      prefix |= ch << bit;
#pragma unroll
      for (int r = 0; r < 16; ++r) {
        unsigned f = (kk[r] >> bit) & 3u;
        kk[r] = (f == ch) ? kk[r] : 0u;
      }
    }
    int nA = base;
    int needT = TOPM - nA;

    int cA = 0, cT = 0;
#pragma unroll
    for (int r = 0; r < 16; ++r) { cA += (k[r] > prefix); cT += (k[r] == prefix); }
    int pkc = cA | (cT << 16);
    int incl = pkc;
#pragma unroll
    for (int o = 1; o < 64; o <<= 1) { int t = __shfl_up(incl, o); if (lane >= o) incl += t; }
    int excl = incl - pkc;
    int tA = excl & 0xFFFF, tT = excl >> 16;

    float M = fmaxf(10.f * vmax, 0.f);
    float e0 = __expf(-M);
    float z = 0.f;
#pragma unroll
    for (int r = 0; r < 16; ++r) {
      unsigned kr = k[r];
      int slot = -1;
      if (kr > prefix) slot = tA++;
      else if (kr == prefix) { if (tT < needT) slot = nA + tT; tT++; }
      if (slot >= 0) {
        float v = unfmap(kr);
        float wv = __expf(10.f * v - M);
        swv[wvi][slot] = wv; z += wv;
        int gi = 256 * (r >> 2) + 4 * lane + (r & 3);
        int lh = gi / OH_, lw = gi - lh * OH_;
        spx[wvi][slot] = ((lh * ST) * W_ + lw * ST) * CI;
      }
    }
#pragma unroll
    for (int o = 32; o; o >>= 1) z += __shfl_down(z, o);
    z = __shfl(z, 0);
    float Z = z + (float)(L_ - TOPM) * e0;
    if (lane == 0) { sinvZ[wvi] = 1.f / Z; sw0[wvi] = e0 / Z; }
  }
  __syncthreads();
  for (int i = tid; i < 4 * TOPM; i += 256) {
    int rr = i / TOPM, s = i - rr * TOPM;
    swv[rr][s] = swv[rr][s] * sinvZ[rr] - sw0[rr];
  }
  __syncthreads();

  // ---- PV phase: dual-row interleaved (rrA = sub, rrB = 2+sub) ----
  if (tid >= 196) return;
  int batch = b0 + bz;
  const ushort_t* B3 = b3 + (size_t)batch * HW * CI;
  const float* S3 = s3 + (size_t)batch * D_;
  float* agg = agb + (size_t)bz * agstride_z;

  int sub = tid / 98;
  int t98 = tid - sub * 98;
  int pos = t98 >> 1;
  int c0 = (t98 & 1) << 3;                 // 0 or 8
  int ki = pos / 7, kj = pos - (pos / 7) * 7;
  int poff = (ki * W_ + kj) * CI + c0;
  const float4 s40 = *(const float4*)(S3 + t98 * 8);
  const float4 s41 = *(const float4*)(S3 + t98 * 8 + 4);

  int rrA = sub, rrB = 2 + sub;
  int lrA = l0 + rrA; if (lrA > L_ - 1) lrA = L_ - 1;
  int lrB = l0 + rrB; if (lrB > L_ - 1) lrB = L_ - 1;
  float w0A = sw0[rrA], w0B = sw0[rrB];

  float a0A = 0.f, a1A = 0.f, a2A = 0.f, a3A = 0.f;
  float a4A = 0.f, a5A = 0.f, a6A = 0.f, a7A = 0.f;
  float a0B = 0.f, a1B = 0.f, a2B = 0.f, a3B = 0.f;
  float a4B = 0.f, a5B = 0.f, a6B = 0.f, a7B = 0.f;

  for (int j0 = 0; j0 < TOPM; j0 += 4) {
    float wA0 = swv[rrA][j0 + 0], wA1 = swv[rrA][j0 + 1];
    float wA2 = swv[rrA][j0 + 2], wA3 = swv[rrA][j0 + 3];
    float wB0 = swv[rrB][j0 + 0], wB1 = swv[rrB][j0 + 1];
    float wB2 = swv[rrB][j0 + 2], wB3 = swv[rrB][j0 + 3];
    int pA0 = spx[rrA][j0 + 0], pA1 = spx[rrA][j0 + 1];
    int pA2 = spx[rrA][j0 + 2], pA3 = spx[rrA][j0 + 3];
    int pB0 = spx[rrB][j0 + 0], pB1 = spx[rrB][j0 + 1];
    int pB2 = spx[rrB][j0 + 2], pB3 = spx[rrB][j0 + 3];
    const uint4 qA0 = *(const uint4*)(B3 + pA0 + poff);
    const uint4 qA1 = *(const uint4*)(B3 + pA1 + poff);
    const uint4 qA2 = *(const uint4*)(B3 + pA2 + poff);
    const uint4 qA3 = *(const uint4*)(B3 + pA3 + poff);
    const uint4 qB0 = *(const uint4*)(B3 + pB0 + poff);
    const uint4 qB1 = *(const uint4*)(B3 + pB1 + poff);
    const uint4 qB2 = *(const uint4*)(B3 + pB2 + poff);
    const uint4 qB3 = *(const uint4*)(B3 + pB3 + poff);
    a0A += wA0 * bflo(qA0.x); a1A += wA0 * bfhi(qA0.x); a2A += wA0 * bflo(qA0.y); a3A += wA0 * bfhi(qA0.y);
    a4A += wA0 * bflo(qA0.z); a5A += wA0 * bfhi(qA0.z); a6A += wA0 * bflo(qA0.w); a7A += wA0 * bfhi(qA0.w);
    a0A += wA1 * bflo(qA1.x); a1A += wA1 * bfhi(qA1.x); a2A += wA1 * bflo(qA1.y); a3A += wA1 * bfhi(qA1.y);
    a4A += wA1 * bflo(qA1.z); a5A += wA1 * bfhi(qA1.z); a6A += wA1 * bflo(qA1.w); a7A += wA1 * bfhi(qA1.w);
    a0A += wA2 * bflo(qA2.x); a1A += wA2 * bfhi(qA2.x); a2A += wA2 * bflo(qA2.y); a3A += wA2 * bfhi(qA2.y);
    a4A += wA2 * bflo(qA2.z); a5A += wA2 * bfhi(qA2.z); a6A += wA2 * bflo(qA2.w); a7A += wA2 * bfhi(qA2.w);
    a0A += wA3 * bflo(qA3.x); a1A += wA3 * bfhi(qA3.x); a2A += wA3 * bflo(qA3.y); a3A += wA3 * bfhi(qA3.y);
    a4A += wA3 * bflo(qA3.z); a5A += wA3 * bfhi(qA3.z); a6A += wA3 * bflo(qA3.w); a7A += wA3 * bfhi(qA3.w);
    a0B += wB0 * bflo(qB0.x); a1B += wB0 * bfhi(qB0.x); a2B += wB0 * bflo(qB0.y); a3B += wB0 * bfhi(qB0.y);
    a4B += wB0 * bflo(qB0.z); a5B += wB0 * bfhi(qB0.z); a6B += wB0 * bflo(qB0.w); a7B += wB0 * bfhi(qB0.w);
    a0B += wB1 * bflo(qB1.x); a1B += wB1 * bfhi(qB1.x); a2B += wB1 * bflo(qB1.y); a3B += wB1 * bfhi(qB1.y);
    a4B += wB1 * bflo(qB1.z); a5B += wB1 * bfhi(qB1.z); a6B += wB1 * bflo(qB1.w); a7B += wB1 * bfhi(qB1.w);
    a0B += wB2 * bflo(qB2.x); a1B += wB2 * bfhi(qB2.x); a2B += wB2 * bflo(qB2.y); a3B += wB2 * bfhi(qB2.y);
    a4B += wB2 * bflo(qB2.z); a5B += wB2 * bfhi(qB2.z); a6B += wB2 * bflo(qB2.w); a7B += wB2 * bfhi(qB2.w);
    a0B += wB3 * bflo(qB3.x); a1B += wB3 * bfhi(qB3.x); a2B += wB3 * bflo(qB3.y); a3B += wB3 * bfhi(qB3.y);
    a4B += wB3 * bflo(qB3.z); a5B += wB3 * bfhi(qB3.z); a6B += wB3 * bflo(qB3.w); a7B += wB3 * bfhi(qB3.w);
  }
  a0A += w0A * s40.x; a1A += w0A * s40.y; a2A += w0A * s40.z; a3A += w0A * s40.w;
  a4A += w0A * s41.x; a5A += w0A * s41.y; a6A += w0A * s41.z; a7A += w0A * s41.w;
  a0B += w0B * s40.x; a1B += w0B * s40.y; a2B += w0B * s40.z; a3B += w0B * s40.w;
  a4B += w0B * s41.x; a5B += w0B * s41.y; a6B += w0B * s41.z; a7B += w0B * s41.w;
  float* dstA = agg + (size_t)lrA * D_ + t98 * 8;
  *(float4*)(dstA)     = make_float4(a0A, a1A, a2A, a3A);
  *(float4*)(dstA + 4) = make_float4(a4A, a5A, a6A, a7A);
  float* dstB = agg + (size_t)lrB * D_ + t98 * 8;
  *(float4*)(dstB)     = make_float4(a0B, a1B, a2B, a3B);
  *(float4*)(dstB + 4) = make_float4(a4B, a5B, a6B, a7B);
}

// -------- fold + mask divide + restore (16->64), batched -------------------------
__global__ __launch_bounds__(256) void k_fold(
    const int* __restrict__ flag, const float* __restrict__ ws,
    const float* __restrict__ agb, void* __restrict__ out,
    int b0, unsigned agstride_z)
{
  __shared__ float srw[CIN * CI];
  int tid = threadIdx.x;
  for (int i = tid; i < CIN * CI; i += 256) srw[i] = ws[RW_O + i];
  __syncthreads();

  int bz = blockIdx.y;
  int batch = b0 + bz;
  const float* agg = agb + (size_t)bz * agstride_z;

  int gid = blockIdx.x * 256 + tid;
  if (gid >= HW) return;
  int h = gid / W_;
  int w = gid % W_;

  int lh0 = (h >= KS - 1) ? ((h - (KS - 1) + (ST - 1)) >> 2) : 0;
  int lh1 = min(OH_ - 1, h >> 2);
  int lw0 = (w >= KS - 1) ? ((w - (KS - 1) + (ST - 1)) >> 2) : 0;
  int lw1 = min(OH_ - 1, w >> 2);

  float t[CI];
#pragma unroll
  for (int c = 0; c < CI; ++c) t[c] = 0.f;
  for (int lh = lh0; lh <= lh1; ++lh) {
    int ki = h - ST * lh;
    for (int lw = lw0; lw <= lw1; ++lw) {
      int kj = w - ST * lw;
      const float* pb = agg + (size_t)(lh * OH_ + lw) * D_ + (ki * KS + kj) * CI;
      float4 q0 = *(const float4*)(pb);
      float4 q1 = *(const float4*)(pb + 4);
      float4 q2 = *(const float4*)(pb + 8);
      float4 q3 = *(const float4*)(pb + 12);
      t[0] += q0.x; t[1] += q0.y; t[2] += q0.z; t[3] += q0.w;
      t[4] += q1.x; t[5] += q1.y; t[6] += q1.z; t[7] += q1.w;
      t[8] += q2.x; t[9] += q2.y; t[10] += q2.z; t[11] += q2.w;
      t[12] += q3.x; t[13] += q3.y; t[14] += q3.z; t[15] += q3.w;
    }
  }
  float cnt = (float)((lh1 - lh0 + 1) * (lw1 - lw0 + 1));
  float r[CI];
#pragma unroll
  for (int c = 0; c < CI; ++c) r[c] = t[c] / (cnt * ws[SM_O + c] + ws[SB_O + c] + 1e-8f);

  size_t ob = (size_t)batch * CIN * HW + (size_t)h * W_ + w;
  if (*flag) {
    float* of = (float*)out;
#pragma unroll
    for (int o = 0; o < CIN; ++o) {
      float s = ws[RB_O + o];
#pragma unroll
      for (int c = 0; c < CI; ++c) s += srw[o * CI + c] * r[c];
      of[ob + (size_t)o * HW] = s;
    }
  } else {
    bf16* of = (bf16*)out;
#pragma unroll
    for (int o = 0; o < CIN; ++o) {
      float s = ws[RB_O + o];
#pragma unroll
      for (int c = 0; c < CI; ++c) s += srw[o * CI + c] * r[c];
      of[ob + (size_t)o * HW] = __float2bfloat16(s);
    }
  }
}

extern "C" void kernel_launch(void* const* d_in, const int* in_sizes, int n_in,
                              void* d_out, int out_size, void* d_ws, size_t ws_size,
                              hipStream_t stream)
{
  const void* x    = d_in[0];
  const void* g_w  = d_in[1];
  const void* g_b  = d_in[2];
  const void* th_w = d_in[3];
  const void* th_b = d_in[4];
  const void* ph_w = d_in[5];
  const void* ph_b = d_in[6];
  const void* m_w  = d_in[7];
  const void* m_b  = d_in[8];
  const void* r_w  = d_in[9];
  const void* r_b  = d_in[10];

  float* W = (float*)d_ws;
  int* flag = (int*)d_ws;
  ushort_t* planes = (ushort_t*)(W + B1_O);
  ushort_t* b1h = planes;
  ushort_t* b1l = planes + (size_t)N1;
  ushort_t* b2h = planes + (size_t)2 * N1;
  ushort_t* b2l = planes + (size_t)3 * N1;
  ushort_t* b3  = planes + (size_t)4 * N1;   // bf16 plane, N1 ushorts
  float* s3 = W + S3_O;

  if (ws_size >= FULL_BYTES) {
    ushort_t* xhh = (ushort_t*)(W + REG_O);    // padded planes, dead after conv
    ushort_t* xhl = xhh + XPU;
    float* sc = W + REG_O;                     // 4 x SCSLOT, aliases dead planes
    ushort_t* pk  = (ushort_t*)(W + PK_O);
    ushort_t* pk2 = (ushort_t*)(W + PK2_O);
    float* ag = W + PK_O;                      // aliases PK1 (dead after k_score)
    k_prep<<<dim3((B_ * HW + 63) / 64), 256, 0, stream>>>(
        x, g_w, th_w, ph_w, g_b, th_b, ph_b, m_w, m_b, r_w, r_b, W, xhh, xhl);
    k_conv3<<<dim3(H_, 1, B_), 256, 0, stream>>>(
        W, xhh, xhl, b1h, b1l, b2h, b2l, b3, pk, pk2);
    k_colsum<<<dim3(B_, 49), 256, 0, stream>>>(b3, s3);
    k_score<<<dim3(16, 8, B_), 256, 0, stream>>>(pk, pk2, sc, SCSLOT, PKSTR);
    k_tkpv<<<dim3((L_ + 3) / 4, B_), 256, 0, stream>>>(sc, b3, s3, ag, 0, SCSLOT, AGSZ);
    k_fold<<<dim3(64, B_), 256, 0, stream>>>(flag, W, ag, d_out, 0, AGSZ);
  } else if (ws_size >= MID_BYTES) {
    ushort_t* xhh = (ushort_t*)(W + REG_O);
    ushort_t* xhl = xhh + XPU;
    float* sc = W + REG_O;
    float* ag = W + REG_O + SCSLOT;
    ushort_t* pk  = (ushort_t*)ag;             // PK1 shares the ag slot
    ushort_t* pk2 = pk + (size_t)PKSTR;        // PK2 right after (within planes region)
    k_prep<<<dim3((B_ * HW + 63) / 64), 256, 0, stream>>>(
        x, g_w, th_w, ph_w, g_b, th_b, ph_b, m_w, m_b, r_w, r_b, W, xhh, xhl);
    k_conv3<<<dim3(H_, 1, B_), 256, 0, stream>>>(
        W, xhh, xhl, b1h, b1l, b2h, b2l, b3, (ushort_t*)nullptr, (ushort_t*)nullptr);
    k_colsum<<<dim3(B_, 49), 256, 0, stream>>>(b3, s3);
    for (int b = 0; b < B_; ++b) {
      k_pack<<<dim3(736, 1), 256, 0, stream>>>(b1h, b1l, b2h, b2l, pk, pk2, b, 0);
      k_score<<<dim3(16, 8, 1), 256, 0, stream>>>(pk, pk2, sc, 0, 0);
      k_tkpv<<<dim3((L_ + 3) / 4, 1), 256, 0, stream>>>(sc, b3, s3, ag, b, 0, 0);
      k_fold<<<dim3(64, 1), 256, 0, stream>>>(flag, W, ag, d_out, b, 0);
    }
  } else {
    float* sc = W + REG_O;
    float* ag = W + REG_O + SCSLOT;
    ushort_t* pk  = (ushort_t*)ag;
    ushort_t* pk2 = pk + (size_t)PKSTR;
    k_prep<<<64, 256, 0, stream>>>(
        x, g_w, th_w, ph_w, g_b, th_b, ph_b, m_w, m_b, r_w, r_b, W,
        (ushort_t*)nullptr, (ushort_t*)nullptr);
    k_convF<<<dim3(4, 16, B_), dim3(32, 8, 1), 0, stream>>>(
        flag, x, g_w, g_b, th_w, th_b, ph_w, ph_b, b1h, b1l, b2h, b2l, b3);
    k_colsum<<<dim3(B_, 49), 256, 0, stream>>>(b3, s3);
    for (int b = 0; b < B_; ++b) {
      k_pack<<<dim3(736, 1), 256, 0, stream>>>(b1h, b1l, b2h, b2l, pk, pk2, b, 0);
      k_score<<<dim3(16, 8, 1), 256, 0, stream>>>(pk, pk2, sc, 0, 0);
      k_tkpv<<<dim3((L_ + 3) / 4, 1), 256, 0, stream>>>(sc, b3, s3, ag, b, 0, 0);
      k_fold<<<dim3(64, 1), 256, 0, stream>>>(flag, W, ag, d_out, b, 0);
    }
  }
}

// Round 13
// 232.977 us; speedup vs baseline: 1.9560x; 1.0251x over previous
//
#include <hip/hip_runtime.h>
#include <hip/hip_bf16.h>

typedef __hip_bfloat16 bf16;
typedef unsigned short ushort_t;
typedef __attribute__((ext_vector_type(8))) __bf16 bfv8;
typedef __attribute__((ext_vector_type(16))) float f32x16;

#define B_   4
#define CIN  64
#define CI   16
#define H_   127
#define W_   127
#define HW   (H_*W_)
#define KS   7
#define ST   4
#define OH_  31
#define L_   961
#define D_   784
#define TOPM 100

// ---- workspace layout (float offsets) ----
#define N1   1032256          // B*HW*CI elements (one conv-out array)
#define WG_O 4
#define WT_O (WG_O + 9216)
#define WP_O (WT_O + 1024)
#define BG_O (WP_O + 1024)
#define BT_O (BG_O + 16)
#define BP_O (BT_O + 16)
#define SM_O (BP_O + 16)
#define SB_O (SM_O + 16)
#define RW_O (SB_O + 16)
#define RB_O (RW_O + 1024)
#define B1_O 12448
// planes at B1_O: b1h,b1l,b2h,b2l each N1 ushorts (2*N1 floats); b3 bf16 N1 ushorts
#define S3_O (B1_O + 3*N1)
#define WB_O (S3_O + B_*D_)   // conv MFMA B: wBh + wBl = 36864 floats
#define REG_O (WB_O + 36864)
#define SROW 964              // padded Sc row stride
#define SCSLOT 926464
#define AGSZ 753424
#define SLST 72               // LDS row stride in ushorts (conflict-free, measured r8)
// PK: unfold-packed operands. Per plane: 7 nki x 961 rows x 112 ushorts = 753424.
#define PKPLANE 753424
#define PKSTR   1506848
// padded x planes: 129x129 pixels x 64 ch, zero borders -> conv3 has NO bounds logic
#define PADW 129
#define PADPIX (PADW*PADW)            // 16641
#define XPB  (PADPIX*64)              // ushorts per batch-plane = 1,065,024
#define XPU  ((size_t)B_ * XPB)       // ushorts per plane (all batches) = 4,260,096
#define PLANES_FL 4260096             // floats spanned by both padded planes
// FULL tier: PK1/PK2 after the planes (conv3 writes them while reading planes).
#define PK_O  (REG_O + PLANES_FL)     // PK1: 4*PKSTR ushorts = 3,013,696 floats
#define PK2_O (PK_O + 3013696)        // PK2 (b2 operand), same size

#define FULL_BYTES ((size_t)(PK2_O + 3013696) * 4)         // ~53.7 MB (ws is 256 MiB)
#define MID_BYTES  ((size_t)(REG_O + PLANES_FL) * 4)       // ~29.6 MB

__device__ __forceinline__ float bf2f(bf16 v) { return __bfloat162float(v); }
__device__ __forceinline__ float bflo(unsigned u) { return __uint_as_float(u << 16); }
__device__ __forceinline__ float bfhi(unsigned u) { return __uint_as_float(u & 0xFFFF0000u); }

template <typename T> struct Ld;
template <> struct Ld<float> {
  static __device__ __forceinline__ float f(const void* p, int i) { return ((const float*)p)[i]; }
};
template <> struct Ld<bf16> {
  static __device__ __forceinline__ float f(const void* p, int i) { return bf2f(((const bf16*)p)[i]); }
};

__device__ __forceinline__ unsigned fmap(float f) {
  unsigned u = __float_as_uint(f);
  return (u & 0x80000000u) ? ~u : (u | 0x80000000u);
}
__device__ __forceinline__ float unfmap(unsigned kk) {
  unsigned u = (kk & 0x80000000u) ? (kk & 0x7fffffffu) : ~kk;
  return __uint_as_float(u);
}

// RNE fp32 -> bf16 bits, and hi/lo split
__device__ __forceinline__ ushort_t f2bf(float x) {
  unsigned u = __float_as_uint(x);
  return (ushort_t)((u + 0x7FFFu + ((u >> 16) & 1u)) >> 16);
}
__device__ __forceinline__ void splitbf(float x, ushort_t& h, ushort_t& l) {
  h = f2bf(x);
  float hf = __uint_as_float(((unsigned)h) << 16);
  l = f2bf(x - hf);
}

// -------- weight prep + inline dtype detect + border zpad + fused HWC ------------
#define LDW(ptr, i) (f ? ((const float*)(ptr))[i] : bf2f(((const bf16*)(ptr))[i]))
__global__ __launch_bounds__(256) void k_prep(
    const void* __restrict__ x,
    const void* g_w, const void* t_w, const void* p_w,
    const void* g_b, const void* t_b, const void* p_b,
    const void* m_w, const void* m_b, const void* r_w, const void* r_b,
    float* __restrict__ ws,
    ushort_t* __restrict__ xhh, ushort_t* __restrict__ xhl)
{
  __shared__ int sflag;
  __shared__ float tile[64][65];
  // inline dtype detect (per block; wave 0 reduces, LDS broadcast)
  {
    const unsigned short* xh = (const unsigned short*)x;
    if (threadIdx.x < 64) {
      int c = 0;
#pragma unroll
      for (int j = 0; j < 2; ++j) {
        unsigned u = xh[threadIdx.x * 2 + j];
        unsigned e = (u >> 7) & 0xFF;
        if (e >= 134) c++;
      }
#pragma unroll
      for (int o = 32; o; o >>= 1) c += __shfl_down(c, o);
      if (threadIdx.x == 0) sflag = (c >= 8) ? 1 : 0;
    }
  }
  __syncthreads();
  int f = sflag;
  if (blockIdx.x == 0 && threadIdx.x == 0) *(int*)ws = f;   // publish for downstream

  int gid = blockIdx.x * 256 + threadIdx.x;
  int gs = gridDim.x * 256;
  for (int i = gid; i < 9216; i += gs) {
    int o = i & 15, t = i >> 4, c = t & 63, tap = t >> 6;
    ws[WG_O + i] = LDW(g_w, (o * 64 + c) * 9 + tap);
  }
  for (int i = gid; i < 1024; i += gs) {
    int o = i & 15, c = i >> 4;
    ws[WT_O + i] = LDW(t_w, o * 64 + c);
    ws[WP_O + i] = LDW(p_w, o * 64 + c);
  }
  if (gid < 16) {
    ws[BG_O + gid] = LDW(g_b, gid);
    ws[BT_O + gid] = LDW(t_b, gid);
    ws[BP_O + gid] = LDW(p_b, gid);
    float s = 0.f;
    for (int c = 0; c < 64; ++c) s += LDW(m_w, gid * 64 + c);
    ws[SM_O + gid] = s;
    ws[SB_O + gid] = LDW(m_b, gid);
  }
  for (int i = gid; i < 1024; i += gs) ws[RW_O + i] = LDW(r_w, i);
  if (gid >= 64 && gid < 128) ws[RB_O + gid - 64] = LDW(r_b, gid - 64);
  // conv MFMA B, split hi/lo: wB[tap][col64][c64]
  ushort_t* wBh = (ushort_t*)(ws + WB_O);
  ushort_t* wBl = wBh + 9 * 64 * 64;
  for (int i = gid; i < 9 * 64 * 64; i += gs) {
    int c = i & 63, t = i >> 6, col = t & 63, tap = t >> 6;
    float v = 0.f;
    if (col < 16) v = LDW(g_w, (col * 64 + c) * 9 + tap);
    else if (col < 32) { if (tap == 4) v = LDW(t_w, (col - 16) * 64 + c); }
    else if (col < 48) { if (tap == 4) v = LDW(p_w, (col - 32) * 64 + c); }
    ushort_t h, l; splitbf(v, h, l);
    wBh[i] = h; wBl[i] = l;
  }
  if (xhh) {
    // fused border zpad
    const int4 z = make_int4(0, 0, 0, 0);
    for (int idx = gid; idx < B_ * 512 * 8; idx += gs) {
      int q = idx & 7, t = idx >> 3;
      int bp = t & 511, bb = t >> 9;
      int pp;
      if (bp < 129) pp = bp;                              // top row
      else if (bp < 258) pp = 128 * PADW + (bp - 129);    // bottom row
      else if (bp < 385) pp = (bp - 257) * PADW;          // left col rows 1..127
      else pp = (bp - 384) * PADW + 128;                  // right col rows 1..127
      size_t off = ((size_t)bb * PADPIX + pp) * 64 + q * 8;
      *(int4*)(xhh + off) = z;
      *(int4*)(xhl + off) = z;
    }
    // fused HWC transpose into padded planes (one 64-pixel tile per block)
    int pix0 = blockIdx.x * 64;
    if (pix0 < B_ * HW) {
      int g = threadIdx.x >> 6, p = threadIdx.x & 63;
      int pix = pix0 + p;
      bool ok = pix < B_ * HW;
      int bb = ok ? pix / HW : 0;
      int r  = ok ? pix - bb * HW : 0;
      if (f) {
        const float* xf = (const float*)x;
        for (int c = g * 16; c < g * 16 + 16; ++c)
          tile[p][c] = ok ? xf[((size_t)bb * CIN + c) * HW + r] : 0.f;
      } else {
        const bf16* xb = (const bf16*)x;
        for (int c = g * 16; c < g * 16 + 16; ++c)
          tile[p][c] = ok ? bf2f(xb[((size_t)bb * CIN + c) * HW + r]) : 0.f;
      }
      __syncthreads();
      int c2 = threadIdx.x & 63, pg = threadIdx.x >> 6;
      int pix2 = pix0 + pg * 16;
      int bb2 = pix2 / HW, r2 = pix2 - bb2 * HW;
      int h2 = r2 / W_, w2 = r2 - h2 * W_;
      for (int k = 0; k < 16; ++k) {
        if (pix2 + k < B_ * HW) {
          ushort_t h, l; splitbf(tile[pg * 16 + k][c2], h, l);
          size_t off = ((size_t)bb2 * PADPIX + (size_t)(h2 + 1) * PADW + (w2 + 1)) * 64 + c2;
          xhh[off] = h;
          xhl[off] = l;
        }
        if (++w2 == W_) { w2 = 0; if (++h2 == H_) { h2 = 0; ++bb2; } }
      }
    }
  }
}

// -------- split-bf16 MFMA conv, one output row per block, contiguous staging -----
// pk != nullptr (FULL): epilogue stages b1 AND b2 in LDS and writes PK1/PK2
// directly (bit-identical values); b1/b2 planes never materialize.
__global__ __launch_bounds__(256) void k_conv3(
    const float* __restrict__ ws,
    const ushort_t* __restrict__ xhh, const ushort_t* __restrict__ xhl,
    ushort_t* __restrict__ b1h, ushort_t* __restrict__ b1l,
    ushort_t* __restrict__ b2h, ushort_t* __restrict__ b2l,
    ushort_t* __restrict__ b3, ushort_t* __restrict__ pk, ushort_t* __restrict__ pk2)
{
  __shared__ ushort_t sAh[128 * SLST], sAl[128 * SLST];
  __shared__ ushort_t sBh[64 * SLST],  sBl[64 * SLST];
  int bz = blockIdx.z;
  int h = blockIdx.x;                       // output row
  int tid = threadIdx.x, lane = tid & 63, wv = tid >> 6;
  int grp = lane >> 3, ch = lane & 7;

  const ushort_t* xplane = ((wv == 0) ? xhh : xhl) + (size_t)bz * XPB;
  const ushort_t* wBh_ = (const ushort_t*)(ws + WB_O);
  const ushort_t* bsrc = (wv == 2) ? wBh_ : (wBh_ + 9 * 64 * 64);
  ushort_t* dplane = (wv == 0) ? sAh : (wv == 1) ? sAl : (wv == 2) ? sBh : sBl;

  int fr = lane & 31, kh = (lane >> 5) << 3;
  int mt = (wv >> 1) << 1;
  int aoff0 = (mt * 32 + fr) * SLST + kh;
  int aoff1 = ((mt + 1) * 32 + fr) * SLST + kh;
  int boff  = (((wv & 1) << 5) + fr) * SLST + kh;

  f32x16 acc0 = {0.f,0.f,0.f,0.f,0.f,0.f,0.f,0.f,0.f,0.f,0.f,0.f,0.f,0.f,0.f,0.f};
  f32x16 acc1 = {0.f,0.f,0.f,0.f,0.f,0.f,0.f,0.f,0.f,0.f,0.f,0.f,0.f,0.f,0.f,0.f};

  int4 pv0, pv1, pv2, pv3, pv4, pv5, pv6, pv7;
  int4 pv8, pv9, pv10, pv11, pv12, pv13, pv14, pv15;

#define LC(j) pv##j = *(const int4*)(src + (j) * 512)
#define LC_A  LC(0); LC(1); LC(2); LC(3); LC(4); LC(5); LC(6); LC(7); \
              LC(8); LC(9); LC(10); LC(11); LC(12); LC(13); LC(14); LC(15)
#define LC_W  LC(0); LC(1); LC(2); LC(3); LC(4); LC(5); LC(6); LC(7)
#define WC(j) *(int4*)(d0 + (j) * 8 * SLST) = pv##j
#define WC_A  WC(0); WC(1); WC(2); WC(3); WC(4); WC(5); WC(6); WC(7); \
              WC(8); WC(9); WC(10); WC(11); WC(12); WC(13); WC(14); WC(15)
#define WC_W  WC(0); WC(1); WC(2); WC(3); WC(4); WC(5); WC(6); WC(7)

  // prefetch tap 0 (dh=-1, dw=-1): padded row h, col 0
  if (wv < 2) {
    const ushort_t* src = xplane + (size_t)h * (PADW * 64) + grp * 64 + ch * 8;
    LC_A;
  } else {
    const ushort_t* src = bsrc + grp * 64 + ch * 8;
    LC_W;
  }

  for (int r = 0; r < 9; ++r) {
    __syncthreads();
    {
      ushort_t* d0 = dplane + grp * SLST + ch * 8;
      if (wv < 2) { WC_A; } else { WC_W; }
    }
    __syncthreads();
    if (r < 8) {
      int rn = r + 1;
      int dh = rn / 3 - 1, dw = rn % 3 - 1;
      if (wv < 2) {
        const ushort_t* src = xplane
            + ((size_t)(h + 1 + dh) * PADW + (1 + dw)) * 64 + grp * 64 + ch * 8;
        LC_A;
      } else {
        const ushort_t* src = bsrc + rn * 4096 + grp * 64 + ch * 8;
        LC_W;
      }
    }
#pragma unroll
    for (int t = 0; t < 4; ++t) {
      bfv8 ah0 = *(const bfv8*)(sAh + aoff0 + t * 16);
      bfv8 al0 = *(const bfv8*)(sAl + aoff0 + t * 16);
      bfv8 ah1 = *(const bfv8*)(sAh + aoff1 + t * 16);
      bfv8 al1 = *(const bfv8*)(sAl + aoff1 + t * 16);
      bfv8 bh  = *(const bfv8*)(sBh + boff + t * 16);
      bfv8 bl  = *(const bfv8*)(sBl + boff + t * 16);
      acc0 = __builtin_amdgcn_mfma_f32_32x32x16_bf16(al0, bh, acc0, 0, 0, 0);
      acc0 = __builtin_amdgcn_mfma_f32_32x32x16_bf16(ah0, bl, acc0, 0, 0, 0);
      acc0 = __builtin_amdgcn_mfma_f32_32x32x16_bf16(ah0, bh, acc0, 0, 0, 0);
      acc1 = __builtin_amdgcn_mfma_f32_32x32x16_bf16(al1, bh, acc1, 0, 0, 0);
      acc1 = __builtin_amdgcn_mfma_f32_32x32x16_bf16(ah1, bl, acc1, 0, 0, 0);
      acc1 = __builtin_amdgcn_mfma_f32_32x32x16_bf16(ah1, bh, acc1, 0, 0, 0);
    }
  }
#undef LC
#undef LC_A
#undef LC_W
#undef WC
#undef WC_A
#undef WC_W

  int nw = ((wv & 1) << 5) + fr;
  if (pk) {
    // ---- PK-direct epilogue (b1 -> PK1, b2 -> PK2) ----
    __syncthreads();                     // main-loop LDS reads done
    ushort_t* sb1h = sAh;                // [128][16]
    ushort_t* sb1l = sAl;
    ushort_t* sb2h = sBh;                // [128][16] (fits in 64*SLST=4608)
    ushort_t* sb2l = sBl;
#pragma unroll
    for (int s = 0; s < 2; ++s) {
      int mbase = (mt + s) * 32;
#pragma unroll
      for (int r = 0; r < 16; ++r) {
        int m = mbase + (r & 3) + ((r >> 2) << 3) + ((lane >> 5) << 2);
        float val = s ? acc1[r] : acc0[r];
        if (nw < 16) {
          ushort_t h2, l2; splitbf(val + ws[BG_O + nw], h2, l2);
          sb1h[m * 16 + nw] = h2; sb1l[m * 16 + nw] = l2;
        } else if (nw < 32) {
          int o = nw - 16; ushort_t h2, l2; splitbf(val + ws[BT_O + o], h2, l2);
          sb2h[m * 16 + o] = h2; sb2l[m * 16 + o] = l2;
        } else if (nw < 48) {
          if (m < W_) {
            size_t ob = ((size_t)bz * HW + h * W_ + m) * 16;
            int o = nw - 32; b3[ob + o] = f2bf(val + ws[BP_O + o]);
          }
        }
      }
    }
    __syncthreads();
    // cooperative PK write: each valid slh owns 31 slw segments x 14 int4 / plane
    ushort_t* pk1b = pk  + (size_t)bz * PKSTR;
    ushort_t* pk2b = pk2 + (size_t)bz * PKSTR;
    int slh_lo = (h >= 6) ? ((h - 3) >> 2) : 0;       // ceil((h-6)/4)
    int slh_hi = h >> 2; if (slh_hi > 30) slh_hi = 30;
    for (int slh = slh_lo; slh <= slh_hi; ++slh) {
      int nki = h - 4 * slh;                          // in [0,6]
      size_t rb = ((size_t)nki * 961 + slh * 31) * 112;
      for (int t = tid; t < 31 * 14; t += 256) {
        int slw = t / 14, q = t - slw * 14;
        int m = slw * 4 + (q >> 1);                   // pixel w (<=126)
        int c0 = (q & 1) << 3;
        size_t doff = rb + (size_t)slw * 112 + q * 8;
        *(int4*)(pk1b + doff)           = *(int4*)(sb1h + m * 16 + c0);
        *(int4*)(pk1b + PKPLANE + doff) = *(int4*)(sb1l + m * 16 + c0);
        *(int4*)(pk2b + doff)           = *(int4*)(sb2h + m * 16 + c0);
        *(int4*)(pk2b + PKPLANE + doff) = *(int4*)(sb2l + m * 16 + c0);
      }
    }
  } else {
    // ---- legacy epilogue (MID tier; k_pack consumes b1/b2) ----
#pragma unroll
    for (int s = 0; s < 2; ++s) {
      int mbase = (mt + s) * 32;
#pragma unroll
      for (int r = 0; r < 16; ++r) {
        int m = mbase + (r & 3) + ((r >> 2) << 3) + ((lane >> 5) << 2);
        if (m >= W_) continue;
        size_t ob = ((size_t)bz * HW + h * W_ + m) * 16;
        float val = s ? acc1[r] : acc0[r];
        if (nw < 16) {
          ushort_t h2, l2; splitbf(val + ws[BG_O + nw], h2, l2);
          b1h[ob + nw] = h2; b1l[ob + nw] = l2;
        } else if (nw < 32) {
          int o = nw - 16; ushort_t h2, l2; splitbf(val + ws[BT_O + o], h2, l2);
          b2h[ob + o] = h2; b2l[ob + o] = l2;
        } else if (nw < 48) {
          int o = nw - 32; b3[ob + o] = f2bf(val + ws[BP_O + o]);
        }
      }
    }
  }
}

// -------- fallback conv (LOW tier), dtype-templated VALU -------------------------
template <typename T>
__device__ __forceinline__ void convF_body(
    const void* x, const void* g_w, const void* g_b,
    const void* t_w, const void* t_b, const void* p_w, const void* p_b,
    ushort_t* b1h, ushort_t* b1l, ushort_t* b2h, ushort_t* b2l, ushort_t* b3,
    float* sgw, float* stw, float* spw)
{
  int tid = threadIdx.y * 32 + threadIdx.x;
  for (int i = tid; i < CI * CIN * 9; i += 256) sgw[i] = Ld<T>::f(g_w, i);
  for (int i = tid; i < CI * CIN; i += 256) { stw[i] = Ld<T>::f(t_w, i); spw[i] = Ld<T>::f(p_w, i); }
  __syncthreads();

  int w = blockIdx.x * 32 + threadIdx.x;
  int h = blockIdx.y * 8 + threadIdx.y;
  int b = blockIdx.z;
  if (w >= W_ || h >= H_) return;

  float a1[CI], a2[CI], a3[CI];
#pragma unroll
  for (int o = 0; o < CI; ++o) { a1[o] = 0.f; a2[o] = 0.f; a3[o] = 0.f; }

  const size_t xb = (size_t)b * CIN * HW;
  for (int c = 0; c < CIN; ++c) {
    float xv[9];
#pragma unroll
    for (int dh = 0; dh < 3; ++dh) {
      int hh = h + dh - 1;
      bool rok = ((unsigned)hh < (unsigned)H_);
#pragma unroll
      for (int dw = 0; dw < 3; ++dw) {
        int ww = w + dw - 1;
        bool ok = rok && ((unsigned)ww < (unsigned)W_);
        xv[dh * 3 + dw] = ok ? Ld<T>::f(x, (int)(xb + (size_t)c * HW + hh * W_ + ww)) : 0.f;
      }
    }
    float xc = xv[4];
#pragma unroll
    for (int o = 0; o < CI; ++o) {
      const float* gg = &sgw[(o * CIN + c) * 9];
      float s = gg[0]*xv[0] + gg[1]*xv[1] + gg[2]*xv[2]
              + gg[3]*xv[3] + gg[4]*xv[4] + gg[5]*xv[5]
              + gg[6]*xv[6] + gg[7]*xv[7] + gg[8]*xv[8];
      a1[o] += s;
      a2[o] += stw[o * CIN + c] * xc;
      a3[o] += spw[o * CIN + c] * xc;
    }
  }
  size_t base = ((size_t)b * HW + h * W_ + w) * CI;
#pragma unroll
  for (int o = 0; o < CI; ++o) {
    float v1 = a1[o] + Ld<T>::f(g_b, o);
    float v2 = a2[o] + Ld<T>::f(t_b, o);
    ushort_t hh2, ll2;
    splitbf(v1, hh2, ll2); b1h[base + o] = hh2; b1l[base + o] = ll2;
    splitbf(v2, hh2, ll2); b2h[base + o] = hh2; b2l[base + o] = ll2;
    b3[base + o] = f2bf(a3[o] + Ld<T>::f(p_b, o));
  }
}

__global__ __launch_bounds__(256) void k_convF(
    const int* __restrict__ flag, const void* x,
    const void* g_w, const void* g_b, const void* t_w, const void* t_b,
    const void* p_w, const void* p_b,
    ushort_t* __restrict__ b1h, ushort_t* __restrict__ b1l,
    ushort_t* __restrict__ b2h, ushort_t* __restrict__ b2l,
    ushort_t* __restrict__ b3)
{
  __shared__ float sgw[CI * CIN * 9];
  __shared__ float stw[CI * CIN];
  __shared__ float spw[CI * CIN];
  if (*flag) convF_body<float>(x, g_w, g_b, t_w, t_b, p_w, p_b, b1h, b1l, b2h, b2l, b3, sgw, stw, spw);
  else       convF_body<bf16 >(x, g_w, g_b, t_w, t_b, p_w, p_b, b1h, b1l, b2h, b2l, b3, sgw, stw, spw);
}

// -------- S3[b, pos*16+c] = sum over patches of b3 (standalone, MID/LOW) ---------
__global__ __launch_bounds__(256) void k_colsum(const ushort_t* __restrict__ b3, float* __restrict__ S3)
{
  __shared__ float red[16][17];
  int b = blockIdx.x, pos = blockIdx.y;
  int ki = pos / 7, kj = pos % 7;
  int c = threadIdx.x & 15, chunk = threadIdx.x >> 4;
  const ushort_t* B3 = b3 + (size_t)b * HW * CI;
  float s = 0.f;
  for (int l = chunk; l < L_; l += 16) {
    int lh = l / OH_, lw = l % OH_;
    s += bflo((unsigned)B3[((lh * ST + ki) * W_ + lw * ST + kj) * CI + c]);
  }
  red[chunk][c] = s;
  __syncthreads();
  if (threadIdx.x < 16) {
    float t = 0.f;
#pragma unroll
    for (int k = 0; k < 16; ++k) t += red[k][threadIdx.x];
    S3[(b * 49 + pos) * 16 + threadIdx.x] = t;
  }
}

// -------- pack operands (MID/LOW tiers): PK1 from b1, PK2 from b2 ----------------
__global__ __launch_bounds__(256) void k_pack(
    const ushort_t* __restrict__ b1h, const ushort_t* __restrict__ b1l,
    const ushort_t* __restrict__ b2h, const ushort_t* __restrict__ b2l,
    ushort_t* __restrict__ pk, ushort_t* __restrict__ pk2,
    int b0, unsigned pkstride_z)
{
  int idx = blockIdx.x * 256 + threadIdx.x;
  if (idx >= 2 * 961 * 98) return;
  int sel = (idx >= 961 * 98);
  int i2 = sel ? idx - 961 * 98 : idx;
  int row = i2 / 98, rem = i2 - row * 98;
  int nki = rem / 14, q = rem - nki * 14;
  int slh = row / OH_, slw = row - slh * OH_;
  int src = ((slh * ST) * W_ + slw * ST + nki * W_) * 16 + q * 8;
  int dst = (nki * 961 + row) * 112 + q * 8;
  int batch = b0 + blockIdx.y;
  size_t poff = (size_t)batch * HW * CI;
  const ushort_t* sh = sel ? b2h : b1h;
  const ushort_t* sl = sel ? b2l : b1l;
  ushort_t* pkb = (sel ? pk2 : pk) + (size_t)blockIdx.y * pkstride_z;
  *(int4*)(pkb + dst)           = *(const int4*)(sh + poff + src);
  *(int4*)(pkb + PKPLANE + dst) = *(const int4*)(sl + poff + src);
}

// -------- score GEMM (z<B_) + fused colsum blocks (z>=B_, FULL tier) -------------
// z<B_: unchanged 128x64 split-bf16 MFMA tile from PK1/PK2.
// z>=B_: 196 light blocks run the byte-identical colsum body (red overlays sAh),
//        co-scheduled with score -> colsum time hides under score, one less launch.
__global__ __launch_bounds__(256) void k_score(
    const ushort_t* __restrict__ pk, const ushort_t* __restrict__ pk2,
    float* __restrict__ scb, unsigned scstride_z, unsigned pkstride_z,
    const ushort_t* __restrict__ b3, float* __restrict__ s3)
{
  __shared__ ushort_t sAh[128 * SLST], sAl[128 * SLST];
  __shared__ ushort_t sBh[64 * SLST],  sBl[64 * SLST];
  int tid = threadIdx.x;

  if (blockIdx.z >= B_) {
    // ---- fused colsum path ----
    int unit = (blockIdx.z - B_) * 128 + blockIdx.y * 16 + blockIdx.x;
    if (unit >= B_ * 49) return;
    int b = unit / 49, pos = unit - b * 49;
    float* red = (float*)sAh;                    // [16][17] overlay
    int ki = pos / 7, kj = pos % 7;
    int c = tid & 15, chunk = tid >> 4;
    const ushort_t* B3 = b3 + (size_t)b * HW * CI;
    float s = 0.f;
    for (int l = chunk; l < L_; l += 16) {
      int lh = l / OH_, lw = l % OH_;
      s += bflo((unsigned)B3[((lh * ST + ki) * W_ + lw * ST + kj) * CI + c]);
    }
    red[chunk * 17 + c] = s;
    __syncthreads();
    if (tid < 16) {
      float t = 0.f;
#pragma unroll
      for (int k = 0; k < 16; ++k) t += red[k * 17 + tid];
      s3[(b * 49 + pos) * 16 + tid] = t;
    }
    return;
  }

  float* Sc = scb + (size_t)blockIdx.z * scstride_z;

  int m0 = blockIdx.y * 128, n0 = blockIdx.x * 64;
  int lane = tid & 63;
  int wv = tid >> 6;
  int grp = lane >> 3, ch = lane & 7;

  const ushort_t* pka = ((wv < 2) ? pk : pk2)
      + (size_t)blockIdx.z * pkstride_z + (size_t)(wv & 1) * PKPLANE;
  int base_mn = (wv < 2) ? m0 : n0;

  ushort_t* dplane = (wv == 0) ? sAh : (wv == 1) ? sAl : (wv == 2) ? sBh : sBl;

  int fr = lane & 31;
  int kh = (lane >> 5) << 3;
  int mt = (wv >> 1) << 1;                         // first m-subtile: 0 or 2
  int aoff0 = (mt * 32 + fr) * SLST + kh;
  int aoff1 = ((mt + 1) * 32 + fr) * SLST + kh;
  int boff  = (((wv & 1) << 5) + fr) * SLST + kh;

  f32x16 acc0 = {0.f,0.f,0.f,0.f,0.f,0.f,0.f,0.f,0.f,0.f,0.f,0.f,0.f,0.f,0.f,0.f};
  f32x16 acc1 = {0.f,0.f,0.f,0.f,0.f,0.f,0.f,0.f,0.f,0.f,0.f,0.f,0.f,0.f,0.f,0.f};

  int4 pv0, pv1, pv2, pv3, pv4, pv5, pv6, pv7;
  int4 pv8, pv9, pv10, pv11, pv12, pv13, pv14, pv15;

#define LA(j) pv##j = *(const int4*)(pks + (size_t)min(base_mn + 8*(j) + grp, 960) * 112)
#define LA_A LA(0); LA(1); LA(2); LA(3); LA(4); LA(5); LA(6); LA(7); \
             LA(8); LA(9); LA(10); LA(11); LA(12); LA(13); LA(14); LA(15)
#define LA_B LA(0); LA(1); LA(2); LA(3); LA(4); LA(5); LA(6); LA(7)
#define WA(j) *(int4*)(d0 + (j) * 8 * SLST) = pv##j
#define WA_A WA(0); WA(1); WA(2); WA(3); WA(4); WA(5); WA(6); WA(7); \
             WA(8); WA(9); WA(10); WA(11); WA(12); WA(13); WA(14); WA(15)
#define WA_B WA(0); WA(1); WA(2); WA(3); WA(4); WA(5); WA(6); WA(7)

  // initial prefetch: rn=0 (nki=0, even)
  {
    const ushort_t* pks = pka + ch * 8;
    if (wv < 2) { LA_A; } else { LA_B; }
  }

  for (int r = 0; r < 14; ++r) {
    int half = r & 1;
    __syncthreads();
    {
      ushort_t* d0 = dplane + grp * SLST + ch * 8;
      if (!half || ch < 6) { if (wv < 2) { WA_A; } else { WA_B; } }
    }
    __syncthreads();
    if (r < 13) {
      int rn = r + 1;
      int nki = rn >> 1, odd = rn & 1;
      const ushort_t* pks = pka + (size_t)nki * (961 * 112) + odd * 64 + ch * 8;
      if (!odd || ch < 6) { if (wv < 2) { LA_A; } else { LA_B; } }
    }
    if (!half) {
#pragma unroll
      for (int t = 0; t < 4; ++t) {
        bfv8 ah0 = *(const bfv8*)(sAh + aoff0 + t * 16);
        bfv8 al0 = *(const bfv8*)(sAl + aoff0 + t * 16);
        bfv8 ah1 = *(const bfv8*)(sAh + aoff1 + t * 16);
        bfv8 al1 = *(const bfv8*)(sAl + aoff1 + t * 16);
        bfv8 bh  = *(const bfv8*)(sBh + boff + t * 16);
        bfv8 bl  = *(const bfv8*)(sBl + boff + t * 16);
        acc0 = __builtin_amdgcn_mfma_f32_32x32x16_bf16(al0, bh, acc0, 0, 0, 0);
        acc0 = __builtin_amdgcn_mfma_f32_32x32x16_bf16(ah0, bl, acc0, 0, 0, 0);
        acc0 = __builtin_amdgcn_mfma_f32_32x32x16_bf16(ah0, bh, acc0, 0, 0, 0);
        acc1 = __builtin_amdgcn_mfma_f32_32x32x16_bf16(al1, bh, acc1, 0, 0, 0);
        acc1 = __builtin_amdgcn_mfma_f32_32x32x16_bf16(ah1, bl, acc1, 0, 0, 0);
        acc1 = __builtin_amdgcn_mfma_f32_32x32x16_bf16(ah1, bh, acc1, 0, 0, 0);
      }
    } else {
#pragma unroll
      for (int t = 0; t < 3; ++t) {
        bfv8 ah0 = *(const bfv8*)(sAh + aoff0 + t * 16);
        bfv8 al0 = *(const bfv8*)(sAl + aoff0 + t * 16);
        bfv8 ah1 = *(const bfv8*)(sAh + aoff1 + t * 16);
        bfv8 al1 = *(const bfv8*)(sAl + aoff1 + t * 16);
        bfv8 bh  = *(const bfv8*)(sBh + boff + t * 16);
        bfv8 bl  = *(const bfv8*)(sBl + boff + t * 16);
        acc0 = __builtin_amdgcn_mfma_f32_32x32x16_bf16(al0, bh, acc0, 0, 0, 0);
        acc0 = __builtin_amdgcn_mfma_f32_32x32x16_bf16(ah0, bl, acc0, 0, 0, 0);
        acc0 = __builtin_amdgcn_mfma_f32_32x32x16_bf16(ah0, bh, acc0, 0, 0, 0);
        acc1 = __builtin_amdgcn_mfma_f32_32x32x16_bf16(al1, bh, acc1, 0, 0, 0);
        acc1 = __builtin_amdgcn_mfma_f32_32x32x16_bf16(ah1, bl, acc1, 0, 0, 0);
        acc1 = __builtin_amdgcn_mfma_f32_32x32x16_bf16(ah1, bh, acc1, 0, 0, 0);
      }
    }
  }
#undef LA
#undef LA_A
#undef LA_B
#undef WA
#undef WA_A
#undef WA_B

  int nw = n0 + ((wv & 1) << 5) + fr;
  if (nw < L_) {
    int mw0 = m0 + mt * 32;
#pragma unroll
    for (int r = 0; r < 16; ++r) {
      int m = mw0 + (r & 3) + ((r >> 2) << 3) + ((lane >> 5) << 2);
      if (m < L_) Sc[(size_t)m * SROW + nw] = acc0[r];
    }
    int mw1 = m0 + (mt + 1) * 32;
#pragma unroll
    for (int r = 0; r < 16; ++r) {
      int m = mw1 + (r & 3) + ((r >> 2) << 3) + ((lane >> 5) << 2);
      if (m < L_) Sc[(size_t)m * SROW + nw] = acc1[r];
    }
  }
}

// -------- fused top-100 softmax + PV: 4 rows/block, dual-row interleaved PV ------
__global__ __launch_bounds__(256) void k_tkpv(
    const float* __restrict__ scb,
    const ushort_t* __restrict__ b3, const float* __restrict__ s3,
    float* __restrict__ agb, int b0, unsigned scstride_z, unsigned agstride_z)
{
  __shared__ float swv[4][TOPM];
  __shared__ int spx[4][TOPM];
  __shared__ float sw0[4], sinvZ[4];
  int tid = threadIdx.x;
  int wvi = tid >> 6, lane = tid & 63;
  int l0 = blockIdx.x * 4;
  int l = l0 + wvi;
  if (l > L_ - 1) l = L_ - 1;        // clamp: duplicate rows produce identical data
  int bz = blockIdx.y;

  // ---- radix top-100 phase (per wave, one row) ----
  {
    const float4* row4 = (const float4*)(scb + (size_t)bz * scstride_z + (size_t)l * SROW);
    unsigned k[16];
#pragma unroll
    for (int q = 0; q < 4; ++q) {
      float4 v = row4[q * 64 + lane];
      int ib = (q * 64 + lane) * 4;
      k[q * 4 + 0] = (ib + 0 < L_) ? fmap(v.x) : 0u;
      k[q * 4 + 1] = (ib + 1 < L_) ? fmap(v.y) : 0u;
      k[q * 4 + 2] = (ib + 2 < L_) ? fmap(v.z) : 0u;
      k[q * 4 + 3] = (ib + 3 < L_) ? fmap(v.w) : 0u;
    }

    unsigned mk = 0;
#pragma unroll
    for (int r = 0; r < 16; ++r) mk = max(mk, k[r]);
#pragma unroll
    for (int o = 32; o; o >>= 1) mk = max(mk, (unsigned)__shfl_down((int)mk, o));
    mk = (unsigned)__shfl((int)mk, 0);
    float vmax = unfmap(mk);

    unsigned kk[16];
#pragma unroll
    for (int r = 0; r < 16; ++r) kk[r] = k[r];

    unsigned prefix = 0; int base = 0;
    for (int bit = 30; bit >= 0; bit -= 2) {
      int n3 = 0, n2 = 0, n1 = 0;
#pragma unroll
      for (int r = 0; r < 16; ++r) {
        unsigned f = (kk[r] >> bit) & 3u;
        n3 += (int)__popcll(__ballot(f == 3u));
        n2 += (int)__popcll(__ballot(f >= 2u));
        n1 += (int)__popcll(__ballot(f >= 1u));
      }
      unsigned ch;
      if (base + n3 >= TOPM) ch = 3;
      else if (base + n2 >= TOPM) { ch = 2; base += n3; }
      else if (base + n1 >= TOPM) { ch = 1; base += n2; }
      else { ch = 0; base += n1; }
      prefix |= ch << bit;
#pragma unroll
      for (int r = 0; r < 16; ++r) {
        unsigned f = (kk[r] >> bit) & 3u;
        kk[r] = (f == ch) ? kk[r] : 0u;
      }
    }
    int nA = base;
    int needT = TOPM - nA;

    int cA = 0, cT = 0;
#pragma unroll
    for (int r = 0; r < 16; ++r) { cA += (k[r] > prefix); cT += (k[r] == prefix); }
    int pkc = cA | (cT << 16);
    int incl = pkc;
#pragma unroll
    for (int o = 1; o < 64; o <<= 1) { int t = __shfl_up(incl, o); if (lane >= o) incl += t; }
    int excl = incl - pkc;
    int tA = excl & 0xFFFF, tT = excl >> 16;

    float M = fmaxf(10.f * vmax, 0.f);
    float e0 = __expf(-M);
    float z = 0.f;
#pragma unroll
    for (int r = 0; r < 16; ++r) {
      unsigned kr = k[r];
      int slot = -1;
      if (kr > prefix) slot = tA++;
      else if (kr == prefix) { if (tT < needT) slot = nA + tT; tT++; }
      if (slot >= 0) {
        float v = unfmap(kr);
        float wv = __expf(10.f * v - M);
        swv[wvi][slot] = wv; z += wv;
        int gi = 256 * (r >> 2) + 4 * lane + (r & 3);
        int lh = gi / OH_, lw = gi - lh * OH_;
        spx[wvi][slot] = ((lh * ST) * W_ + lw * ST) * CI;
      }
    }
#pragma unroll
    for (int o = 32; o; o >>= 1) z += __shfl_down(z, o);
    z = __shfl(z, 0);
    float Z = z + (float)(L_ - TOPM) * e0;
    if (lane == 0) { sinvZ[wvi] = 1.f / Z; sw0[wvi] = e0 / Z; }
  }
  __syncthreads();
  for (int i = tid; i < 4 * TOPM; i += 256) {
    int rr = i / TOPM, s = i - rr * TOPM;
    swv[rr][s] = swv[rr][s] * sinvZ[rr] - sw0[rr];
  }
  __syncthreads();

  // ---- PV phase: dual-row interleaved (rrA = sub, rrB = 2+sub) ----
  if (tid >= 196) return;
  int batch = b0 + bz;
  const ushort_t* B3 = b3 + (size_t)batch * HW * CI;
  const float* S3 = s3 + (size_t)batch * D_;
  float* agg = agb + (size_t)bz * agstride_z;

  int sub = tid / 98;
  int t98 = tid - sub * 98;
  int pos = t98 >> 1;
  int c0 = (t98 & 1) << 3;                 // 0 or 8
  int ki = pos / 7, kj = pos - (pos / 7) * 7;
  int poff = (ki * W_ + kj) * CI + c0;
  const float4 s40 = *(const float4*)(S3 + t98 * 8);
  const float4 s41 = *(const float4*)(S3 + t98 * 8 + 4);

  int rrA = sub, rrB = 2 + sub;
  int lrA = l0 + rrA; if (lrA > L_ - 1) lrA = L_ - 1;
  int lrB = l0 + rrB; if (lrB > L_ - 1) lrB = L_ - 1;
  float w0A = sw0[rrA], w0B = sw0[rrB];

  float a0A = 0.f, a1A = 0.f, a2A = 0.f, a3A = 0.f;
  float a4A = 0.f, a5A = 0.f, a6A = 0.f, a7A = 0.f;
  float a0B = 0.f, a1B = 0.f, a2B = 0.f, a3B = 0.f;
  float a4B = 0.f, a5B = 0.f, a6B = 0.f, a7B = 0.f;

  for (int j0 = 0; j0 < TOPM; j0 += 4) {
    float wA0 = swv[rrA][j0 + 0], wA1 = swv[rrA][j0 + 1];
    float wA2 = swv[rrA][j0 + 2], wA3 = swv[rrA][j0 + 3];
    float wB0 = swv[rrB][j0 + 0], wB1 = swv[rrB][j0 + 1];
    float wB2 = swv[rrB][j0 + 2], wB3 = swv[rrB][j0 + 3];
    int pA0 = spx[rrA][j0 + 0], pA1 = spx[rrA][j0 + 1];
    int pA2 = spx[rrA][j0 + 2], pA3 = spx[rrA][j0 + 3];
    int pB0 = spx[rrB][j0 + 0], pB1 = spx[rrB][j0 + 1];
    int pB2 = spx[rrB][j0 + 2], pB3 = spx[rrB][j0 + 3];
    const uint4 qA0 = *(const uint4*)(B3 + pA0 + poff);
    const uint4 qA1 = *(const uint4*)(B3 + pA1 + poff);
    const uint4 qA2 = *(const uint4*)(B3 + pA2 + poff);
    const uint4 qA3 = *(const uint4*)(B3 + pA3 + poff);
    const uint4 qB0 = *(const uint4*)(B3 + pB0 + poff);
    const uint4 qB1 = *(const uint4*)(B3 + pB1 + poff);
    const uint4 qB2 = *(const uint4*)(B3 + pB2 + poff);
    const uint4 qB3 = *(const uint4*)(B3 + pB3 + poff);
    a0A += wA0 * bflo(qA0.x); a1A += wA0 * bfhi(qA0.x); a2A += wA0 * bflo(qA0.y); a3A += wA0 * bfhi(qA0.y);
    a4A += wA0 * bflo(qA0.z); a5A += wA0 * bfhi(qA0.z); a6A += wA0 * bflo(qA0.w); a7A += wA0 * bfhi(qA0.w);
    a0A += wA1 * bflo(qA1.x); a1A += wA1 * bfhi(qA1.x); a2A += wA1 * bflo(qA1.y); a3A += wA1 * bfhi(qA1.y);
    a4A += wA1 * bflo(qA1.z); a5A += wA1 * bfhi(qA1.z); a6A += wA1 * bflo(qA1.w); a7A += wA1 * bfhi(qA1.w);
    a0A += wA2 * bflo(qA2.x); a1A += wA2 * bfhi(qA2.x); a2A += wA2 * bflo(qA2.y); a3A += wA2 * bfhi(qA2.y);
    a4A += wA2 * bflo(qA2.z); a5A += wA2 * bfhi(qA2.z); a6A += wA2 * bflo(qA2.w); a7A += wA2 * bfhi(qA2.w);
    a0A += wA3 * bflo(qA3.x); a1A += wA3 * bfhi(qA3.x); a2A += wA3 * bflo(qA3.y); a3A += wA3 * bfhi(qA3.y);
    a4A += wA3 * bflo(qA3.z); a5A += wA3 * bfhi(qA3.z); a6A += wA3 * bflo(qA3.w); a7A += wA3 * bfhi(qA3.w);
    a0B += wB0 * bflo(qB0.x); a1B += wB0 * bfhi(qB0.x); a2B += wB0 * bflo(qB0.y); a3B += wB0 * bfhi(qB0.y);
    a4B += wB0 * bflo(qB0.z); a5B += wB0 * bfhi(qB0.z); a6B += wB0 * bflo(qB0.w); a7B += wB0 * bfhi(qB0.w);
    a0B += wB1 * bflo(qB1.x); a1B += wB1 * bfhi(qB1.x); a2B += wB1 * bflo(qB1.y); a3B += wB1 * bfhi(qB1.y);
    a4B += wB1 * bflo(qB1.z); a5B += wB1 * bfhi(qB1.z); a6B += wB1 * bflo(qB1.w); a7B += wB1 * bfhi(qB1.w);
    a0B += wB2 * bflo(qB2.x); a1B += wB2 * bfhi(qB2.x); a2B += wB2 * bflo(qB2.y); a3B += wB2 * bfhi(qB2.y);
    a4B += wB2 * bflo(qB2.z); a5B += wB2 * bfhi(qB2.z); a6B += wB2 * bflo(qB2.w); a7B += wB2 * bfhi(qB2.w);
    a0B += wB3 * bflo(qB3.x); a1B += wB3 * bfhi(qB3.x); a2B += wB3 * bflo(qB3.y); a3B += wB3 * bfhi(qB3.y);
    a4B += wB3 * bflo(qB3.z); a5B += wB3 * bfhi(qB3.z); a6B += wB3 * bflo(qB3.w); a7B += wB3 * bfhi(qB3.w);
  }
  a0A += w0A * s40.x; a1A += w0A * s40.y; a2A += w0A * s40.z; a3A += w0A * s40.w;
  a4A += w0A * s41.x; a5A += w0A * s41.y; a6A += w0A * s41.z; a7A += w0A * s41.w;
  a0B += w0B * s40.x; a1B += w0B * s40.y; a2B += w0B * s40.z; a3B += w0B * s40.w;
  a4B += w0B * s41.x; a5B += w0B * s41.y; a6B += w0B * s41.z; a7B += w0B * s41.w;
  float* dstA = agg + (size_t)lrA * D_ + t98 * 8;
  *(float4*)(dstA)     = make_float4(a0A, a1A, a2A, a3A);
  *(float4*)(dstA + 4) = make_float4(a4A, a5A, a6A, a7A);
  float* dstB = agg + (size_t)lrB * D_ + t98 * 8;
  *(float4*)(dstB)     = make_float4(a0B, a1B, a2B, a3B);
  *(float4*)(dstB + 4) = make_float4(a4B, a5B, a6B, a7B);
}

// -------- fold + mask divide + restore (16->64), batched -------------------------
__global__ __launch_bounds__(256) void k_fold(
    const int* __restrict__ flag, const float* __restrict__ ws,
    const float* __restrict__ agb, void* __restrict__ out,
    int b0, unsigned agstride_z)
{
  __shared__ float srw[CIN * CI];
  int tid = threadIdx.x;
  for (int i = tid; i < CIN * CI; i += 256) srw[i] = ws[RW_O + i];
  __syncthreads();

  int bz = blockIdx.y;
  int batch = b0 + bz;
  const float* agg = agb + (size_t)bz * agstride_z;

  int gid = blockIdx.x * 256 + tid;
  if (gid >= HW) return;
  int h = gid / W_;
  int w = gid % W_;

  int lh0 = (h >= KS - 1) ? ((h - (KS - 1) + (ST - 1)) >> 2) : 0;
  int lh1 = min(OH_ - 1, h >> 2);
  int lw0 = (w >= KS - 1) ? ((w - (KS - 1) + (ST - 1)) >> 2) : 0;
  int lw1 = min(OH_ - 1, w >> 2);

  float t[CI];
#pragma unroll
  for (int c = 0; c < CI; ++c) t[c] = 0.f;
  for (int lh = lh0; lh <= lh1; ++lh) {
    int ki = h - ST * lh;
    for (int lw = lw0; lw <= lw1; ++lw) {
      int kj = w - ST * lw;
      const float* pb = agg + (size_t)(lh * OH_ + lw) * D_ + (ki * KS + kj) * CI;
      float4 q0 = *(const float4*)(pb);
      float4 q1 = *(const float4*)(pb + 4);
      float4 q2 = *(const float4*)(pb + 8);
      float4 q3 = *(const float4*)(pb + 12);
      t[0] += q0.x; t[1] += q0.y; t[2] += q0.z; t[3] += q0.w;
      t[4] += q1.x; t[5] += q1.y; t[6] += q1.z; t[7] += q1.w;
      t[8] += q2.x; t[9] += q2.y; t[10] += q2.z; t[11] += q2.w;
      t[12] += q3.x; t[13] += q3.y; t[14] += q3.z; t[15] += q3.w;
    }
  }
  float cnt = (float)((lh1 - lh0 + 1) * (lw1 - lw0 + 1));
  float r[CI];
#pragma unroll
  for (int c = 0; c < CI; ++c) r[c] = t[c] / (cnt * ws[SM_O + c] + ws[SB_O + c] + 1e-8f);

  size_t ob = (size_t)batch * CIN * HW + (size_t)h * W_ + w;
  if (*flag) {
    float* of = (float*)out;
#pragma unroll
    for (int o = 0; o < CIN; ++o) {
      float s = ws[RB_O + o];
#pragma unroll
      for (int c = 0; c < CI; ++c) s += srw[o * CI + c] * r[c];
      of[ob + (size_t)o * HW] = s;
    }
  } else {
    bf16* of = (bf16*)out;
#pragma unroll
    for (int o = 0; o < CIN; ++o) {
      float s = ws[RB_O + o];
#pragma unroll
      for (int c = 0; c < CI; ++c) s += srw[o * CI + c] * r[c];
      of[ob + (size_t)o * HW] = __float2bfloat16(s);
    }
  }
}

extern "C" void kernel_launch(void* const* d_in, const int* in_sizes, int n_in,
                              void* d_out, int out_size, void* d_ws, size_t ws_size,
                              hipStream_t stream)
{
  const void* x    = d_in[0];
  const void* g_w  = d_in[1];
  const void* g_b  = d_in[2];
  const void* th_w = d_in[3];
  const void* th_b = d_in[4];
  const void* ph_w = d_in[5];
  const void* ph_b = d_in[6];
  const void* m_w  = d_in[7];
  const void* m_b  = d_in[8];
  const void* r_w  = d_in[9];
  const void* r_b  = d_in[10];

  float* W = (float*)d_ws;
  int* flag = (int*)d_ws;
  ushort_t* planes = (ushort_t*)(W + B1_O);
  ushort_t* b1h = planes;
  ushort_t* b1l = planes + (size_t)N1;
  ushort_t* b2h = planes + (size_t)2 * N1;
  ushort_t* b2l = planes + (size_t)3 * N1;
  ushort_t* b3  = planes + (size_t)4 * N1;   // bf16 plane, N1 ushorts
  float* s3 = W + S3_O;

  if (ws_size >= FULL_BYTES) {
    ushort_t* xhh = (ushort_t*)(W + REG_O);    // padded planes, dead after conv
    ushort_t* xhl = xhh + XPU;
    float* sc = W + REG_O;                     // 4 x SCSLOT, aliases dead planes
    ushort_t* pk  = (ushort_t*)(W + PK_O);
    ushort_t* pk2 = (ushort_t*)(W + PK2_O);
    float* ag = W + PK_O;                      // aliases PK1 (dead after k_score)
    k_prep<<<dim3((B_ * HW + 63) / 64), 256, 0, stream>>>(
        x, g_w, th_w, ph_w, g_b, th_b, ph_b, m_w, m_b, r_w, r_b, W, xhh, xhl);
    k_conv3<<<dim3(H_, 1, B_), 256, 0, stream>>>(
        W, xhh, xhl, b1h, b1l, b2h, b2l, b3, pk, pk2);
    k_score<<<dim3(16, 8, B_ + 2), 256, 0, stream>>>(
        pk, pk2, sc, SCSLOT, PKSTR, b3, s3);   // z>=B_: fused colsum blocks
    k_tkpv<<<dim3((L_ + 3) / 4, B_), 256, 0, stream>>>(sc, b3, s3, ag, 0, SCSLOT, AGSZ);
    k_fold<<<dim3(64, B_), 256, 0, stream>>>(flag, W, ag, d_out, 0, AGSZ);
  } else if (ws_size >= MID_BYTES) {
    ushort_t* xhh = (ushort_t*)(W + REG_O);
    ushort_t* xhl = xhh + XPU;
    float* sc = W + REG_O;
    float* ag = W + REG_O + SCSLOT;
    ushort_t* pk  = (ushort_t*)ag;             // PK1 shares the ag slot
    ushort_t* pk2 = pk + (size_t)PKSTR;        // PK2 right after (within planes region)
    k_prep<<<dim3((B_ * HW + 63) / 64), 256, 0, stream>>>(
        x, g_w, th_w, ph_w, g_b, th_b, ph_b, m_w, m_b, r_w, r_b, W, xhh, xhl);
    k_conv3<<<dim3(H_, 1, B_), 256, 0, stream>>>(
        W, xhh, xhl, b1h, b1l, b2h, b2l, b3, (ushort_t*)nullptr, (ushort_t*)nullptr);
    k_colsum<<<dim3(B_, 49), 256, 0, stream>>>(b3, s3);
    for (int b = 0; b < B_; ++b) {
      k_pack<<<dim3(736, 1), 256, 0, stream>>>(b1h, b1l, b2h, b2l, pk, pk2, b, 0);
      k_score<<<dim3(16, 8, 1), 256, 0, stream>>>(pk, pk2, sc, 0, 0, b3, s3);
      k_tkpv<<<dim3((L_ + 3) / 4, 1), 256, 0, stream>>>(sc, b3, s3, ag, b, 0, 0);
      k_fold<<<dim3(64, 1), 256, 0, stream>>>(flag, W, ag, d_out, b, 0);
    }
  } else {
    float* sc = W + REG_O;
    float* ag = W + REG_O + SCSLOT;
    ushort_t* pk  = (ushort_t*)ag;
    ushort_t* pk2 = pk + (size_t)PKSTR;
    k_prep<<<64, 256, 0, stream>>>(
        x, g_w, th_w, ph_w, g_b, th_b, ph_b, m_w, m_b, r_w, r_b, W,
        (ushort_t*)nullptr, (ushort_t*)nullptr);
    k_convF<<<dim3(4, 16, B_), dim3(32, 8, 1), 0, stream>>>(
        flag, x, g_w, g_b, th_w, th_b, ph_w, ph_b, b1h, b1l, b2h, b2l, b3);
    k_colsum<<<dim3(B_, 49), 256, 0, stream>>>(b3, s3);
    for (int b = 0; b < B_; ++b) {
      k_pack<<<dim3(736, 1), 256, 0, stream>>>(b1h, b1l, b2h, b2l, pk, pk2, b, 0);
      k_score<<<dim3(16, 8, 1), 256, 0, stream>>>(pk, pk2, sc, 0, 0, b3, s3);
      k_tkpv<<<dim3((L_ + 3) / 4, 1), 256, 0, stream>>>(sc, b3, s3, ag, b, 0, 0);
      k_fold<<<dim3(64, 1), 256, 0, stream>>>(flag, W, ag, d_out, b, 0);
    }
  }
}